// Round 16
// baseline (542.369 us; speedup 1.0000x reference)
//
#include <hip/hip_runtime.h>
#include <cstdint>
#include <cstddef>

// GatedDeltaNet forward, MI355X/gfx950.
// R16 = R15 with k_prep P4's output path fixed: per-tc result tile staged in
// LDS (Stg[128][24], 48B rows: aligned + 2-way-free banks) then stored as one
// 16B coalesced global store per thread per tc (was 128 scalar 2B scattered
// stores per thread - the dominant ~50us of k_prep's 136us).

typedef unsigned short ushort_t;
typedef __attribute__((ext_vector_type(8))) __bf16 bf16x8;
typedef __attribute__((ext_vector_type(4))) float f32x4;
typedef __attribute__((ext_vector_type(4))) short short4v;

#define B_   2
#define T_   2048
#define HID_ 2048
#define NK_  8
#define NV_  16
#define HD_  128
#define KD_  1024
#define VD_  2048
#define CD_  4096
#define CHM_ 16384   // 128*128 elems per per-chunk matrix (MT/NT/Sc)

__device__ __forceinline__ float b2f(ushort_t u) {
  union { unsigned int i; float f; } v; v.i = ((unsigned int)u) << 16; return v.f;
}
__device__ __forceinline__ ushort_t f2b(float f) {   // RNE bf16 round
  unsigned int x = __builtin_bit_cast(unsigned int, f);
  unsigned int r = x + 0x7fffu + ((x >> 16) & 1u);
  return (ushort_t)(r >> 16);
}

// ---------------------------------------------------------------------------
// fp32 -> bf16 cast
// ---------------------------------------------------------------------------
__global__ __launch_bounds__(256)
void k_cast_bf16(const float* __restrict__ in, ushort_t* __restrict__ out, int n4) {
  const int i = blockIdx.x * 256 + threadIdx.x;
  if (i >= n4) return;
  float4 v = *(const float4*)(in + (size_t)i * 4);
  short4v o;
  o[0] = (short)f2b(v.x); o[1] = (short)f2b(v.y);
  o[2] = (short)f2b(v.z); o[3] = (short)f2b(v.w);
  *(short4v*)(out + (size_t)i * 4) = o;
}

// ---------------------------------------------------------------------------
// GEMM 256x256 body, BK=64, 8 waves, counted-vmcnt pipeline (R8-verified).
// ---------------------------------------------------------------------------
#define LPOS(BUF, OP, HALF) ((((BUF) * 2 + (OP)) * 2 + (HALF)) * 8192)

template <typename OutT>
__device__ __forceinline__ void gemm256_body(
    const ushort_t* __restrict__ A, const ushort_t* __restrict__ Bw,
    OutT* __restrict__ C, int M, int N, int K, int tile, ushort_t* lds) {
  const int tid = threadIdx.x;
  const int lane = tid & 63, wave = tid >> 6;
  const int wm = wave >> 2, wc = wave & 3;
  const int l15 = lane & 15;
  const int ks16 = (lane >> 4) * 16;
  const int r4 = (lane >> 4) * 4;
  const int nkt = K >> 6;
  const int nbx = N >> 8;
  const size_t row0 = (size_t)(tile / nbx) * 256;
  const size_t col0 = (size_t)(tile % nbx) * 256;

#define STAGE4(BUF, HALF, KT) {                                               \
    const int kt_ = ((KT) < nkt) ? (KT) : (nkt - 1);                          \
    const int kb_ = kt_ * 64 + (HALF) * 32;                                   \
    _Pragma("unroll") for (int r_ = 0; r_ < 2; ++r_) {                        \
      const int wb_ = r_ * 8192 + wave * 1024;                                \
      const int o_  = wb_ + lane * 16;                                        \
      const int row_ = o_ >> 6;                                               \
      const int src_ = (o_ & 63) ^ (((row_) & 3) << 4);                       \
      const ushort_t* ga_ = A  + (row0 + row_) * (size_t)K + kb_ + (src_ >> 1); \
      const ushort_t* gb_ = Bw + (col0 + row_) * (size_t)K + kb_ + (src_ >> 1); \
      __builtin_amdgcn_global_load_lds(                                       \
          (const __attribute__((address_space(1))) unsigned int*)ga_,         \
          (__attribute__((address_space(3))) unsigned int*)                   \
              (lds + LPOS(BUF, 0, HALF) + (wb_ >> 1)), 16, 0, 0);             \
      __builtin_amdgcn_global_load_lds(                                       \
          (const __attribute__((address_space(1))) unsigned int*)gb_,         \
          (__attribute__((address_space(3))) unsigned int*)                   \
              (lds + LPOS(BUF, 1, HALF) + (wb_ >> 1)), 16, 0, 0);             \
    }                                                                         \
  }

#define RD(BUF, OP, HALF, ROW)                                                \
  (*(const bf16x8*)((const char*)(lds + LPOS(BUF, OP, HALF)) +                \
                    ((((ROW) * 64 + ks16)) ^ (((ROW) & 3) << 4))))

  f32x4 acc[8][4] = {};
  STAGE4(0, 0, 0)
  STAGE4(0, 1, 0)
  STAGE4(1, 0, 1)

  for (int kt = 0; kt < nkt; ++kt) {
    const int cb = kt & 1, nb = cb ^ 1;
    asm volatile("s_waitcnt vmcnt(8)" ::: "memory");
    __builtin_amdgcn_s_barrier();
    {
      bf16x8 af[8], bfr[4];
#pragma unroll
      for (int mf = 0; mf < 8; ++mf) af[mf] = RD(cb, 0, 0, wm * 128 + mf * 16 + l15);
#pragma unroll
      for (int nf = 0; nf < 4; ++nf) bfr[nf] = RD(cb, 1, 0, wc * 64 + nf * 16 + l15);
      STAGE4(nb, 1, kt + 1)
      __builtin_amdgcn_s_setprio(1);
#pragma unroll
      for (int mf = 0; mf < 8; ++mf)
#pragma unroll
        for (int nf = 0; nf < 4; ++nf)
          acc[mf][nf] = __builtin_amdgcn_mfma_f32_16x16x32_bf16(af[mf], bfr[nf], acc[mf][nf], 0, 0, 0);
      __builtin_amdgcn_s_setprio(0);
    }
    asm volatile("s_waitcnt vmcnt(8)" ::: "memory");
    __builtin_amdgcn_s_barrier();
    {
      bf16x8 af[8], bfr[4];
#pragma unroll
      for (int mf = 0; mf < 8; ++mf) af[mf] = RD(cb, 0, 1, wm * 128 + mf * 16 + l15);
#pragma unroll
      for (int nf = 0; nf < 4; ++nf) bfr[nf] = RD(cb, 1, 1, wc * 64 + nf * 16 + l15);
      STAGE4(cb, 0, kt + 2)
      __builtin_amdgcn_s_setprio(1);
#pragma unroll
      for (int mf = 0; mf < 8; ++mf)
#pragma unroll
        for (int nf = 0; nf < 4; ++nf)
          acc[mf][nf] = __builtin_amdgcn_mfma_f32_16x16x32_bf16(af[mf], bfr[nf], acc[mf][nf], 0, 0, 0);
      __builtin_amdgcn_s_setprio(0);
    }
  }
#undef STAGE4
#undef RD

#pragma unroll
  for (int mf = 0; mf < 8; ++mf)
#pragma unroll
    for (int nf = 0; nf < 4; ++nf)
#pragma unroll
      for (int j = 0; j < 4; ++j) {
        const size_t row = row0 + wm * 128 + mf * 16 + r4 + j;
        const size_t col = col0 + wc * 64 + nf * 16 + l15;
        if constexpr (sizeof(OutT) == 4)
          C[row * (size_t)N + col] = acc[mf][nf][j];
        else
          C[row * (size_t)N + col] = (OutT)f2b(acc[mf][nf][j]);
      }
}

template <typename OutT>
__global__ __launch_bounds__(512, 2)
void k_gemm256(const ushort_t* __restrict__ A, const ushort_t* __restrict__ Bw,
               OutT* __restrict__ C, int M, int N, int K) {
  __shared__ alignas(16) ushort_t lds[2 * 2 * 2 * 8192];
  const int nwg = gridDim.x;
  const int q8 = nwg >> 3, r8 = nwg & 7;
  const int xcd = blockIdx.x & 7, idx8 = blockIdx.x >> 3;
  const int s = (xcd < r8) ? (xcd * (q8 + 1) + idx8)
                           : (r8 * (q8 + 1) + (xcd - r8) * q8 + idx8);
  gemm256_body<OutT>(A, Bw, C, M, N, K, s, lds);
}

// ---------------------------------------------------------------------------
// b/a projection, W-amortized (R12-verified).
// ---------------------------------------------------------------------------
__global__ __launch_bounds__(256, 2)
void k_proj_ba(const float* __restrict__ x, const float* __restrict__ Wb,
               const float* __restrict__ Wa, const float* __restrict__ dtb,
               const float* __restrict__ alog,
               float* __restrict__ beta, float* __restrict__ gout) {
  __shared__ __bf16 Wl[16][2048];   // 64 KB (accessed via swizzled byte offsets)
  __shared__ float part[16][16];
  const int tid = threadIdx.x;
  const int o = tid & 15, seg = tid >> 4;    // 16 outputs x 16 k-segs(128)
  const int bt0 = blockIdx.x * 16;

#define PROJ_PASS(WSRC, EMIT) {                                               \
    for (int i = tid; i < 8192; i += 256) {                                   \
      const int os_ = i >> 9, k4_ = i & 511;                                  \
      float4 w_ = *(const float4*)(WSRC + (size_t)os_ * HID_ + k4_ * 4);      \
      const int b_ = k4_ * 8;                                                 \
      __bf16* d_ = (__bf16*)((char*)&Wl[0][0] + os_ * 4096 +                  \
                   (((b_ & ~15) ^ ((os_ & 15) << 4)) | (b_ & 8)));            \
      d_[0] = (__bf16)w_.x; d_[1] = (__bf16)w_.y;                             \
      d_[2] = (__bf16)w_.z; d_[3] = (__bf16)w_.w;                             \
    }                                                                         \
    __syncthreads();                                                          \
    for (int rr = 0; rr < 16; ++rr) {                                         \
      const int bt = bt0 + rr;                                                \
      const float* xr = x + (size_t)bt * HID_;                                \
      float s = 0.f;                                                          \
      _Pragma("unroll") for (int j = 0; j < 16; ++j) {                        \
        const int k = seg * 128 + j * 8;                                      \
        float4 xa = *(const float4*)&xr[k];                                   \
        float4 xb = *(const float4*)&xr[k + 4];                               \
        bf16x8 wv = *(const bf16x8*)((const char*)&Wl[0][0] + o * 4096 +      \
                     ((k * 2) ^ ((o & 15) << 4)));                            \
        s += (float)wv[0]*xa.x + (float)wv[1]*xa.y + (float)wv[2]*xa.z +      \
             (float)wv[3]*xa.w + (float)wv[4]*xb.x + (float)wv[5]*xb.y +      \
             (float)wv[6]*xb.z + (float)wv[7]*xb.w;                           \
      }                                                                       \
      part[o][seg] = s;                                                       \
      __syncthreads();                                                        \
      if (tid < 16) {                                                         \
        float t_ = 0.f;                                                       \
        _Pragma("unroll") for (int i2 = 0; i2 < 16; ++i2) t_ += part[tid][i2];\
        EMIT                                                                  \
      }                                                                       \
      __syncthreads();                                                        \
    }                                                                         \
  }

  PROJ_PASS(Wb, {
    beta[(size_t)bt * NV_ + tid] = 1.f / (1.f + expf(-t_));
  })
  __syncthreads();
  PROJ_PASS(Wa, {
    float aa = t_ + dtb[tid];
    float sp = (aa > 20.f) ? aa : log1pf(expf(aa));
    gout[(size_t)bt * NV_ + tid] = -expf(alog[tid]) * sp;
  })
#undef PROJ_PASS
}

// ---------------------------------------------------------------------------
// Fused depthwise causal conv1d (K=4) + silu + l2norm(q,k). (R14-verified)
// ---------------------------------------------------------------------------
__global__ __launch_bounds__(256)
void k_conv_silu_norm(const ushort_t* __restrict__ qkv, const float* __restrict__ cw,
                      ushort_t* __restrict__ act) {
  const int bt = blockIdx.x;
  const int tid = threadIdx.x;
  const int t = bt & (T_ - 1);
  const int c = tid * 16;
  const ushort_t* rowp = qkv + (size_t)bt * CD_ + c;

  float wf[16][4];
#pragma unroll
  for (int i = 0; i < 16; ++i) {
    float4 w = *(const float4*)&cw[(c + i) * 4];
    wf[i][0] = w.x; wf[i][1] = w.y; wf[i][2] = w.z; wf[i][3] = w.w;
  }
  float a[16];
#pragma unroll
  for (int i = 0; i < 16; ++i) a[i] = 0.f;
#pragma unroll
  for (int j = 0; j < 4; ++j) {
    const int tt = t - 3 + j;
    if (tt >= 0) {
      const ushort_t* src = rowp + ((ptrdiff_t)j - 3) * CD_;
      bf16x8 v0 = *(const bf16x8*)(const void*)src;
      bf16x8 v1 = *(const bf16x8*)(const void*)(src + 8);
#pragma unroll
      for (int i = 0; i < 8; ++i) {
        a[i]     += (float)v0[i] * wf[i][j];
        a[8 + i] += (float)v1[i] * wf[8 + i][j];
      }
    }
  }
#pragma unroll
  for (int i = 0; i < 16; ++i) a[i] = a[i] / (1.f + expf(-a[i]));
  float ss = 0.f;
#pragma unroll
  for (int i = 0; i < 16; ++i) ss += a[i] * a[i];
  ss += __shfl_xor(ss, 1); ss += __shfl_xor(ss, 2); ss += __shfl_xor(ss, 4);
  const int seg = tid >> 3;            // 0..7 q, 8..15 k, 16..31 v
  float scale = 1.f;
  if (seg < 16) {
    scale = 1.f / fmaxf(sqrtf(ss), 1e-12f);
    if (seg < 8) scale *= 0.08838834764831845f;   // HD^-0.5
  }
  ushort_t ov[16];
#pragma unroll
  for (int i = 0; i < 16; ++i) ov[i] = f2b(a[i] * scale);
  ushort_t* dst = act + (size_t)bt * CD_ + c;
  *(uint4*)(void*)dst       = *(const uint4*)&ov[0];
  *(uint4*)(void*)(dst + 8) = *(const uint4*)&ov[8];
}

// ---------------------------------------------------------------------------
__device__ __forceinline__ bf16x8 cvt8f(const float* p) {
  float4 a = *(const float4*)p;
  float4 b = *(const float4*)(p + 4);
  bf16x8 o;
  o[0] = (__bf16)a.x; o[1] = (__bf16)a.y; o[2] = (__bf16)a.z; o[3] = (__bf16)a.w;
  o[4] = (__bf16)b.x; o[5] = (__bf16)b.y; o[6] = (__bf16)b.z; o[7] = (__bf16)b.w;
  return o;
}

// ---------------------------------------------------------------------------
// k_prep: per-chunk parallel precompute. grid = 1024. act is bf16.
// P2: R12 scalar solve (known-good). P4: results staged in LDS then stored as
// 16B coalesced chunks (R16) - was 128 scalar 2B global stores per thread.
// ---------------------------------------------------------------------------
__global__ __launch_bounds__(256, 1)
void k_prep(const ushort_t* __restrict__ act, const float* __restrict__ gB,
            const float* __restrict__ betaB,
            ushort_t* __restrict__ WkG, ushort_t* __restrict__ UlT,
            float* __restrict__ gtG,
            ushort_t* __restrict__ MTG, ushort_t* __restrict__ NTG) {
  __shared__ __bf16 Kl[64][136];
  __shared__ __bf16 AbL[64][40];
  __shared__ __bf16 AbH[32][33];
  __shared__ __bf16 Xl[64][264];
  __shared__ alignas(16) ushort_t Stg[128][24];   // 6144 B, P4 store staging
  __shared__ float gc[65], Et[65], Rt[65], bts[64], geT[64], escT[64];

  const int wg = blockIdx.x;
  const int c = wg & 31, h = (wg >> 5) & 15, b = wg >> 9;
  const int hq = h >> 1, t0 = c * 64;
  const int tid = threadIdx.x, lane = tid & 63, wave = tid >> 6;
  const int l15 = lane & 15, kcol0 = (lane >> 4) * 8, rrow = (lane >> 4) * 4;
  const size_t bhc = (size_t)wg;

  const ushort_t* baseQ = act + (size_t)b * T_ * CD_ + hq * HD_;
  const ushort_t* baseK = baseQ + KD_;

  if (tid < 64) {
    float g = gB[((size_t)b * T_ + t0 + tid) * NV_ + h];
    bts[tid] = betaB[((size_t)b * T_ + t0 + tid) * NV_ + h];
#pragma unroll
    for (int o = 1; o < 64; o <<= 1) {
      float up = __shfl_up(g, (unsigned)o);
      if (tid >= o) g += up;
    }
    gc[tid + 1] = g;
    if (tid == 0) gc[0] = 0.f;
  }
  __syncthreads();
  if (tid < 65) {
    float gm = gc[32];
    Et[tid] = __expf(gc[tid] - gm);
    Rt[tid] = __expf(gm - gc[tid]);
  }
  if (tid < 64) {
    geT[tid] = bts[tid] * __expf(gc[tid + 1]);
    escT[tid] = __expf(gc[64] - gc[tid + 1]);
    gtG[bhc * 64 + tid] = gc[tid + 1];
  }
  {
    const int t = tid >> 2, d0 = (tid & 3) * 32;
    const ushort_t* src = baseK + (size_t)(t0 + t) * CD_ + d0;
#pragma unroll
    for (int j = 0; j < 4; ++j)
      *(uint4*)&Kl[t][d0 + j * 8] = *(const uint4*)(const void*)(src + j * 8);
  }
  __syncthreads();

  // P1: Ab (strict lower, -beta*scale*KK^T) in LDS
  {
    bf16x8 kf[4];
#pragma unroll
    for (int kk = 0; kk < 4; ++kk)
      kf[kk] = *(const bf16x8*)&Kl[16 * wave + l15][kk * 32 + kcol0];
#pragma unroll
    for (int st = 0; st < 4; ++st) {
      if (st <= wave) {
        f32x4 accA = {};
#pragma unroll
        for (int kk = 0; kk < 4; ++kk) {
          bf16x8 bfr = *(const bf16x8*)&Kl[st * 16 + l15][kk * 32 + kcol0];
          accA = __builtin_amdgcn_mfma_f32_16x16x32_bf16(kf[kk], bfr, accA, 0, 0, 0);
        }
        const int scol = st * 16 + l15;
#pragma unroll
        for (int r = 0; r < 4; ++r) {
          const int t = 16 * wave + rrow + r;
          if (scol < t) {
            const float av = -bts[t] * Et[t + 1] * Rt[scol + 1] * accA[r];
            if (scol < 32) AbL[t][scol] = (__bf16)av;
            else           AbH[t - 32][scol - 32] = (__bf16)av;
          }
        }
      }
    }
  }
  __syncthreads();

  // P2: triangular solve (I+L)X = RHS, 256 threads = 256 columns (R12 scalar)
  {
    float r1[32], r2[32];
    if (tid < 128) {
      const int d = tid;
#pragma unroll
      for (int t = 0; t < 32; ++t) r1[t] = geT[t] * (float)Kl[t][d];
#pragma unroll
      for (int t = 0; t < 32; ++t) r2[t] = geT[32 + t] * (float)Kl[32 + t][d];
    } else {
      const int j = tid - 128;
      const ushort_t* vsrc = act + ((size_t)b * T_ + t0) * CD_ + 2 * KD_ + h * HD_ + j;
#pragma unroll
      for (int t = 0; t < 32; ++t) r1[t] = bts[t] * b2f(vsrc[(size_t)t * CD_]);
#pragma unroll
      for (int t = 0; t < 32; ++t) r2[t] = bts[32 + t] * b2f(vsrc[(size_t)(32 + t) * CD_]);
    }
    float u1[32];
#pragma unroll
    for (int j = 0; j < 32; ++j) {
      float a = r1[j];
#pragma unroll
      for (int i = 0; i < j; ++i) a += (float)AbL[j][i] * u1[i];
      u1[j] = a;
      Xl[j][tid] = (__bf16)a;
    }
#pragma unroll
    for (int t2 = 0; t2 < 32; ++t2) {
      float a = r2[t2];
#pragma unroll
      for (int i = 0; i < 32; ++i) a += (float)AbL[32 + t2][i] * u1[i];
      r2[t2] = a;
    }
    float u2[32];
#pragma unroll
    for (int j = 0; j < 32; ++j) {
      float a = r2[j];
#pragma unroll
      for (int i = 0; i < j; ++i) a += (float)AbH[j][i] * u2[i];
      u2[j] = a;
      Xl[32 + j][tid] = (__bf16)a;
    }
  }
  __syncthreads();

  // P3: Wk copy (negated, stride 128) + Uloc^T store (stride 64)
#pragma unroll
  for (int kck = 0; kck < 4; ++kck) {
    const int q = tid + kck * 256;
    const int t = q >> 4, d0 = (q & 15) * 8;
    uint4 v = *(const uint4*)&Xl[t][d0];
    v.x ^= 0x80008000u; v.y ^= 0x80008000u; v.z ^= 0x80008000u; v.w ^= 0x80008000u;
    *(uint4*)(void*)(WkG + bhc * (64 * 128) + (size_t)t * 128 + d0) = v;
  }
  {
    const int e = tid >> 1, t8 = (tid & 1) * 32;
#pragma unroll
    for (int i8 = 0; i8 < 4; ++i8) {
      bf16x8 tmp;
#pragma unroll
      for (int jj = 0; jj < 8; ++jj) tmp[jj] = Xl[t8 + i8 * 8 + jj][128 + e];
      *(bf16x8*)(void*)(UlT + bhc * (128 * 64) + (size_t)e * 64 + t8 + i8 * 8) = tmp;
    }
  }

  // P4: M^T and N^T via MFMA; results staged in Stg then 16B-stored.
  // Wave w owns dr rows [32w, 32w+32) = its own Stg region (no barrier).
  {
    const float gCe = __expf(gc[64]);
    bf16x8 afr[2][2];
#pragma unroll
    for (int dtl = 0; dtl < 2; ++dtl) {
      const int d = 16 * (2 * wave + dtl) + l15;
#pragma unroll
      for (int kt = 0; kt < 2; ++kt) {
        bf16x8 o;
#pragma unroll
        for (int j = 0; j < 8; ++j) {
          const int t = kt * 32 + kcol0 + j;
          o[j] = (__bf16)(escT[t] * (float)Kl[t][d]);
        }
        afr[dtl][kt] = o;
      }
    }
    const int srow = 32 * wave + (lane >> 1);     // this thread's store row
    const int scol8 = (lane & 1) * 8;             // 16B half of the 16-col tile
#pragma unroll
    for (int tc = 0; tc < 16; ++tc) {
      bf16x8 bfr[2];
#pragma unroll
      for (int kt = 0; kt < 2; ++kt) {
        bf16x8 o;
#pragma unroll
        for (int j = 0; j < 8; ++j) {
          const int t = kt * 32 + kcol0 + j;
          o[j] = (tc < 8) ? (__bf16)(-(float)Xl[t][16 * tc + l15])
                          : Xl[t][128 + 16 * (tc - 8) + l15];
        }
        bfr[kt] = o;
      }
#pragma unroll
      for (int dtl = 0; dtl < 2; ++dtl) {
        f32x4 acc = {};
        acc = __builtin_amdgcn_mfma_f32_16x16x32_bf16(afr[dtl][0], bfr[0], acc, 0, 0, 0);
        acc = __builtin_amdgcn_mfma_f32_16x16x32_bf16(afr[dtl][1], bfr[1], acc, 0, 0, 0);
        const int col = 16 * (tc & 7) + l15;
#pragma unroll
        for (int r = 0; r < 4; ++r) {
          const int dr = 16 * (2 * wave + dtl) + rrow + r;
          Stg[dr][l15] = (tc < 8)
              ? f2b(acc[r] + ((dr == col) ? gCe : 0.f))
              : f2b(acc[r]);
        }
      }
      // one 16B coalesced store per thread (wave-local rows, no barrier)
      uint4 v = *(const uint4*)&Stg[srow][scol8];
      ushort_t* dst = (tc < 8) ? MTG : NTG;
      dst[0] = 0;  // (dead store elided below; keep pointer form explicit)
      *(uint4*)(void*)(((tc < 8) ? MTG : NTG) + bhc * CHM_ +
                       (size_t)srow * 128 + 16 * (tc & 7) + scol8) = v;
    }
  }
}

// ---------------------------------------------------------------------------
// scan body: S' = S*M + N, M/N double-buffered in LDS via global_load_lds
// (pre-swizzled source, swizzled ds_read). (R12-verified)
// ---------------------------------------------------------------------------
__device__ __forceinline__ void scan_body(
    const ushort_t* __restrict__ MTG, const ushort_t* __restrict__ NTG,
    ushort_t* __restrict__ ScG, int sb, char* smem) {
  const int eh = sb & 1, wg = sb >> 1;
  const int e0 = eh * 64;
  const int tid = threadIdx.x, lane = tid & 63, wave = tid >> 6;
  const int l15 = lane & 15, kcol0 = (lane >> 4) * 8, rrow = (lane >> 4) * 4;
  const int et = wave & 3, dh = wave >> 2;

  char* Mb0 = smem;                                      // [2][128][128] bf16 = 64 KB
  char* Nb0 = smem + 65536;                              // [2][128][64]  bf16 = 32 KB
  __bf16 (*S16)[136] = (__bf16(*)[136])(smem + 98304);   // [64][136] = 17408 B

#define SSTAGE(BUF, CN) {                                                     \
    const int cn_ = ((CN) < 32) ? (CN) : 31;                                  \
    const size_t bhcn_ = (size_t)wg * 32 + cn_;                               \
    const ushort_t* MTR_ = MTG + bhcn_ * CHM_;                                \
    const ushort_t* NTR_ = NTG + bhcn_ * CHM_;                                \
    _Pragma("unroll") for (int r_ = 0; r_ < 4; ++r_) {                        \
      const int idx_ = r_ * 512 + tid;                                        \
      const int d_ = idx_ >> 4, sl_ = idx_ & 15;                              \
      const ushort_t* src_ = MTR_ + (size_t)d_ * 128 + ((sl_ ^ (d_ & 7)) << 3); \
      __builtin_amdgcn_global_load_lds(                                       \
          (const __attribute__((address_space(1))) unsigned int*)src_,        \
          (__attribute__((address_space(3))) unsigned int*)                   \
              (Mb0 + (BUF) * 32768 + r_ * 8192 + wave * 1024), 16, 0, 0);     \
    }                                                                         \
    _Pragma("unroll") for (int r_ = 0; r_ < 2; ++r_) {                        \
      const int idx_ = r_ * 512 + tid;                                        \
      const int d_ = idx_ >> 3, sl_ = idx_ & 7;                               \
      const ushort_t* src_ = NTR_ + (size_t)d_ * 128 + e0 + ((sl_ ^ (d_ & 7)) << 3); \
      __builtin_amdgcn_global_load_lds(                                       \
          (const __attribute__((address_space(1))) unsigned int*)src_,        \
          (__attribute__((address_space(3))) unsigned int*)                   \
              (Nb0 + (BUF) * 16384 + r_ * 8192 + wave * 1024), 16, 0, 0);     \
    }                                                                         \
  }

#define MRD(BUF, ROW, KC)                                                     \
  (*(const bf16x8*)(Mb0 + (BUF) * 32768 + ((ROW) << 8) +                      \
                    ((((KC) << 1)) ^ (((ROW) & 7) << 4))))
#define NRD(BUF, DROW, EC)                                                    \
  (*(const short4v*)(Nb0 + (BUF) * 16384 + ((DROW) << 7) +                    \
                    ((((EC) << 1)) ^ (((DROW) & 7) << 4))))

  f32x4 s_acc[4] = {};   // S^T[e0+16et+rrow+r][16*(4dh+dl)+l15]
  SSTAGE(0, 0)

  for (int c = 0; c < 32; ++c) {
    const int buf = c & 1;
    ushort_t* ScR = ScG + ((size_t)wg * 32 + c) * CHM_;

    __syncthreads();                 // drains vmcnt: stage(c) landed; all waves synced
    SSTAGE(buf ^ 1, c + 1)           // issue next chunk's loads (stay in flight)

#pragma unroll
    for (int dl = 0; dl < 4; ++dl)
#pragma unroll
      for (int r = 0; r < 4; ++r)
        S16[16 * et + rrow + r][(4 * dh + dl) * 16 + l15] = (__bf16)s_acc[dl][r];
    asm volatile("s_waitcnt lgkmcnt(0)" ::: "memory");
    __builtin_amdgcn_sched_barrier(0);
    __builtin_amdgcn_s_barrier();    // S16 visible; vmcnt NOT drained
    __builtin_amdgcn_sched_barrier(0);

    // snapshot S at chunk start (fire-and-forget stores)
#pragma unroll
    for (int cc = 0; cc < 2; ++cc) {
      const int idx = tid + cc * 512;
      const int row = idx >> 4, seg = idx & 15;
      *(uint4*)(void*)(ScR + (size_t)(e0 + row) * 128 + seg * 8) =
          *(const uint4*)&S16[row][seg * 8];
    }

    f32x4 acc[4];
#pragma unroll
    for (int dl = 0; dl < 4; ++dl) {
      short4v nv = NRD(buf, 16 * (4 * dh + dl) + l15, 16 * et + rrow);
#pragma unroll
      for (int r = 0; r < 4; ++r) acc[dl][r] = b2f((ushort_t)nv[r]);
    }
#pragma unroll
    for (int kk = 0; kk < 4; ++kk) {
      bf16x8 sa = *(const bf16x8*)&S16[16 * et + l15][kk * 32 + kcol0];
#pragma unroll
      for (int dl = 0; dl < 4; ++dl) {
        bf16x8 mb = MRD(buf, 16 * (4 * dh + dl) + l15, kk * 32 + kcol0);
        acc[dl] = __builtin_amdgcn_mfma_f32_16x16x32_bf16(sa, mb, acc[dl], 0, 0, 0);
      }
    }
#pragma unroll
    for (int dl = 0; dl < 4; ++dl) s_acc[dl] = acc[dl];
  }
#undef SSTAGE
#undef MRD
#undef NRD
}

// ---------------------------------------------------------------------------
// FUSED launch: blocks 0..63 = scan, 64..191 = z-gemm tiles (independent).
// ---------------------------------------------------------------------------
__global__ __launch_bounds__(512, 2)
void k_scan_zgemm(const ushort_t* __restrict__ MTG, const ushort_t* __restrict__ NTG,
                  ushort_t* __restrict__ ScG,
                  const ushort_t* __restrict__ xB, const ushort_t* __restrict__ WzB,
                  ushort_t* __restrict__ zbuf) {
  __shared__ alignas(16) char smem[131072];
  if (blockIdx.x < 64)
    scan_body(MTG, NTG, ScG, blockIdx.x, smem);
  else
    gemm256_body<ushort_t>(xB, WzB, zbuf, B_ * T_, VD_, HID_,
                           blockIdx.x - 64, (ushort_t*)smem);
}

// ---------------------------------------------------------------------------
// k_out: fully parallel per (b,h,c): u = Ul + Wkneg@S_c; Pm recomputed from
// q,k; o = gam*Q@S_c + Pm@u; fused gated RMSNorm -> bf16 outg. grid=1024.
// ---------------------------------------------------------------------------
__global__ __launch_bounds__(256, 2)
void k_out(const ushort_t* __restrict__ act,
           const ushort_t* __restrict__ WkG, const ushort_t* __restrict__ UlT,
           const float* __restrict__ gtG,
           const ushort_t* __restrict__ ScG, const ushort_t* __restrict__ zbuf,
           const float* __restrict__ nw, ushort_t* __restrict__ outg) {
  __shared__ __bf16 S16[128][136];   // 34816 B
  __shared__ __bf16 uTl[128][72];    // 18432 B
  __shared__ __bf16 PmL[64][72];     //  9216 B
  __shared__ float Egc[65], Rgc[65], gam[64], nws[128];

  const int bhc = blockIdx.x;
  const int c = bhc & 31, h = (bhc >> 5) & 15, b = bhc >> 9;
  const int hq = h >> 1, t0g = c * 64;
  const int tid = threadIdx.x, lane = tid & 63, wave = tid >> 6;  // wave = t-tile
  const int l15 = lane & 15, kcol0 = (lane >> 4) * 8, rrow = (lane >> 4) * 4;

  const ushort_t* ScR = ScG + (size_t)bhc * CHM_;
  const ushort_t* WkR = WkG + (size_t)bhc * (64 * 128);
  const ushort_t* UlR = UlT + (size_t)bhc * (128 * 64);
  const ushort_t* actQ = act + ((size_t)b * T_ + t0g) * CD_ + hq * HD_;
  const ushort_t* actK = actQ + KD_;

#pragma unroll
  for (int cc = 0; cc < 8; ++cc) {
    const int idx = tid + cc * 256;          // 2048 x 16B chunks
    const int row = idx >> 4, seg = idx & 15;
    *(uint4*)&S16[row][seg * 8] =
        *(const uint4*)(const void*)(ScR + (size_t)row * 128 + seg * 8);
  }
  {
    const float gc32 = gtG[(size_t)bhc * 64 + 31];
    if (tid < 65) {
      const float gcv = (tid == 0) ? 0.f : gtG[(size_t)bhc * 64 + tid - 1];
      Egc[tid] = __expf(gcv - gc32);
      Rgc[tid] = __expf(gc32 - gcv);
    }
    if (tid < 64) gam[tid] = __expf(gtG[(size_t)bhc * 64 + tid]);
    if (tid < 128) nws[tid] = nw[tid];
  }
  __syncthreads();

  // q fragments (reused for Pm-compute and QS)
  bf16x8 qf[4];
#pragma unroll
  for (int kk = 0; kk < 4; ++kk)
    qf[kk] = *(const bf16x8*)(const void*)
        (actQ + (size_t)(16 * wave + l15) * CD_ + kk * 32 + kcol0);

  // u-phase: u[t][e] = Ul[t][e] + Wkneg@S ; write uTl[e][t]
  bf16x8 wa[4];
#pragma unroll
  for (int kk = 0; kk < 4; ++kk)
    wa[kk] = *(const bf16x8*)(const void*)(WkR + (size_t)(16 * wave + l15) * 128 + kk * 32 + kcol0);
  f32x4 au[8] = {};
#pragma unroll
  for (int kk = 0; kk < 4; ++kk)
#pragma unroll
    for (int jt = 0; jt < 8; ++jt) {
      bf16x8 sb = *(const bf16x8*)&S16[jt * 16 + l15][kk * 32 + kcol0];
      au[jt] = __builtin_amdgcn_mfma_f32_16x16x32_bf16(wa[kk], sb, au[jt], 0, 0, 0);
    }
#pragma unroll
  for (int jt = 0; jt < 8; ++jt) {
    short4v uv = *(const short4v*)(const void*)(UlR + (size_t)(16 * jt + l15) * 64 + wave * 16 + rrow);
#pragma unroll
    for (int r = 0; r < 4; ++r)
      uTl[16 * jt + l15][16 * wave + rrow + r] = (__bf16)(au[jt][r] + b2f((ushort_t)uv[r]));
  }

  // Pm recompute: Pm[t][s] = (s<=t) ? Egc[t+1]*Rgc[s+1]*(Q[t].K[s]) : 0
#pragma unroll
  for (int st = 0; st < 4; ++st) {
    f32x4 accP = {};
#pragma unroll
    for (int kk = 0; kk < 4; ++kk) {
      bf16x8 kb = *(const bf16x8*)(const void*)
          (actK + (size_t)(st * 16 + l15) * CD_ + kk * 32 + kcol0);
      accP = __builtin_amdgcn_mfma_f32_16x16x32_bf16(qf[kk], kb, accP, 0, 0, 0);
    }
    const int scol = st * 16 + l15;
#pragma unroll
    for (int r = 0; r < 4; ++r) {
      const int t = 16 * wave + rrow + r;
      PmL[t][scol] = (scol <= t) ? (__bf16)(Egc[t + 1] * Rgc[scol + 1] * accP[r])
                                 : (__bf16)0.f;
    }
  }
  __syncthreads();

  // o-phase + fused gated RMSNorm
  f32x4 qs[8] = {}, o2[8] = {};
#pragma unroll
  for (int kk = 0; kk < 4; ++kk)
#pragma unroll
    for (int jt = 0; jt < 8; ++jt) {
      bf16x8 sb = *(const bf16x8*)&S16[jt * 16 + l15][kk * 32 + kcol0];
      qs[jt] = __builtin_amdgcn_mfma_f32_16x16x32_bf16(qf[kk], sb, qs[jt], 0, 0, 0);
    }
#pragma unroll
  for (int ks = 0; ks < 2; ++ks) {
    bf16x8 pa = *(const bf16x8*)&PmL[16 * wave + l15][ks * 32 + kcol0];
#pragma unroll
    for (int jt = 0; jt < 8; ++jt) {
      bf16x8 ub = *(const bf16x8*)&uTl[jt * 16 + l15][ks * 32 + kcol0];
      o2[jt] = __builtin_amdgcn_mfma_f32_16x16x32_bf16(pa, ub, o2[jt], 0, 0, 0);
    }
  }
  float ov[8][4];
  float ss0 = 0.f, ss1 = 0.f, ss2 = 0.f, ss3 = 0.f;
#pragma unroll
  for (int jt = 0; jt < 8; ++jt) {
    ov[jt][0] = gam[16 * wave + rrow + 0] * qs[jt][0] + o2[jt][0];
    ov[jt][1] = gam[16 * wave + rrow + 1] * qs[jt][1] + o2[jt][1];
    ov[jt][2] = gam[16 * wave + rrow + 2] * qs[jt][2] + o2[jt][2];
    ov[jt][3] = gam[16 * wave + rrow + 3] * qs[jt][3] + o2[jt][3];
    ss0 += ov[jt][0] * ov[jt][0];
    ss1 += ov[jt][1] * ov[jt][1];
    ss2 += ov[jt][2] * ov[jt][2];
    ss3 += ov[jt][3] * ov[jt][3];
  }
#pragma unroll
  for (int m = 1; m < 16; m <<= 1) {
    ss0 += __shfl_xor(ss0, m);
    ss1 += __shfl_xor(ss1, m);
    ss2 += __shfl_xor(ss2, m);
    ss3 += __shfl_xor(ss3, m);
  }
  float rr[4];
  rr[0] = 1.f / sqrtf(ss0 * (1.f / HD_) + 1e-6f);
  rr[1] = 1.f / sqrtf(ss1 * (1.f / HD_) + 1e-6f);
  rr[2] = 1.f / sqrtf(ss2 * (1.f / HD_) + 1e-6f);
  rr[3] = 1.f / sqrtf(ss3 * (1.f / HD_) + 1e-6f);
#pragma unroll
  for (int jt = 0; jt < 8; ++jt) {
    const int e = 16 * jt + l15;
    const float wv = nws[e];
#pragma unroll
    for (int r = 0; r < 4; ++r) {
      const int t = 16 * wave + rrow + r;
      const float zf = b2f(zbuf[((size_t)b * T_ + t0g + t) * VD_ + h * HD_ + e]);
      const float g = zf / (1.f + expf(-zf));
      outg[(((size_t)b * T_ + t0g + t) * NV_ + h) * HD_ + e] =
          f2b(ov[jt][r] * rr[r] * wv * g);
    }
  }
}

// ---------------------------------------------------------------------------
extern "C" void kernel_launch(void* const* d_in, const int* in_sizes, int n_in,
                              void* d_out, int out_size, void* d_ws, size_t ws_size,
                              hipStream_t stream) {
  const float* x    = (const float*)d_in[0];
  const float* Wqkv = (const float*)d_in[1];
  const float* Wz   = (const float*)d_in[2];
  const float* Wb   = (const float*)d_in[3];
  const float* Wa   = (const float*)d_in[4];
  const float* cw   = (const float*)d_in[5];
  const float* dtb  = (const float*)d_in[6];
  const float* alog = (const float*)d_in[7];
  const float* nw   = (const float*)d_in[8];
  const float* Wout = (const float*)d_in[9];

  // ---- workspace layout: 210.5 MB total (<= proven-safe 213.4 MB) ----
  char* p = (char*)d_ws;
  ushort_t* qkv_raw = (ushort_t*)p; p += (size_t)B_ * T_ * CD_ * 2;       // 33.55 MB
  ushort_t* zbuf    = (ushort_t*)p; p += (size_t)B_ * T_ * VD_ * 2;       // 16.78 MB
  ushort_t* act     = (ushort_t*)p; p += (size_t)B_ * T_ * CD_ * 2;       // 33.55 MB (bf16)
  float*    betaB   = (float*)p;    p += (size_t)B_ * T_ * NV_ * 4;       //  0.26 MB
  float*    gBuf    = (float*)p;    p += (size_t)B_ * T_ * NV_ * 4;       //  0.26 MB
  float*    gtG     = (float*)p;    p += (size_t)1024 * 64 * 4;           //  0.26 MB
  ushort_t* xB      = (ushort_t*)p; p += (size_t)B_ * T_ * HID_ * 2;      // 16.78 MB
  ushort_t* WzB     = (ushort_t*)p; p += (size_t)VD_ * HID_ * 2;          //  8.39 MB
  ushort_t* MTG     = (ushort_t*)p; p += (size_t)1024 * CHM_ * 2;         // 33.55 MB
  ushort_t* NTG     = (ushort_t*)p; p += (size_t)1024 * CHM_ * 2;         // 33.55 MB
  ushort_t* ScG     = (ushort_t*)p; p += (size_t)1024 * CHM_ * 2;         // 33.55 MB
  // overlays:
  ushort_t* WkG   = qkv_raw;                             // 16.78 MB (post-conv)
  ushort_t* UlT   = qkv_raw + (size_t)1024 * 64 * 128;   // 16.78 MB (post-conv, exact fit)
  ushort_t* WqkvB = act;                                 // 16.78 MB (pre-conv)
  ushort_t* outg  = MTG;                                 // 16.78 MB (post-scan)
  ushort_t* WoutB = NTG;                                 //  8.39 MB (post-scan; cast moved)

  const int M = B_ * T_;  // 4096

  hipLaunchKernelGGL(k_cast_bf16, dim3(M * HID_ / 4 / 256), dim3(256), 0, stream,
                     x, xB, M * HID_ / 4);
  hipLaunchKernelGGL(k_cast_bf16, dim3(CD_ * HID_ / 4 / 256), dim3(256), 0, stream,
                     Wqkv, WqkvB, CD_ * HID_ / 4);
  hipLaunchKernelGGL(k_cast_bf16, dim3(VD_ * HID_ / 4 / 256), dim3(256), 0, stream,
                     Wz, WzB, VD_ * HID_ / 4);

  hipLaunchKernelGGL(k_gemm256<ushort_t>, dim3((M / 256) * (CD_ / 256)), dim3(512), 0, stream,
                     xB, WqkvB, qkv_raw, M, CD_, HID_);
  hipLaunchKernelGGL(k_proj_ba, dim3(M / 16), dim3(256), 0, stream,
                     x, Wb, Wa, dtb, alog, betaB, gBuf);
  hipLaunchKernelGGL(k_conv_silu_norm, dim3(M), dim3(256), 0, stream,
                     qkv_raw, cw, act);
  hipLaunchKernelGGL(k_prep, dim3(B_ * NV_ * 32), dim3(256), 0, stream,
                     act, gBuf, betaB, WkG, UlT, gtG, MTG, NTG);
  hipLaunchKernelGGL(k_scan_zgemm, dim3(64 + (M / 256) * (VD_ / 256)), dim3(512), 0, stream,
                     MTG, NTG, ScG, xB, WzB, zbuf);
  hipLaunchKernelGGL(k_cast_bf16, dim3(HID_ * VD_ / 4 / 256), dim3(256), 0, stream,
                     Wout, WoutB, HID_ * VD_ / 4);
  hipLaunchKernelGGL(k_out, dim3(B_ * NV_ * 32), dim3(256), 0, stream,
                     act, WkG, UlT, gtG, ScG, zbuf, nw, outg);
  hipLaunchKernelGGL(k_gemm256<float>, dim3((M / 256) * (HID_ / 256)), dim3(512), 0, stream,
                     outg, WoutB, (float*)d_out, M, HID_, VD_);
}

// Round 17
// 529.858 us; speedup vs baseline: 1.0236x; 1.0236x over previous
//
#include <hip/hip_runtime.h>
#include <cstdint>
#include <cstddef>

// GatedDeltaNet forward, MI355X/gfx950.
// R17 = R15 exact (k_prep P4 reverted to scalar stores; R16 staging was
// neutral-negative) + out-GEMM retiled to 256x128 (k_gemm256x128): M=4096,
// N=2048 gave only 128 blocks at 256^2 (half the GPU idle); 256x128 fills all
// 256 CUs with the same R8-verified counted-vmcnt schedule (3 loads/half-stage
// -> vmcnt(6)).

typedef unsigned short ushort_t;
typedef __attribute__((ext_vector_type(8))) __bf16 bf16x8;
typedef __attribute__((ext_vector_type(4))) float f32x4;
typedef __attribute__((ext_vector_type(4))) short short4v;

#define B_   2
#define T_   2048
#define HID_ 2048
#define NK_  8
#define NV_  16
#define HD_  128
#define KD_  1024
#define VD_  2048
#define CD_  4096
#define CHM_ 16384   // 128*128 elems per per-chunk matrix (MT/NT/Sc)

__device__ __forceinline__ float b2f(ushort_t u) {
  union { unsigned int i; float f; } v; v.i = ((unsigned int)u) << 16; return v.f;
}
__device__ __forceinline__ ushort_t f2b(float f) {   // RNE bf16 round
  unsigned int x = __builtin_bit_cast(unsigned int, f);
  unsigned int r = x + 0x7fffu + ((x >> 16) & 1u);
  return (ushort_t)(r >> 16);
}

// ---------------------------------------------------------------------------
// fp32 -> bf16 cast
// ---------------------------------------------------------------------------
__global__ __launch_bounds__(256)
void k_cast_bf16(const float* __restrict__ in, ushort_t* __restrict__ out, int n4) {
  const int i = blockIdx.x * 256 + threadIdx.x;
  if (i >= n4) return;
  float4 v = *(const float4*)(in + (size_t)i * 4);
  short4v o;
  o[0] = (short)f2b(v.x); o[1] = (short)f2b(v.y);
  o[2] = (short)f2b(v.z); o[3] = (short)f2b(v.w);
  *(short4v*)(out + (size_t)i * 4) = o;
}

// ---------------------------------------------------------------------------
// GEMM 256x256 body, BK=64, 8 waves, counted-vmcnt pipeline (R8-verified).
// ---------------------------------------------------------------------------
#define LPOS(BUF, OP, HALF) ((((BUF) * 2 + (OP)) * 2 + (HALF)) * 8192)

template <typename OutT>
__device__ __forceinline__ void gemm256_body(
    const ushort_t* __restrict__ A, const ushort_t* __restrict__ Bw,
    OutT* __restrict__ C, int M, int N, int K, int tile, ushort_t* lds) {
  const int tid = threadIdx.x;
  const int lane = tid & 63, wave = tid >> 6;
  const int wm = wave >> 2, wc = wave & 3;
  const int l15 = lane & 15;
  const int ks16 = (lane >> 4) * 16;
  const int r4 = (lane >> 4) * 4;
  const int nkt = K >> 6;
  const int nbx = N >> 8;
  const size_t row0 = (size_t)(tile / nbx) * 256;
  const size_t col0 = (size_t)(tile % nbx) * 256;

#define STAGE4(BUF, HALF, KT) {                                               \
    const int kt_ = ((KT) < nkt) ? (KT) : (nkt - 1);                          \
    const int kb_ = kt_ * 64 + (HALF) * 32;                                   \
    _Pragma("unroll") for (int r_ = 0; r_ < 2; ++r_) {                        \
      const int wb_ = r_ * 8192 + wave * 1024;                                \
      const int o_  = wb_ + lane * 16;                                        \
      const int row_ = o_ >> 6;                                               \
      const int src_ = (o_ & 63) ^ (((row_) & 3) << 4);                       \
      const ushort_t* ga_ = A  + (row0 + row_) * (size_t)K + kb_ + (src_ >> 1); \
      const ushort_t* gb_ = Bw + (col0 + row_) * (size_t)K + kb_ + (src_ >> 1); \
      __builtin_amdgcn_global_load_lds(                                       \
          (const __attribute__((address_space(1))) unsigned int*)ga_,         \
          (__attribute__((address_space(3))) unsigned int*)                   \
              (lds + LPOS(BUF, 0, HALF) + (wb_ >> 1)), 16, 0, 0);             \
      __builtin_amdgcn_global_load_lds(                                       \
          (const __attribute__((address_space(1))) unsigned int*)gb_,         \
          (__attribute__((address_space(3))) unsigned int*)                   \
              (lds + LPOS(BUF, 1, HALF) + (wb_ >> 1)), 16, 0, 0);             \
    }                                                                         \
  }

#define RD(BUF, OP, HALF, ROW)                                                \
  (*(const bf16x8*)((const char*)(lds + LPOS(BUF, OP, HALF)) +                \
                    ((((ROW) * 64 + ks16)) ^ (((ROW) & 3) << 4))))

  f32x4 acc[8][4] = {};
  STAGE4(0, 0, 0)
  STAGE4(0, 1, 0)
  STAGE4(1, 0, 1)

  for (int kt = 0; kt < nkt; ++kt) {
    const int cb = kt & 1, nb = cb ^ 1;
    asm volatile("s_waitcnt vmcnt(8)" ::: "memory");
    __builtin_amdgcn_s_barrier();
    {
      bf16x8 af[8], bfr[4];
#pragma unroll
      for (int mf = 0; mf < 8; ++mf) af[mf] = RD(cb, 0, 0, wm * 128 + mf * 16 + l15);
#pragma unroll
      for (int nf = 0; nf < 4; ++nf) bfr[nf] = RD(cb, 1, 0, wc * 64 + nf * 16 + l15);
      STAGE4(nb, 1, kt + 1)
      __builtin_amdgcn_s_setprio(1);
#pragma unroll
      for (int mf = 0; mf < 8; ++mf)
#pragma unroll
        for (int nf = 0; nf < 4; ++nf)
          acc[mf][nf] = __builtin_amdgcn_mfma_f32_16x16x32_bf16(af[mf], bfr[nf], acc[mf][nf], 0, 0, 0);
      __builtin_amdgcn_s_setprio(0);
    }
    asm volatile("s_waitcnt vmcnt(8)" ::: "memory");
    __builtin_amdgcn_s_barrier();
    {
      bf16x8 af[8], bfr[4];
#pragma unroll
      for (int mf = 0; mf < 8; ++mf) af[mf] = RD(cb, 0, 1, wm * 128 + mf * 16 + l15);
#pragma unroll
      for (int nf = 0; nf < 4; ++nf) bfr[nf] = RD(cb, 1, 1, wc * 64 + nf * 16 + l15);
      STAGE4(cb, 0, kt + 2)
      __builtin_amdgcn_s_setprio(1);
#pragma unroll
      for (int mf = 0; mf < 8; ++mf)
#pragma unroll
        for (int nf = 0; nf < 4; ++nf)
          acc[mf][nf] = __builtin_amdgcn_mfma_f32_16x16x32_bf16(af[mf], bfr[nf], acc[mf][nf], 0, 0, 0);
      __builtin_amdgcn_s_setprio(0);
    }
  }
#undef STAGE4
#undef RD

#pragma unroll
  for (int mf = 0; mf < 8; ++mf)
#pragma unroll
    for (int nf = 0; nf < 4; ++nf)
#pragma unroll
      for (int j = 0; j < 4; ++j) {
        const size_t row = row0 + wm * 128 + mf * 16 + r4 + j;
        const size_t col = col0 + wc * 64 + nf * 16 + l15;
        if constexpr (sizeof(OutT) == 4)
          C[row * (size_t)N + col] = acc[mf][nf][j];
        else
          C[row * (size_t)N + col] = (OutT)f2b(acc[mf][nf][j]);
      }
}

template <typename OutT>
__global__ __launch_bounds__(512, 2)
void k_gemm256(const ushort_t* __restrict__ A, const ushort_t* __restrict__ Bw,
               OutT* __restrict__ C, int M, int N, int K) {
  __shared__ alignas(16) ushort_t lds[2 * 2 * 2 * 8192];
  const int nwg = gridDim.x;
  const int q8 = nwg >> 3, r8 = nwg & 7;
  const int xcd = blockIdx.x & 7, idx8 = blockIdx.x >> 3;
  const int s = (xcd < r8) ? (xcd * (q8 + 1) + idx8)
                           : (r8 * (q8 + 1) + (xcd - r8) * q8 + idx8);
  gemm256_body<OutT>(A, Bw, C, M, N, K, s, lds);
}

// ---------------------------------------------------------------------------
// GEMM 256x128 tile (R17): same counted-vmcnt schedule, 3 loads/half-stage,
// vmcnt(6). 8 waves as 4m x 2n; acc[4][4]/thread. LDS 96 KB.
// A region: [buf][half] 8192 ushort; B region: [buf][half] 4096 ushort.
// ---------------------------------------------------------------------------
#define LPA(BUF, HALF) (((BUF) * 2 + (HALF)) * 8192)
#define LPB(BUF, HALF) (32768 + ((BUF) * 2 + (HALF)) * 4096)

template <typename OutT>
__global__ __launch_bounds__(512, 1)
void k_gemm256x128(const ushort_t* __restrict__ A, const ushort_t* __restrict__ Bw,
                   OutT* __restrict__ C, int M, int N, int K) {
  __shared__ alignas(16) ushort_t lds[49152];   // 96 KB
  const int tid = threadIdx.x;
  const int lane = tid & 63, wave = tid >> 6;
  const int wm = wave >> 1, wc = wave & 1;
  const int l15 = lane & 15;
  const int ks16 = (lane >> 4) * 16;
  const int r4 = (lane >> 4) * 4;
  const int nkt = K >> 6;
  const int nbx = N >> 7;                       // 128-col tiles
  const int nwg = gridDim.x;
  const int q8 = nwg >> 3, r8 = nwg & 7;
  const int xcd = blockIdx.x & 7, idx8 = blockIdx.x >> 3;
  const int s = (xcd < r8) ? (xcd * (q8 + 1) + idx8)
                           : (r8 * (q8 + 1) + (xcd - r8) * q8 + idx8);
  const size_t row0 = (size_t)(s / nbx) * 256;
  const size_t col0 = (size_t)(s % nbx) * 128;

#define STG3(BUF, HALF, KT) {                                                 \
    const int kt_ = ((KT) < nkt) ? (KT) : (nkt - 1);                          \
    const int kb_ = kt_ * 64 + (HALF) * 32;                                   \
    _Pragma("unroll") for (int r_ = 0; r_ < 2; ++r_) {                        \
      const int wb_ = r_ * 8192 + wave * 1024;                                \
      const int o_  = wb_ + lane * 16;                                        \
      const int row_ = o_ >> 6;                                               \
      const int src_ = (o_ & 63) ^ (((row_) & 3) << 4);                       \
      const ushort_t* ga_ = A + (row0 + row_) * (size_t)K + kb_ + (src_ >> 1); \
      __builtin_amdgcn_global_load_lds(                                       \
          (const __attribute__((address_space(1))) unsigned int*)ga_,         \
          (__attribute__((address_space(3))) unsigned int*)                   \
              (lds + LPA(BUF, HALF) + (wb_ >> 1)), 16, 0, 0);                 \
    }                                                                         \
    {                                                                         \
      const int wb_ = wave * 1024;                                            \
      const int o_  = wb_ + lane * 16;                                        \
      const int row_ = o_ >> 6;                                               \
      const int src_ = (o_ & 63) ^ (((row_) & 3) << 4);                       \
      const ushort_t* gb_ = Bw + (col0 + row_) * (size_t)K + kb_ + (src_ >> 1); \
      __builtin_amdgcn_global_load_lds(                                       \
          (const __attribute__((address_space(1))) unsigned int*)gb_,         \
          (__attribute__((address_space(3))) unsigned int*)                   \
              (lds + LPB(BUF, HALF) + (wb_ >> 1)), 16, 0, 0);                 \
    }                                                                         \
  }

#define RDA(BUF, HALF, ROW)                                                   \
  (*(const bf16x8*)((const char*)(lds + LPA(BUF, HALF)) +                     \
                    ((((ROW) * 64 + ks16)) ^ (((ROW) & 3) << 4))))
#define RDB(BUF, HALF, ROW)                                                   \
  (*(const bf16x8*)((const char*)(lds + LPB(BUF, HALF)) +                     \
                    ((((ROW) * 64 + ks16)) ^ (((ROW) & 3) << 4))))

  f32x4 acc[4][4] = {};
  STG3(0, 0, 0)
  STG3(0, 1, 0)
  STG3(1, 0, 1)

  for (int kt = 0; kt < nkt; ++kt) {
    const int cb = kt & 1, nb = cb ^ 1;
    asm volatile("s_waitcnt vmcnt(6)" ::: "memory");
    __builtin_amdgcn_s_barrier();
    {
      bf16x8 af[4], bfr[4];
#pragma unroll
      for (int mf = 0; mf < 4; ++mf) af[mf] = RDA(cb, 0, wm * 64 + mf * 16 + l15);
#pragma unroll
      for (int nf = 0; nf < 4; ++nf) bfr[nf] = RDB(cb, 0, wc * 64 + nf * 16 + l15);
      STG3(nb, 1, kt + 1)
      __builtin_amdgcn_s_setprio(1);
#pragma unroll
      for (int mf = 0; mf < 4; ++mf)
#pragma unroll
        for (int nf = 0; nf < 4; ++nf)
          acc[mf][nf] = __builtin_amdgcn_mfma_f32_16x16x32_bf16(af[mf], bfr[nf], acc[mf][nf], 0, 0, 0);
      __builtin_amdgcn_s_setprio(0);
    }
    asm volatile("s_waitcnt vmcnt(6)" ::: "memory");
    __builtin_amdgcn_s_barrier();
    {
      bf16x8 af[4], bfr[4];
#pragma unroll
      for (int mf = 0; mf < 4; ++mf) af[mf] = RDA(cb, 1, wm * 64 + mf * 16 + l15);
#pragma unroll
      for (int nf = 0; nf < 4; ++nf) bfr[nf] = RDB(cb, 1, wc * 64 + nf * 16 + l15);
      STG3(cb, 0, kt + 2)
      __builtin_amdgcn_s_setprio(1);
#pragma unroll
      for (int mf = 0; mf < 4; ++mf)
#pragma unroll
        for (int nf = 0; nf < 4; ++nf)
          acc[mf][nf] = __builtin_amdgcn_mfma_f32_16x16x32_bf16(af[mf], bfr[nf], acc[mf][nf], 0, 0, 0);
      __builtin_amdgcn_s_setprio(0);
    }
  }
#undef STG3
#undef RDA
#undef RDB

#pragma unroll
  for (int mf = 0; mf < 4; ++mf)
#pragma unroll
    for (int nf = 0; nf < 4; ++nf)
#pragma unroll
      for (int j = 0; j < 4; ++j) {
        const size_t row = row0 + wm * 64 + mf * 16 + r4 + j;
        const size_t col = col0 + wc * 64 + nf * 16 + l15;
        if constexpr (sizeof(OutT) == 4)
          C[row * (size_t)N + col] = acc[mf][nf][j];
        else
          C[row * (size_t)N + col] = (OutT)f2b(acc[mf][nf][j]);
      }
}

// ---------------------------------------------------------------------------
// b/a projection, W-amortized (R12-verified).
// ---------------------------------------------------------------------------
__global__ __launch_bounds__(256, 2)
void k_proj_ba(const float* __restrict__ x, const float* __restrict__ Wb,
               const float* __restrict__ Wa, const float* __restrict__ dtb,
               const float* __restrict__ alog,
               float* __restrict__ beta, float* __restrict__ gout) {
  __shared__ __bf16 Wl[16][2048];   // 64 KB (accessed via swizzled byte offsets)
  __shared__ float part[16][16];
  const int tid = threadIdx.x;
  const int o = tid & 15, seg = tid >> 4;    // 16 outputs x 16 k-segs(128)
  const int bt0 = blockIdx.x * 16;

#define PROJ_PASS(WSRC, EMIT) {                                               \
    for (int i = tid; i < 8192; i += 256) {                                   \
      const int os_ = i >> 9, k4_ = i & 511;                                  \
      float4 w_ = *(const float4*)(WSRC + (size_t)os_ * HID_ + k4_ * 4);      \
      const int b_ = k4_ * 8;                                                 \
      __bf16* d_ = (__bf16*)((char*)&Wl[0][0] + os_ * 4096 +                  \
                   (((b_ & ~15) ^ ((os_ & 15) << 4)) | (b_ & 8)));            \
      d_[0] = (__bf16)w_.x; d_[1] = (__bf16)w_.y;                             \
      d_[2] = (__bf16)w_.z; d_[3] = (__bf16)w_.w;                             \
    }                                                                         \
    __syncthreads();                                                          \
    for (int rr = 0; rr < 16; ++rr) {                                         \
      const int bt = bt0 + rr;                                                \
      const float* xr = x + (size_t)bt * HID_;                                \
      float s = 0.f;                                                          \
      _Pragma("unroll") for (int j = 0; j < 16; ++j) {                        \
        const int k = seg * 128 + j * 8;                                      \
        float4 xa = *(const float4*)&xr[k];                                   \
        float4 xb = *(const float4*)&xr[k + 4];                               \
        bf16x8 wv = *(const bf16x8*)((const char*)&Wl[0][0] + o * 4096 +      \
                     ((k * 2) ^ ((o & 15) << 4)));                            \
        s += (float)wv[0]*xa.x + (float)wv[1]*xa.y + (float)wv[2]*xa.z +      \
             (float)wv[3]*xa.w + (float)wv[4]*xb.x + (float)wv[5]*xb.y +      \
             (float)wv[6]*xb.z + (float)wv[7]*xb.w;                           \
      }                                                                       \
      part[o][seg] = s;                                                       \
      __syncthreads();                                                        \
      if (tid < 16) {                                                         \
        float t_ = 0.f;                                                       \
        _Pragma("unroll") for (int i2 = 0; i2 < 16; ++i2) t_ += part[tid][i2];\
        EMIT                                                                  \
      }                                                                       \
      __syncthreads();                                                        \
    }                                                                         \
  }

  PROJ_PASS(Wb, {
    beta[(size_t)bt * NV_ + tid] = 1.f / (1.f + expf(-t_));
  })
  __syncthreads();
  PROJ_PASS(Wa, {
    float aa = t_ + dtb[tid];
    float sp = (aa > 20.f) ? aa : log1pf(expf(aa));
    gout[(size_t)bt * NV_ + tid] = -expf(alog[tid]) * sp;
  })
#undef PROJ_PASS
}

// ---------------------------------------------------------------------------
// Fused depthwise causal conv1d (K=4) + silu + l2norm(q,k). (R14-verified)
// ---------------------------------------------------------------------------
__global__ __launch_bounds__(256)
void k_conv_silu_norm(const ushort_t* __restrict__ qkv, const float* __restrict__ cw,
                      ushort_t* __restrict__ act) {
  const int bt = blockIdx.x;
  const int tid = threadIdx.x;
  const int t = bt & (T_ - 1);
  const int c = tid * 16;
  const ushort_t* rowp = qkv + (size_t)bt * CD_ + c;

  float wf[16][4];
#pragma unroll
  for (int i = 0; i < 16; ++i) {
    float4 w = *(const float4*)&cw[(c + i) * 4];
    wf[i][0] = w.x; wf[i][1] = w.y; wf[i][2] = w.z; wf[i][3] = w.w;
  }
  float a[16];
#pragma unroll
  for (int i = 0; i < 16; ++i) a[i] = 0.f;
#pragma unroll
  for (int j = 0; j < 4; ++j) {
    const int tt = t - 3 + j;
    if (tt >= 0) {
      const ushort_t* src = rowp + ((ptrdiff_t)j - 3) * CD_;
      bf16x8 v0 = *(const bf16x8*)(const void*)src;
      bf16x8 v1 = *(const bf16x8*)(const void*)(src + 8);
#pragma unroll
      for (int i = 0; i < 8; ++i) {
        a[i]     += (float)v0[i] * wf[i][j];
        a[8 + i] += (float)v1[i] * wf[8 + i][j];
      }
    }
  }
#pragma unroll
  for (int i = 0; i < 16; ++i) a[i] = a[i] / (1.f + expf(-a[i]));
  float ss = 0.f;
#pragma unroll
  for (int i = 0; i < 16; ++i) ss += a[i] * a[i];
  ss += __shfl_xor(ss, 1); ss += __shfl_xor(ss, 2); ss += __shfl_xor(ss, 4);
  const int seg = tid >> 3;            // 0..7 q, 8..15 k, 16..31 v
  float scale = 1.f;
  if (seg < 16) {
    scale = 1.f / fmaxf(sqrtf(ss), 1e-12f);
    if (seg < 8) scale *= 0.08838834764831845f;   // HD^-0.5
  }
  ushort_t ov[16];
#pragma unroll
  for (int i = 0; i < 16; ++i) ov[i] = f2b(a[i] * scale);
  ushort_t* dst = act + (size_t)bt * CD_ + c;
  *(uint4*)(void*)dst       = *(const uint4*)&ov[0];
  *(uint4*)(void*)(dst + 8) = *(const uint4*)&ov[8];
}

// ---------------------------------------------------------------------------
__device__ __forceinline__ bf16x8 cvt8f(const float* p) {
  float4 a = *(const float4*)p;
  float4 b = *(const float4*)(p + 4);
  bf16x8 o;
  o[0] = (__bf16)a.x; o[1] = (__bf16)a.y; o[2] = (__bf16)a.z; o[3] = (__bf16)a.w;
  o[4] = (__bf16)b.x; o[5] = (__bf16)b.y; o[6] = (__bf16)b.z; o[7] = (__bf16)b.w;
  return o;
}

// ---------------------------------------------------------------------------
// k_prep: per-chunk parallel precompute. grid = 1024. act is bf16. (R15 exact)
// ---------------------------------------------------------------------------
__global__ __launch_bounds__(256, 1)
void k_prep(const ushort_t* __restrict__ act, const float* __restrict__ gB,
            const float* __restrict__ betaB,
            ushort_t* __restrict__ WkG, ushort_t* __restrict__ UlT,
            float* __restrict__ gtG,
            ushort_t* __restrict__ MTG, ushort_t* __restrict__ NTG) {
  __shared__ __bf16 Kl[64][136];
  __shared__ __bf16 AbL[64][40];
  __shared__ __bf16 AbH[32][33];
  __shared__ __bf16 Xl[64][264];
  __shared__ float gc[65], Et[65], Rt[65], bts[64], geT[64], escT[64];

  const int wg = blockIdx.x;
  const int c = wg & 31, h = (wg >> 5) & 15, b = wg >> 9;
  const int hq = h >> 1, t0 = c * 64;
  const int tid = threadIdx.x, lane = tid & 63, wave = tid >> 6;
  const int l15 = lane & 15, kcol0 = (lane >> 4) * 8, rrow = (lane >> 4) * 4;
  const size_t bhc = (size_t)wg;

  const ushort_t* baseQ = act + (size_t)b * T_ * CD_ + hq * HD_;
  const ushort_t* baseK = baseQ + KD_;

  if (tid < 64) {
    float g = gB[((size_t)b * T_ + t0 + tid) * NV_ + h];
    bts[tid] = betaB[((size_t)b * T_ + t0 + tid) * NV_ + h];
#pragma unroll
    for (int o = 1; o < 64; o <<= 1) {
      float up = __shfl_up(g, (unsigned)o);
      if (tid >= o) g += up;
    }
    gc[tid + 1] = g;
    if (tid == 0) gc[0] = 0.f;
  }
  __syncthreads();
  if (tid < 65) {
    float gm = gc[32];
    Et[tid] = __expf(gc[tid] - gm);
    Rt[tid] = __expf(gm - gc[tid]);
  }
  if (tid < 64) {
    geT[tid] = bts[tid] * __expf(gc[tid + 1]);
    escT[tid] = __expf(gc[64] - gc[tid + 1]);
    gtG[bhc * 64 + tid] = gc[tid + 1];
  }
  {
    const int t = tid >> 2, d0 = (tid & 3) * 32;
    const ushort_t* src = baseK + (size_t)(t0 + t) * CD_ + d0;
#pragma unroll
    for (int j = 0; j < 4; ++j)
      *(uint4*)&Kl[t][d0 + j * 8] = *(const uint4*)(const void*)(src + j * 8);
  }
  __syncthreads();

  // P1: Ab (strict lower, -beta*scale*KK^T) in LDS
  {
    bf16x8 kf[4];
#pragma unroll
    for (int kk = 0; kk < 4; ++kk)
      kf[kk] = *(const bf16x8*)&Kl[16 * wave + l15][kk * 32 + kcol0];
#pragma unroll
    for (int st = 0; st < 4; ++st) {
      if (st <= wave) {
        f32x4 accA = {};
#pragma unroll
        for (int kk = 0; kk < 4; ++kk) {
          bf16x8 bfr = *(const bf16x8*)&Kl[st * 16 + l15][kk * 32 + kcol0];
          accA = __builtin_amdgcn_mfma_f32_16x16x32_bf16(kf[kk], bfr, accA, 0, 0, 0);
        }
        const int scol = st * 16 + l15;
#pragma unroll
        for (int r = 0; r < 4; ++r) {
          const int t = 16 * wave + rrow + r;
          if (scol < t) {
            const float av = -bts[t] * Et[t + 1] * Rt[scol + 1] * accA[r];
            if (scol < 32) AbL[t][scol] = (__bf16)av;
            else           AbH[t - 32][scol - 32] = (__bf16)av;
          }
        }
      }
    }
  }
  __syncthreads();

  // P2: triangular solve (I+L)X = RHS, 256 threads = 256 columns (R12 scalar)
  {
    float r1[32], r2[32];
    if (tid < 128) {
      const int d = tid;
#pragma unroll
      for (int t = 0; t < 32; ++t) r1[t] = geT[t] * (float)Kl[t][d];
#pragma unroll
      for (int t = 0; t < 32; ++t) r2[t] = geT[32 + t] * (float)Kl[32 + t][d];
    } else {
      const int j = tid - 128;
      const ushort_t* vsrc = act + ((size_t)b * T_ + t0) * CD_ + 2 * KD_ + h * HD_ + j;
#pragma unroll
      for (int t = 0; t < 32; ++t) r1[t] = bts[t] * b2f(vsrc[(size_t)t * CD_]);
#pragma unroll
      for (int t = 0; t < 32; ++t) r2[t] = bts[32 + t] * b2f(vsrc[(size_t)(32 + t) * CD_]);
    }
    float u1[32];
#pragma unroll
    for (int j = 0; j < 32; ++j) {
      float a = r1[j];
#pragma unroll
      for (int i = 0; i < j; ++i) a += (float)AbL[j][i] * u1[i];
      u1[j] = a;
      Xl[j][tid] = (__bf16)a;
    }
#pragma unroll
    for (int t2 = 0; t2 < 32; ++t2) {
      float a = r2[t2];
#pragma unroll
      for (int i = 0; i < 32; ++i) a += (float)AbL[32 + t2][i] * u1[i];
      r2[t2] = a;
    }
    float u2[32];
#pragma unroll
    for (int j = 0; j < 32; ++j) {
      float a = r2[j];
#pragma unroll
      for (int i = 0; i < j; ++i) a += (float)AbH[j][i] * u2[i];
      u2[j] = a;
      Xl[32 + j][tid] = (__bf16)a;
    }
  }
  __syncthreads();

  // P3: Wk copy (negated, stride 128) + Uloc^T store (stride 64)
#pragma unroll
  for (int kck = 0; kck < 4; ++kck) {
    const int q = tid + kck * 256;
    const int t = q >> 4, d0 = (q & 15) * 8;
    uint4 v = *(const uint4*)&Xl[t][d0];
    v.x ^= 0x80008000u; v.y ^= 0x80008000u; v.z ^= 0x80008000u; v.w ^= 0x80008000u;
    *(uint4*)(void*)(WkG + bhc * (64 * 128) + (size_t)t * 128 + d0) = v;
  }
  {
    const int e = tid >> 1, t8 = (tid & 1) * 32;
#pragma unroll
    for (int i8 = 0; i8 < 4; ++i8) {
      bf16x8 tmp;
#pragma unroll
      for (int jj = 0; jj < 8; ++jj) tmp[jj] = Xl[t8 + i8 * 8 + jj][128 + e];
      *(bf16x8*)(void*)(UlT + bhc * (128 * 64) + (size_t)e * 64 + t8 + i8 * 8) = tmp;
    }
  }

  // P4: M^T and N^T via MFMA. wave owns d-row-tiles {2w, 2w+1}. (R15 exact)
  {
    const float gCe = __expf(gc[64]);
    bf16x8 afr[2][2];
#pragma unroll
    for (int dtl = 0; dtl < 2; ++dtl) {
      const int d = 16 * (2 * wave + dtl) + l15;
#pragma unroll
      for (int kt = 0; kt < 2; ++kt) {
        bf16x8 o;
#pragma unroll
        for (int j = 0; j < 8; ++j) {
          const int t = kt * 32 + kcol0 + j;
          o[j] = (__bf16)(escT[t] * (float)Kl[t][d]);
        }
        afr[dtl][kt] = o;
      }
    }
#pragma unroll
    for (int tc = 0; tc < 16; ++tc) {
      bf16x8 bfr[2];
#pragma unroll
      for (int kt = 0; kt < 2; ++kt) {
        bf16x8 o;
#pragma unroll
        for (int j = 0; j < 8; ++j) {
          const int t = kt * 32 + kcol0 + j;
          o[j] = (tc < 8) ? (__bf16)(-(float)Xl[t][16 * tc + l15])
                          : Xl[t][128 + 16 * (tc - 8) + l15];
        }
        bfr[kt] = o;
      }
#pragma unroll
      for (int dtl = 0; dtl < 2; ++dtl) {
        f32x4 acc = {};
        acc = __builtin_amdgcn_mfma_f32_16x16x32_bf16(afr[dtl][0], bfr[0], acc, 0, 0, 0);
        acc = __builtin_amdgcn_mfma_f32_16x16x32_bf16(afr[dtl][1], bfr[1], acc, 0, 0, 0);
        const int col = 16 * (tc & 7) + l15;
#pragma unroll
        for (int r = 0; r < 4; ++r) {
          const int dr = 16 * (2 * wave + dtl) + rrow + r;
          if (tc < 8)
            MTG[bhc * CHM_ + (size_t)dr * 128 + col] =
                f2b(acc[r] + ((dr == col) ? gCe : 0.f));
          else
            NTG[bhc * CHM_ + (size_t)dr * 128 + col] = f2b(acc[r]);
        }
      }
    }
  }
}

// ---------------------------------------------------------------------------
// scan body: S' = S*M + N, M/N double-buffered in LDS via global_load_lds
// (pre-swizzled source, swizzled ds_read). (R12-verified)
// ---------------------------------------------------------------------------
__device__ __forceinline__ void scan_body(
    const ushort_t* __restrict__ MTG, const ushort_t* __restrict__ NTG,
    ushort_t* __restrict__ ScG, int sb, char* smem) {
  const int eh = sb & 1, wg = sb >> 1;
  const int e0 = eh * 64;
  const int tid = threadIdx.x, lane = tid & 63, wave = tid >> 6;
  const int l15 = lane & 15, kcol0 = (lane >> 4) * 8, rrow = (lane >> 4) * 4;
  const int et = wave & 3, dh = wave >> 2;

  char* Mb0 = smem;                                      // [2][128][128] bf16 = 64 KB
  char* Nb0 = smem + 65536;                              // [2][128][64]  bf16 = 32 KB
  __bf16 (*S16)[136] = (__bf16(*)[136])(smem + 98304);   // [64][136] = 17408 B

#define SSTAGE(BUF, CN) {                                                     \
    const int cn_ = ((CN) < 32) ? (CN) : 31;                                  \
    const size_t bhcn_ = (size_t)wg * 32 + cn_;                               \
    const ushort_t* MTR_ = MTG + bhcn_ * CHM_;                                \
    const ushort_t* NTR_ = NTG + bhcn_ * CHM_;                                \
    _Pragma("unroll") for (int r_ = 0; r_ < 4; ++r_) {                        \
      const int idx_ = r_ * 512 + tid;                                        \
      const int d_ = idx_ >> 4, sl_ = idx_ & 15;                              \
      const ushort_t* src_ = MTR_ + (size_t)d_ * 128 + ((sl_ ^ (d_ & 7)) << 3); \
      __builtin_amdgcn_global_load_lds(                                       \
          (const __attribute__((address_space(1))) unsigned int*)src_,        \
          (__attribute__((address_space(3))) unsigned int*)                   \
              (Mb0 + (BUF) * 32768 + r_ * 8192 + wave * 1024), 16, 0, 0);     \
    }                                                                         \
    _Pragma("unroll") for (int r_ = 0; r_ < 2; ++r_) {                        \
      const int idx_ = r_ * 512 + tid;                                        \
      const int d_ = idx_ >> 3, sl_ = idx_ & 7;                               \
      const ushort_t* src_ = NTR_ + (size_t)d_ * 128 + e0 + ((sl_ ^ (d_ & 7)) << 3); \
      __builtin_amdgcn_global_load_lds(                                       \
          (const __attribute__((address_space(1))) unsigned int*)src_,        \
          (__attribute__((address_space(3))) unsigned int*)                   \
              (Nb0 + (BUF) * 16384 + r_ * 8192 + wave * 1024), 16, 0, 0);     \
    }                                                                         \
  }

#define MRD(BUF, ROW, KC)                                                     \
  (*(const bf16x8*)(Mb0 + (BUF) * 32768 + ((ROW) << 8) +                      \
                    ((((KC) << 1)) ^ (((ROW) & 7) << 4))))
#define NRD(BUF, DROW, EC)                                                    \
  (*(const short4v*)(Nb0 + (BUF) * 16384 + ((DROW) << 7) +                    \
                    ((((EC) << 1)) ^ (((DROW) & 7) << 4))))

  f32x4 s_acc[4] = {};   // S^T[e0+16et+rrow+r][16*(4dh+dl)+l15]
  SSTAGE(0, 0)

  for (int c = 0; c < 32; ++c) {
    const int buf = c & 1;
    ushort_t* ScR = ScG + ((size_t)wg * 32 + c) * CHM_;

    __syncthreads();                 // drains vmcnt: stage(c) landed; all waves synced
    SSTAGE(buf ^ 1, c + 1)           // issue next chunk's loads (stay in flight)

#pragma unroll
    for (int dl = 0; dl < 4; ++dl)
#pragma unroll
      for (int r = 0; r < 4; ++r)
        S16[16 * et + rrow + r][(4 * dh + dl) * 16 + l15] = (__bf16)s_acc[dl][r];
    asm volatile("s_waitcnt lgkmcnt(0)" ::: "memory");
    __builtin_amdgcn_sched_barrier(0);
    __builtin_amdgcn_s_barrier();    // S16 visible; vmcnt NOT drained
    __builtin_amdgcn_sched_barrier(0);

    // snapshot S at chunk start (fire-and-forget stores)
#pragma unroll
    for (int cc = 0; cc < 2; ++cc) {
      const int idx = tid + cc * 512;
      const int row = idx >> 4, seg = idx & 15;
      *(uint4*)(void*)(ScR + (size_t)(e0 + row) * 128 + seg * 8) =
          *(const uint4*)&S16[row][seg * 8];
    }

    f32x4 acc[4];
#pragma unroll
    for (int dl = 0; dl < 4; ++dl) {
      short4v nv = NRD(buf, 16 * (4 * dh + dl) + l15, 16 * et + rrow);
#pragma unroll
      for (int r = 0; r < 4; ++r) acc[dl][r] = b2f((ushort_t)nv[r]);
    }
#pragma unroll
    for (int kk = 0; kk < 4; ++kk) {
      bf16x8 sa = *(const bf16x8*)&S16[16 * et + l15][kk * 32 + kcol0];
#pragma unroll
      for (int dl = 0; dl < 4; ++dl) {
        bf16x8 mb = MRD(buf, 16 * (4 * dh + dl) + l15, kk * 32 + kcol0);
        acc[dl] = __builtin_amdgcn_mfma_f32_16x16x32_bf16(sa, mb, acc[dl], 0, 0, 0);
      }
    }
#pragma unroll
    for (int dl = 0; dl < 4; ++dl) s_acc[dl] = acc[dl];
  }
#undef SSTAGE
#undef MRD
#undef NRD
}

// ---------------------------------------------------------------------------
// FUSED launch: blocks 0..63 = scan, 64..191 = z-gemm tiles (independent).
// ---------------------------------------------------------------------------
__global__ __launch_bounds__(512, 2)
void k_scan_zgemm(const ushort_t* __restrict__ MTG, const ushort_t* __restrict__ NTG,
                  ushort_t* __restrict__ ScG,
                  const ushort_t* __restrict__ xB, const ushort_t* __restrict__ WzB,
                  ushort_t* __restrict__ zbuf) {
  __shared__ alignas(16) char smem[131072];
  if (blockIdx.x < 64)
    scan_body(MTG, NTG, ScG, blockIdx.x, smem);
  else
    gemm256_body<ushort_t>(xB, WzB, zbuf, B_ * T_, VD_, HID_,
                           blockIdx.x - 64, (ushort_t*)smem);
}

// ---------------------------------------------------------------------------
// k_out: fully parallel per (b,h,c): u = Ul + Wkneg@S_c; Pm recomputed from
// q,k; o = gam*Q@S_c + Pm@u; fused gated RMSNorm -> bf16 outg. grid=1024.
// ---------------------------------------------------------------------------
__global__ __launch_bounds__(256, 2)
void k_out(const ushort_t* __restrict__ act,
           const ushort_t* __restrict__ WkG, const ushort_t* __restrict__ UlT,
           const float* __restrict__ gtG,
           const ushort_t* __restrict__ ScG, const ushort_t* __restrict__ zbuf,
           const float* __restrict__ nw, ushort_t* __restrict__ outg) {
  __shared__ __bf16 S16[128][136];   // 34816 B
  __shared__ __bf16 uTl[128][72];    // 18432 B
  __shared__ __bf16 PmL[64][72];     //  9216 B
  __shared__ float Egc[65], Rgc[65], gam[64], nws[128];

  const int bhc = blockIdx.x;
  const int c = bhc & 31, h = (bhc >> 5) & 15, b = bhc >> 9;
  const int hq = h >> 1, t0g = c * 64;
  const int tid = threadIdx.x, lane = tid & 63, wave = tid >> 6;  // wave = t-tile
  const int l15 = lane & 15, kcol0 = (lane >> 4) * 8, rrow = (lane >> 4) * 4;

  const ushort_t* ScR = ScG + (size_t)bhc * CHM_;
  const ushort_t* WkR = WkG + (size_t)bhc * (64 * 128);
  const ushort_t* UlR = UlT + (size_t)bhc * (128 * 64);
  const ushort_t* actQ = act + ((size_t)b * T_ + t0g) * CD_ + hq * HD_;
  const ushort_t* actK = actQ + KD_;

#pragma unroll
  for (int cc = 0; cc < 8; ++cc) {
    const int idx = tid + cc * 256;          // 2048 x 16B chunks
    const int row = idx >> 4, seg = idx & 15;
    *(uint4*)&S16[row][seg * 8] =
        *(const uint4*)(const void*)(ScR + (size_t)row * 128 + seg * 8);
  }
  {
    const float gc32 = gtG[(size_t)bhc * 64 + 31];
    if (tid < 65) {
      const float gcv = (tid == 0) ? 0.f : gtG[(size_t)bhc * 64 + tid - 1];
      Egc[tid] = __expf(gcv - gc32);
      Rgc[tid] = __expf(gc32 - gcv);
    }
    if (tid < 64) gam[tid] = __expf(gtG[(size_t)bhc * 64 + tid]);
    if (tid < 128) nws[tid] = nw[tid];
  }
  __syncthreads();

  // q fragments (reused for Pm-compute and QS)
  bf16x8 qf[4];
#pragma unroll
  for (int kk = 0; kk < 4; ++kk)
    qf[kk] = *(const bf16x8*)(const void*)
        (actQ + (size_t)(16 * wave + l15) * CD_ + kk * 32 + kcol0);

  // u-phase: u[t][e] = Ul[t][e] + Wkneg@S ; write uTl[e][t]
  bf16x8 wa[4];
#pragma unroll
  for (int kk = 0; kk < 4; ++kk)
    wa[kk] = *(const bf16x8*)(const void*)(WkR + (size_t)(16 * wave + l15) * 128 + kk * 32 + kcol0);
  f32x4 au[8] = {};
#pragma unroll
  for (int kk = 0; kk < 4; ++kk)
#pragma unroll
    for (int jt = 0; jt < 8; ++jt) {
      bf16x8 sb = *(const bf16x8*)&S16[jt * 16 + l15][kk * 32 + kcol0];
      au[jt] = __builtin_amdgcn_mfma_f32_16x16x32_bf16(wa[kk], sb, au[jt], 0, 0, 0);
    }
#pragma unroll
  for (int jt = 0; jt < 8; ++jt) {
    short4v uv = *(const short4v*)(const void*)(UlR + (size_t)(16 * jt + l15) * 64 + wave * 16 + rrow);
#pragma unroll
    for (int r = 0; r < 4; ++r)
      uTl[16 * jt + l15][16 * wave + rrow + r] = (__bf16)(au[jt][r] + b2f((ushort_t)uv[r]));
  }

  // Pm recompute: Pm[t][s] = (s<=t) ? Egc[t+1]*Rgc[s+1]*(Q[t].K[s]) : 0
#pragma unroll
  for (int st = 0; st < 4; ++st) {
    f32x4 accP = {};
#pragma unroll
    for (int kk = 0; kk < 4; ++kk) {
      bf16x8 kb = *(const bf16x8*)(const void*)
          (actK + (size_t)(st * 16 + l15) * CD_ + kk * 32 + kcol0);
      accP = __builtin_amdgcn_mfma_f32_16x16x32_bf16(qf[kk], kb, accP, 0, 0, 0);
    }
    const int scol = st * 16 + l15;
#pragma unroll
    for (int r = 0; r < 4; ++r) {
      const int t = 16 * wave + rrow + r;
      PmL[t][scol] = (scol <= t) ? (__bf16)(Egc[t + 1] * Rgc[scol + 1] * accP[r])
                                 : (__bf16)0.f;
    }
  }
  __syncthreads();

  // o-phase + fused gated RMSNorm
  f32x4 qs[8] = {}, o2[8] = {};
#pragma unroll
  for (int kk = 0; kk < 4; ++kk)
#pragma unroll
    for (int jt = 0; jt < 8; ++jt) {
      bf16x8 sb = *(const bf16x8*)&S16[jt * 16 + l15][kk * 32 + kcol0];
      qs[jt] = __builtin_amdgcn_mfma_f32_16x16x32_bf16(qf[kk], sb, qs[jt], 0, 0, 0);
    }
#pragma unroll
  for (int ks = 0; ks < 2; ++ks) {
    bf16x8 pa = *(const bf16x8*)&PmL[16 * wave + l15][ks * 32 + kcol0];
#pragma unroll
    for (int jt = 0; jt < 8; ++jt) {
      bf16x8 ub = *(const bf16x8*)&uTl[jt * 16 + l15][ks * 32 + kcol0];
      o2[jt] = __builtin_amdgcn_mfma_f32_16x16x32_bf16(pa, ub, o2[jt], 0, 0, 0);
    }
  }
  float ov[8][4];
  float ss0 = 0.f, ss1 = 0.f, ss2 = 0.f, ss3 = 0.f;
#pragma unroll
  for (int jt = 0; jt < 8; ++jt) {
    ov[jt][0] = gam[16 * wave + rrow + 0] * qs[jt][0] + o2[jt][0];
    ov[jt][1] = gam[16 * wave + rrow + 1] * qs[jt][1] + o2[jt][1];
    ov[jt][2] = gam[16 * wave + rrow + 2] * qs[jt][2] + o2[jt][2];
    ov[jt][3] = gam[16 * wave + rrow + 3] * qs[jt][3] + o2[jt][3];
    ss0 += ov[jt][0] * ov[jt][0];
    ss1 += ov[jt][1] * ov[jt][1];
    ss2 += ov[jt][2] * ov[jt][2];
    ss3 += ov[jt][3] * ov[jt][3];
  }
#pragma unroll
  for (int m = 1; m < 16; m <<= 1) {
    ss0 += __shfl_xor(ss0, m);
    ss1 += __shfl_xor(ss1, m);
    ss2 += __shfl_xor(ss2, m);
    ss3 += __shfl_xor(ss3, m);
  }
  float rr[4];
  rr[0] = 1.f / sqrtf(ss0 * (1.f / HD_) + 1e-6f);
  rr[1] = 1.f / sqrtf(ss1 * (1.f / HD_) + 1e-6f);
  rr[2] = 1.f / sqrtf(ss2 * (1.f / HD_) + 1e-6f);
  rr[3] = 1.f / sqrtf(ss3 * (1.f / HD_) + 1e-6f);
#pragma unroll
  for (int jt = 0; jt < 8; ++jt) {
    const int e = 16 * jt + l15;
    const float wv = nws[e];
#pragma unroll
    for (int r = 0; r < 4; ++r) {
      const int t = 16 * wave + rrow + r;
      const float zf = b2f(zbuf[((size_t)b * T_ + t0g + t) * VD_ + h * HD_ + e]);
      const float g = zf / (1.f + expf(-zf));
      outg[(((size_t)b * T_ + t0g + t) * NV_ + h) * HD_ + e] =
          f2b(ov[jt][r] * rr[r] * wv * g);
    }
  }
}

// ---------------------------------------------------------------------------
extern "C" void kernel_launch(void* const* d_in, const int* in_sizes, int n_in,
                              void* d_out, int out_size, void* d_ws, size_t ws_size,
                              hipStream_t stream) {
  const float* x    = (const float*)d_in[0];
  const float* Wqkv = (const float*)d_in[1];
  const float* Wz   = (const float*)d_in[2];
  const float* Wb   = (const float*)d_in[3];
  const float* Wa   = (const float*)d_in[4];
  const float* cw   = (const float*)d_in[5];
  const float* dtb  = (const float*)d_in[6];
  const float* alog = (const float*)d_in[7];
  const float* nw   = (const float*)d_in[8];
  const float* Wout = (const float*)d_in[9];

  // ---- workspace layout: 210.5 MB total (<= proven-safe 213.4 MB) ----
  char* p = (char*)d_ws;
  ushort_t* qkv_raw = (ushort_t*)p; p += (size_t)B_ * T_ * CD_ * 2;       // 33.55 MB
  ushort_t* zbuf    = (ushort_t*)p; p += (size_t)B_ * T_ * VD_ * 2;       // 16.78 MB
  ushort_t* act     = (ushort_t*)p; p += (size_t)B_ * T_ * CD_ * 2;       // 33.55 MB (bf16)
  float*    betaB   = (float*)p;    p += (size_t)B_ * T_ * NV_ * 4;       //  0.26 MB
  float*    gBuf    = (float*)p;    p += (size_t)B_ * T_ * NV_ * 4;       //  0.26 MB
  float*    gtG     = (float*)p;    p += (size_t)1024 * 64 * 4;           //  0.26 MB
  ushort_t* xB      = (ushort_t*)p; p += (size_t)B_ * T_ * HID_ * 2;      // 16.78 MB
  ushort_t* WzB     = (ushort_t*)p; p += (size_t)VD_ * HID_ * 2;          //  8.39 MB
  ushort_t* MTG     = (ushort_t*)p; p += (size_t)1024 * CHM_ * 2;         // 33.55 MB
  ushort_t* NTG     = (ushort_t*)p; p += (size_t)1024 * CHM_ * 2;         // 33.55 MB
  ushort_t* ScG     = (ushort_t*)p; p += (size_t)1024 * CHM_ * 2;         // 33.55 MB
  // overlays:
  ushort_t* WkG   = qkv_raw;                             // 16.78 MB (post-conv)
  ushort_t* UlT   = qkv_raw + (size_t)1024 * 64 * 128;   // 16.78 MB (post-conv, exact fit)
  ushort_t* WqkvB = act;                                 // 16.78 MB (pre-conv)
  ushort_t* outg  = MTG;                                 // 16.78 MB (post-scan)
  ushort_t* WoutB = NTG;                                 //  8.39 MB (post-scan; cast moved)

  const int M = B_ * T_;  // 4096

  hipLaunchKernelGGL(k_cast_bf16, dim3(M * HID_ / 4 / 256), dim3(256), 0, stream,
                     x, xB, M * HID_ / 4);
  hipLaunchKernelGGL(k_cast_bf16, dim3(CD_ * HID_ / 4 / 256), dim3(256), 0, stream,
                     Wqkv, WqkvB, CD_ * HID_ / 4);
  hipLaunchKernelGGL(k_cast_bf16, dim3(VD_ * HID_ / 4 / 256), dim3(256), 0, stream,
                     Wz, WzB, VD_ * HID_ / 4);

  hipLaunchKernelGGL(k_gemm256<ushort_t>, dim3((M / 256) * (CD_ / 256)), dim3(512), 0, stream,
                     xB, WqkvB, qkv_raw, M, CD_, HID_);
  hipLaunchKernelGGL(k_proj_ba, dim3(M / 16), dim3(256), 0, stream,
                     x, Wb, Wa, dtb, alog, betaB, gBuf);
  hipLaunchKernelGGL(k_conv_silu_norm, dim3(M), dim3(256), 0, stream,
                     qkv_raw, cw, act);
  hipLaunchKernelGGL(k_prep, dim3(B_ * NV_ * 32), dim3(256), 0, stream,
                     act, gBuf, betaB, WkG, UlT, gtG, MTG, NTG);
  hipLaunchKernelGGL(k_scan_zgemm, dim3(64 + (M / 256) * (VD_ / 256)), dim3(512), 0, stream,
                     MTG, NTG, ScG, xB, WzB, zbuf);
  hipLaunchKernelGGL(k_cast_bf16, dim3(HID_ * VD_ / 4 / 256), dim3(256), 0, stream,
                     Wout, WoutB, HID_ * VD_ / 4);
  hipLaunchKernelGGL(k_out, dim3(B_ * NV_ * 32), dim3(256), 0, stream,
                     act, WkG, UlT, gtG, ScG, zbuf, nw, outg);
  hipLaunchKernelGGL(k_gemm256x128<float>, dim3((M / 256) * (HID_ / 128)), dim3(512), 0, stream,
                     outg, WoutB, (float*)d_out, M, HID_, VD_);
}

// Round 18
// 496.071 us; speedup vs baseline: 1.0933x; 1.0681x over previous
//
#include <hip/hip_runtime.h>
#include <cstdint>
#include <cstddef>

// GatedDeltaNet forward, MI355X/gfx950.
// R18 = R17 with ONE change: k_prep P2's middle pass (dense 32x32 @ 32x256
// cross-block correction = 1024 broadcast LDS reads + 1024 FMAs per thread)
// replaced by 8 MFMAs/wave using u1 already in LDS (Xl, bf16). Correction
// staged in Cr[32][264] bf16 (+16.9KB LDS, still 2 blocks/CU). u1/u2 serial
// passes and all other kernels R17-exact.

typedef unsigned short ushort_t;
typedef __attribute__((ext_vector_type(8))) __bf16 bf16x8;
typedef __attribute__((ext_vector_type(4))) float f32x4;
typedef __attribute__((ext_vector_type(4))) short short4v;

#define B_   2
#define T_   2048
#define HID_ 2048
#define NK_  8
#define NV_  16
#define HD_  128
#define KD_  1024
#define VD_  2048
#define CD_  4096
#define CHM_ 16384   // 128*128 elems per per-chunk matrix (MT/NT/Sc)

__device__ __forceinline__ float b2f(ushort_t u) {
  union { unsigned int i; float f; } v; v.i = ((unsigned int)u) << 16; return v.f;
}
__device__ __forceinline__ ushort_t f2b(float f) {   // RNE bf16 round
  unsigned int x = __builtin_bit_cast(unsigned int, f);
  unsigned int r = x + 0x7fffu + ((x >> 16) & 1u);
  return (ushort_t)(r >> 16);
}

// ---------------------------------------------------------------------------
// fp32 -> bf16 cast
// ---------------------------------------------------------------------------
__global__ __launch_bounds__(256)
void k_cast_bf16(const float* __restrict__ in, ushort_t* __restrict__ out, int n4) {
  const int i = blockIdx.x * 256 + threadIdx.x;
  if (i >= n4) return;
  float4 v = *(const float4*)(in + (size_t)i * 4);
  short4v o;
  o[0] = (short)f2b(v.x); o[1] = (short)f2b(v.y);
  o[2] = (short)f2b(v.z); o[3] = (short)f2b(v.w);
  *(short4v*)(out + (size_t)i * 4) = o;
}

// ---------------------------------------------------------------------------
// GEMM 256x256 body, BK=64, 8 waves, counted-vmcnt pipeline (R8-verified).
// ---------------------------------------------------------------------------
#define LPOS(BUF, OP, HALF) ((((BUF) * 2 + (OP)) * 2 + (HALF)) * 8192)

template <typename OutT>
__device__ __forceinline__ void gemm256_body(
    const ushort_t* __restrict__ A, const ushort_t* __restrict__ Bw,
    OutT* __restrict__ C, int M, int N, int K, int tile, ushort_t* lds) {
  const int tid = threadIdx.x;
  const int lane = tid & 63, wave = tid >> 6;
  const int wm = wave >> 2, wc = wave & 3;
  const int l15 = lane & 15;
  const int ks16 = (lane >> 4) * 16;
  const int r4 = (lane >> 4) * 4;
  const int nkt = K >> 6;
  const int nbx = N >> 8;
  const size_t row0 = (size_t)(tile / nbx) * 256;
  const size_t col0 = (size_t)(tile % nbx) * 256;

#define STAGE4(BUF, HALF, KT) {                                               \
    const int kt_ = ((KT) < nkt) ? (KT) : (nkt - 1);                          \
    const int kb_ = kt_ * 64 + (HALF) * 32;                                   \
    _Pragma("unroll") for (int r_ = 0; r_ < 2; ++r_) {                        \
      const int wb_ = r_ * 8192 + wave * 1024;                                \
      const int o_  = wb_ + lane * 16;                                        \
      const int row_ = o_ >> 6;                                               \
      const int src_ = (o_ & 63) ^ (((row_) & 3) << 4);                       \
      const ushort_t* ga_ = A  + (row0 + row_) * (size_t)K + kb_ + (src_ >> 1); \
      const ushort_t* gb_ = Bw + (col0 + row_) * (size_t)K + kb_ + (src_ >> 1); \
      __builtin_amdgcn_global_load_lds(                                       \
          (const __attribute__((address_space(1))) unsigned int*)ga_,         \
          (__attribute__((address_space(3))) unsigned int*)                   \
              (lds + LPOS(BUF, 0, HALF) + (wb_ >> 1)), 16, 0, 0);             \
      __builtin_amdgcn_global_load_lds(                                       \
          (const __attribute__((address_space(1))) unsigned int*)gb_,         \
          (__attribute__((address_space(3))) unsigned int*)                   \
              (lds + LPOS(BUF, 1, HALF) + (wb_ >> 1)), 16, 0, 0);             \
    }                                                                         \
  }

#define RD(BUF, OP, HALF, ROW)                                                \
  (*(const bf16x8*)((const char*)(lds + LPOS(BUF, OP, HALF)) +                \
                    ((((ROW) * 64 + ks16)) ^ (((ROW) & 3) << 4))))

  f32x4 acc[8][4] = {};
  STAGE4(0, 0, 0)
  STAGE4(0, 1, 0)
  STAGE4(1, 0, 1)

  for (int kt = 0; kt < nkt; ++kt) {
    const int cb = kt & 1, nb = cb ^ 1;
    asm volatile("s_waitcnt vmcnt(8)" ::: "memory");
    __builtin_amdgcn_s_barrier();
    {
      bf16x8 af[8], bfr[4];
#pragma unroll
      for (int mf = 0; mf < 8; ++mf) af[mf] = RD(cb, 0, 0, wm * 128 + mf * 16 + l15);
#pragma unroll
      for (int nf = 0; nf < 4; ++nf) bfr[nf] = RD(cb, 1, 0, wc * 64 + nf * 16 + l15);
      STAGE4(nb, 1, kt + 1)
      __builtin_amdgcn_s_setprio(1);
#pragma unroll
      for (int mf = 0; mf < 8; ++mf)
#pragma unroll
        for (int nf = 0; nf < 4; ++nf)
          acc[mf][nf] = __builtin_amdgcn_mfma_f32_16x16x32_bf16(af[mf], bfr[nf], acc[mf][nf], 0, 0, 0);
      __builtin_amdgcn_s_setprio(0);
    }
    asm volatile("s_waitcnt vmcnt(8)" ::: "memory");
    __builtin_amdgcn_s_barrier();
    {
      bf16x8 af[8], bfr[4];
#pragma unroll
      for (int mf = 0; mf < 8; ++mf) af[mf] = RD(cb, 0, 1, wm * 128 + mf * 16 + l15);
#pragma unroll
      for (int nf = 0; nf < 4; ++nf) bfr[nf] = RD(cb, 1, 1, wc * 64 + nf * 16 + l15);
      STAGE4(cb, 0, kt + 2)
      __builtin_amdgcn_s_setprio(1);
#pragma unroll
      for (int mf = 0; mf < 8; ++mf)
#pragma unroll
        for (int nf = 0; nf < 4; ++nf)
          acc[mf][nf] = __builtin_amdgcn_mfma_f32_16x16x32_bf16(af[mf], bfr[nf], acc[mf][nf], 0, 0, 0);
      __builtin_amdgcn_s_setprio(0);
    }
  }
#undef STAGE4
#undef RD

#pragma unroll
  for (int mf = 0; mf < 8; ++mf)
#pragma unroll
    for (int nf = 0; nf < 4; ++nf)
#pragma unroll
      for (int j = 0; j < 4; ++j) {
        const size_t row = row0 + wm * 128 + mf * 16 + r4 + j;
        const size_t col = col0 + wc * 64 + nf * 16 + l15;
        if constexpr (sizeof(OutT) == 4)
          C[row * (size_t)N + col] = acc[mf][nf][j];
        else
          C[row * (size_t)N + col] = (OutT)f2b(acc[mf][nf][j]);
      }
}

template <typename OutT>
__global__ __launch_bounds__(512, 2)
void k_gemm256(const ushort_t* __restrict__ A, const ushort_t* __restrict__ Bw,
               OutT* __restrict__ C, int M, int N, int K) {
  __shared__ alignas(16) ushort_t lds[2 * 2 * 2 * 8192];
  const int nwg = gridDim.x;
  const int q8 = nwg >> 3, r8 = nwg & 7;
  const int xcd = blockIdx.x & 7, idx8 = blockIdx.x >> 3;
  const int s = (xcd < r8) ? (xcd * (q8 + 1) + idx8)
                           : (r8 * (q8 + 1) + (xcd - r8) * q8 + idx8);
  gemm256_body<OutT>(A, Bw, C, M, N, K, s, lds);
}

// ---------------------------------------------------------------------------
// GEMM 256x128 tile (R17-verified): counted-vmcnt, 3 loads/half, vmcnt(6).
// ---------------------------------------------------------------------------
#define LPA(BUF, HALF) (((BUF) * 2 + (HALF)) * 8192)
#define LPB(BUF, HALF) (32768 + ((BUF) * 2 + (HALF)) * 4096)

template <typename OutT>
__global__ __launch_bounds__(512, 1)
void k_gemm256x128(const ushort_t* __restrict__ A, const ushort_t* __restrict__ Bw,
                   OutT* __restrict__ C, int M, int N, int K) {
  __shared__ alignas(16) ushort_t lds[49152];   // 96 KB
  const int tid = threadIdx.x;
  const int lane = tid & 63, wave = tid >> 6;
  const int wm = wave >> 1, wc = wave & 1;
  const int l15 = lane & 15;
  const int ks16 = (lane >> 4) * 16;
  const int r4 = (lane >> 4) * 4;
  const int nkt = K >> 6;
  const int nbx = N >> 7;
  const int nwg = gridDim.x;
  const int q8 = nwg >> 3, r8 = nwg & 7;
  const int xcd = blockIdx.x & 7, idx8 = blockIdx.x >> 3;
  const int s = (xcd < r8) ? (xcd * (q8 + 1) + idx8)
                           : (r8 * (q8 + 1) + (xcd - r8) * q8 + idx8);
  const size_t row0 = (size_t)(s / nbx) * 256;
  const size_t col0 = (size_t)(s % nbx) * 128;

#define STG3(BUF, HALF, KT) {                                                 \
    const int kt_ = ((KT) < nkt) ? (KT) : (nkt - 1);                          \
    const int kb_ = kt_ * 64 + (HALF) * 32;                                   \
    _Pragma("unroll") for (int r_ = 0; r_ < 2; ++r_) {                        \
      const int wb_ = r_ * 8192 + wave * 1024;                                \
      const int o_  = wb_ + lane * 16;                                        \
      const int row_ = o_ >> 6;                                               \
      const int src_ = (o_ & 63) ^ (((row_) & 3) << 4);                       \
      const ushort_t* ga_ = A + (row0 + row_) * (size_t)K + kb_ + (src_ >> 1); \
      __builtin_amdgcn_global_load_lds(                                       \
          (const __attribute__((address_space(1))) unsigned int*)ga_,         \
          (__attribute__((address_space(3))) unsigned int*)                   \
              (lds + LPA(BUF, HALF) + (wb_ >> 1)), 16, 0, 0);                 \
    }                                                                         \
    {                                                                         \
      const int wb_ = wave * 1024;                                            \
      const int o_  = wb_ + lane * 16;                                        \
      const int row_ = o_ >> 6;                                               \
      const int src_ = (o_ & 63) ^ (((row_) & 3) << 4);                       \
      const ushort_t* gb_ = Bw + (col0 + row_) * (size_t)K + kb_ + (src_ >> 1); \
      __builtin_amdgcn_global_load_lds(                                       \
          (const __attribute__((address_space(1))) unsigned int*)gb_,         \
          (__attribute__((address_space(3))) unsigned int*)                   \
              (lds + LPB(BUF, HALF) + (wb_ >> 1)), 16, 0, 0);                 \
    }                                                                         \
  }

#define RDA(BUF, HALF, ROW)                                                   \
  (*(const bf16x8*)((const char*)(lds + LPA(BUF, HALF)) +                     \
                    ((((ROW) * 64 + ks16)) ^ (((ROW) & 3) << 4))))
#define RDB(BUF, HALF, ROW)                                                   \
  (*(const bf16x8*)((const char*)(lds + LPB(BUF, HALF)) +                     \
                    ((((ROW) * 64 + ks16)) ^ (((ROW) & 3) << 4))))

  f32x4 acc[4][4] = {};
  STG3(0, 0, 0)
  STG3(0, 1, 0)
  STG3(1, 0, 1)

  for (int kt = 0; kt < nkt; ++kt) {
    const int cb = kt & 1, nb = cb ^ 1;
    asm volatile("s_waitcnt vmcnt(6)" ::: "memory");
    __builtin_amdgcn_s_barrier();
    {
      bf16x8 af[4], bfr[4];
#pragma unroll
      for (int mf = 0; mf < 4; ++mf) af[mf] = RDA(cb, 0, wm * 64 + mf * 16 + l15);
#pragma unroll
      for (int nf = 0; nf < 4; ++nf) bfr[nf] = RDB(cb, 0, wc * 64 + nf * 16 + l15);
      STG3(nb, 1, kt + 1)
      __builtin_amdgcn_s_setprio(1);
#pragma unroll
      for (int mf = 0; mf < 4; ++mf)
#pragma unroll
        for (int nf = 0; nf < 4; ++nf)
          acc[mf][nf] = __builtin_amdgcn_mfma_f32_16x16x32_bf16(af[mf], bfr[nf], acc[mf][nf], 0, 0, 0);
      __builtin_amdgcn_s_setprio(0);
    }
    asm volatile("s_waitcnt vmcnt(6)" ::: "memory");
    __builtin_amdgcn_s_barrier();
    {
      bf16x8 af[4], bfr[4];
#pragma unroll
      for (int mf = 0; mf < 4; ++mf) af[mf] = RDA(cb, 1, wm * 64 + mf * 16 + l15);
#pragma unroll
      for (int nf = 0; nf < 4; ++nf) bfr[nf] = RDB(cb, 1, wc * 64 + nf * 16 + l15);
      STG3(cb, 0, kt + 2)
      __builtin_amdgcn_s_setprio(1);
#pragma unroll
      for (int mf = 0; mf < 4; ++mf)
#pragma unroll
        for (int nf = 0; nf < 4; ++nf)
          acc[mf][nf] = __builtin_amdgcn_mfma_f32_16x16x32_bf16(af[mf], bfr[nf], acc[mf][nf], 0, 0, 0);
      __builtin_amdgcn_s_setprio(0);
    }
  }
#undef STG3
#undef RDA
#undef RDB

#pragma unroll
  for (int mf = 0; mf < 4; ++mf)
#pragma unroll
    for (int nf = 0; nf < 4; ++nf)
#pragma unroll
      for (int j = 0; j < 4; ++j) {
        const size_t row = row0 + wm * 64 + mf * 16 + r4 + j;
        const size_t col = col0 + wc * 64 + nf * 16 + l15;
        if constexpr (sizeof(OutT) == 4)
          C[row * (size_t)N + col] = acc[mf][nf][j];
        else
          C[row * (size_t)N + col] = (OutT)f2b(acc[mf][nf][j]);
      }
}

// ---------------------------------------------------------------------------
// b/a projection, W-amortized (R12-verified).
// ---------------------------------------------------------------------------
__global__ __launch_bounds__(256, 2)
void k_proj_ba(const float* __restrict__ x, const float* __restrict__ Wb,
               const float* __restrict__ Wa, const float* __restrict__ dtb,
               const float* __restrict__ alog,
               float* __restrict__ beta, float* __restrict__ gout) {
  __shared__ __bf16 Wl[16][2048];
  __shared__ float part[16][16];
  const int tid = threadIdx.x;
  const int o = tid & 15, seg = tid >> 4;
  const int bt0 = blockIdx.x * 16;

#define PROJ_PASS(WSRC, EMIT) {                                               \
    for (int i = tid; i < 8192; i += 256) {                                   \
      const int os_ = i >> 9, k4_ = i & 511;                                  \
      float4 w_ = *(const float4*)(WSRC + (size_t)os_ * HID_ + k4_ * 4);      \
      const int b_ = k4_ * 8;                                                 \
      __bf16* d_ = (__bf16*)((char*)&Wl[0][0] + os_ * 4096 +                  \
                   (((b_ & ~15) ^ ((os_ & 15) << 4)) | (b_ & 8)));            \
      d_[0] = (__bf16)w_.x; d_[1] = (__bf16)w_.y;                             \
      d_[2] = (__bf16)w_.z; d_[3] = (__bf16)w_.w;                             \
    }                                                                         \
    __syncthreads();                                                          \
    for (int rr = 0; rr < 16; ++rr) {                                         \
      const int bt = bt0 + rr;                                                \
      const float* xr = x + (size_t)bt * HID_;                                \
      float s = 0.f;                                                          \
      _Pragma("unroll") for (int j = 0; j < 16; ++j) {                        \
        const int k = seg * 128 + j * 8;                                      \
        float4 xa = *(const float4*)&xr[k];                                   \
        float4 xb = *(const float4*)&xr[k + 4];                               \
        bf16x8 wv = *(const bf16x8*)((const char*)&Wl[0][0] + o * 4096 +      \
                     ((k * 2) ^ ((o & 15) << 4)));                            \
        s += (float)wv[0]*xa.x + (float)wv[1]*xa.y + (float)wv[2]*xa.z +      \
             (float)wv[3]*xa.w + (float)wv[4]*xb.x + (float)wv[5]*xb.y +      \
             (float)wv[6]*xb.z + (float)wv[7]*xb.w;                           \
      }                                                                       \
      part[o][seg] = s;                                                       \
      __syncthreads();                                                        \
      if (tid < 16) {                                                         \
        float t_ = 0.f;                                                       \
        _Pragma("unroll") for (int i2 = 0; i2 < 16; ++i2) t_ += part[tid][i2];\
        EMIT                                                                  \
      }                                                                       \
      __syncthreads();                                                        \
    }                                                                         \
  }

  PROJ_PASS(Wb, {
    beta[(size_t)bt * NV_ + tid] = 1.f / (1.f + expf(-t_));
  })
  __syncthreads();
  PROJ_PASS(Wa, {
    float aa = t_ + dtb[tid];
    float sp = (aa > 20.f) ? aa : log1pf(expf(aa));
    gout[(size_t)bt * NV_ + tid] = -expf(alog[tid]) * sp;
  })
#undef PROJ_PASS
}

// ---------------------------------------------------------------------------
// Fused depthwise causal conv1d (K=4) + silu + l2norm(q,k). (R14-verified)
// ---------------------------------------------------------------------------
__global__ __launch_bounds__(256)
void k_conv_silu_norm(const ushort_t* __restrict__ qkv, const float* __restrict__ cw,
                      ushort_t* __restrict__ act) {
  const int bt = blockIdx.x;
  const int tid = threadIdx.x;
  const int t = bt & (T_ - 1);
  const int c = tid * 16;
  const ushort_t* rowp = qkv + (size_t)bt * CD_ + c;

  float wf[16][4];
#pragma unroll
  for (int i = 0; i < 16; ++i) {
    float4 w = *(const float4*)&cw[(c + i) * 4];
    wf[i][0] = w.x; wf[i][1] = w.y; wf[i][2] = w.z; wf[i][3] = w.w;
  }
  float a[16];
#pragma unroll
  for (int i = 0; i < 16; ++i) a[i] = 0.f;
#pragma unroll
  for (int j = 0; j < 4; ++j) {
    const int tt = t - 3 + j;
    if (tt >= 0) {
      const ushort_t* src = rowp + ((ptrdiff_t)j - 3) * CD_;
      bf16x8 v0 = *(const bf16x8*)(const void*)src;
      bf16x8 v1 = *(const bf16x8*)(const void*)(src + 8);
#pragma unroll
      for (int i = 0; i < 8; ++i) {
        a[i]     += (float)v0[i] * wf[i][j];
        a[8 + i] += (float)v1[i] * wf[8 + i][j];
      }
    }
  }
#pragma unroll
  for (int i = 0; i < 16; ++i) a[i] = a[i] / (1.f + expf(-a[i]));
  float ss = 0.f;
#pragma unroll
  for (int i = 0; i < 16; ++i) ss += a[i] * a[i];
  ss += __shfl_xor(ss, 1); ss += __shfl_xor(ss, 2); ss += __shfl_xor(ss, 4);
  const int seg = tid >> 3;
  float scale = 1.f;
  if (seg < 16) {
    scale = 1.f / fmaxf(sqrtf(ss), 1e-12f);
    if (seg < 8) scale *= 0.08838834764831845f;
  }
  ushort_t ov[16];
#pragma unroll
  for (int i = 0; i < 16; ++i) ov[i] = f2b(a[i] * scale);
  ushort_t* dst = act + (size_t)bt * CD_ + c;
  *(uint4*)(void*)dst       = *(const uint4*)&ov[0];
  *(uint4*)(void*)(dst + 8) = *(const uint4*)&ov[8];
}

// ---------------------------------------------------------------------------
__device__ __forceinline__ bf16x8 cvt8f(const float* p) {
  float4 a = *(const float4*)p;
  float4 b = *(const float4*)(p + 4);
  bf16x8 o;
  o[0] = (__bf16)a.x; o[1] = (__bf16)a.y; o[2] = (__bf16)a.z; o[3] = (__bf16)a.w;
  o[4] = (__bf16)b.x; o[5] = (__bf16)b.y; o[6] = (__bf16)b.z; o[7] = (__bf16)b.w;
  return o;
}

// ---------------------------------------------------------------------------
// k_prep: per-chunk parallel precompute. grid = 1024. act is bf16.
// R18: P2 middle pass (cross-block correction) via MFMA + Cr staging.
// ---------------------------------------------------------------------------
__global__ __launch_bounds__(256, 1)
void k_prep(const ushort_t* __restrict__ act, const float* __restrict__ gB,
            const float* __restrict__ betaB,
            ushort_t* __restrict__ WkG, ushort_t* __restrict__ UlT,
            float* __restrict__ gtG,
            ushort_t* __restrict__ MTG, ushort_t* __restrict__ NTG) {
  __shared__ __bf16 Kl[64][136];
  __shared__ __bf16 AbL[64][40];
  __shared__ __bf16 AbH[32][33];
  __shared__ __bf16 Xl[64][264];
  __shared__ alignas(16) __bf16 Cr[32][264];   // 16.9 KB: MFMA correction
  __shared__ float gc[65], Et[65], Rt[65], bts[64], geT[64], escT[64];

  const int wg = blockIdx.x;
  const int c = wg & 31, h = (wg >> 5) & 15, b = wg >> 9;
  const int hq = h >> 1, t0 = c * 64;
  const int tid = threadIdx.x, lane = tid & 63, wave = tid >> 6;
  const int l15 = lane & 15, kcol0 = (lane >> 4) * 8, rrow = (lane >> 4) * 4;
  const size_t bhc = (size_t)wg;

  const ushort_t* baseQ = act + (size_t)b * T_ * CD_ + hq * HD_;
  const ushort_t* baseK = baseQ + KD_;

  if (tid < 64) {
    float g = gB[((size_t)b * T_ + t0 + tid) * NV_ + h];
    bts[tid] = betaB[((size_t)b * T_ + t0 + tid) * NV_ + h];
#pragma unroll
    for (int o = 1; o < 64; o <<= 1) {
      float up = __shfl_up(g, (unsigned)o);
      if (tid >= o) g += up;
    }
    gc[tid + 1] = g;
    if (tid == 0) gc[0] = 0.f;
  }
  __syncthreads();
  if (tid < 65) {
    float gm = gc[32];
    Et[tid] = __expf(gc[tid] - gm);
    Rt[tid] = __expf(gm - gc[tid]);
  }
  if (tid < 64) {
    geT[tid] = bts[tid] * __expf(gc[tid + 1]);
    escT[tid] = __expf(gc[64] - gc[tid + 1]);
    gtG[bhc * 64 + tid] = gc[tid + 1];
  }
  {
    const int t = tid >> 2, d0 = (tid & 3) * 32;
    const ushort_t* src = baseK + (size_t)(t0 + t) * CD_ + d0;
#pragma unroll
    for (int j = 0; j < 4; ++j)
      *(uint4*)&Kl[t][d0 + j * 8] = *(const uint4*)(const void*)(src + j * 8);
  }
  __syncthreads();

  // P1: Ab (strict lower, -beta*scale*KK^T) in LDS
  {
    bf16x8 kf[4];
#pragma unroll
    for (int kk = 0; kk < 4; ++kk)
      kf[kk] = *(const bf16x8*)&Kl[16 * wave + l15][kk * 32 + kcol0];
#pragma unroll
    for (int st = 0; st < 4; ++st) {
      if (st <= wave) {
        f32x4 accA = {};
#pragma unroll
        for (int kk = 0; kk < 4; ++kk) {
          bf16x8 bfr = *(const bf16x8*)&Kl[st * 16 + l15][kk * 32 + kcol0];
          accA = __builtin_amdgcn_mfma_f32_16x16x32_bf16(kf[kk], bfr, accA, 0, 0, 0);
        }
        const int scol = st * 16 + l15;
#pragma unroll
        for (int r = 0; r < 4; ++r) {
          const int t = 16 * wave + rrow + r;
          if (scol < t) {
            const float av = -bts[t] * Et[t + 1] * Rt[scol + 1] * accA[r];
            if (scol < 32) AbL[t][scol] = (__bf16)av;
            else           AbH[t - 32][scol - 32] = (__bf16)av;
          }
        }
      }
    }
  }
  __syncthreads();

  // P2: triangular solve (I+L)X = RHS, 256 threads = 256 columns.
  // u1 pass scalar (R12); middle pass via MFMA (R18); u2 pass scalar.
  {
    float r1[32], r2[32];
    if (tid < 128) {
      const int d = tid;
#pragma unroll
      for (int t = 0; t < 32; ++t) r1[t] = geT[t] * (float)Kl[t][d];
#pragma unroll
      for (int t = 0; t < 32; ++t) r2[t] = geT[32 + t] * (float)Kl[32 + t][d];
    } else {
      const int j = tid - 128;
      const ushort_t* vsrc = act + ((size_t)b * T_ + t0) * CD_ + 2 * KD_ + h * HD_ + j;
#pragma unroll
      for (int t = 0; t < 32; ++t) r1[t] = bts[t] * b2f(vsrc[(size_t)t * CD_]);
#pragma unroll
      for (int t = 0; t < 32; ++t) r2[t] = bts[32 + t] * b2f(vsrc[(size_t)(32 + t) * CD_]);
    }
    float u1[32];
#pragma unroll
    for (int j = 0; j < 32; ++j) {
      float a = r1[j];
#pragma unroll
      for (int i = 0; i < j; ++i) a += (float)AbL[j][i] * u1[i];
      u1[j] = a;
      Xl[j][tid] = (__bf16)a;
    }
    __syncthreads();   // all u1 columns visible in Xl

    // middle pass: Cr = AbL[32:64][0:32] @ U1  (U1 from Xl, bf16)
    {
#pragma unroll
      for (int ct4 = 0; ct4 < 4; ++ct4) {
        const int ct = wave * 4 + ct4;
#pragma unroll
        for (int rt = 0; rt < 2; ++rt) {
          bf16x8 afr2 = *(const bf16x8*)&AbL[32 + 16 * rt + l15][kcol0];
          bf16x8 bfr2;
#pragma unroll
          for (int j = 0; j < 8; ++j) bfr2[j] = Xl[kcol0 + j][16 * ct + l15];
          f32x4 acc2 = {};
          acc2 = __builtin_amdgcn_mfma_f32_16x16x32_bf16(afr2, bfr2, acc2, 0, 0, 0);
#pragma unroll
          for (int r = 0; r < 4; ++r)
            Cr[16 * rt + rrow + r][16 * ct + l15] = (__bf16)acc2[r];
        }
      }
    }
    __syncthreads();   // Cr visible

    float u2[32];
#pragma unroll
    for (int j = 0; j < 32; ++j) {
      float a = r2[j] + (float)Cr[j][tid];
#pragma unroll
      for (int i = 0; i < j; ++i) a += (float)AbH[j][i] * u2[i];
      u2[j] = a;
      Xl[32 + j][tid] = (__bf16)a;
    }
  }
  __syncthreads();

  // P3: Wk copy (negated, stride 128) + Uloc^T store (stride 64)
#pragma unroll
  for (int kck = 0; kck < 4; ++kck) {
    const int q = tid + kck * 256;
    const int t = q >> 4, d0 = (q & 15) * 8;
    uint4 v = *(const uint4*)&Xl[t][d0];
    v.x ^= 0x80008000u; v.y ^= 0x80008000u; v.z ^= 0x80008000u; v.w ^= 0x80008000u;
    *(uint4*)(void*)(WkG + bhc * (64 * 128) + (size_t)t * 128 + d0) = v;
  }
  {
    const int e = tid >> 1, t8 = (tid & 1) * 32;
#pragma unroll
    for (int i8 = 0; i8 < 4; ++i8) {
      bf16x8 tmp;
#pragma unroll
      for (int jj = 0; jj < 8; ++jj) tmp[jj] = Xl[t8 + i8 * 8 + jj][128 + e];
      *(bf16x8*)(void*)(UlT + bhc * (128 * 64) + (size_t)e * 64 + t8 + i8 * 8) = tmp;
    }
  }

  // P4: M^T and N^T via MFMA. wave owns d-row-tiles {2w, 2w+1}. (R15 exact)
  {
    const float gCe = __expf(gc[64]);
    bf16x8 afr[2][2];
#pragma unroll
    for (int dtl = 0; dtl < 2; ++dtl) {
      const int d = 16 * (2 * wave + dtl) + l15;
#pragma unroll
      for (int kt = 0; kt < 2; ++kt) {
        bf16x8 o;
#pragma unroll
        for (int j = 0; j < 8; ++j) {
          const int t = kt * 32 + kcol0 + j;
          o[j] = (__bf16)(escT[t] * (float)Kl[t][d]);
        }
        afr[dtl][kt] = o;
      }
    }
#pragma unroll
    for (int tc = 0; tc < 16; ++tc) {
      bf16x8 bfr[2];
#pragma unroll
      for (int kt = 0; kt < 2; ++kt) {
        bf16x8 o;
#pragma unroll
        for (int j = 0; j < 8; ++j) {
          const int t = kt * 32 + kcol0 + j;
          o[j] = (tc < 8) ? (__bf16)(-(float)Xl[t][16 * tc + l15])
                          : Xl[t][128 + 16 * (tc - 8) + l15];
        }
        bfr[kt] = o;
      }
#pragma unroll
      for (int dtl = 0; dtl < 2; ++dtl) {
        f32x4 acc = {};
        acc = __builtin_amdgcn_mfma_f32_16x16x32_bf16(afr[dtl][0], bfr[0], acc, 0, 0, 0);
        acc = __builtin_amdgcn_mfma_f32_16x16x32_bf16(afr[dtl][1], bfr[1], acc, 0, 0, 0);
        const int col = 16 * (tc & 7) + l15;
#pragma unroll
        for (int r = 0; r < 4; ++r) {
          const int dr = 16 * (2 * wave + dtl) + rrow + r;
          if (tc < 8)
            MTG[bhc * CHM_ + (size_t)dr * 128 + col] =
                f2b(acc[r] + ((dr == col) ? gCe : 0.f));
          else
            NTG[bhc * CHM_ + (size_t)dr * 128 + col] = f2b(acc[r]);
        }
      }
    }
  }
}

// ---------------------------------------------------------------------------
// scan body: S' = S*M + N, M/N double-buffered in LDS via global_load_lds
// (pre-swizzled source, swizzled ds_read). (R12-verified)
// ---------------------------------------------------------------------------
__device__ __forceinline__ void scan_body(
    const ushort_t* __restrict__ MTG, const ushort_t* __restrict__ NTG,
    ushort_t* __restrict__ ScG, int sb, char* smem) {
  const int eh = sb & 1, wg = sb >> 1;
  const int e0 = eh * 64;
  const int tid = threadIdx.x, lane = tid & 63, wave = tid >> 6;
  const int l15 = lane & 15, kcol0 = (lane >> 4) * 8, rrow = (lane >> 4) * 4;
  const int et = wave & 3, dh = wave >> 2;

  char* Mb0 = smem;                                      // [2][128][128] bf16 = 64 KB
  char* Nb0 = smem + 65536;                              // [2][128][64]  bf16 = 32 KB
  __bf16 (*S16)[136] = (__bf16(*)[136])(smem + 98304);   // [64][136] = 17408 B

#define SSTAGE(BUF, CN) {                                                     \
    const int cn_ = ((CN) < 32) ? (CN) : 31;                                  \
    const size_t bhcn_ = (size_t)wg * 32 + cn_;                               \
    const ushort_t* MTR_ = MTG + bhcn_ * CHM_;                                \
    const ushort_t* NTR_ = NTG + bhcn_ * CHM_;                                \
    _Pragma("unroll") for (int r_ = 0; r_ < 4; ++r_) {                        \
      const int idx_ = r_ * 512 + tid;                                        \
      const int d_ = idx_ >> 4, sl_ = idx_ & 15;                              \
      const ushort_t* src_ = MTR_ + (size_t)d_ * 128 + ((sl_ ^ (d_ & 7)) << 3); \
      __builtin_amdgcn_global_load_lds(                                       \
          (const __attribute__((address_space(1))) unsigned int*)src_,        \
          (__attribute__((address_space(3))) unsigned int*)                   \
              (Mb0 + (BUF) * 32768 + r_ * 8192 + wave * 1024), 16, 0, 0);     \
    }                                                                         \
    _Pragma("unroll") for (int r_ = 0; r_ < 2; ++r_) {                        \
      const int idx_ = r_ * 512 + tid;                                        \
      const int d_ = idx_ >> 3, sl_ = idx_ & 7;                               \
      const ushort_t* src_ = NTR_ + (size_t)d_ * 128 + e0 + ((sl_ ^ (d_ & 7)) << 3); \
      __builtin_amdgcn_global_load_lds(                                       \
          (const __attribute__((address_space(1))) unsigned int*)src_,        \
          (__attribute__((address_space(3))) unsigned int*)                   \
              (Nb0 + (BUF) * 16384 + r_ * 8192 + wave * 1024), 16, 0, 0);     \
    }                                                                         \
  }

#define MRD(BUF, ROW, KC)                                                     \
  (*(const bf16x8*)(Mb0 + (BUF) * 32768 + ((ROW) << 8) +                      \
                    ((((KC) << 1)) ^ (((ROW) & 7) << 4))))
#define NRD(BUF, DROW, EC)                                                    \
  (*(const short4v*)(Nb0 + (BUF) * 16384 + ((DROW) << 7) +                    \
                    ((((EC) << 1)) ^ (((DROW) & 7) << 4))))

  f32x4 s_acc[4] = {};   // S^T[e0+16et+rrow+r][16*(4dh+dl)+l15]
  SSTAGE(0, 0)

  for (int c = 0; c < 32; ++c) {
    const int buf = c & 1;
    ushort_t* ScR = ScG + ((size_t)wg * 32 + c) * CHM_;

    __syncthreads();
    SSTAGE(buf ^ 1, c + 1)

#pragma unroll
    for (int dl = 0; dl < 4; ++dl)
#pragma unroll
      for (int r = 0; r < 4; ++r)
        S16[16 * et + rrow + r][(4 * dh + dl) * 16 + l15] = (__bf16)s_acc[dl][r];
    asm volatile("s_waitcnt lgkmcnt(0)" ::: "memory");
    __builtin_amdgcn_sched_barrier(0);
    __builtin_amdgcn_s_barrier();
    __builtin_amdgcn_sched_barrier(0);

#pragma unroll
    for (int cc = 0; cc < 2; ++cc) {
      const int idx = tid + cc * 512;
      const int row = idx >> 4, seg = idx & 15;
      *(uint4*)(void*)(ScR + (size_t)(e0 + row) * 128 + seg * 8) =
          *(const uint4*)&S16[row][seg * 8];
    }

    f32x4 acc[4];
#pragma unroll
    for (int dl = 0; dl < 4; ++dl) {
      short4v nv = NRD(buf, 16 * (4 * dh + dl) + l15, 16 * et + rrow);
#pragma unroll
      for (int r = 0; r < 4; ++r) acc[dl][r] = b2f((ushort_t)nv[r]);
    }
#pragma unroll
    for (int kk = 0; kk < 4; ++kk) {
      bf16x8 sa = *(const bf16x8*)&S16[16 * et + l15][kk * 32 + kcol0];
#pragma unroll
      for (int dl = 0; dl < 4; ++dl) {
        bf16x8 mb = MRD(buf, 16 * (4 * dh + dl) + l15, kk * 32 + kcol0);
        acc[dl] = __builtin_amdgcn_mfma_f32_16x16x32_bf16(sa, mb, acc[dl], 0, 0, 0);
      }
    }
#pragma unroll
    for (int dl = 0; dl < 4; ++dl) s_acc[dl] = acc[dl];
  }
#undef SSTAGE
#undef MRD
#undef NRD
}

// ---------------------------------------------------------------------------
// FUSED launch: blocks 0..63 = scan, 64..191 = z-gemm tiles (independent).
// ---------------------------------------------------------------------------
__global__ __launch_bounds__(512, 2)
void k_scan_zgemm(const ushort_t* __restrict__ MTG, const ushort_t* __restrict__ NTG,
                  ushort_t* __restrict__ ScG,
                  const ushort_t* __restrict__ xB, const ushort_t* __restrict__ WzB,
                  ushort_t* __restrict__ zbuf) {
  __shared__ alignas(16) char smem[131072];
  if (blockIdx.x < 64)
    scan_body(MTG, NTG, ScG, blockIdx.x, smem);
  else
    gemm256_body<ushort_t>(xB, WzB, zbuf, B_ * T_, VD_, HID_,
                           blockIdx.x - 64, (ushort_t*)smem);
}

// ---------------------------------------------------------------------------
// k_out: fully parallel per (b,h,c): u = Ul + Wkneg@S_c; Pm recomputed from
// q,k; o = gam*Q@S_c + Pm@u; fused gated RMSNorm -> bf16 outg. grid=1024.
// ---------------------------------------------------------------------------
__global__ __launch_bounds__(256, 2)
void k_out(const ushort_t* __restrict__ act,
           const ushort_t* __restrict__ WkG, const ushort_t* __restrict__ UlT,
           const float* __restrict__ gtG,
           const ushort_t* __restrict__ ScG, const ushort_t* __restrict__ zbuf,
           const float* __restrict__ nw, ushort_t* __restrict__ outg) {
  __shared__ __bf16 S16[128][136];
  __shared__ __bf16 uTl[128][72];
  __shared__ __bf16 PmL[64][72];
  __shared__ float Egc[65], Rgc[65], gam[64], nws[128];

  const int bhc = blockIdx.x;
  const int c = bhc & 31, h = (bhc >> 5) & 15, b = bhc >> 9;
  const int hq = h >> 1, t0g = c * 64;
  const int tid = threadIdx.x, lane = tid & 63, wave = tid >> 6;
  const int l15 = lane & 15, kcol0 = (lane >> 4) * 8, rrow = (lane >> 4) * 4;

  const ushort_t* ScR = ScG + (size_t)bhc * CHM_;
  const ushort_t* WkR = WkG + (size_t)bhc * (64 * 128);
  const ushort_t* UlR = UlT + (size_t)bhc * (128 * 64);
  const ushort_t* actQ = act + ((size_t)b * T_ + t0g) * CD_ + hq * HD_;
  const ushort_t* actK = actQ + KD_;

#pragma unroll
  for (int cc = 0; cc < 8; ++cc) {
    const int idx = tid + cc * 256;
    const int row = idx >> 4, seg = idx & 15;
    *(uint4*)&S16[row][seg * 8] =
        *(const uint4*)(const void*)(ScR + (size_t)row * 128 + seg * 8);
  }
  {
    const float gc32 = gtG[(size_t)bhc * 64 + 31];
    if (tid < 65) {
      const float gcv = (tid == 0) ? 0.f : gtG[(size_t)bhc * 64 + tid - 1];
      Egc[tid] = __expf(gcv - gc32);
      Rgc[tid] = __expf(gc32 - gcv);
    }
    if (tid < 64) gam[tid] = __expf(gtG[(size_t)bhc * 64 + tid]);
    if (tid < 128) nws[tid] = nw[tid];
  }
  __syncthreads();

  bf16x8 qf[4];
#pragma unroll
  for (int kk = 0; kk < 4; ++kk)
    qf[kk] = *(const bf16x8*)(const void*)
        (actQ + (size_t)(16 * wave + l15) * CD_ + kk * 32 + kcol0);

  bf16x8 wa[4];
#pragma unroll
  for (int kk = 0; kk < 4; ++kk)
    wa[kk] = *(const bf16x8*)(const void*)(WkR + (size_t)(16 * wave + l15) * 128 + kk * 32 + kcol0);
  f32x4 au[8] = {};
#pragma unroll
  for (int kk = 0; kk < 4; ++kk)
#pragma unroll
    for (int jt = 0; jt < 8; ++jt) {
      bf16x8 sb = *(const bf16x8*)&S16[jt * 16 + l15][kk * 32 + kcol0];
      au[jt] = __builtin_amdgcn_mfma_f32_16x16x32_bf16(wa[kk], sb, au[jt], 0, 0, 0);
    }
#pragma unroll
  for (int jt = 0; jt < 8; ++jt) {
    short4v uv = *(const short4v*)(const void*)(UlR + (size_t)(16 * jt + l15) * 64 + wave * 16 + rrow);
#pragma unroll
    for (int r = 0; r < 4; ++r)
      uTl[16 * jt + l15][16 * wave + rrow + r] = (__bf16)(au[jt][r] + b2f((ushort_t)uv[r]));
  }

#pragma unroll
  for (int st = 0; st < 4; ++st) {
    f32x4 accP = {};
#pragma unroll
    for (int kk = 0; kk < 4; ++kk) {
      bf16x8 kb = *(const bf16x8*)(const void*)
          (actK + (size_t)(st * 16 + l15) * CD_ + kk * 32 + kcol0);
      accP = __builtin_amdgcn_mfma_f32_16x16x32_bf16(qf[kk], kb, accP, 0, 0, 0);
    }
    const int scol = st * 16 + l15;
#pragma unroll
    for (int r = 0; r < 4; ++r) {
      const int t = 16 * wave + rrow + r;
      PmL[t][scol] = (scol <= t) ? (__bf16)(Egc[t + 1] * Rgc[scol + 1] * accP[r])
                                 : (__bf16)0.f;
    }
  }
  __syncthreads();

  f32x4 qs[8] = {}, o2[8] = {};
#pragma unroll
  for (int kk = 0; kk < 4; ++kk)
#pragma unroll
    for (int jt = 0; jt < 8; ++jt) {
      bf16x8 sb = *(const bf16x8*)&S16[jt * 16 + l15][kk * 32 + kcol0];
      qs[jt] = __builtin_amdgcn_mfma_f32_16x16x32_bf16(qf[kk], sb, qs[jt], 0, 0, 0);
    }
#pragma unroll
  for (int ks = 0; ks < 2; ++ks) {
    bf16x8 pa = *(const bf16x8*)&PmL[16 * wave + l15][ks * 32 + kcol0];
#pragma unroll
    for (int jt = 0; jt < 8; ++jt) {
      bf16x8 ub = *(const bf16x8*)&uTl[jt * 16 + l15][ks * 32 + kcol0];
      o2[jt] = __builtin_amdgcn_mfma_f32_16x16x32_bf16(pa, ub, o2[jt], 0, 0, 0);
    }
  }
  float ov[8][4];
  float ss0 = 0.f, ss1 = 0.f, ss2 = 0.f, ss3 = 0.f;
#pragma unroll
  for (int jt = 0; jt < 8; ++jt) {
    ov[jt][0] = gam[16 * wave + rrow + 0] * qs[jt][0] + o2[jt][0];
    ov[jt][1] = gam[16 * wave + rrow + 1] * qs[jt][1] + o2[jt][1];
    ov[jt][2] = gam[16 * wave + rrow + 2] * qs[jt][2] + o2[jt][2];
    ov[jt][3] = gam[16 * wave + rrow + 3] * qs[jt][3] + o2[jt][3];
    ss0 += ov[jt][0] * ov[jt][0];
    ss1 += ov[jt][1] * ov[jt][1];
    ss2 += ov[jt][2] * ov[jt][2];
    ss3 += ov[jt][3] * ov[jt][3];
  }
#pragma unroll
  for (int m = 1; m < 16; m <<= 1) {
    ss0 += __shfl_xor(ss0, m);
    ss1 += __shfl_xor(ss1, m);
    ss2 += __shfl_xor(ss2, m);
    ss3 += __shfl_xor(ss3, m);
  }
  float rr[4];
  rr[0] = 1.f / sqrtf(ss0 * (1.f / HD_) + 1e-6f);
  rr[1] = 1.f / sqrtf(ss1 * (1.f / HD_) + 1e-6f);
  rr[2] = 1.f / sqrtf(ss2 * (1.f / HD_) + 1e-6f);
  rr[3] = 1.f / sqrtf(ss3 * (1.f / HD_) + 1e-6f);
#pragma unroll
  for (int jt = 0; jt < 8; ++jt) {
    const int e = 16 * jt + l15;
    const float wv = nws[e];
#pragma unroll
    for (int r = 0; r < 4; ++r) {
      const int t = 16 * wave + rrow + r;
      const float zf = b2f(zbuf[((size_t)b * T_ + t0g + t) * VD_ + h * HD_ + e]);
      const float g = zf / (1.f + expf(-zf));
      outg[(((size_t)b * T_ + t0g + t) * NV_ + h) * HD_ + e] =
          f2b(ov[jt][r] * rr[r] * wv * g);
    }
  }
}

// ---------------------------------------------------------------------------
extern "C" void kernel_launch(void* const* d_in, const int* in_sizes, int n_in,
                              void* d_out, int out_size, void* d_ws, size_t ws_size,
                              hipStream_t stream) {
  const float* x    = (const float*)d_in[0];
  const float* Wqkv = (const float*)d_in[1];
  const float* Wz   = (const float*)d_in[2];
  const float* Wb   = (const float*)d_in[3];
  const float* Wa   = (const float*)d_in[4];
  const float* cw   = (const float*)d_in[5];
  const float* dtb  = (const float*)d_in[6];
  const float* alog = (const float*)d_in[7];
  const float* nw   = (const float*)d_in[8];
  const float* Wout = (const float*)d_in[9];

  // ---- workspace layout: 210.5 MB total (<= proven-safe 213.4 MB) ----
  char* p = (char*)d_ws;
  ushort_t* qkv_raw = (ushort_t*)p; p += (size_t)B_ * T_ * CD_ * 2;       // 33.55 MB
  ushort_t* zbuf    = (ushort_t*)p; p += (size_t)B_ * T_ * VD_ * 2;       // 16.78 MB
  ushort_t* act     = (ushort_t*)p; p += (size_t)B_ * T_ * CD_ * 2;       // 33.55 MB (bf16)
  float*    betaB   = (float*)p;    p += (size_t)B_ * T_ * NV_ * 4;       //  0.26 MB
  float*    gBuf    = (float*)p;    p += (size_t)B_ * T_ * NV_ * 4;       //  0.26 MB
  float*    gtG     = (float*)p;    p += (size_t)1024 * 64 * 4;           //  0.26 MB
  ushort_t* xB      = (ushort_t*)p; p += (size_t)B_ * T_ * HID_ * 2;      // 16.78 MB
  ushort_t* WzB     = (ushort_t*)p; p += (size_t)VD_ * HID_ * 2;          //  8.39 MB
  ushort_t* MTG     = (ushort_t*)p; p += (size_t)1024 * CHM_ * 2;         // 33.55 MB
  ushort_t* NTG     = (ushort_t*)p; p += (size_t)1024 * CHM_ * 2;         // 33.55 MB
  ushort_t* ScG     = (ushort_t*)p; p += (size_t)1024 * CHM_ * 2;         // 33.55 MB
  // overlays:
  ushort_t* WkG   = qkv_raw;                             // 16.78 MB (post-conv)
  ushort_t* UlT   = qkv_raw + (size_t)1024 * 64 * 128;   // 16.78 MB (post-conv, exact fit)
  ushort_t* WqkvB = act;                                 // 16.78 MB (pre-conv)
  ushort_t* outg  = MTG;                                 // 16.78 MB (post-scan)
  ushort_t* WoutB = NTG;                                 //  8.39 MB (post-scan; cast moved)

  const int M = B_ * T_;  // 4096

  hipLaunchKernelGGL(k_cast_bf16, dim3(M * HID_ / 4 / 256), dim3(256), 0, stream,
                     x, xB, M * HID_ / 4);
  hipLaunchKernelGGL(k_cast_bf16, dim3(CD_ * HID_ / 4 / 256), dim3(256), 0, stream,
                     Wqkv, WqkvB, CD_ * HID_ / 4);
  hipLaunchKernelGGL(k_cast_bf16, dim3(VD_ * HID_ / 4 / 256), dim3(256), 0, stream,
                     Wz, WzB, VD_ * HID_ / 4);

  hipLaunchKernelGGL(k_gemm256<ushort_t>, dim3((M / 256) * (CD_ / 256)), dim3(512), 0, stream,
                     xB, WqkvB, qkv_raw, M, CD_, HID_);
  hipLaunchKernelGGL(k_proj_ba, dim3(M / 16), dim3(256), 0, stream,
                     x, Wb, Wa, dtb, alog, betaB, gBuf);
  hipLaunchKernelGGL(k_conv_silu_norm, dim3(M), dim3(256), 0, stream,
                     qkv_raw, cw, act);
  hipLaunchKernelGGL(k_prep, dim3(B_ * NV_ * 32), dim3(256), 0, stream,
                     act, gBuf, betaB, WkG, UlT, gtG, MTG, NTG);
  hipLaunchKernelGGL(k_scan_zgemm, dim3(64 + (M / 256) * (VD_ / 256)), dim3(512), 0, stream,
                     MTG, NTG, ScG, xB, WzB, zbuf);
  hipLaunchKernelGGL(k_cast_bf16, dim3(HID_ * VD_ / 4 / 256), dim3(256), 0, stream,
                     Wout, WoutB, HID_ * VD_ / 4);
  hipLaunchKernelGGL(k_out, dim3(B_ * NV_ * 32), dim3(256), 0, stream,
                     act, WkG, UlT, gtG, ScG, zbuf, nw, outg);
  hipLaunchKernelGGL(k_gemm256x128<float>, dim3((M / 256) * (HID_ / 128)), dim3(512), 0, stream,
                     outg, WoutB, (float*)d_out, M, HID_, VD_);
}

// Round 19
// 476.227 us; speedup vs baseline: 1.1389x; 1.0417x over previous
//
#include <hip/hip_runtime.h>
#include <cstdint>
#include <cstddef>

// GatedDeltaNet forward, MI355X/gfx950.
// R19 = R18 with (a) k_prep P2 solve made block-16 recursive: 4 scalar
// 16-solves + 3 MFMA cross-block corrections (R18-validated pattern, one
// level deeper; zero-padded K in REGISTERS on both operands); (b) the three
// input casts merged into one k_cast3 launch.

typedef unsigned short ushort_t;
typedef __attribute__((ext_vector_type(8))) __bf16 bf16x8;
typedef __attribute__((ext_vector_type(4))) float f32x4;
typedef __attribute__((ext_vector_type(4))) short short4v;

#define B_   2
#define T_   2048
#define HID_ 2048
#define NK_  8
#define NV_  16
#define HD_  128
#define KD_  1024
#define VD_  2048
#define CD_  4096
#define CHM_ 16384   // 128*128 elems per per-chunk matrix (MT/NT/Sc)

__device__ __forceinline__ float b2f(ushort_t u) {
  union { unsigned int i; float f; } v; v.i = ((unsigned int)u) << 16; return v.f;
}
__device__ __forceinline__ ushort_t f2b(float f) {   // RNE bf16 round
  unsigned int x = __builtin_bit_cast(unsigned int, f);
  unsigned int r = x + 0x7fffu + ((x >> 16) & 1u);
  return (ushort_t)(r >> 16);
}

// ---------------------------------------------------------------------------
// fp32 -> bf16 casts: single kernel, three (src,dst) ranges
// ---------------------------------------------------------------------------
__global__ __launch_bounds__(256)
void k_cast3(const float* __restrict__ s0, ushort_t* __restrict__ d0, int n0,
             const float* __restrict__ s1, ushort_t* __restrict__ d1, int n1,
             const float* __restrict__ s2, ushort_t* __restrict__ d2, int n2) {
  int i = blockIdx.x * 256 + threadIdx.x;
  const float* s; ushort_t* d;
  if (i < n0) { s = s0; d = d0; }
  else if (i < n0 + n1) { i -= n0; s = s1; d = d1; }
  else { i -= n0 + n1; if (i >= n2) return; s = s2; d = d2; }
  float4 v = *(const float4*)(s + (size_t)i * 4);
  short4v o;
  o[0] = (short)f2b(v.x); o[1] = (short)f2b(v.y);
  o[2] = (short)f2b(v.z); o[3] = (short)f2b(v.w);
  *(short4v*)(d + (size_t)i * 4) = o;
}

__global__ __launch_bounds__(256)
void k_cast_bf16(const float* __restrict__ in, ushort_t* __restrict__ out, int n4) {
  const int i = blockIdx.x * 256 + threadIdx.x;
  if (i >= n4) return;
  float4 v = *(const float4*)(in + (size_t)i * 4);
  short4v o;
  o[0] = (short)f2b(v.x); o[1] = (short)f2b(v.y);
  o[2] = (short)f2b(v.z); o[3] = (short)f2b(v.w);
  *(short4v*)(out + (size_t)i * 4) = o;
}

// ---------------------------------------------------------------------------
// GEMM 256x256 body, BK=64, 8 waves, counted-vmcnt pipeline (R8-verified).
// ---------------------------------------------------------------------------
#define LPOS(BUF, OP, HALF) ((((BUF) * 2 + (OP)) * 2 + (HALF)) * 8192)

template <typename OutT>
__device__ __forceinline__ void gemm256_body(
    const ushort_t* __restrict__ A, const ushort_t* __restrict__ Bw,
    OutT* __restrict__ C, int M, int N, int K, int tile, ushort_t* lds) {
  const int tid = threadIdx.x;
  const int lane = tid & 63, wave = tid >> 6;
  const int wm = wave >> 2, wc = wave & 3;
  const int l15 = lane & 15;
  const int ks16 = (lane >> 4) * 16;
  const int r4 = (lane >> 4) * 4;
  const int nkt = K >> 6;
  const int nbx = N >> 8;
  const size_t row0 = (size_t)(tile / nbx) * 256;
  const size_t col0 = (size_t)(tile % nbx) * 256;

#define STAGE4(BUF, HALF, KT) {                                               \
    const int kt_ = ((KT) < nkt) ? (KT) : (nkt - 1);                          \
    const int kb_ = kt_ * 64 + (HALF) * 32;                                   \
    _Pragma("unroll") for (int r_ = 0; r_ < 2; ++r_) {                        \
      const int wb_ = r_ * 8192 + wave * 1024;                                \
      const int o_  = wb_ + lane * 16;                                        \
      const int row_ = o_ >> 6;                                               \
      const int src_ = (o_ & 63) ^ (((row_) & 3) << 4);                       \
      const ushort_t* ga_ = A  + (row0 + row_) * (size_t)K + kb_ + (src_ >> 1); \
      const ushort_t* gb_ = Bw + (col0 + row_) * (size_t)K + kb_ + (src_ >> 1); \
      __builtin_amdgcn_global_load_lds(                                       \
          (const __attribute__((address_space(1))) unsigned int*)ga_,         \
          (__attribute__((address_space(3))) unsigned int*)                   \
              (lds + LPOS(BUF, 0, HALF) + (wb_ >> 1)), 16, 0, 0);             \
      __builtin_amdgcn_global_load_lds(                                       \
          (const __attribute__((address_space(1))) unsigned int*)gb_,         \
          (__attribute__((address_space(3))) unsigned int*)                   \
              (lds + LPOS(BUF, 1, HALF) + (wb_ >> 1)), 16, 0, 0);             \
    }                                                                         \
  }

#define RD(BUF, OP, HALF, ROW)                                                \
  (*(const bf16x8*)((const char*)(lds + LPOS(BUF, OP, HALF)) +                \
                    ((((ROW) * 64 + ks16)) ^ (((ROW) & 3) << 4))))

  f32x4 acc[8][4] = {};
  STAGE4(0, 0, 0)
  STAGE4(0, 1, 0)
  STAGE4(1, 0, 1)

  for (int kt = 0; kt < nkt; ++kt) {
    const int cb = kt & 1, nb = cb ^ 1;
    asm volatile("s_waitcnt vmcnt(8)" ::: "memory");
    __builtin_amdgcn_s_barrier();
    {
      bf16x8 af[8], bfr[4];
#pragma unroll
      for (int mf = 0; mf < 8; ++mf) af[mf] = RD(cb, 0, 0, wm * 128 + mf * 16 + l15);
#pragma unroll
      for (int nf = 0; nf < 4; ++nf) bfr[nf] = RD(cb, 1, 0, wc * 64 + nf * 16 + l15);
      STAGE4(nb, 1, kt + 1)
      __builtin_amdgcn_s_setprio(1);
#pragma unroll
      for (int mf = 0; mf < 8; ++mf)
#pragma unroll
        for (int nf = 0; nf < 4; ++nf)
          acc[mf][nf] = __builtin_amdgcn_mfma_f32_16x16x32_bf16(af[mf], bfr[nf], acc[mf][nf], 0, 0, 0);
      __builtin_amdgcn_s_setprio(0);
    }
    asm volatile("s_waitcnt vmcnt(8)" ::: "memory");
    __builtin_amdgcn_s_barrier();
    {
      bf16x8 af[8], bfr[4];
#pragma unroll
      for (int mf = 0; mf < 8; ++mf) af[mf] = RD(cb, 0, 1, wm * 128 + mf * 16 + l15);
#pragma unroll
      for (int nf = 0; nf < 4; ++nf) bfr[nf] = RD(cb, 1, 1, wc * 64 + nf * 16 + l15);
      STAGE4(cb, 0, kt + 2)
      __builtin_amdgcn_s_setprio(1);
#pragma unroll
      for (int mf = 0; mf < 8; ++mf)
#pragma unroll
        for (int nf = 0; nf < 4; ++nf)
          acc[mf][nf] = __builtin_amdgcn_mfma_f32_16x16x32_bf16(af[mf], bfr[nf], acc[mf][nf], 0, 0, 0);
      __builtin_amdgcn_s_setprio(0);
    }
  }
#undef STAGE4
#undef RD

#pragma unroll
  for (int mf = 0; mf < 8; ++mf)
#pragma unroll
    for (int nf = 0; nf < 4; ++nf)
#pragma unroll
      for (int j = 0; j < 4; ++j) {
        const size_t row = row0 + wm * 128 + mf * 16 + r4 + j;
        const size_t col = col0 + wc * 64 + nf * 16 + l15;
        if constexpr (sizeof(OutT) == 4)
          C[row * (size_t)N + col] = acc[mf][nf][j];
        else
          C[row * (size_t)N + col] = (OutT)f2b(acc[mf][nf][j]);
      }
}

template <typename OutT>
__global__ __launch_bounds__(512, 2)
void k_gemm256(const ushort_t* __restrict__ A, const ushort_t* __restrict__ Bw,
               OutT* __restrict__ C, int M, int N, int K) {
  __shared__ alignas(16) ushort_t lds[2 * 2 * 2 * 8192];
  const int nwg = gridDim.x;
  const int q8 = nwg >> 3, r8 = nwg & 7;
  const int xcd = blockIdx.x & 7, idx8 = blockIdx.x >> 3;
  const int s = (xcd < r8) ? (xcd * (q8 + 1) + idx8)
                           : (r8 * (q8 + 1) + (xcd - r8) * q8 + idx8);
  gemm256_body<OutT>(A, Bw, C, M, N, K, s, lds);
}

// ---------------------------------------------------------------------------
// GEMM 256x128 tile (R17-verified): counted-vmcnt, 3 loads/half, vmcnt(6).
// ---------------------------------------------------------------------------
#define LPA(BUF, HALF) (((BUF) * 2 + (HALF)) * 8192)
#define LPB(BUF, HALF) (32768 + ((BUF) * 2 + (HALF)) * 4096)

template <typename OutT>
__global__ __launch_bounds__(512, 1)
void k_gemm256x128(const ushort_t* __restrict__ A, const ushort_t* __restrict__ Bw,
                   OutT* __restrict__ C, int M, int N, int K) {
  __shared__ alignas(16) ushort_t lds[49152];   // 96 KB
  const int tid = threadIdx.x;
  const int lane = tid & 63, wave = tid >> 6;
  const int wm = wave >> 1, wc = wave & 1;
  const int l15 = lane & 15;
  const int ks16 = (lane >> 4) * 16;
  const int r4 = (lane >> 4) * 4;
  const int nkt = K >> 6;
  const int nbx = N >> 7;
  const int nwg = gridDim.x;
  const int q8 = nwg >> 3, r8 = nwg & 7;
  const int xcd = blockIdx.x & 7, idx8 = blockIdx.x >> 3;
  const int s = (xcd < r8) ? (xcd * (q8 + 1) + idx8)
                           : (r8 * (q8 + 1) + (xcd - r8) * q8 + idx8);
  const size_t row0 = (size_t)(s / nbx) * 256;
  const size_t col0 = (size_t)(s % nbx) * 128;

#define STG3(BUF, HALF, KT) {                                                 \
    const int kt_ = ((KT) < nkt) ? (KT) : (nkt - 1);                          \
    const int kb_ = kt_ * 64 + (HALF) * 32;                                   \
    _Pragma("unroll") for (int r_ = 0; r_ < 2; ++r_) {                        \
      const int wb_ = r_ * 8192 + wave * 1024;                                \
      const int o_  = wb_ + lane * 16;                                        \
      const int row_ = o_ >> 6;                                               \
      const int src_ = (o_ & 63) ^ (((row_) & 3) << 4);                       \
      const ushort_t* ga_ = A + (row0 + row_) * (size_t)K + kb_ + (src_ >> 1); \
      __builtin_amdgcn_global_load_lds(                                       \
          (const __attribute__((address_space(1))) unsigned int*)ga_,         \
          (__attribute__((address_space(3))) unsigned int*)                   \
              (lds + LPA(BUF, HALF) + (wb_ >> 1)), 16, 0, 0);                 \
    }                                                                         \
    {                                                                         \
      const int wb_ = wave * 1024;                                            \
      const int o_  = wb_ + lane * 16;                                        \
      const int row_ = o_ >> 6;                                               \
      const int src_ = (o_ & 63) ^ (((row_) & 3) << 4);                       \
      const ushort_t* gb_ = Bw + (col0 + row_) * (size_t)K + kb_ + (src_ >> 1); \
      __builtin_amdgcn_global_load_lds(                                       \
          (const __attribute__((address_space(1))) unsigned int*)gb_,         \
          (__attribute__((address_space(3))) unsigned int*)                   \
              (lds + LPB(BUF, HALF) + (wb_ >> 1)), 16, 0, 0);                 \
    }                                                                         \
  }

#define RDA(BUF, HALF, ROW)                                                   \
  (*(const bf16x8*)((const char*)(lds + LPA(BUF, HALF)) +                     \
                    ((((ROW) * 64 + ks16)) ^ (((ROW) & 3) << 4))))
#define RDB(BUF, HALF, ROW)                                                   \
  (*(const bf16x8*)((const char*)(lds + LPB(BUF, HALF)) +                     \
                    ((((ROW) * 64 + ks16)) ^ (((ROW) & 3) << 4))))

  f32x4 acc[4][4] = {};
  STG3(0, 0, 0)
  STG3(0, 1, 0)
  STG3(1, 0, 1)

  for (int kt = 0; kt < nkt; ++kt) {
    const int cb = kt & 1, nb = cb ^ 1;
    asm volatile("s_waitcnt vmcnt(6)" ::: "memory");
    __builtin_amdgcn_s_barrier();
    {
      bf16x8 af[4], bfr[4];
#pragma unroll
      for (int mf = 0; mf < 4; ++mf) af[mf] = RDA(cb, 0, wm * 64 + mf * 16 + l15);
#pragma unroll
      for (int nf = 0; nf < 4; ++nf) bfr[nf] = RDB(cb, 0, wc * 64 + nf * 16 + l15);
      STG3(nb, 1, kt + 1)
      __builtin_amdgcn_s_setprio(1);
#pragma unroll
      for (int mf = 0; mf < 4; ++mf)
#pragma unroll
        for (int nf = 0; nf < 4; ++nf)
          acc[mf][nf] = __builtin_amdgcn_mfma_f32_16x16x32_bf16(af[mf], bfr[nf], acc[mf][nf], 0, 0, 0);
      __builtin_amdgcn_s_setprio(0);
    }
    asm volatile("s_waitcnt vmcnt(6)" ::: "memory");
    __builtin_amdgcn_s_barrier();
    {
      bf16x8 af[4], bfr[4];
#pragma unroll
      for (int mf = 0; mf < 4; ++mf) af[mf] = RDA(cb, 1, wm * 64 + mf * 16 + l15);
#pragma unroll
      for (int nf = 0; nf < 4; ++nf) bfr[nf] = RDB(cb, 1, wc * 64 + nf * 16 + l15);
      STG3(cb, 0, kt + 2)
      __builtin_amdgcn_s_setprio(1);
#pragma unroll
      for (int mf = 0; mf < 4; ++mf)
#pragma unroll
        for (int nf = 0; nf < 4; ++nf)
          acc[mf][nf] = __builtin_amdgcn_mfma_f32_16x16x32_bf16(af[mf], bfr[nf], acc[mf][nf], 0, 0, 0);
      __builtin_amdgcn_s_setprio(0);
    }
  }
#undef STG3
#undef RDA
#undef RDB

#pragma unroll
  for (int mf = 0; mf < 4; ++mf)
#pragma unroll
    for (int nf = 0; nf < 4; ++nf)
#pragma unroll
      for (int j = 0; j < 4; ++j) {
        const size_t row = row0 + wm * 64 + mf * 16 + r4 + j;
        const size_t col = col0 + wc * 64 + nf * 16 + l15;
        if constexpr (sizeof(OutT) == 4)
          C[row * (size_t)N + col] = acc[mf][nf][j];
        else
          C[row * (size_t)N + col] = (OutT)f2b(acc[mf][nf][j]);
      }
}

// ---------------------------------------------------------------------------
// b/a projection, W-amortized (R12-verified).
// ---------------------------------------------------------------------------
__global__ __launch_bounds__(256, 2)
void k_proj_ba(const float* __restrict__ x, const float* __restrict__ Wb,
               const float* __restrict__ Wa, const float* __restrict__ dtb,
               const float* __restrict__ alog,
               float* __restrict__ beta, float* __restrict__ gout) {
  __shared__ __bf16 Wl[16][2048];
  __shared__ float part[16][16];
  const int tid = threadIdx.x;
  const int o = tid & 15, seg = tid >> 4;
  const int bt0 = blockIdx.x * 16;

#define PROJ_PASS(WSRC, EMIT) {                                               \
    for (int i = tid; i < 8192; i += 256) {                                   \
      const int os_ = i >> 9, k4_ = i & 511;                                  \
      float4 w_ = *(const float4*)(WSRC + (size_t)os_ * HID_ + k4_ * 4);      \
      const int b_ = k4_ * 8;                                                 \
      __bf16* d_ = (__bf16*)((char*)&Wl[0][0] + os_ * 4096 +                  \
                   (((b_ & ~15) ^ ((os_ & 15) << 4)) | (b_ & 8)));            \
      d_[0] = (__bf16)w_.x; d_[1] = (__bf16)w_.y;                             \
      d_[2] = (__bf16)w_.z; d_[3] = (__bf16)w_.w;                             \
    }                                                                         \
    __syncthreads();                                                          \
    for (int rr = 0; rr < 16; ++rr) {                                         \
      const int bt = bt0 + rr;                                                \
      const float* xr = x + (size_t)bt * HID_;                                \
      float s = 0.f;                                                          \
      _Pragma("unroll") for (int j = 0; j < 16; ++j) {                        \
        const int k = seg * 128 + j * 8;                                      \
        float4 xa = *(const float4*)&xr[k];                                   \
        float4 xb = *(const float4*)&xr[k + 4];                               \
        bf16x8 wv = *(const bf16x8*)((const char*)&Wl[0][0] + o * 4096 +      \
                     ((k * 2) ^ ((o & 15) << 4)));                            \
        s += (float)wv[0]*xa.x + (float)wv[1]*xa.y + (float)wv[2]*xa.z +      \
             (float)wv[3]*xa.w + (float)wv[4]*xb.x + (float)wv[5]*xb.y +      \
             (float)wv[6]*xb.z + (float)wv[7]*xb.w;                           \
      }                                                                       \
      part[o][seg] = s;                                                       \
      __syncthreads();                                                        \
      if (tid < 16) {                                                         \
        float t_ = 0.f;                                                       \
        _Pragma("unroll") for (int i2 = 0; i2 < 16; ++i2) t_ += part[tid][i2];\
        EMIT                                                                  \
      }                                                                       \
      __syncthreads();                                                        \
    }                                                                         \
  }

  PROJ_PASS(Wb, {
    beta[(size_t)bt * NV_ + tid] = 1.f / (1.f + expf(-t_));
  })
  __syncthreads();
  PROJ_PASS(Wa, {
    float aa = t_ + dtb[tid];
    float sp = (aa > 20.f) ? aa : log1pf(expf(aa));
    gout[(size_t)bt * NV_ + tid] = -expf(alog[tid]) * sp;
  })
#undef PROJ_PASS
}

// ---------------------------------------------------------------------------
// Fused depthwise causal conv1d (K=4) + silu + l2norm(q,k). (R14-verified)
// ---------------------------------------------------------------------------
__global__ __launch_bounds__(256)
void k_conv_silu_norm(const ushort_t* __restrict__ qkv, const float* __restrict__ cw,
                      ushort_t* __restrict__ act) {
  const int bt = blockIdx.x;
  const int tid = threadIdx.x;
  const int t = bt & (T_ - 1);
  const int c = tid * 16;
  const ushort_t* rowp = qkv + (size_t)bt * CD_ + c;

  float wf[16][4];
#pragma unroll
  for (int i = 0; i < 16; ++i) {
    float4 w = *(const float4*)&cw[(c + i) * 4];
    wf[i][0] = w.x; wf[i][1] = w.y; wf[i][2] = w.z; wf[i][3] = w.w;
  }
  float a[16];
#pragma unroll
  for (int i = 0; i < 16; ++i) a[i] = 0.f;
#pragma unroll
  for (int j = 0; j < 4; ++j) {
    const int tt = t - 3 + j;
    if (tt >= 0) {
      const ushort_t* src = rowp + ((ptrdiff_t)j - 3) * CD_;
      bf16x8 v0 = *(const bf16x8*)(const void*)src;
      bf16x8 v1 = *(const bf16x8*)(const void*)(src + 8);
#pragma unroll
      for (int i = 0; i < 8; ++i) {
        a[i]     += (float)v0[i] * wf[i][j];
        a[8 + i] += (float)v1[i] * wf[8 + i][j];
      }
    }
  }
#pragma unroll
  for (int i = 0; i < 16; ++i) a[i] = a[i] / (1.f + expf(-a[i]));
  float ss = 0.f;
#pragma unroll
  for (int i = 0; i < 16; ++i) ss += a[i] * a[i];
  ss += __shfl_xor(ss, 1); ss += __shfl_xor(ss, 2); ss += __shfl_xor(ss, 4);
  const int seg = tid >> 3;
  float scale = 1.f;
  if (seg < 16) {
    scale = 1.f / fmaxf(sqrtf(ss), 1e-12f);
    if (seg < 8) scale *= 0.08838834764831845f;
  }
  ushort_t ov[16];
#pragma unroll
  for (int i = 0; i < 16; ++i) ov[i] = f2b(a[i] * scale);
  ushort_t* dst = act + (size_t)bt * CD_ + c;
  *(uint4*)(void*)dst       = *(const uint4*)&ov[0];
  *(uint4*)(void*)(dst + 8) = *(const uint4*)&ov[8];
}

// ---------------------------------------------------------------------------
__device__ __forceinline__ bf16x8 cvt8f(const float* p) {
  float4 a = *(const float4*)p;
  float4 b = *(const float4*)(p + 4);
  bf16x8 o;
  o[0] = (__bf16)a.x; o[1] = (__bf16)a.y; o[2] = (__bf16)a.z; o[3] = (__bf16)a.w;
  o[4] = (__bf16)b.x; o[5] = (__bf16)b.y; o[6] = (__bf16)b.z; o[7] = (__bf16)b.w;
  return o;
}

// ---------------------------------------------------------------------------
// k_prep: per-chunk parallel precompute. grid = 1024. act is bf16.
// R19: P2 solve block-16 recursive (4 scalar 16-solves + 3 MFMA corrections).
// ---------------------------------------------------------------------------
__global__ __launch_bounds__(256, 1)
void k_prep(const ushort_t* __restrict__ act, const float* __restrict__ gB,
            const float* __restrict__ betaB,
            ushort_t* __restrict__ WkG, ushort_t* __restrict__ UlT,
            float* __restrict__ gtG,
            ushort_t* __restrict__ MTG, ushort_t* __restrict__ NTG) {
  __shared__ __bf16 Kl[64][136];
  __shared__ __bf16 AbL[64][40];
  __shared__ __bf16 AbH[32][33];
  __shared__ __bf16 Xl[64][264];
  __shared__ alignas(16) __bf16 Cr[16][264];   // 8.4 KB: correction staging
  __shared__ float gc[65], Et[65], Rt[65], bts[64], geT[64], escT[64];

  const int wg = blockIdx.x;
  const int c = wg & 31, h = (wg >> 5) & 15, b = wg >> 9;
  const int hq = h >> 1, t0 = c * 64;
  const int tid = threadIdx.x, lane = tid & 63, wave = tid >> 6;
  const int l15 = lane & 15, kcol0 = (lane >> 4) * 8, rrow = (lane >> 4) * 4;
  const size_t bhc = (size_t)wg;

  const ushort_t* baseQ = act + (size_t)b * T_ * CD_ + hq * HD_;
  const ushort_t* baseK = baseQ + KD_;

  if (tid < 64) {
    float g = gB[((size_t)b * T_ + t0 + tid) * NV_ + h];
    bts[tid] = betaB[((size_t)b * T_ + t0 + tid) * NV_ + h];
#pragma unroll
    for (int o = 1; o < 64; o <<= 1) {
      float up = __shfl_up(g, (unsigned)o);
      if (tid >= o) g += up;
    }
    gc[tid + 1] = g;
    if (tid == 0) gc[0] = 0.f;
  }
  __syncthreads();
  if (tid < 65) {
    float gm = gc[32];
    Et[tid] = __expf(gc[tid] - gm);
    Rt[tid] = __expf(gm - gc[tid]);
  }
  if (tid < 64) {
    geT[tid] = bts[tid] * __expf(gc[tid + 1]);
    escT[tid] = __expf(gc[64] - gc[tid + 1]);
    gtG[bhc * 64 + tid] = gc[tid + 1];
  }
  {
    const int t = tid >> 2, d0 = (tid & 3) * 32;
    const ushort_t* src = baseK + (size_t)(t0 + t) * CD_ + d0;
#pragma unroll
    for (int j = 0; j < 4; ++j)
      *(uint4*)&Kl[t][d0 + j * 8] = *(const uint4*)(const void*)(src + j * 8);
  }
  __syncthreads();

  // P1: Ab (strict lower, -beta*scale*KK^T) in LDS
  {
    bf16x8 kf[4];
#pragma unroll
    for (int kk = 0; kk < 4; ++kk)
      kf[kk] = *(const bf16x8*)&Kl[16 * wave + l15][kk * 32 + kcol0];
#pragma unroll
    for (int st = 0; st < 4; ++st) {
      if (st <= wave) {
        f32x4 accA = {};
#pragma unroll
        for (int kk = 0; kk < 4; ++kk) {
          bf16x8 bfr = *(const bf16x8*)&Kl[st * 16 + l15][kk * 32 + kcol0];
          accA = __builtin_amdgcn_mfma_f32_16x16x32_bf16(kf[kk], bfr, accA, 0, 0, 0);
        }
        const int scol = st * 16 + l15;
#pragma unroll
        for (int r = 0; r < 4; ++r) {
          const int t = 16 * wave + rrow + r;
          if (scol < t) {
            const float av = -bts[t] * Et[t + 1] * Rt[scol + 1] * accA[r];
            if (scol < 32) AbL[t][scol] = (__bf16)av;
            else           AbH[t - 32][scol - 32] = (__bf16)av;
          }
        }
      }
    }
  }
  __syncthreads();

  // P2: block-16 recursive triangular solve (R19). 256 threads = 256 cols.
  {
    float r1[32], r2[32];
    if (tid < 128) {
      const int d = tid;
#pragma unroll
      for (int t = 0; t < 32; ++t) r1[t] = geT[t] * (float)Kl[t][d];
#pragma unroll
      for (int t = 0; t < 32; ++t) r2[t] = geT[32 + t] * (float)Kl[32 + t][d];
    } else {
      const int j = tid - 128;
      const ushort_t* vsrc = act + ((size_t)b * T_ + t0) * CD_ + 2 * KD_ + h * HD_ + j;
#pragma unroll
      for (int t = 0; t < 32; ++t) r1[t] = bts[t] * b2f(vsrc[(size_t)t * CD_]);
#pragma unroll
      for (int t = 0; t < 32; ++t) r2[t] = bts[32 + t] * b2f(vsrc[(size_t)(32 + t) * CD_]);
    }

    // ---- block 0: rows 0..15 (diag AbL[j][i], i<j<16)
    {
      float u[16];
#pragma unroll
      for (int j = 0; j < 16; ++j) {
        float a = r1[j];
#pragma unroll
        for (int i = 0; i < j; ++i) a += (float)AbL[j][i] * u[i];
        u[j] = a;
        Xl[j][tid] = (__bf16)a;
      }
    }
    __syncthreads();

    // ---- corr 1: rows 16..31 <- L(1,0)@U0 (K=16, register-zero-padded)
    {
      bf16x8 afr2;
#pragma unroll
      for (int j = 0; j < 8; ++j) {
        const int k = kcol0 + j;
        afr2[j] = (k < 16) ? AbL[16 + l15][k] : (__bf16)0.f;
      }
#pragma unroll
      for (int ct4 = 0; ct4 < 4; ++ct4) {
        const int ct = wave * 4 + ct4;
        bf16x8 bfr2;
#pragma unroll
        for (int j = 0; j < 8; ++j) {
          const int k = kcol0 + j;
          bfr2[j] = (k < 16) ? Xl[k][16 * ct + l15] : (__bf16)0.f;
        }
        f32x4 acc2 = {};
        acc2 = __builtin_amdgcn_mfma_f32_16x16x32_bf16(afr2, bfr2, acc2, 0, 0, 0);
#pragma unroll
        for (int r = 0; r < 4; ++r)
          Cr[rrow + r][16 * ct + l15] = (__bf16)acc2[r];
      }
    }
    __syncthreads();

    // ---- block 1: rows 16..31 (diag AbL[16+j][16+i])
    {
      float u[16];
#pragma unroll
      for (int j = 0; j < 16; ++j) {
        float a = r1[16 + j] + (float)Cr[j][tid];
#pragma unroll
        for (int i = 0; i < j; ++i) a += (float)AbL[16 + j][16 + i] * u[i];
        u[j] = a;
        Xl[16 + j][tid] = (__bf16)a;
      }
    }
    __syncthreads();

    // ---- corr 2: rows 32..47 <- [L(2,0) L(2,1)]@[U0;U1] (K=32 full)
    {
      bf16x8 afr2 = *(const bf16x8*)&AbL[32 + l15][kcol0];
#pragma unroll
      for (int ct4 = 0; ct4 < 4; ++ct4) {
        const int ct = wave * 4 + ct4;
        bf16x8 bfr2;
#pragma unroll
        for (int j = 0; j < 8; ++j) bfr2[j] = Xl[kcol0 + j][16 * ct + l15];
        f32x4 acc2 = {};
        acc2 = __builtin_amdgcn_mfma_f32_16x16x32_bf16(afr2, bfr2, acc2, 0, 0, 0);
#pragma unroll
        for (int r = 0; r < 4; ++r)
          Cr[rrow + r][16 * ct + l15] = (__bf16)acc2[r];
      }
    }
    __syncthreads();

    // ---- block 2: rows 32..47 (diag AbH[j][i], j,i<16)
    {
      float u[16];
#pragma unroll
      for (int j = 0; j < 16; ++j) {
        float a = r2[j] + (float)Cr[j][tid];
#pragma unroll
        for (int i = 0; i < j; ++i) a += (float)AbH[j][i] * u[i];
        u[j] = a;
        Xl[32 + j][tid] = (__bf16)a;
      }
    }
    __syncthreads();

    // ---- corr 3: rows 48..63 <- [L(3,0) L(3,1)]@[U0;U1] (K=32)
    //                           + L(3,2)@U2 (K=16, register-zero-padded)
    {
      bf16x8 afrA = *(const bf16x8*)&AbL[48 + l15][kcol0];
      bf16x8 afrB;
#pragma unroll
      for (int j = 0; j < 8; ++j) {
        const int k = kcol0 + j;
        afrB[j] = (k < 16) ? AbH[16 + l15][k] : (__bf16)0.f;
      }
#pragma unroll
      for (int ct4 = 0; ct4 < 4; ++ct4) {
        const int ct = wave * 4 + ct4;
        bf16x8 bfrA, bfrB;
#pragma unroll
        for (int j = 0; j < 8; ++j) {
          const int k = kcol0 + j;
          bfrA[j] = Xl[k][16 * ct + l15];
          bfrB[j] = (k < 16) ? Xl[32 + k][16 * ct + l15] : (__bf16)0.f;
        }
        f32x4 acc2 = {};
        acc2 = __builtin_amdgcn_mfma_f32_16x16x32_bf16(afrA, bfrA, acc2, 0, 0, 0);
        acc2 = __builtin_amdgcn_mfma_f32_16x16x32_bf16(afrB, bfrB, acc2, 0, 0, 0);
#pragma unroll
        for (int r = 0; r < 4; ++r)
          Cr[rrow + r][16 * ct + l15] = (__bf16)acc2[r];
      }
    }
    __syncthreads();

    // ---- block 3: rows 48..63 (diag AbH[16+j][16+i])
    {
      float u[16];
#pragma unroll
      for (int j = 0; j < 16; ++j) {
        float a = r2[16 + j] + (float)Cr[j][tid];
#pragma unroll
        for (int i = 0; i < j; ++i) a += (float)AbH[16 + j][16 + i] * u[i];
        u[j] = a;
        Xl[48 + j][tid] = (__bf16)a;
      }
    }
  }
  __syncthreads();

  // P3: Wk copy (negated, stride 128) + Uloc^T store (stride 64)
#pragma unroll
  for (int kck = 0; kck < 4; ++kck) {
    const int q = tid + kck * 256;
    const int t = q >> 4, d0 = (q & 15) * 8;
    uint4 v = *(const uint4*)&Xl[t][d0];
    v.x ^= 0x80008000u; v.y ^= 0x80008000u; v.z ^= 0x80008000u; v.w ^= 0x80008000u;
    *(uint4*)(void*)(WkG + bhc * (64 * 128) + (size_t)t * 128 + d0) = v;
  }
  {
    const int e = tid >> 1, t8 = (tid & 1) * 32;
#pragma unroll
    for (int i8 = 0; i8 < 4; ++i8) {
      bf16x8 tmp;
#pragma unroll
      for (int jj = 0; jj < 8; ++jj) tmp[jj] = Xl[t8 + i8 * 8 + jj][128 + e];
      *(bf16x8*)(void*)(UlT + bhc * (128 * 64) + (size_t)e * 64 + t8 + i8 * 8) = tmp;
    }
  }

  // P4: M^T and N^T via MFMA. wave owns d-row-tiles {2w, 2w+1}. (R15 exact)
  {
    const float gCe = __expf(gc[64]);
    bf16x8 afr[2][2];
#pragma unroll
    for (int dtl = 0; dtl < 2; ++dtl) {
      const int d = 16 * (2 * wave + dtl) + l15;
#pragma unroll
      for (int kt = 0; kt < 2; ++kt) {
        bf16x8 o;
#pragma unroll
        for (int j = 0; j < 8; ++j) {
          const int t = kt * 32 + kcol0 + j;
          o[j] = (__bf16)(escT[t] * (float)Kl[t][d]);
        }
        afr[dtl][kt] = o;
      }
    }
#pragma unroll
    for (int tc = 0; tc < 16; ++tc) {
      bf16x8 bfr[2];
#pragma unroll
      for (int kt = 0; kt < 2; ++kt) {
        bf16x8 o;
#pragma unroll
        for (int j = 0; j < 8; ++j) {
          const int t = kt * 32 + kcol0 + j;
          o[j] = (tc < 8) ? (__bf16)(-(float)Xl[t][16 * tc + l15])
                          : Xl[t][128 + 16 * (tc - 8) + l15];
        }
        bfr[kt] = o;
      }
#pragma unroll
      for (int dtl = 0; dtl < 2; ++dtl) {
        f32x4 acc = {};
        acc = __builtin_amdgcn_mfma_f32_16x16x32_bf16(afr[dtl][0], bfr[0], acc, 0, 0, 0);
        acc = __builtin_amdgcn_mfma_f32_16x16x32_bf16(afr[dtl][1], bfr[1], acc, 0, 0, 0);
        const int col = 16 * (tc & 7) + l15;
#pragma unroll
        for (int r = 0; r < 4; ++r) {
          const int dr = 16 * (2 * wave + dtl) + rrow + r;
          if (tc < 8)
            MTG[bhc * CHM_ + (size_t)dr * 128 + col] =
                f2b(acc[r] + ((dr == col) ? gCe : 0.f));
          else
            NTG[bhc * CHM_ + (size_t)dr * 128 + col] = f2b(acc[r]);
        }
      }
    }
  }
}

// ---------------------------------------------------------------------------
// scan body: S' = S*M + N, M/N double-buffered in LDS via global_load_lds
// (pre-swizzled source, swizzled ds_read). (R12-verified)
// ---------------------------------------------------------------------------
__device__ __forceinline__ void scan_body(
    const ushort_t* __restrict__ MTG, const ushort_t* __restrict__ NTG,
    ushort_t* __restrict__ ScG, int sb, char* smem) {
  const int eh = sb & 1, wg = sb >> 1;
  const int e0 = eh * 64;
  const int tid = threadIdx.x, lane = tid & 63, wave = tid >> 6;
  const int l15 = lane & 15, kcol0 = (lane >> 4) * 8, rrow = (lane >> 4) * 4;
  const int et = wave & 3, dh = wave >> 2;

  char* Mb0 = smem;                                      // [2][128][128] bf16 = 64 KB
  char* Nb0 = smem + 65536;                              // [2][128][64]  bf16 = 32 KB
  __bf16 (*S16)[136] = (__bf16(*)[136])(smem + 98304);   // [64][136] = 17408 B

#define SSTAGE(BUF, CN) {                                                     \
    const int cn_ = ((CN) < 32) ? (CN) : 31;                                  \
    const size_t bhcn_ = (size_t)wg * 32 + cn_;                               \
    const ushort_t* MTR_ = MTG + bhcn_ * CHM_;                                \
    const ushort_t* NTR_ = NTG + bhcn_ * CHM_;                                \
    _Pragma("unroll") for (int r_ = 0; r_ < 4; ++r_) {                        \
      const int idx_ = r_ * 512 + tid;                                        \
      const int d_ = idx_ >> 4, sl_ = idx_ & 15;                              \
      const ushort_t* src_ = MTR_ + (size_t)d_ * 128 + ((sl_ ^ (d_ & 7)) << 3); \
      __builtin_amdgcn_global_load_lds(                                       \
          (const __attribute__((address_space(1))) unsigned int*)src_,        \
          (__attribute__((address_space(3))) unsigned int*)                   \
              (Mb0 + (BUF) * 32768 + r_ * 8192 + wave * 1024), 16, 0, 0);     \
    }                                                                         \
    _Pragma("unroll") for (int r_ = 0; r_ < 2; ++r_) {                        \
      const int idx_ = r_ * 512 + tid;                                        \
      const int d_ = idx_ >> 3, sl_ = idx_ & 7;                               \
      const ushort_t* src_ = NTR_ + (size_t)d_ * 128 + e0 + ((sl_ ^ (d_ & 7)) << 3); \
      __builtin_amdgcn_global_load_lds(                                       \
          (const __attribute__((address_space(1))) unsigned int*)src_,        \
          (__attribute__((address_space(3))) unsigned int*)                   \
              (Nb0 + (BUF) * 16384 + r_ * 8192 + wave * 1024), 16, 0, 0);     \
    }                                                                         \
  }

#define MRD(BUF, ROW, KC)                                                     \
  (*(const bf16x8*)(Mb0 + (BUF) * 32768 + ((ROW) << 8) +                      \
                    ((((KC) << 1)) ^ (((ROW) & 7) << 4))))
#define NRD(BUF, DROW, EC)                                                    \
  (*(const short4v*)(Nb0 + (BUF) * 16384 + ((DROW) << 7) +                    \
                    ((((EC) << 1)) ^ (((DROW) & 7) << 4))))

  f32x4 s_acc[4] = {};   // S^T[e0+16et+rrow+r][16*(4dh+dl)+l15]
  SSTAGE(0, 0)

  for (int c = 0; c < 32; ++c) {
    const int buf = c & 1;
    ushort_t* ScR = ScG + ((size_t)wg * 32 + c) * CHM_;

    __syncthreads();
    SSTAGE(buf ^ 1, c + 1)

#pragma unroll
    for (int dl = 0; dl < 4; ++dl)
#pragma unroll
      for (int r = 0; r < 4; ++r)
        S16[16 * et + rrow + r][(4 * dh + dl) * 16 + l15] = (__bf16)s_acc[dl][r];
    asm volatile("s_waitcnt lgkmcnt(0)" ::: "memory");
    __builtin_amdgcn_sched_barrier(0);
    __builtin_amdgcn_s_barrier();
    __builtin_amdgcn_sched_barrier(0);

#pragma unroll
    for (int cc = 0; cc < 2; ++cc) {
      const int idx = tid + cc * 512;
      const int row = idx >> 4, seg = idx & 15;
      *(uint4*)(void*)(ScR + (size_t)(e0 + row) * 128 + seg * 8) =
          *(const uint4*)&S16[row][seg * 8];
    }

    f32x4 acc[4];
#pragma unroll
    for (int dl = 0; dl < 4; ++dl) {
      short4v nv = NRD(buf, 16 * (4 * dh + dl) + l15, 16 * et + rrow);
#pragma unroll
      for (int r = 0; r < 4; ++r) acc[dl][r] = b2f((ushort_t)nv[r]);
    }
#pragma unroll
    for (int kk = 0; kk < 4; ++kk) {
      bf16x8 sa = *(const bf16x8*)&S16[16 * et + l15][kk * 32 + kcol0];
#pragma unroll
      for (int dl = 0; dl < 4; ++dl) {
        bf16x8 mb = MRD(buf, 16 * (4 * dh + dl) + l15, kk * 32 + kcol0);
        acc[dl] = __builtin_amdgcn_mfma_f32_16x16x32_bf16(sa, mb, acc[dl], 0, 0, 0);
      }
    }
#pragma unroll
    for (int dl = 0; dl < 4; ++dl) s_acc[dl] = acc[dl];
  }
#undef SSTAGE
#undef MRD
#undef NRD
}

// ---------------------------------------------------------------------------
// FUSED launch: blocks 0..63 = scan, 64..191 = z-gemm tiles (independent).
// ---------------------------------------------------------------------------
__global__ __launch_bounds__(512, 2)
void k_scan_zgemm(const ushort_t* __restrict__ MTG, const ushort_t* __restrict__ NTG,
                  ushort_t* __restrict__ ScG,
                  const ushort_t* __restrict__ xB, const ushort_t* __restrict__ WzB,
                  ushort_t* __restrict__ zbuf) {
  __shared__ alignas(16) char smem[131072];
  if (blockIdx.x < 64)
    scan_body(MTG, NTG, ScG, blockIdx.x, smem);
  else
    gemm256_body<ushort_t>(xB, WzB, zbuf, B_ * T_, VD_, HID_,
                           blockIdx.x - 64, (ushort_t*)smem);
}

// ---------------------------------------------------------------------------
// k_out: fully parallel per (b,h,c): u = Ul + Wkneg@S_c; Pm recomputed from
// q,k; o = gam*Q@S_c + Pm@u; fused gated RMSNorm -> bf16 outg. grid=1024.
// ---------------------------------------------------------------------------
__global__ __launch_bounds__(256, 2)
void k_out(const ushort_t* __restrict__ act,
           const ushort_t* __restrict__ WkG, const ushort_t* __restrict__ UlT,
           const float* __restrict__ gtG,
           const ushort_t* __restrict__ ScG, const ushort_t* __restrict__ zbuf,
           const float* __restrict__ nw, ushort_t* __restrict__ outg) {
  __shared__ __bf16 S16[128][136];
  __shared__ __bf16 uTl[128][72];
  __shared__ __bf16 PmL[64][72];
  __shared__ float Egc[65], Rgc[65], gam[64], nws[128];

  const int bhc = blockIdx.x;
  const int c = bhc & 31, h = (bhc >> 5) & 15, b = bhc >> 9;
  const int hq = h >> 1, t0g = c * 64;
  const int tid = threadIdx.x, lane = tid & 63, wave = tid >> 6;
  const int l15 = lane & 15, kcol0 = (lane >> 4) * 8, rrow = (lane >> 4) * 4;

  const ushort_t* ScR = ScG + (size_t)bhc * CHM_;
  const ushort_t* WkR = WkG + (size_t)bhc * (64 * 128);
  const ushort_t* UlR = UlT + (size_t)bhc * (128 * 64);
  const ushort_t* actQ = act + ((size_t)b * T_ + t0g) * CD_ + hq * HD_;
  const ushort_t* actK = actQ + KD_;

#pragma unroll
  for (int cc = 0; cc < 8; ++cc) {
    const int idx = tid + cc * 256;
    const int row = idx >> 4, seg = idx & 15;
    *(uint4*)&S16[row][seg * 8] =
        *(const uint4*)(const void*)(ScR + (size_t)row * 128 + seg * 8);
  }
  {
    const float gc32 = gtG[(size_t)bhc * 64 + 31];
    if (tid < 65) {
      const float gcv = (tid == 0) ? 0.f : gtG[(size_t)bhc * 64 + tid - 1];
      Egc[tid] = __expf(gcv - gc32);
      Rgc[tid] = __expf(gc32 - gcv);
    }
    if (tid < 64) gam[tid] = __expf(gtG[(size_t)bhc * 64 + tid]);
    if (tid < 128) nws[tid] = nw[tid];
  }
  __syncthreads();

  bf16x8 qf[4];
#pragma unroll
  for (int kk = 0; kk < 4; ++kk)
    qf[kk] = *(const bf16x8*)(const void*)
        (actQ + (size_t)(16 * wave + l15) * CD_ + kk * 32 + kcol0);

  bf16x8 wa[4];
#pragma unroll
  for (int kk = 0; kk < 4; ++kk)
    wa[kk] = *(const bf16x8*)(const void*)(WkR + (size_t)(16 * wave + l15) * 128 + kk * 32 + kcol0);
  f32x4 au[8] = {};
#pragma unroll
  for (int kk = 0; kk < 4; ++kk)
#pragma unroll
    for (int jt = 0; jt < 8; ++jt) {
      bf16x8 sb = *(const bf16x8*)&S16[jt * 16 + l15][kk * 32 + kcol0];
      au[jt] = __builtin_amdgcn_mfma_f32_16x16x32_bf16(wa[kk], sb, au[jt], 0, 0, 0);
    }
#pragma unroll
  for (int jt = 0; jt < 8; ++jt) {
    short4v uv = *(const short4v*)(const void*)(UlR + (size_t)(16 * jt + l15) * 64 + wave * 16 + rrow);
#pragma unroll
    for (int r = 0; r < 4; ++r)
      uTl[16 * jt + l15][16 * wave + rrow + r] = (__bf16)(au[jt][r] + b2f((ushort_t)uv[r]));
  }

#pragma unroll
  for (int st = 0; st < 4; ++st) {
    f32x4 accP = {};
#pragma unroll
    for (int kk = 0; kk < 4; ++kk) {
      bf16x8 kb = *(const bf16x8*)(const void*)
          (actK + (size_t)(st * 16 + l15) * CD_ + kk * 32 + kcol0);
      accP = __builtin_amdgcn_mfma_f32_16x16x32_bf16(qf[kk], kb, accP, 0, 0, 0);
    }
    const int scol = st * 16 + l15;
#pragma unroll
    for (int r = 0; r < 4; ++r) {
      const int t = 16 * wave + rrow + r;
      PmL[t][scol] = (scol <= t) ? (__bf16)(Egc[t + 1] * Rgc[scol + 1] * accP[r])
                                 : (__bf16)0.f;
    }
  }
  __syncthreads();

  f32x4 qs[8] = {}, o2[8] = {};
#pragma unroll
  for (int kk = 0; kk < 4; ++kk)
#pragma unroll
    for (int jt = 0; jt < 8; ++jt) {
      bf16x8 sb = *(const bf16x8*)&S16[jt * 16 + l15][kk * 32 + kcol0];
      qs[jt] = __builtin_amdgcn_mfma_f32_16x16x32_bf16(qf[kk], sb, qs[jt], 0, 0, 0);
    }
#pragma unroll
  for (int ks = 0; ks < 2; ++ks) {
    bf16x8 pa = *(const bf16x8*)&PmL[16 * wave + l15][ks * 32 + kcol0];
#pragma unroll
    for (int jt = 0; jt < 8; ++jt) {
      bf16x8 ub = *(const bf16x8*)&uTl[jt * 16 + l15][ks * 32 + kcol0];
      o2[jt] = __builtin_amdgcn_mfma_f32_16x16x32_bf16(pa, ub, o2[jt], 0, 0, 0);
    }
  }
  float ov[8][4];
  float ss0 = 0.f, ss1 = 0.f, ss2 = 0.f, ss3 = 0.f;
#pragma unroll
  for (int jt = 0; jt < 8; ++jt) {
    ov[jt][0] = gam[16 * wave + rrow + 0] * qs[jt][0] + o2[jt][0];
    ov[jt][1] = gam[16 * wave + rrow + 1] * qs[jt][1] + o2[jt][1];
    ov[jt][2] = gam[16 * wave + rrow + 2] * qs[jt][2] + o2[jt][2];
    ov[jt][3] = gam[16 * wave + rrow + 3] * qs[jt][3] + o2[jt][3];
    ss0 += ov[jt][0] * ov[jt][0];
    ss1 += ov[jt][1] * ov[jt][1];
    ss2 += ov[jt][2] * ov[jt][2];
    ss3 += ov[jt][3] * ov[jt][3];
  }
#pragma unroll
  for (int m = 1; m < 16; m <<= 1) {
    ss0 += __shfl_xor(ss0, m);
    ss1 += __shfl_xor(ss1, m);
    ss2 += __shfl_xor(ss2, m);
    ss3 += __shfl_xor(ss3, m);
  }
  float rr[4];
  rr[0] = 1.f / sqrtf(ss0 * (1.f / HD_) + 1e-6f);
  rr[1] = 1.f / sqrtf(ss1 * (1.f / HD_) + 1e-6f);
  rr[2] = 1.f / sqrtf(ss2 * (1.f / HD_) + 1e-6f);
  rr[3] = 1.f / sqrtf(ss3 * (1.f / HD_) + 1e-6f);
#pragma unroll
  for (int jt = 0; jt < 8; ++jt) {
    const int e = 16 * jt + l15;
    const float wv = nws[e];
#pragma unroll
    for (int r = 0; r < 4; ++r) {
      const int t = 16 * wave + rrow + r;
      const float zf = b2f(zbuf[((size_t)b * T_ + t0g + t) * VD_ + h * HD_ + e]);
      const float g = zf / (1.f + expf(-zf));
      outg[(((size_t)b * T_ + t0g + t) * NV_ + h) * HD_ + e] =
          f2b(ov[jt][r] * rr[r] * wv * g);
    }
  }
}

// ---------------------------------------------------------------------------
extern "C" void kernel_launch(void* const* d_in, const int* in_sizes, int n_in,
                              void* d_out, int out_size, void* d_ws, size_t ws_size,
                              hipStream_t stream) {
  const float* x    = (const float*)d_in[0];
  const float* Wqkv = (const float*)d_in[1];
  const float* Wz   = (const float*)d_in[2];
  const float* Wb   = (const float*)d_in[3];
  const float* Wa   = (const float*)d_in[4];
  const float* cw   = (const float*)d_in[5];
  const float* dtb  = (const float*)d_in[6];
  const float* alog = (const float*)d_in[7];
  const float* nw   = (const float*)d_in[8];
  const float* Wout = (const float*)d_in[9];

  // ---- workspace layout: 210.5 MB total (<= proven-safe 213.4 MB) ----
  char* p = (char*)d_ws;
  ushort_t* qkv_raw = (ushort_t*)p; p += (size_t)B_ * T_ * CD_ * 2;       // 33.55 MB
  ushort_t* zbuf    = (ushort_t*)p; p += (size_t)B_ * T_ * VD_ * 2;       // 16.78 MB
  ushort_t* act     = (ushort_t*)p; p += (size_t)B_ * T_ * CD_ * 2;       // 33.55 MB (bf16)
  float*    betaB   = (float*)p;    p += (size_t)B_ * T_ * NV_ * 4;       //  0.26 MB
  float*    gBuf    = (float*)p;    p += (size_t)B_ * T_ * NV_ * 4;       //  0.26 MB
  float*    gtG     = (float*)p;    p += (size_t)1024 * 64 * 4;           //  0.26 MB
  ushort_t* xB      = (ushort_t*)p; p += (size_t)B_ * T_ * HID_ * 2;      // 16.78 MB
  ushort_t* WzB     = (ushort_t*)p; p += (size_t)VD_ * HID_ * 2;          //  8.39 MB
  ushort_t* MTG     = (ushort_t*)p; p += (size_t)1024 * CHM_ * 2;         // 33.55 MB
  ushort_t* NTG     = (ushort_t*)p; p += (size_t)1024 * CHM_ * 2;         // 33.55 MB
  ushort_t* ScG     = (ushort_t*)p; p += (size_t)1024 * CHM_ * 2;         // 33.55 MB
  // overlays:
  ushort_t* WkG   = qkv_raw;                             // 16.78 MB (post-conv)
  ushort_t* UlT   = qkv_raw + (size_t)1024 * 64 * 128;   // 16.78 MB (post-conv, exact fit)
  ushort_t* WqkvB = act;                                 // 16.78 MB (pre-conv)
  ushort_t* outg  = MTG;                                 // 16.78 MB (post-scan)
  ushort_t* WoutB = NTG;                                 //  8.39 MB (post-scan; cast moved)

  const int M = B_ * T_;  // 4096

  const int n0 = M * HID_ / 4, n1 = CD_ * HID_ / 4, n2 = VD_ * HID_ / 4;
  hipLaunchKernelGGL(k_cast3, dim3((n0 + n1 + n2 + 255) / 256), dim3(256), 0, stream,
                     x, xB, n0, Wqkv, WqkvB, n1, Wz, WzB, n2);

  hipLaunchKernelGGL(k_gemm256<ushort_t>, dim3((M / 256) * (CD_ / 256)), dim3(512), 0, stream,
                     xB, WqkvB, qkv_raw, M, CD_, HID_);
  hipLaunchKernelGGL(k_proj_ba, dim3(M / 16), dim3(256), 0, stream,
                     x, Wb, Wa, dtb, alog, betaB, gBuf);
  hipLaunchKernelGGL(k_conv_silu_norm, dim3(M), dim3(256), 0, stream,
                     qkv_raw, cw, act);
  hipLaunchKernelGGL(k_prep, dim3(B_ * NV_ * 32), dim3(256), 0, stream,
                     act, gBuf, betaB, WkG, UlT, gtG, MTG, NTG);
  hipLaunchKernelGGL(k_scan_zgemm, dim3(64 + (M / 256) * (VD_ / 256)), dim3(512), 0, stream,
                     MTG, NTG, ScG, xB, WzB, zbuf);
  hipLaunchKernelGGL(k_cast_bf16, dim3(HID_ * VD_ / 4 / 256), dim3(256), 0, stream,
                     Wout, WoutB, HID_ * VD_ / 4);
  hipLaunchKernelGGL(k_out, dim3(B_ * NV_ * 32), dim3(256), 0, stream,
                     act, WkG, UlT, gtG, ScG, zbuf, nw, outg);
  hipLaunchKernelGGL(k_gemm256x128<float>, dim3((M / 256) * (HID_ / 128)), dim3(512), 0, stream,
                     outg, WoutB, (float*)d_out, M, HID_, VD_);
}

// Round 20
// 444.265 us; speedup vs baseline: 1.2208x; 1.0719x over previous
//
#include <hip/hip_runtime.h>
#include <cstdint>
#include <cstddef>

// GatedDeltaNet forward, MI355X/gfx950.
// R20 = R19 with M/N dematerialized: k_prep drops P4 (-67 MB writes, -64 MFMA,
// -384 scalar LDS ops/thread) and stores only KTG (raw K^T, even-h blocks);
// the scan recomputes u-phase + S-update in-loop (R9-verified math, R12-
// verified staging): u^ = esc*(Ul^T + S.Wk^T); S' = gCe*S + u^T.K.
// Casts merged into one 4-range k_cast4 (WoutB now dedicated, cast early).

typedef unsigned short ushort_t;
typedef __attribute__((ext_vector_type(8))) __bf16 bf16x8;
typedef __attribute__((ext_vector_type(4))) float f32x4;
typedef __attribute__((ext_vector_type(4))) short short4v;

#define B_   2
#define T_   2048
#define HID_ 2048
#define NK_  8
#define NV_  16
#define HD_  128
#define KD_  1024
#define VD_  2048
#define CD_  4096
#define CHM_ 16384   // 128*128 elems per per-chunk Sc snapshot

__device__ __forceinline__ float b2f(ushort_t u) {
  union { unsigned int i; float f; } v; v.i = ((unsigned int)u) << 16; return v.f;
}
__device__ __forceinline__ ushort_t f2b(float f) {   // RNE bf16 round
  unsigned int x = __builtin_bit_cast(unsigned int, f);
  unsigned int r = x + 0x7fffu + ((x >> 16) & 1u);
  return (ushort_t)(r >> 16);
}

// ---------------------------------------------------------------------------
// fp32 -> bf16 casts: single kernel, four (src,dst) ranges
// ---------------------------------------------------------------------------
__global__ __launch_bounds__(256)
void k_cast4(const float* __restrict__ s0, ushort_t* __restrict__ d0, int n0,
             const float* __restrict__ s1, ushort_t* __restrict__ d1, int n1,
             const float* __restrict__ s2, ushort_t* __restrict__ d2, int n2,
             const float* __restrict__ s3, ushort_t* __restrict__ d3, int n3) {
  int i = blockIdx.x * 256 + threadIdx.x;
  const float* s; ushort_t* d;
  if (i < n0) { s = s0; d = d0; }
  else if (i < n0 + n1) { i -= n0; s = s1; d = d1; }
  else if (i < n0 + n1 + n2) { i -= n0 + n1; s = s2; d = d2; }
  else { i -= n0 + n1 + n2; if (i >= n3) return; s = s3; d = d3; }
  float4 v = *(const float4*)(s + (size_t)i * 4);
  short4v o;
  o[0] = (short)f2b(v.x); o[1] = (short)f2b(v.y);
  o[2] = (short)f2b(v.z); o[3] = (short)f2b(v.w);
  *(short4v*)(d + (size_t)i * 4) = o;
}

// ---------------------------------------------------------------------------
// GEMM 256x256 body, BK=64, 8 waves, counted-vmcnt pipeline (R8-verified).
// ---------------------------------------------------------------------------
#define LPOS(BUF, OP, HALF) ((((BUF) * 2 + (OP)) * 2 + (HALF)) * 8192)

template <typename OutT>
__device__ __forceinline__ void gemm256_body(
    const ushort_t* __restrict__ A, const ushort_t* __restrict__ Bw,
    OutT* __restrict__ C, int M, int N, int K, int tile, ushort_t* lds) {
  const int tid = threadIdx.x;
  const int lane = tid & 63, wave = tid >> 6;
  const int wm = wave >> 2, wc = wave & 3;
  const int l15 = lane & 15;
  const int ks16 = (lane >> 4) * 16;
  const int r4 = (lane >> 4) * 4;
  const int nkt = K >> 6;
  const int nbx = N >> 8;
  const size_t row0 = (size_t)(tile / nbx) * 256;
  const size_t col0 = (size_t)(tile % nbx) * 256;

#define STAGE4(BUF, HALF, KT) {                                               \
    const int kt_ = ((KT) < nkt) ? (KT) : (nkt - 1);                          \
    const int kb_ = kt_ * 64 + (HALF) * 32;                                   \
    _Pragma("unroll") for (int r_ = 0; r_ < 2; ++r_) {                        \
      const int wb_ = r_ * 8192 + wave * 1024;                                \
      const int o_  = wb_ + lane * 16;                                        \
      const int row_ = o_ >> 6;                                               \
      const int src_ = (o_ & 63) ^ (((row_) & 3) << 4);                       \
      const ushort_t* ga_ = A  + (row0 + row_) * (size_t)K + kb_ + (src_ >> 1); \
      const ushort_t* gb_ = Bw + (col0 + row_) * (size_t)K + kb_ + (src_ >> 1); \
      __builtin_amdgcn_global_load_lds(                                       \
          (const __attribute__((address_space(1))) unsigned int*)ga_,         \
          (__attribute__((address_space(3))) unsigned int*)                   \
              (lds + LPOS(BUF, 0, HALF) + (wb_ >> 1)), 16, 0, 0);             \
      __builtin_amdgcn_global_load_lds(                                       \
          (const __attribute__((address_space(1))) unsigned int*)gb_,         \
          (__attribute__((address_space(3))) unsigned int*)                   \
              (lds + LPOS(BUF, 1, HALF) + (wb_ >> 1)), 16, 0, 0);             \
    }                                                                         \
  }

#define RD(BUF, OP, HALF, ROW)                                                \
  (*(const bf16x8*)((const char*)(lds + LPOS(BUF, OP, HALF)) +                \
                    ((((ROW) * 64 + ks16)) ^ (((ROW) & 3) << 4))))

  f32x4 acc[8][4] = {};
  STAGE4(0, 0, 0)
  STAGE4(0, 1, 0)
  STAGE4(1, 0, 1)

  for (int kt = 0; kt < nkt; ++kt) {
    const int cb = kt & 1, nb = cb ^ 1;
    asm volatile("s_waitcnt vmcnt(8)" ::: "memory");
    __builtin_amdgcn_s_barrier();
    {
      bf16x8 af[8], bfr[4];
#pragma unroll
      for (int mf = 0; mf < 8; ++mf) af[mf] = RD(cb, 0, 0, wm * 128 + mf * 16 + l15);
#pragma unroll
      for (int nf = 0; nf < 4; ++nf) bfr[nf] = RD(cb, 1, 0, wc * 64 + nf * 16 + l15);
      STAGE4(nb, 1, kt + 1)
      __builtin_amdgcn_s_setprio(1);
#pragma unroll
      for (int mf = 0; mf < 8; ++mf)
#pragma unroll
        for (int nf = 0; nf < 4; ++nf)
          acc[mf][nf] = __builtin_amdgcn_mfma_f32_16x16x32_bf16(af[mf], bfr[nf], acc[mf][nf], 0, 0, 0);
      __builtin_amdgcn_s_setprio(0);
    }
    asm volatile("s_waitcnt vmcnt(8)" ::: "memory");
    __builtin_amdgcn_s_barrier();
    {
      bf16x8 af[8], bfr[4];
#pragma unroll
      for (int mf = 0; mf < 8; ++mf) af[mf] = RD(cb, 0, 1, wm * 128 + mf * 16 + l15);
#pragma unroll
      for (int nf = 0; nf < 4; ++nf) bfr[nf] = RD(cb, 1, 1, wc * 64 + nf * 16 + l15);
      STAGE4(cb, 0, kt + 2)
      __builtin_amdgcn_s_setprio(1);
#pragma unroll
      for (int mf = 0; mf < 8; ++mf)
#pragma unroll
        for (int nf = 0; nf < 4; ++nf)
          acc[mf][nf] = __builtin_amdgcn_mfma_f32_16x16x32_bf16(af[mf], bfr[nf], acc[mf][nf], 0, 0, 0);
      __builtin_amdgcn_s_setprio(0);
    }
  }
#undef STAGE4
#undef RD

#pragma unroll
  for (int mf = 0; mf < 8; ++mf)
#pragma unroll
    for (int nf = 0; nf < 4; ++nf)
#pragma unroll
      for (int j = 0; j < 4; ++j) {
        const size_t row = row0 + wm * 128 + mf * 16 + r4 + j;
        const size_t col = col0 + wc * 64 + nf * 16 + l15;
        if constexpr (sizeof(OutT) == 4)
          C[row * (size_t)N + col] = acc[mf][nf][j];
        else
          C[row * (size_t)N + col] = (OutT)f2b(acc[mf][nf][j]);
      }
}

template <typename OutT>
__global__ __launch_bounds__(512, 2)
void k_gemm256(const ushort_t* __restrict__ A, const ushort_t* __restrict__ Bw,
               OutT* __restrict__ C, int M, int N, int K) {
  __shared__ alignas(16) ushort_t lds[2 * 2 * 2 * 8192];
  const int nwg = gridDim.x;
  const int q8 = nwg >> 3, r8 = nwg & 7;
  const int xcd = blockIdx.x & 7, idx8 = blockIdx.x >> 3;
  const int s = (xcd < r8) ? (xcd * (q8 + 1) + idx8)
                           : (r8 * (q8 + 1) + (xcd - r8) * q8 + idx8);
  gemm256_body<OutT>(A, Bw, C, M, N, K, s, lds);
}

// ---------------------------------------------------------------------------
// GEMM 256x128 tile (R17-verified): counted-vmcnt, 3 loads/half, vmcnt(6).
// ---------------------------------------------------------------------------
#define LPA(BUF, HALF) (((BUF) * 2 + (HALF)) * 8192)
#define LPB(BUF, HALF) (32768 + ((BUF) * 2 + (HALF)) * 4096)

template <typename OutT>
__global__ __launch_bounds__(512, 1)
void k_gemm256x128(const ushort_t* __restrict__ A, const ushort_t* __restrict__ Bw,
                   OutT* __restrict__ C, int M, int N, int K) {
  __shared__ alignas(16) ushort_t lds[49152];   // 96 KB
  const int tid = threadIdx.x;
  const int lane = tid & 63, wave = tid >> 6;
  const int wm = wave >> 1, wc = wave & 1;
  const int l15 = lane & 15;
  const int ks16 = (lane >> 4) * 16;
  const int r4 = (lane >> 4) * 4;
  const int nkt = K >> 6;
  const int nbx = N >> 7;
  const int nwg = gridDim.x;
  const int q8 = nwg >> 3, r8 = nwg & 7;
  const int xcd = blockIdx.x & 7, idx8 = blockIdx.x >> 3;
  const int s = (xcd < r8) ? (xcd * (q8 + 1) + idx8)
                           : (r8 * (q8 + 1) + (xcd - r8) * q8 + idx8);
  const size_t row0 = (size_t)(s / nbx) * 256;
  const size_t col0 = (size_t)(s % nbx) * 128;

#define STG3(BUF, HALF, KT) {                                                 \
    const int kt_ = ((KT) < nkt) ? (KT) : (nkt - 1);                          \
    const int kb_ = kt_ * 64 + (HALF) * 32;                                   \
    _Pragma("unroll") for (int r_ = 0; r_ < 2; ++r_) {                        \
      const int wb_ = r_ * 8192 + wave * 1024;                                \
      const int o_  = wb_ + lane * 16;                                        \
      const int row_ = o_ >> 6;                                               \
      const int src_ = (o_ & 63) ^ (((row_) & 3) << 4);                       \
      const ushort_t* ga_ = A + (row0 + row_) * (size_t)K + kb_ + (src_ >> 1); \
      __builtin_amdgcn_global_load_lds(                                       \
          (const __attribute__((address_space(1))) unsigned int*)ga_,         \
          (__attribute__((address_space(3))) unsigned int*)                   \
              (lds + LPA(BUF, HALF) + (wb_ >> 1)), 16, 0, 0);                 \
    }                                                                         \
    {                                                                         \
      const int wb_ = wave * 1024;                                            \
      const int o_  = wb_ + lane * 16;                                        \
      const int row_ = o_ >> 6;                                               \
      const int src_ = (o_ & 63) ^ (((row_) & 3) << 4);                       \
      const ushort_t* gb_ = Bw + (col0 + row_) * (size_t)K + kb_ + (src_ >> 1); \
      __builtin_amdgcn_global_load_lds(                                       \
          (const __attribute__((address_space(1))) unsigned int*)gb_,         \
          (__attribute__((address_space(3))) unsigned int*)                   \
              (lds + LPB(BUF, HALF) + (wb_ >> 1)), 16, 0, 0);                 \
    }                                                                         \
  }

#define RDA(BUF, HALF, ROW)                                                   \
  (*(const bf16x8*)((const char*)(lds + LPA(BUF, HALF)) +                     \
                    ((((ROW) * 64 + ks16)) ^ (((ROW) & 3) << 4))))
#define RDB(BUF, HALF, ROW)                                                   \
  (*(const bf16x8*)((const char*)(lds + LPB(BUF, HALF)) +                     \
                    ((((ROW) * 64 + ks16)) ^ (((ROW) & 3) << 4))))

  f32x4 acc[4][4] = {};
  STG3(0, 0, 0)
  STG3(0, 1, 0)
  STG3(1, 0, 1)

  for (int kt = 0; kt < nkt; ++kt) {
    const int cb = kt & 1, nb = cb ^ 1;
    asm volatile("s_waitcnt vmcnt(6)" ::: "memory");
    __builtin_amdgcn_s_barrier();
    {
      bf16x8 af[4], bfr[4];
#pragma unroll
      for (int mf = 0; mf < 4; ++mf) af[mf] = RDA(cb, 0, wm * 64 + mf * 16 + l15);
#pragma unroll
      for (int nf = 0; nf < 4; ++nf) bfr[nf] = RDB(cb, 0, wc * 64 + nf * 16 + l15);
      STG3(nb, 1, kt + 1)
      __builtin_amdgcn_s_setprio(1);
#pragma unroll
      for (int mf = 0; mf < 4; ++mf)
#pragma unroll
        for (int nf = 0; nf < 4; ++nf)
          acc[mf][nf] = __builtin_amdgcn_mfma_f32_16x16x32_bf16(af[mf], bfr[nf], acc[mf][nf], 0, 0, 0);
      __builtin_amdgcn_s_setprio(0);
    }
    asm volatile("s_waitcnt vmcnt(6)" ::: "memory");
    __builtin_amdgcn_s_barrier();
    {
      bf16x8 af[4], bfr[4];
#pragma unroll
      for (int mf = 0; mf < 4; ++mf) af[mf] = RDA(cb, 1, wm * 64 + mf * 16 + l15);
#pragma unroll
      for (int nf = 0; nf < 4; ++nf) bfr[nf] = RDB(cb, 1, wc * 64 + nf * 16 + l15);
      STG3(cb, 0, kt + 2)
      __builtin_amdgcn_s_setprio(1);
#pragma unroll
      for (int mf = 0; mf < 4; ++mf)
#pragma unroll
        for (int nf = 0; nf < 4; ++nf)
          acc[mf][nf] = __builtin_amdgcn_mfma_f32_16x16x32_bf16(af[mf], bfr[nf], acc[mf][nf], 0, 0, 0);
      __builtin_amdgcn_s_setprio(0);
    }
  }
#undef STG3
#undef RDA
#undef RDB

#pragma unroll
  for (int mf = 0; mf < 4; ++mf)
#pragma unroll
    for (int nf = 0; nf < 4; ++nf)
#pragma unroll
      for (int j = 0; j < 4; ++j) {
        const size_t row = row0 + wm * 64 + mf * 16 + r4 + j;
        const size_t col = col0 + wc * 64 + nf * 16 + l15;
        if constexpr (sizeof(OutT) == 4)
          C[row * (size_t)N + col] = acc[mf][nf][j];
        else
          C[row * (size_t)N + col] = (OutT)f2b(acc[mf][nf][j]);
      }
}

// ---------------------------------------------------------------------------
// b/a projection, W-amortized (R12-verified).
// ---------------------------------------------------------------------------
__global__ __launch_bounds__(256, 2)
void k_proj_ba(const float* __restrict__ x, const float* __restrict__ Wb,
               const float* __restrict__ Wa, const float* __restrict__ dtb,
               const float* __restrict__ alog,
               float* __restrict__ beta, float* __restrict__ gout) {
  __shared__ __bf16 Wl[16][2048];
  __shared__ float part[16][16];
  const int tid = threadIdx.x;
  const int o = tid & 15, seg = tid >> 4;
  const int bt0 = blockIdx.x * 16;

#define PROJ_PASS(WSRC, EMIT) {                                               \
    for (int i = tid; i < 8192; i += 256) {                                   \
      const int os_ = i >> 9, k4_ = i & 511;                                  \
      float4 w_ = *(const float4*)(WSRC + (size_t)os_ * HID_ + k4_ * 4);      \
      const int b_ = k4_ * 8;                                                 \
      __bf16* d_ = (__bf16*)((char*)&Wl[0][0] + os_ * 4096 +                  \
                   (((b_ & ~15) ^ ((os_ & 15) << 4)) | (b_ & 8)));            \
      d_[0] = (__bf16)w_.x; d_[1] = (__bf16)w_.y;                             \
      d_[2] = (__bf16)w_.z; d_[3] = (__bf16)w_.w;                             \
    }                                                                         \
    __syncthreads();                                                          \
    for (int rr = 0; rr < 16; ++rr) {                                         \
      const int bt = bt0 + rr;                                                \
      const float* xr = x + (size_t)bt * HID_;                                \
      float s = 0.f;                                                          \
      _Pragma("unroll") for (int j = 0; j < 16; ++j) {                        \
        const int k = seg * 128 + j * 8;                                      \
        float4 xa = *(const float4*)&xr[k];                                   \
        float4 xb = *(const float4*)&xr[k + 4];                               \
        bf16x8 wv = *(const bf16x8*)((const char*)&Wl[0][0] + o * 4096 +      \
                     ((k * 2) ^ ((o & 15) << 4)));                            \
        s += (float)wv[0]*xa.x + (float)wv[1]*xa.y + (float)wv[2]*xa.z +      \
             (float)wv[3]*xa.w + (float)wv[4]*xb.x + (float)wv[5]*xb.y +      \
             (float)wv[6]*xb.z + (float)wv[7]*xb.w;                           \
      }                                                                       \
      part[o][seg] = s;                                                       \
      __syncthreads();                                                        \
      if (tid < 16) {                                                         \
        float t_ = 0.f;                                                       \
        _Pragma("unroll") for (int i2 = 0; i2 < 16; ++i2) t_ += part[tid][i2];\
        EMIT                                                                  \
      }                                                                       \
      __syncthreads();                                                        \
    }                                                                         \
  }

  PROJ_PASS(Wb, {
    beta[(size_t)bt * NV_ + tid] = 1.f / (1.f + expf(-t_));
  })
  __syncthreads();
  PROJ_PASS(Wa, {
    float aa = t_ + dtb[tid];
    float sp = (aa > 20.f) ? aa : log1pf(expf(aa));
    gout[(size_t)bt * NV_ + tid] = -expf(alog[tid]) * sp;
  })
#undef PROJ_PASS
}

// ---------------------------------------------------------------------------
// Fused depthwise causal conv1d (K=4) + silu + l2norm(q,k). (R14-verified)
// ---------------------------------------------------------------------------
__global__ __launch_bounds__(256)
void k_conv_silu_norm(const ushort_t* __restrict__ qkv, const float* __restrict__ cw,
                      ushort_t* __restrict__ act) {
  const int bt = blockIdx.x;
  const int tid = threadIdx.x;
  const int t = bt & (T_ - 1);
  const int c = tid * 16;
  const ushort_t* rowp = qkv + (size_t)bt * CD_ + c;

  float wf[16][4];
#pragma unroll
  for (int i = 0; i < 16; ++i) {
    float4 w = *(const float4*)&cw[(c + i) * 4];
    wf[i][0] = w.x; wf[i][1] = w.y; wf[i][2] = w.z; wf[i][3] = w.w;
  }
  float a[16];
#pragma unroll
  for (int i = 0; i < 16; ++i) a[i] = 0.f;
#pragma unroll
  for (int j = 0; j < 4; ++j) {
    const int tt = t - 3 + j;
    if (tt >= 0) {
      const ushort_t* src = rowp + ((ptrdiff_t)j - 3) * CD_;
      bf16x8 v0 = *(const bf16x8*)(const void*)src;
      bf16x8 v1 = *(const bf16x8*)(const void*)(src + 8);
#pragma unroll
      for (int i = 0; i < 8; ++i) {
        a[i]     += (float)v0[i] * wf[i][j];
        a[8 + i] += (float)v1[i] * wf[8 + i][j];
      }
    }
  }
#pragma unroll
  for (int i = 0; i < 16; ++i) a[i] = a[i] / (1.f + expf(-a[i]));
  float ss = 0.f;
#pragma unroll
  for (int i = 0; i < 16; ++i) ss += a[i] * a[i];
  ss += __shfl_xor(ss, 1); ss += __shfl_xor(ss, 2); ss += __shfl_xor(ss, 4);
  const int seg = tid >> 3;
  float scale = 1.f;
  if (seg < 16) {
    scale = 1.f / fmaxf(sqrtf(ss), 1e-12f);
    if (seg < 8) scale *= 0.08838834764831845f;
  }
  ushort_t ov[16];
#pragma unroll
  for (int i = 0; i < 16; ++i) ov[i] = f2b(a[i] * scale);
  ushort_t* dst = act + (size_t)bt * CD_ + c;
  *(uint4*)(void*)dst       = *(const uint4*)&ov[0];
  *(uint4*)(void*)(dst + 8) = *(const uint4*)&ov[8];
}

// ---------------------------------------------------------------------------
// k_prep: per-chunk parallel precompute. grid = 1024. act is bf16.
// R20: P4 removed; outputs WkG, UlT, KTG (even h), gtG only.
// ---------------------------------------------------------------------------
__global__ __launch_bounds__(256, 1)
void k_prep(const ushort_t* __restrict__ act, const float* __restrict__ gB,
            const float* __restrict__ betaB,
            ushort_t* __restrict__ WkG, ushort_t* __restrict__ UlT,
            ushort_t* __restrict__ KTG, float* __restrict__ gtG) {
  __shared__ __bf16 Kl[64][136];
  __shared__ __bf16 AbL[64][40];
  __shared__ __bf16 AbH[32][33];
  __shared__ __bf16 Xl[64][264];
  __shared__ alignas(16) __bf16 Cr[16][264];
  __shared__ float gc[65], Et[65], Rt[65], bts[64], geT[64];

  const int wg = blockIdx.x;
  const int c = wg & 31, h = (wg >> 5) & 15, b = wg >> 9;
  const int hq = h >> 1, t0 = c * 64;
  const int tid = threadIdx.x, lane = tid & 63, wave = tid >> 6;
  const int l15 = lane & 15, kcol0 = (lane >> 4) * 8, rrow = (lane >> 4) * 4;
  const size_t bhc = (size_t)wg;

  const ushort_t* baseQ = act + (size_t)b * T_ * CD_ + hq * HD_;
  const ushort_t* baseK = baseQ + KD_;

  if (tid < 64) {
    float g = gB[((size_t)b * T_ + t0 + tid) * NV_ + h];
    bts[tid] = betaB[((size_t)b * T_ + t0 + tid) * NV_ + h];
#pragma unroll
    for (int o = 1; o < 64; o <<= 1) {
      float up = __shfl_up(g, (unsigned)o);
      if (tid >= o) g += up;
    }
    gc[tid + 1] = g;
    if (tid == 0) gc[0] = 0.f;
  }
  __syncthreads();
  if (tid < 65) {
    float gm = gc[32];
    Et[tid] = __expf(gc[tid] - gm);
    Rt[tid] = __expf(gm - gc[tid]);
  }
  if (tid < 64) {
    geT[tid] = bts[tid] * __expf(gc[tid + 1]);
    gtG[bhc * 64 + tid] = gc[tid + 1];
  }
  {
    const int t = tid >> 2, d0 = (tid & 3) * 32;
    const ushort_t* src = baseK + (size_t)(t0 + t) * CD_ + d0;
#pragma unroll
    for (int j = 0; j < 4; ++j)
      *(uint4*)&Kl[t][d0 + j * 8] = *(const uint4*)(const void*)(src + j * 8);
  }
  __syncthreads();

  // P1: Ab (strict lower, -beta*scale*KK^T) in LDS
  {
    bf16x8 kf[4];
#pragma unroll
    for (int kk = 0; kk < 4; ++kk)
      kf[kk] = *(const bf16x8*)&Kl[16 * wave + l15][kk * 32 + kcol0];
#pragma unroll
    for (int st = 0; st < 4; ++st) {
      if (st <= wave) {
        f32x4 accA = {};
#pragma unroll
        for (int kk = 0; kk < 4; ++kk) {
          bf16x8 bfr = *(const bf16x8*)&Kl[st * 16 + l15][kk * 32 + kcol0];
          accA = __builtin_amdgcn_mfma_f32_16x16x32_bf16(kf[kk], bfr, accA, 0, 0, 0);
        }
        const int scol = st * 16 + l15;
#pragma unroll
        for (int r = 0; r < 4; ++r) {
          const int t = 16 * wave + rrow + r;
          if (scol < t) {
            const float av = -bts[t] * Et[t + 1] * Rt[scol + 1] * accA[r];
            if (scol < 32) AbL[t][scol] = (__bf16)av;
            else           AbH[t - 32][scol - 32] = (__bf16)av;
          }
        }
      }
    }
  }
  __syncthreads();

  // KT store (raw K^T, shared by the v-head pair; even h only)
  if ((h & 1) == 0) {
    const size_t kto = (((size_t)b * 8 + hq) * 32 + c) * (128 * 64);
    const int d = tid >> 1, t8 = (tid & 1) * 32;
#pragma unroll
    for (int i8 = 0; i8 < 4; ++i8) {
      bf16x8 tmp;
#pragma unroll
      for (int jj = 0; jj < 8; ++jj) tmp[jj] = Kl[t8 + i8 * 8 + jj][d];
      *(bf16x8*)(void*)(KTG + kto + (size_t)d * 64 + t8 + i8 * 8) = tmp;
    }
  }

  // P2: block-16 recursive triangular solve (R19-verified).
  {
    float r1[32], r2[32];
    if (tid < 128) {
      const int d = tid;
#pragma unroll
      for (int t = 0; t < 32; ++t) r1[t] = geT[t] * (float)Kl[t][d];
#pragma unroll
      for (int t = 0; t < 32; ++t) r2[t] = geT[32 + t] * (float)Kl[32 + t][d];
    } else {
      const int j = tid - 128;
      const ushort_t* vsrc = act + ((size_t)b * T_ + t0) * CD_ + 2 * KD_ + h * HD_ + j;
#pragma unroll
      for (int t = 0; t < 32; ++t) r1[t] = bts[t] * b2f(vsrc[(size_t)t * CD_]);
#pragma unroll
      for (int t = 0; t < 32; ++t) r2[t] = bts[32 + t] * b2f(vsrc[(size_t)(32 + t) * CD_]);
    }

    // block 0: rows 0..15
    {
      float u[16];
#pragma unroll
      for (int j = 0; j < 16; ++j) {
        float a = r1[j];
#pragma unroll
        for (int i = 0; i < j; ++i) a += (float)AbL[j][i] * u[i];
        u[j] = a;
        Xl[j][tid] = (__bf16)a;
      }
    }
    __syncthreads();

    // corr 1: rows 16..31 <- L(1,0)@U0 (K=16, register-zero-padded)
    {
      bf16x8 afr2;
#pragma unroll
      for (int j = 0; j < 8; ++j) {
        const int k = kcol0 + j;
        afr2[j] = (k < 16) ? AbL[16 + l15][k] : (__bf16)0.f;
      }
#pragma unroll
      for (int ct4 = 0; ct4 < 4; ++ct4) {
        const int ct = wave * 4 + ct4;
        bf16x8 bfr2;
#pragma unroll
        for (int j = 0; j < 8; ++j) {
          const int k = kcol0 + j;
          bfr2[j] = (k < 16) ? Xl[k][16 * ct + l15] : (__bf16)0.f;
        }
        f32x4 acc2 = {};
        acc2 = __builtin_amdgcn_mfma_f32_16x16x32_bf16(afr2, bfr2, acc2, 0, 0, 0);
#pragma unroll
        for (int r = 0; r < 4; ++r)
          Cr[rrow + r][16 * ct + l15] = (__bf16)acc2[r];
      }
    }
    __syncthreads();

    // block 1: rows 16..31
    {
      float u[16];
#pragma unroll
      for (int j = 0; j < 16; ++j) {
        float a = r1[16 + j] + (float)Cr[j][tid];
#pragma unroll
        for (int i = 0; i < j; ++i) a += (float)AbL[16 + j][16 + i] * u[i];
        u[j] = a;
        Xl[16 + j][tid] = (__bf16)a;
      }
    }
    __syncthreads();

    // corr 2: rows 32..47 <- [L(2,0) L(2,1)]@[U0;U1] (K=32)
    {
      bf16x8 afr2 = *(const bf16x8*)&AbL[32 + l15][kcol0];
#pragma unroll
      for (int ct4 = 0; ct4 < 4; ++ct4) {
        const int ct = wave * 4 + ct4;
        bf16x8 bfr2;
#pragma unroll
        for (int j = 0; j < 8; ++j) bfr2[j] = Xl[kcol0 + j][16 * ct + l15];
        f32x4 acc2 = {};
        acc2 = __builtin_amdgcn_mfma_f32_16x16x32_bf16(afr2, bfr2, acc2, 0, 0, 0);
#pragma unroll
        for (int r = 0; r < 4; ++r)
          Cr[rrow + r][16 * ct + l15] = (__bf16)acc2[r];
      }
    }
    __syncthreads();

    // block 2: rows 32..47
    {
      float u[16];
#pragma unroll
      for (int j = 0; j < 16; ++j) {
        float a = r2[j] + (float)Cr[j][tid];
#pragma unroll
        for (int i = 0; i < j; ++i) a += (float)AbH[j][i] * u[i];
        u[j] = a;
        Xl[32 + j][tid] = (__bf16)a;
      }
    }
    __syncthreads();

    // corr 3: rows 48..63 <- [L(3,0) L(3,1)]@[U0;U1] + L(3,2)@U2 (K=16 padded)
    {
      bf16x8 afrA = *(const bf16x8*)&AbL[48 + l15][kcol0];
      bf16x8 afrB;
#pragma unroll
      for (int j = 0; j < 8; ++j) {
        const int k = kcol0 + j;
        afrB[j] = (k < 16) ? AbH[16 + l15][k] : (__bf16)0.f;
      }
#pragma unroll
      for (int ct4 = 0; ct4 < 4; ++ct4) {
        const int ct = wave * 4 + ct4;
        bf16x8 bfrA, bfrB;
#pragma unroll
        for (int j = 0; j < 8; ++j) {
          const int k = kcol0 + j;
          bfrA[j] = Xl[k][16 * ct + l15];
          bfrB[j] = (k < 16) ? Xl[32 + k][16 * ct + l15] : (__bf16)0.f;
        }
        f32x4 acc2 = {};
        acc2 = __builtin_amdgcn_mfma_f32_16x16x32_bf16(afrA, bfrA, acc2, 0, 0, 0);
        acc2 = __builtin_amdgcn_mfma_f32_16x16x32_bf16(afrB, bfrB, acc2, 0, 0, 0);
#pragma unroll
        for (int r = 0; r < 4; ++r)
          Cr[rrow + r][16 * ct + l15] = (__bf16)acc2[r];
      }
    }
    __syncthreads();

    // block 3: rows 48..63
    {
      float u[16];
#pragma unroll
      for (int j = 0; j < 16; ++j) {
        float a = r2[16 + j] + (float)Cr[j][tid];
#pragma unroll
        for (int i = 0; i < j; ++i) a += (float)AbH[16 + j][16 + i] * u[i];
        u[j] = a;
        Xl[48 + j][tid] = (__bf16)a;
      }
    }
  }
  __syncthreads();

  // P3: Wk copy (negated, stride 128) + Uloc^T store (stride 64)
#pragma unroll
  for (int kck = 0; kck < 4; ++kck) {
    const int q = tid + kck * 256;
    const int t = q >> 4, d0 = (q & 15) * 8;
    uint4 v = *(const uint4*)&Xl[t][d0];
    v.x ^= 0x80008000u; v.y ^= 0x80008000u; v.z ^= 0x80008000u; v.w ^= 0x80008000u;
    *(uint4*)(void*)(WkG + bhc * (64 * 128) + (size_t)t * 128 + d0) = v;
  }
  {
    const int e = tid >> 1, t8 = (tid & 1) * 32;
#pragma unroll
    for (int i8 = 0; i8 < 4; ++i8) {
      bf16x8 tmp;
#pragma unroll
      for (int jj = 0; jj < 8; ++jj) tmp[jj] = Xl[t8 + i8 * 8 + jj][128 + e];
      *(bf16x8*)(void*)(UlT + bhc * (128 * 64) + (size_t)e * 64 + t8 + i8 * 8) = tmp;
    }
  }
}

// ---------------------------------------------------------------------------
// scan body (R20): per chunk, u-phase + S-update recomputed from Wk/Ul/KT
// (M/N dematerialized). Staging: R12 discipline (pre-swizzled source +
// XOR reads, double-buffered, vmcnt drained only at chunk-top __syncthreads).
// ---------------------------------------------------------------------------
__device__ __forceinline__ void scan_body(
    const ushort_t* __restrict__ WkG, const ushort_t* __restrict__ UlT,
    const ushort_t* __restrict__ KTG, const float* __restrict__ gtG,
    ushort_t* __restrict__ ScG, int sb, char* smem) {
  const int eh = sb & 1, wg = sb >> 1;
  const int h = wg & 15, b = wg >> 4, hq = h >> 1;
  const int e0 = eh * 64;
  const int tid = threadIdx.x, lane = tid & 63, wave = tid >> 6;
  const int l15 = lane & 15, kcol0 = (lane >> 4) * 8, rrow = (lane >> 4) * 4;
  const int et = wave & 3, dh = wave >> 2;        // S-update tiles
  const int ue = wave >> 1, ut0 = (wave & 1) * 2; // u-phase tiles

  char* WkS = smem;                               // [2][64][128] bf16 = 32 KB
  char* KTS = smem + 32768;                       // [2][128][64] bf16 = 32 KB
  char* UlS = smem + 65536;                       // [2][64][64]  bf16 = 16 KB
  __bf16 (*S16)[136] = (__bf16(*)[136])(smem + 81920);   // 17408 B
  __bf16 (*uS)[72]   = (__bf16(*)[72])(smem + 99328);    //  9216 B
  float* escS = (float*)(smem + 108544);          // [64]

#define SSTAGE(BUF, CN) {                                                     \
    const int cn_ = ((CN) < 32) ? (CN) : 31;                                  \
    const ushort_t* WkR_ = WkG + ((size_t)wg * 32 + cn_) * (64 * 128);        \
    const ushort_t* KTR_ = KTG + (((size_t)b * 8 + hq) * 32 + cn_) * (128 * 64); \
    const ushort_t* UlR_ = UlT + ((size_t)wg * 32 + cn_) * (128 * 64)         \
                               + (size_t)e0 * 64;                             \
    _Pragma("unroll") for (int r_ = 0; r_ < 2; ++r_) {                        \
      const int idx_ = r_ * 512 + tid;                                        \
      const int d_ = idx_ >> 4, sl_ = idx_ & 15;                              \
      const ushort_t* src_ = WkR_ + (size_t)d_ * 128 + ((sl_ ^ (d_ & 7)) << 3); \
      __builtin_amdgcn_global_load_lds(                                       \
          (const __attribute__((address_space(1))) unsigned int*)src_,        \
          (__attribute__((address_space(3))) unsigned int*)                   \
              (WkS + (BUF) * 16384 + r_ * 8192 + wave * 1024), 16, 0, 0);     \
    }                                                                         \
    _Pragma("unroll") for (int r_ = 0; r_ < 2; ++r_) {                        \
      const int idx_ = r_ * 512 + tid;                                        \
      const int d_ = idx_ >> 3, sl_ = idx_ & 7;                               \
      const ushort_t* src_ = KTR_ + (size_t)d_ * 64 + ((sl_ ^ (d_ & 7)) << 3); \
      __builtin_amdgcn_global_load_lds(                                       \
          (const __attribute__((address_space(1))) unsigned int*)src_,        \
          (__attribute__((address_space(3))) unsigned int*)                   \
              (KTS + (BUF) * 16384 + r_ * 8192 + wave * 1024), 16, 0, 0);     \
    }                                                                         \
    {                                                                         \
      const int e_ = tid >> 3, sl_ = tid & 7;                                 \
      const ushort_t* src_ = UlR_ + (size_t)e_ * 64 + ((sl_ ^ (e_ & 7)) << 3); \
      __builtin_amdgcn_global_load_lds(                                       \
          (const __attribute__((address_space(1))) unsigned int*)src_,        \
          (__attribute__((address_space(3))) unsigned int*)                   \
              (UlS + (BUF) * 8192 + wave * 1024), 16, 0, 0);                  \
    }                                                                         \
  }

#define WRD(BUF, ROW, KC)                                                     \
  (*(const bf16x8*)(WkS + (BUF) * 16384 + ((ROW) << 8) +                      \
                    (((KC) << 1) ^ (((ROW) & 7) << 4))))
#define KRD(BUF, ROW, KC)                                                     \
  (*(const bf16x8*)(KTS + (BUF) * 16384 + ((ROW) << 7) +                      \
                    (((KC) << 1) ^ (((ROW) & 7) << 4))))
#define ULS(BUF, E, T)                                                        \
  (*(const ushort_t*)(UlS + (BUF) * 8192 + ((E) << 7) +                       \
                      (((((T) >> 3) << 4)) ^ (((E) & 7) << 4)) + ((T) & 7) * 2))

  f32x4 s_acc[4] = {};   // S^T[e0+16et+rrow+r][16*(4dh+dl)+l15]
  SSTAGE(0, 0)

  for (int c = 0; c < 32; ++c) {
    const int buf = c & 1;
    ushort_t* ScR = ScG + ((size_t)wg * 32 + c) * CHM_;
    const float* gtR = gtG + ((size_t)wg * 32 + c) * 64;

    __syncthreads();                 // stage(c) landed; prev compute done
    SSTAGE(buf ^ 1, c + 1)           // next chunk in flight

    const float g63 = gtR[63];
    if (tid < 64) escS[tid] = __expf(g63 - gtR[tid]);
    const float gCe = __expf(g63);

#pragma unroll
    for (int dl = 0; dl < 4; ++dl)
#pragma unroll
      for (int r = 0; r < 4; ++r)
        S16[16 * et + rrow + r][(4 * dh + dl) * 16 + l15] = (__bf16)s_acc[dl][r];
    asm volatile("s_waitcnt lgkmcnt(0)" ::: "memory");
    __builtin_amdgcn_sched_barrier(0);
    __builtin_amdgcn_s_barrier();    // S16 + escS visible; vmcnt NOT drained
    __builtin_amdgcn_sched_barrier(0);

    // snapshot S at chunk start
#pragma unroll
    for (int cc = 0; cc < 2; ++cc) {
      const int idx = tid + cc * 512;
      const int row = idx >> 4, seg = idx & 15;
      *(uint4*)(void*)(ScR + (size_t)(e0 + row) * 128 + seg * 8) =
          *(const uint4*)&S16[row][seg * 8];
    }

    // u-phase: u^T[e][t] = Ul^T[e][t] + sum_d S^T[e][d]*Wkneg[t][d]; scale esc
#pragma unroll
    for (int t2 = 0; t2 < 2; ++t2) {
      const int tt = ut0 + t2;
      f32x4 a = {};
#pragma unroll
      for (int r = 0; r < 4; ++r)
        a[r] = b2f(ULS(buf, 16 * ue + rrow + r, 16 * tt + l15));
#pragma unroll
      for (int kk = 0; kk < 4; ++kk) {
        bf16x8 af = *(const bf16x8*)&S16[16 * ue + l15][kk * 32 + kcol0];
        bf16x8 bw = WRD(buf, 16 * tt + l15, kk * 32 + kcol0);
        a = __builtin_amdgcn_mfma_f32_16x16x32_bf16(af, bw, a, 0, 0, 0);
      }
      const float es = escS[16 * tt + l15];
#pragma unroll
      for (int r = 0; r < 4; ++r)
        uS[16 * ue + rrow + r][16 * tt + l15] = (__bf16)(a[r] * es);
    }
    asm volatile("s_waitcnt lgkmcnt(0)" ::: "memory");
    __builtin_amdgcn_sched_barrier(0);
    __builtin_amdgcn_s_barrier();    // uS visible
    __builtin_amdgcn_sched_barrier(0);

    // S-update: S' = gCe*S + sum_t u^[e][t]*K[t][d]  (KT rows d)
#pragma unroll
    for (int dl = 0; dl < 4; ++dl)
#pragma unroll
      for (int r = 0; r < 4; ++r) s_acc[dl][r] *= gCe;
#pragma unroll
    for (int ks = 0; ks < 2; ++ks) {
      bf16x8 ua = *(const bf16x8*)&uS[16 * et + l15][ks * 32 + kcol0];
#pragma unroll
      for (int dl = 0; dl < 4; ++dl) {
        bf16x8 kb = KRD(buf, 16 * (4 * dh + dl) + l15, ks * 32 + kcol0);
        s_acc[dl] = __builtin_amdgcn_mfma_f32_16x16x32_bf16(ua, kb, s_acc[dl], 0, 0, 0);
      }
    }
  }
#undef SSTAGE
#undef WRD
#undef KRD
#undef ULS
}

// ---------------------------------------------------------------------------
// FUSED launch: blocks 0..63 = scan, 64..191 = z-gemm tiles (independent).
// ---------------------------------------------------------------------------
__global__ __launch_bounds__(512, 2)
void k_scan_zgemm(const ushort_t* __restrict__ WkG, const ushort_t* __restrict__ UlT,
                  const ushort_t* __restrict__ KTG, const float* __restrict__ gtG,
                  ushort_t* __restrict__ ScG,
                  const ushort_t* __restrict__ xB, const ushort_t* __restrict__ WzB,
                  ushort_t* __restrict__ zbuf) {
  __shared__ alignas(16) char smem[131072];
  if (blockIdx.x < 64)
    scan_body(WkG, UlT, KTG, gtG, ScG, blockIdx.x, smem);
  else
    gemm256_body<ushort_t>(xB, WzB, zbuf, B_ * T_, VD_, HID_,
                           blockIdx.x - 64, (ushort_t*)smem);
}

// ---------------------------------------------------------------------------
// k_out: fully parallel per (b,h,c): u = Ul + Wkneg@S_c; Pm recomputed from
// q,k; o = gam*Q@S_c + Pm@u; fused gated RMSNorm -> bf16 outg. grid=1024.
// (R19-exact)
// ---------------------------------------------------------------------------
__global__ __launch_bounds__(256, 2)
void k_out(const ushort_t* __restrict__ act,
           const ushort_t* __restrict__ WkG, const ushort_t* __restrict__ UlT,
           const float* __restrict__ gtG,
           const ushort_t* __restrict__ ScG, const ushort_t* __restrict__ zbuf,
           const float* __restrict__ nw, ushort_t* __restrict__ outg) {
  __shared__ __bf16 S16[128][136];
  __shared__ __bf16 uTl[128][72];
  __shared__ __bf16 PmL[64][72];
  __shared__ float Egc[65], Rgc[65], gam[64], nws[128];

  const int bhc = blockIdx.x;
  const int c = bhc & 31, h = (bhc >> 5) & 15, b = bhc >> 9;
  const int hq = h >> 1, t0g = c * 64;
  const int tid = threadIdx.x, lane = tid & 63, wave = tid >> 6;
  const int l15 = lane & 15, kcol0 = (lane >> 4) * 8, rrow = (lane >> 4) * 4;

  const ushort_t* ScR = ScG + (size_t)bhc * CHM_;
  const ushort_t* WkR = WkG + (size_t)bhc * (64 * 128);
  const ushort_t* UlR = UlT + (size_t)bhc * (128 * 64);
  const ushort_t* actQ = act + ((size_t)b * T_ + t0g) * CD_ + hq * HD_;
  const ushort_t* actK = actQ + KD_;

#pragma unroll
  for (int cc = 0; cc < 8; ++cc) {
    const int idx = tid + cc * 256;
    const int row = idx >> 4, seg = idx & 15;
    *(uint4*)&S16[row][seg * 8] =
        *(const uint4*)(const void*)(ScR + (size_t)row * 128 + seg * 8);
  }
  {
    const float gc32 = gtG[(size_t)bhc * 64 + 31];
    if (tid < 65) {
      const float gcv = (tid == 0) ? 0.f : gtG[(size_t)bhc * 64 + tid - 1];
      Egc[tid] = __expf(gcv - gc32);
      Rgc[tid] = __expf(gc32 - gcv);
    }
    if (tid < 64) gam[tid] = __expf(gtG[(size_t)bhc * 64 + tid]);
    if (tid < 128) nws[tid] = nw[tid];
  }
  __syncthreads();

  bf16x8 qf[4];
#pragma unroll
  for (int kk = 0; kk < 4; ++kk)
    qf[kk] = *(const bf16x8*)(const void*)
        (actQ + (size_t)(16 * wave + l15) * CD_ + kk * 32 + kcol0);

  bf16x8 wa[4];
#pragma unroll
  for (int kk = 0; kk < 4; ++kk)
    wa[kk] = *(const bf16x8*)(const void*)(WkR + (size_t)(16 * wave + l15) * 128 + kk * 32 + kcol0);
  f32x4 au[8] = {};
#pragma unroll
  for (int kk = 0; kk < 4; ++kk)
#pragma unroll
    for (int jt = 0; jt < 8; ++jt) {
      bf16x8 sb = *(const bf16x8*)&S16[jt * 16 + l15][kk * 32 + kcol0];
      au[jt] = __builtin_amdgcn_mfma_f32_16x16x32_bf16(wa[kk], sb, au[jt], 0, 0, 0);
    }
#pragma unroll
  for (int jt = 0; jt < 8; ++jt) {
    short4v uv = *(const short4v*)(const void*)(UlR + (size_t)(16 * jt + l15) * 64 + wave * 16 + rrow);
#pragma unroll
    for (int r = 0; r < 4; ++r)
      uTl[16 * jt + l15][16 * wave + rrow + r] = (__bf16)(au[jt][r] + b2f((ushort_t)uv[r]));
  }

#pragma unroll
  for (int st = 0; st < 4; ++st) {
    f32x4 accP = {};
#pragma unroll
    for (int kk = 0; kk < 4; ++kk) {
      bf16x8 kb = *(const bf16x8*)(const void*)
          (actK + (size_t)(st * 16 + l15) * CD_ + kk * 32 + kcol0);
      accP = __builtin_amdgcn_mfma_f32_16x16x32_bf16(qf[kk], kb, accP, 0, 0, 0);
    }
    const int scol = st * 16 + l15;
#pragma unroll
    for (int r = 0; r < 4; ++r) {
      const int t = 16 * wave + rrow + r;
      PmL[t][scol] = (scol <= t) ? (__bf16)(Egc[t + 1] * Rgc[scol + 1] * accP[r])
                                 : (__bf16)0.f;
    }
  }
  __syncthreads();

  f32x4 qs[8] = {}, o2[8] = {};
#pragma unroll
  for (int kk = 0; kk < 4; ++kk)
#pragma unroll
    for (int jt = 0; jt < 8; ++jt) {
      bf16x8 sb = *(const bf16x8*)&S16[jt * 16 + l15][kk * 32 + kcol0];
      qs[jt] = __builtin_amdgcn_mfma_f32_16x16x32_bf16(qf[kk], sb, qs[jt], 0, 0, 0);
    }
#pragma unroll
  for (int ks = 0; ks < 2; ++ks) {
    bf16x8 pa = *(const bf16x8*)&PmL[16 * wave + l15][ks * 32 + kcol0];
#pragma unroll
    for (int jt = 0; jt < 8; ++jt) {
      bf16x8 ub = *(const bf16x8*)&uTl[jt * 16 + l15][ks * 32 + kcol0];
      o2[jt] = __builtin_amdgcn_mfma_f32_16x16x32_bf16(pa, ub, o2[jt], 0, 0, 0);
    }
  }
  float ov[8][4];
  float ss0 = 0.f, ss1 = 0.f, ss2 = 0.f, ss3 = 0.f;
#pragma unroll
  for (int jt = 0; jt < 8; ++jt) {
    ov[jt][0] = gam[16 * wave + rrow + 0] * qs[jt][0] + o2[jt][0];
    ov[jt][1] = gam[16 * wave + rrow + 1] * qs[jt][1] + o2[jt][1];
    ov[jt][2] = gam[16 * wave + rrow + 2] * qs[jt][2] + o2[jt][2];
    ov[jt][3] = gam[16 * wave + rrow + 3] * qs[jt][3] + o2[jt][3];
    ss0 += ov[jt][0] * ov[jt][0];
    ss1 += ov[jt][1] * ov[jt][1];
    ss2 += ov[jt][2] * ov[jt][2];
    ss3 += ov[jt][3] * ov[jt][3];
  }
#pragma unroll
  for (int m = 1; m < 16; m <<= 1) {
    ss0 += __shfl_xor(ss0, m);
    ss1 += __shfl_xor(ss1, m);
    ss2 += __shfl_xor(ss2, m);
    ss3 += __shfl_xor(ss3, m);
  }
  float rr[4];
  rr[0] = 1.f / sqrtf(ss0 * (1.f / HD_) + 1e-6f);
  rr[1] = 1.f / sqrtf(ss1 * (1.f / HD_) + 1e-6f);
  rr[2] = 1.f / sqrtf(ss2 * (1.f / HD_) + 1e-6f);
  rr[3] = 1.f / sqrtf(ss3 * (1.f / HD_) + 1e-6f);
#pragma unroll
  for (int jt = 0; jt < 8; ++jt) {
    const int e = 16 * jt + l15;
    const float wv = nws[e];
#pragma unroll
    for (int r = 0; r < 4; ++r) {
      const int t = 16 * wave + rrow + r;
      const float zf = b2f(zbuf[((size_t)b * T_ + t0g + t) * VD_ + h * HD_ + e]);
      const float g = zf / (1.f + expf(-zf));
      outg[(((size_t)b * T_ + t0g + t) * NV_ + h) * HD_ + e] =
          f2b(ov[jt][r] * rr[r] * wv * g);
    }
  }
}

// ---------------------------------------------------------------------------
extern "C" void kernel_launch(void* const* d_in, const int* in_sizes, int n_in,
                              void* d_out, int out_size, void* d_ws, size_t ws_size,
                              hipStream_t stream) {
  const float* x    = (const float*)d_in[0];
  const float* Wqkv = (const float*)d_in[1];
  const float* Wz   = (const float*)d_in[2];
  const float* Wb   = (const float*)d_in[3];
  const float* Wa   = (const float*)d_in[4];
  const float* cw   = (const float*)d_in[5];
  const float* dtb  = (const float*)d_in[6];
  const float* alog = (const float*)d_in[7];
  const float* nw   = (const float*)d_in[8];
  const float* Wout = (const float*)d_in[9];

  // ---- workspace layout: ~177 MB total ----
  char* p = (char*)d_ws;
  ushort_t* qkv_raw = (ushort_t*)p; p += (size_t)B_ * T_ * CD_ * 2;       // 33.55 MB
  ushort_t* zbuf    = (ushort_t*)p; p += (size_t)B_ * T_ * VD_ * 2;       // 16.78 MB
  ushort_t* act     = (ushort_t*)p; p += (size_t)B_ * T_ * CD_ * 2;       // 33.55 MB
  float*    betaB   = (float*)p;    p += (size_t)B_ * T_ * NV_ * 4;       //  0.26 MB
  float*    gBuf    = (float*)p;    p += (size_t)B_ * T_ * NV_ * 4;       //  0.26 MB
  float*    gtG     = (float*)p;    p += (size_t)1024 * 64 * 4;           //  0.26 MB
  ushort_t* xB      = (ushort_t*)p; p += (size_t)B_ * T_ * HID_ * 2;      // 16.78 MB
  ushort_t* WzB     = (ushort_t*)p; p += (size_t)VD_ * HID_ * 2;          //  8.39 MB
  ushort_t* WoutB   = (ushort_t*)p; p += (size_t)HID_ * VD_ * 2;          //  8.39 MB
  ushort_t* outg    = (ushort_t*)p; p += (size_t)B_ * T_ * VD_ * 2;       // 16.78 MB
  ushort_t* ScG     = (ushort_t*)p; p += (size_t)1024 * CHM_ * 2;         // 33.55 MB
  ushort_t* KTG     = (ushort_t*)p; p += (size_t)512 * 128 * 64 * 2;      //  8.39 MB
  // overlays (qkv_raw dead after conv):
  ushort_t* WkG   = qkv_raw;                             // 16.78 MB
  ushort_t* UlT   = qkv_raw + (size_t)1024 * 64 * 128;   // 16.78 MB (exact fit)
  ushort_t* WqkvB = act;                                 // pre-conv overlay

  const int M = B_ * T_;  // 4096

  const int n0 = M * HID_ / 4, n1 = CD_ * HID_ / 4;
  const int n2 = VD_ * HID_ / 4, n3 = HID_ * VD_ / 4;
  hipLaunchKernelGGL(k_cast4, dim3((n0 + n1 + n2 + n3 + 255) / 256), dim3(256), 0, stream,
                     x, xB, n0, Wqkv, WqkvB, n1, Wz, WzB, n2, Wout, WoutB, n3);

  hipLaunchKernelGGL(k_gemm256<ushort_t>, dim3((M / 256) * (CD_ / 256)), dim3(512), 0, stream,
                     xB, WqkvB, qkv_raw, M, CD_, HID_);
  hipLaunchKernelGGL(k_proj_ba, dim3(M / 16), dim3(256), 0, stream,
                     x, Wb, Wa, dtb, alog, betaB, gBuf);
  hipLaunchKernelGGL(k_conv_silu_norm, dim3(M), dim3(256), 0, stream,
                     qkv_raw, cw, act);
  hipLaunchKernelGGL(k_prep, dim3(B_ * NV_ * 32), dim3(256), 0, stream,
                     act, gBuf, betaB, WkG, UlT, KTG, gtG);
  hipLaunchKernelGGL(k_scan_zgemm, dim3(64 + (M / 256) * (VD_ / 256)), dim3(512), 0, stream,
                     WkG, UlT, KTG, gtG, ScG, xB, WzB, zbuf);
  hipLaunchKernelGGL(k_out, dim3(B_ * NV_ * 32), dim3(256), 0, stream,
                     act, WkG, UlT, gtG, ScG, zbuf, nw, outg);
  hipLaunchKernelGGL(k_gemm256x128<float>, dim3((M / 256) * (HID_ / 128)), dim3(512), 0, stream,
                     outg, WoutB, (float*)d_out, M, HID_, VD_);
}

// Round 21
// 373.360 us; speedup vs baseline: 1.4527x; 1.1899x over previous
//
#include <hip/hip_runtime.h>
#include <cstdint>
#include <cstddef>

// GatedDeltaNet forward, MI355X/gfx950.
// R21 = R20 with k_proj_ba rewritten: grid 1024 (4 rows/block), bf16 x/W
// (WbB/WaB added to the merged cast), 2 barriers total (was 64), no redundant
// x reads. Everything else R20-exact.

typedef unsigned short ushort_t;
typedef __attribute__((ext_vector_type(8))) __bf16 bf16x8;
typedef __attribute__((ext_vector_type(4))) float f32x4;
typedef __attribute__((ext_vector_type(4))) short short4v;

#define B_   2
#define T_   2048
#define HID_ 2048
#define NK_  8
#define NV_  16
#define HD_  128
#define KD_  1024
#define VD_  2048
#define CD_  4096
#define CHM_ 16384

__device__ __forceinline__ float b2f(ushort_t u) {
  union { unsigned int i; float f; } v; v.i = ((unsigned int)u) << 16; return v.f;
}
__device__ __forceinline__ ushort_t f2b(float f) {   // RNE bf16 round
  unsigned int x = __builtin_bit_cast(unsigned int, f);
  unsigned int r = x + 0x7fffu + ((x >> 16) & 1u);
  return (ushort_t)(r >> 16);
}

// ---------------------------------------------------------------------------
// fp32 -> bf16 casts: single kernel, six (src,dst) ranges
// ---------------------------------------------------------------------------
__global__ __launch_bounds__(256)
void k_cast6(const float* __restrict__ s0, ushort_t* __restrict__ d0, int n0,
             const float* __restrict__ s1, ushort_t* __restrict__ d1, int n1,
             const float* __restrict__ s2, ushort_t* __restrict__ d2, int n2,
             const float* __restrict__ s3, ushort_t* __restrict__ d3, int n3,
             const float* __restrict__ s4, ushort_t* __restrict__ d4, int n4,
             const float* __restrict__ s5, ushort_t* __restrict__ d5, int n5) {
  int i = blockIdx.x * 256 + threadIdx.x;
  const float* s; ushort_t* d;
  if (i < n0) { s = s0; d = d0; }
  else if (i < n0 + n1) { i -= n0; s = s1; d = d1; }
  else if (i < n0 + n1 + n2) { i -= n0 + n1; s = s2; d = d2; }
  else if (i < n0 + n1 + n2 + n3) { i -= n0 + n1 + n2; s = s3; d = d3; }
  else if (i < n0 + n1 + n2 + n3 + n4) { i -= n0 + n1 + n2 + n3; s = s4; d = d4; }
  else { i -= n0 + n1 + n2 + n3 + n4; if (i >= n5) return; s = s5; d = d5; }
  float4 v = *(const float4*)(s + (size_t)i * 4);
  short4v o;
  o[0] = (short)f2b(v.x); o[1] = (short)f2b(v.y);
  o[2] = (short)f2b(v.z); o[3] = (short)f2b(v.w);
  *(short4v*)(d + (size_t)i * 4) = o;
}

// ---------------------------------------------------------------------------
// GEMM 256x256 body, BK=64, 8 waves, counted-vmcnt pipeline (R8-verified).
// ---------------------------------------------------------------------------
#define LPOS(BUF, OP, HALF) ((((BUF) * 2 + (OP)) * 2 + (HALF)) * 8192)

template <typename OutT>
__device__ __forceinline__ void gemm256_body(
    const ushort_t* __restrict__ A, const ushort_t* __restrict__ Bw,
    OutT* __restrict__ C, int M, int N, int K, int tile, ushort_t* lds) {
  const int tid = threadIdx.x;
  const int lane = tid & 63, wave = tid >> 6;
  const int wm = wave >> 2, wc = wave & 3;
  const int l15 = lane & 15;
  const int ks16 = (lane >> 4) * 16;
  const int r4 = (lane >> 4) * 4;
  const int nkt = K >> 6;
  const int nbx = N >> 8;
  const size_t row0 = (size_t)(tile / nbx) * 256;
  const size_t col0 = (size_t)(tile % nbx) * 256;

#define STAGE4(BUF, HALF, KT) {                                               \
    const int kt_ = ((KT) < nkt) ? (KT) : (nkt - 1);                          \
    const int kb_ = kt_ * 64 + (HALF) * 32;                                   \
    _Pragma("unroll") for (int r_ = 0; r_ < 2; ++r_) {                        \
      const int wb_ = r_ * 8192 + wave * 1024;                                \
      const int o_  = wb_ + lane * 16;                                        \
      const int row_ = o_ >> 6;                                               \
      const int src_ = (o_ & 63) ^ (((row_) & 3) << 4);                       \
      const ushort_t* ga_ = A  + (row0 + row_) * (size_t)K + kb_ + (src_ >> 1); \
      const ushort_t* gb_ = Bw + (col0 + row_) * (size_t)K + kb_ + (src_ >> 1); \
      __builtin_amdgcn_global_load_lds(                                       \
          (const __attribute__((address_space(1))) unsigned int*)ga_,         \
          (__attribute__((address_space(3))) unsigned int*)                   \
              (lds + LPOS(BUF, 0, HALF) + (wb_ >> 1)), 16, 0, 0);             \
      __builtin_amdgcn_global_load_lds(                                       \
          (const __attribute__((address_space(1))) unsigned int*)gb_,         \
          (__attribute__((address_space(3))) unsigned int*)                   \
              (lds + LPOS(BUF, 1, HALF) + (wb_ >> 1)), 16, 0, 0);             \
    }                                                                         \
  }

#define RD(BUF, OP, HALF, ROW)                                                \
  (*(const bf16x8*)((const char*)(lds + LPOS(BUF, OP, HALF)) +                \
                    ((((ROW) * 64 + ks16)) ^ (((ROW) & 3) << 4))))

  f32x4 acc[8][4] = {};
  STAGE4(0, 0, 0)
  STAGE4(0, 1, 0)
  STAGE4(1, 0, 1)

  for (int kt = 0; kt < nkt; ++kt) {
    const int cb = kt & 1, nb = cb ^ 1;
    asm volatile("s_waitcnt vmcnt(8)" ::: "memory");
    __builtin_amdgcn_s_barrier();
    {
      bf16x8 af[8], bfr[4];
#pragma unroll
      for (int mf = 0; mf < 8; ++mf) af[mf] = RD(cb, 0, 0, wm * 128 + mf * 16 + l15);
#pragma unroll
      for (int nf = 0; nf < 4; ++nf) bfr[nf] = RD(cb, 1, 0, wc * 64 + nf * 16 + l15);
      STAGE4(nb, 1, kt + 1)
      __builtin_amdgcn_s_setprio(1);
#pragma unroll
      for (int mf = 0; mf < 8; ++mf)
#pragma unroll
        for (int nf = 0; nf < 4; ++nf)
          acc[mf][nf] = __builtin_amdgcn_mfma_f32_16x16x32_bf16(af[mf], bfr[nf], acc[mf][nf], 0, 0, 0);
      __builtin_amdgcn_s_setprio(0);
    }
    asm volatile("s_waitcnt vmcnt(8)" ::: "memory");
    __builtin_amdgcn_s_barrier();
    {
      bf16x8 af[8], bfr[4];
#pragma unroll
      for (int mf = 0; mf < 8; ++mf) af[mf] = RD(cb, 0, 1, wm * 128 + mf * 16 + l15);
#pragma unroll
      for (int nf = 0; nf < 4; ++nf) bfr[nf] = RD(cb, 1, 1, wc * 64 + nf * 16 + l15);
      STAGE4(cb, 0, kt + 2)
      __builtin_amdgcn_s_setprio(1);
#pragma unroll
      for (int mf = 0; mf < 8; ++mf)
#pragma unroll
        for (int nf = 0; nf < 4; ++nf)
          acc[mf][nf] = __builtin_amdgcn_mfma_f32_16x16x32_bf16(af[mf], bfr[nf], acc[mf][nf], 0, 0, 0);
      __builtin_amdgcn_s_setprio(0);
    }
  }
#undef STAGE4
#undef RD

#pragma unroll
  for (int mf = 0; mf < 8; ++mf)
#pragma unroll
    for (int nf = 0; nf < 4; ++nf)
#pragma unroll
      for (int j = 0; j < 4; ++j) {
        const size_t row = row0 + wm * 128 + mf * 16 + r4 + j;
        const size_t col = col0 + wc * 64 + nf * 16 + l15;
        if constexpr (sizeof(OutT) == 4)
          C[row * (size_t)N + col] = acc[mf][nf][j];
        else
          C[row * (size_t)N + col] = (OutT)f2b(acc[mf][nf][j]);
      }
}

template <typename OutT>
__global__ __launch_bounds__(512, 2)
void k_gemm256(const ushort_t* __restrict__ A, const ushort_t* __restrict__ Bw,
               OutT* __restrict__ C, int M, int N, int K) {
  __shared__ alignas(16) ushort_t lds[2 * 2 * 2 * 8192];
  const int nwg = gridDim.x;
  const int q8 = nwg >> 3, r8 = nwg & 7;
  const int xcd = blockIdx.x & 7, idx8 = blockIdx.x >> 3;
  const int s = (xcd < r8) ? (xcd * (q8 + 1) + idx8)
                           : (r8 * (q8 + 1) + (xcd - r8) * q8 + idx8);
  gemm256_body<OutT>(A, Bw, C, M, N, K, s, lds);
}

// ---------------------------------------------------------------------------
// GEMM 256x128 tile (R17-verified): counted-vmcnt, 3 loads/half, vmcnt(6).
// ---------------------------------------------------------------------------
#define LPA(BUF, HALF) (((BUF) * 2 + (HALF)) * 8192)
#define LPB(BUF, HALF) (32768 + ((BUF) * 2 + (HALF)) * 4096)

template <typename OutT>
__global__ __launch_bounds__(512, 1)
void k_gemm256x128(const ushort_t* __restrict__ A, const ushort_t* __restrict__ Bw,
                   OutT* __restrict__ C, int M, int N, int K) {
  __shared__ alignas(16) ushort_t lds[49152];   // 96 KB
  const int tid = threadIdx.x;
  const int lane = tid & 63, wave = tid >> 6;
  const int wm = wave >> 1, wc = wave & 1;
  const int l15 = lane & 15;
  const int ks16 = (lane >> 4) * 16;
  const int r4 = (lane >> 4) * 4;
  const int nkt = K >> 6;
  const int nbx = N >> 7;
  const int nwg = gridDim.x;
  const int q8 = nwg >> 3, r8 = nwg & 7;
  const int xcd = blockIdx.x & 7, idx8 = blockIdx.x >> 3;
  const int s = (xcd < r8) ? (xcd * (q8 + 1) + idx8)
                           : (r8 * (q8 + 1) + (xcd - r8) * q8 + idx8);
  const size_t row0 = (size_t)(s / nbx) * 256;
  const size_t col0 = (size_t)(s % nbx) * 128;

#define STG3(BUF, HALF, KT) {                                                 \
    const int kt_ = ((KT) < nkt) ? (KT) : (nkt - 1);                          \
    const int kb_ = kt_ * 64 + (HALF) * 32;                                   \
    _Pragma("unroll") for (int r_ = 0; r_ < 2; ++r_) {                        \
      const int wb_ = r_ * 8192 + wave * 1024;                                \
      const int o_  = wb_ + lane * 16;                                        \
      const int row_ = o_ >> 6;                                               \
      const int src_ = (o_ & 63) ^ (((row_) & 3) << 4);                       \
      const ushort_t* ga_ = A + (row0 + row_) * (size_t)K + kb_ + (src_ >> 1); \
      __builtin_amdgcn_global_load_lds(                                       \
          (const __attribute__((address_space(1))) unsigned int*)ga_,         \
          (__attribute__((address_space(3))) unsigned int*)                   \
              (lds + LPA(BUF, HALF) + (wb_ >> 1)), 16, 0, 0);                 \
    }                                                                         \
    {                                                                         \
      const int wb_ = wave * 1024;                                            \
      const int o_  = wb_ + lane * 16;                                        \
      const int row_ = o_ >> 6;                                               \
      const int src_ = (o_ & 63) ^ (((row_) & 3) << 4);                       \
      const ushort_t* gb_ = Bw + (col0 + row_) * (size_t)K + kb_ + (src_ >> 1); \
      __builtin_amdgcn_global_load_lds(                                       \
          (const __attribute__((address_space(1))) unsigned int*)gb_,         \
          (__attribute__((address_space(3))) unsigned int*)                   \
              (lds + LPB(BUF, HALF) + (wb_ >> 1)), 16, 0, 0);                 \
    }                                                                         \
  }

#define RDA(BUF, HALF, ROW)                                                   \
  (*(const bf16x8*)((const char*)(lds + LPA(BUF, HALF)) +                     \
                    ((((ROW) * 64 + ks16)) ^ (((ROW) & 3) << 4))))
#define RDB(BUF, HALF, ROW)                                                   \
  (*(const bf16x8*)((const char*)(lds + LPB(BUF, HALF)) +                     \
                    ((((ROW) * 64 + ks16)) ^ (((ROW) & 3) << 4))))

  f32x4 acc[4][4] = {};
  STG3(0, 0, 0)
  STG3(0, 1, 0)
  STG3(1, 0, 1)

  for (int kt = 0; kt < nkt; ++kt) {
    const int cb = kt & 1, nb = cb ^ 1;
    asm volatile("s_waitcnt vmcnt(6)" ::: "memory");
    __builtin_amdgcn_s_barrier();
    {
      bf16x8 af[4], bfr[4];
#pragma unroll
      for (int mf = 0; mf < 4; ++mf) af[mf] = RDA(cb, 0, wm * 64 + mf * 16 + l15);
#pragma unroll
      for (int nf = 0; nf < 4; ++nf) bfr[nf] = RDB(cb, 0, wc * 64 + nf * 16 + l15);
      STG3(nb, 1, kt + 1)
      __builtin_amdgcn_s_setprio(1);
#pragma unroll
      for (int mf = 0; mf < 4; ++mf)
#pragma unroll
        for (int nf = 0; nf < 4; ++nf)
          acc[mf][nf] = __builtin_amdgcn_mfma_f32_16x16x32_bf16(af[mf], bfr[nf], acc[mf][nf], 0, 0, 0);
      __builtin_amdgcn_s_setprio(0);
    }
    asm volatile("s_waitcnt vmcnt(6)" ::: "memory");
    __builtin_amdgcn_s_barrier();
    {
      bf16x8 af[4], bfr[4];
#pragma unroll
      for (int mf = 0; mf < 4; ++mf) af[mf] = RDA(cb, 1, wm * 64 + mf * 16 + l15);
#pragma unroll
      for (int nf = 0; nf < 4; ++nf) bfr[nf] = RDB(cb, 1, wc * 64 + nf * 16 + l15);
      STG3(cb, 0, kt + 2)
      __builtin_amdgcn_s_setprio(1);
#pragma unroll
      for (int mf = 0; mf < 4; ++mf)
#pragma unroll
        for (int nf = 0; nf < 4; ++nf)
          acc[mf][nf] = __builtin_amdgcn_mfma_f32_16x16x32_bf16(af[mf], bfr[nf], acc[mf][nf], 0, 0, 0);
      __builtin_amdgcn_s_setprio(0);
    }
  }
#undef STG3
#undef RDA
#undef RDB

#pragma unroll
  for (int mf = 0; mf < 4; ++mf)
#pragma unroll
    for (int nf = 0; nf < 4; ++nf)
#pragma unroll
      for (int j = 0; j < 4; ++j) {
        const size_t row = row0 + wm * 64 + mf * 16 + r4 + j;
        const size_t col = col0 + wc * 64 + nf * 16 + l15;
        if constexpr (sizeof(OutT) == 4)
          C[row * (size_t)N + col] = acc[mf][nf][j];
        else
          C[row * (size_t)N + col] = (OutT)f2b(acc[mf][nf][j]);
      }
}

// ---------------------------------------------------------------------------
// b/a projection (R21): grid 1024 x 4 rows, bf16 x/W, 2 barriers.
// beta = sigmoid(x@Wb^T); g = -exp(A_log)*softplus(x@Wa^T+dtb).
// ---------------------------------------------------------------------------
__global__ __launch_bounds__(256)
void k_proj_ba2(const ushort_t* __restrict__ xB, const ushort_t* __restrict__ WbB,
                const ushort_t* __restrict__ WaB, const float* __restrict__ dtb,
                const float* __restrict__ alog,
                float* __restrict__ beta, float* __restrict__ gout) {
  __shared__ alignas(16) ushort_t xs[4][2048];   // 16 KB
  __shared__ float part[32][8][4];               //  4 KB
  const int tid = threadIdx.x;
  const int bt0 = blockIdx.x * 4;
#pragma unroll
  for (int r = 0; r < 4; ++r)
    *(uint4*)&xs[r][tid * 8] =
        *(const uint4*)(const void*)(xB + (size_t)(bt0 + r) * HID_ + tid * 8);
  __syncthreads();
  const int o = tid & 31, seg = tid >> 5;        // 32 outputs x 8 segs(256)
  const ushort_t* W = (o < 16) ? (WbB + (size_t)o * HID_)
                               : (WaB + (size_t)(o - 16) * HID_);
  float acc0 = 0.f, acc1 = 0.f, acc2 = 0.f, acc3 = 0.f;
  for (int j = 0; j < 32; ++j) {
    const int k = seg * 256 + j * 8;
    bf16x8 wv = *(const bf16x8*)(const void*)(W + k);
    bf16x8 x0 = *(const bf16x8*)&xs[0][k];
    bf16x8 x1 = *(const bf16x8*)&xs[1][k];
    bf16x8 x2 = *(const bf16x8*)&xs[2][k];
    bf16x8 x3 = *(const bf16x8*)&xs[3][k];
#pragma unroll
    for (int i = 0; i < 8; ++i) {
      const float w = (float)wv[i];
      acc0 += w * (float)x0[i];
      acc1 += w * (float)x1[i];
      acc2 += w * (float)x2[i];
      acc3 += w * (float)x3[i];
    }
  }
  part[o][seg][0] = acc0; part[o][seg][1] = acc1;
  part[o][seg][2] = acc2; part[o][seg][3] = acc3;
  __syncthreads();
  if (tid < 128) {
    const int r = tid >> 5, oo = tid & 31;
    float t_ = 0.f;
#pragma unroll
    for (int s2 = 0; s2 < 8; ++s2) t_ += part[oo][s2][r];
    const int bt = bt0 + r;
    if (oo < 16) {
      beta[(size_t)bt * NV_ + oo] = 1.f / (1.f + expf(-t_));
    } else {
      const int hh = oo - 16;
      float aa = t_ + dtb[hh];
      float sp = (aa > 20.f) ? aa : log1pf(expf(aa));
      gout[(size_t)bt * NV_ + hh] = -expf(alog[hh]) * sp;
    }
  }
}

// ---------------------------------------------------------------------------
// Fused depthwise causal conv1d (K=4) + silu + l2norm(q,k). (R14-verified)
// ---------------------------------------------------------------------------
__global__ __launch_bounds__(256)
void k_conv_silu_norm(const ushort_t* __restrict__ qkv, const float* __restrict__ cw,
                      ushort_t* __restrict__ act) {
  const int bt = blockIdx.x;
  const int tid = threadIdx.x;
  const int t = bt & (T_ - 1);
  const int c = tid * 16;
  const ushort_t* rowp = qkv + (size_t)bt * CD_ + c;

  float wf[16][4];
#pragma unroll
  for (int i = 0; i < 16; ++i) {
    float4 w = *(const float4*)&cw[(c + i) * 4];
    wf[i][0] = w.x; wf[i][1] = w.y; wf[i][2] = w.z; wf[i][3] = w.w;
  }
  float a[16];
#pragma unroll
  for (int i = 0; i < 16; ++i) a[i] = 0.f;
#pragma unroll
  for (int j = 0; j < 4; ++j) {
    const int tt = t - 3 + j;
    if (tt >= 0) {
      const ushort_t* src = rowp + ((ptrdiff_t)j - 3) * CD_;
      bf16x8 v0 = *(const bf16x8*)(const void*)src;
      bf16x8 v1 = *(const bf16x8*)(const void*)(src + 8);
#pragma unroll
      for (int i = 0; i < 8; ++i) {
        a[i]     += (float)v0[i] * wf[i][j];
        a[8 + i] += (float)v1[i] * wf[8 + i][j];
      }
    }
  }
#pragma unroll
  for (int i = 0; i < 16; ++i) a[i] = a[i] / (1.f + expf(-a[i]));
  float ss = 0.f;
#pragma unroll
  for (int i = 0; i < 16; ++i) ss += a[i] * a[i];
  ss += __shfl_xor(ss, 1); ss += __shfl_xor(ss, 2); ss += __shfl_xor(ss, 4);
  const int seg = tid >> 3;
  float scale = 1.f;
  if (seg < 16) {
    scale = 1.f / fmaxf(sqrtf(ss), 1e-12f);
    if (seg < 8) scale *= 0.08838834764831845f;
  }
  ushort_t ov[16];
#pragma unroll
  for (int i = 0; i < 16; ++i) ov[i] = f2b(a[i] * scale);
  ushort_t* dst = act + (size_t)bt * CD_ + c;
  *(uint4*)(void*)dst       = *(const uint4*)&ov[0];
  *(uint4*)(void*)(dst + 8) = *(const uint4*)&ov[8];
}

// ---------------------------------------------------------------------------
// k_prep: per-chunk parallel precompute. grid = 1024. (R20-exact)
// ---------------------------------------------------------------------------
__global__ __launch_bounds__(256, 1)
void k_prep(const ushort_t* __restrict__ act, const float* __restrict__ gB,
            const float* __restrict__ betaB,
            ushort_t* __restrict__ WkG, ushort_t* __restrict__ UlT,
            ushort_t* __restrict__ KTG, float* __restrict__ gtG) {
  __shared__ __bf16 Kl[64][136];
  __shared__ __bf16 AbL[64][40];
  __shared__ __bf16 AbH[32][33];
  __shared__ __bf16 Xl[64][264];
  __shared__ alignas(16) __bf16 Cr[16][264];
  __shared__ float gc[65], Et[65], Rt[65], bts[64], geT[64];

  const int wg = blockIdx.x;
  const int c = wg & 31, h = (wg >> 5) & 15, b = wg >> 9;
  const int hq = h >> 1, t0 = c * 64;
  const int tid = threadIdx.x, lane = tid & 63, wave = tid >> 6;
  const int l15 = lane & 15, kcol0 = (lane >> 4) * 8, rrow = (lane >> 4) * 4;
  const size_t bhc = (size_t)wg;

  const ushort_t* baseQ = act + (size_t)b * T_ * CD_ + hq * HD_;
  const ushort_t* baseK = baseQ + KD_;

  if (tid < 64) {
    float g = gB[((size_t)b * T_ + t0 + tid) * NV_ + h];
    bts[tid] = betaB[((size_t)b * T_ + t0 + tid) * NV_ + h];
#pragma unroll
    for (int o = 1; o < 64; o <<= 1) {
      float up = __shfl_up(g, (unsigned)o);
      if (tid >= o) g += up;
    }
    gc[tid + 1] = g;
    if (tid == 0) gc[0] = 0.f;
  }
  __syncthreads();
  if (tid < 65) {
    float gm = gc[32];
    Et[tid] = __expf(gc[tid] - gm);
    Rt[tid] = __expf(gm - gc[tid]);
  }
  if (tid < 64) {
    geT[tid] = bts[tid] * __expf(gc[tid + 1]);
    gtG[bhc * 64 + tid] = gc[tid + 1];
  }
  {
    const int t = tid >> 2, d0 = (tid & 3) * 32;
    const ushort_t* src = baseK + (size_t)(t0 + t) * CD_ + d0;
#pragma unroll
    for (int j = 0; j < 4; ++j)
      *(uint4*)&Kl[t][d0 + j * 8] = *(const uint4*)(const void*)(src + j * 8);
  }
  __syncthreads();

  // P1: Ab (strict lower, -beta*scale*KK^T) in LDS
  {
    bf16x8 kf[4];
#pragma unroll
    for (int kk = 0; kk < 4; ++kk)
      kf[kk] = *(const bf16x8*)&Kl[16 * wave + l15][kk * 32 + kcol0];
#pragma unroll
    for (int st = 0; st < 4; ++st) {
      if (st <= wave) {
        f32x4 accA = {};
#pragma unroll
        for (int kk = 0; kk < 4; ++kk) {
          bf16x8 bfr = *(const bf16x8*)&Kl[st * 16 + l15][kk * 32 + kcol0];
          accA = __builtin_amdgcn_mfma_f32_16x16x32_bf16(kf[kk], bfr, accA, 0, 0, 0);
        }
        const int scol = st * 16 + l15;
#pragma unroll
        for (int r = 0; r < 4; ++r) {
          const int t = 16 * wave + rrow + r;
          if (scol < t) {
            const float av = -bts[t] * Et[t + 1] * Rt[scol + 1] * accA[r];
            if (scol < 32) AbL[t][scol] = (__bf16)av;
            else           AbH[t - 32][scol - 32] = (__bf16)av;
          }
        }
      }
    }
  }
  __syncthreads();

  // KT store (raw K^T, shared by the v-head pair; even h only)
  if ((h & 1) == 0) {
    const size_t kto = (((size_t)b * 8 + hq) * 32 + c) * (128 * 64);
    const int d = tid >> 1, t8 = (tid & 1) * 32;
#pragma unroll
    for (int i8 = 0; i8 < 4; ++i8) {
      bf16x8 tmp;
#pragma unroll
      for (int jj = 0; jj < 8; ++jj) tmp[jj] = Kl[t8 + i8 * 8 + jj][d];
      *(bf16x8*)(void*)(KTG + kto + (size_t)d * 64 + t8 + i8 * 8) = tmp;
    }
  }

  // P2: block-16 recursive triangular solve (R19-verified).
  {
    float r1[32], r2[32];
    if (tid < 128) {
      const int d = tid;
#pragma unroll
      for (int t = 0; t < 32; ++t) r1[t] = geT[t] * (float)Kl[t][d];
#pragma unroll
      for (int t = 0; t < 32; ++t) r2[t] = geT[32 + t] * (float)Kl[32 + t][d];
    } else {
      const int j = tid - 128;
      const ushort_t* vsrc = act + ((size_t)b * T_ + t0) * CD_ + 2 * KD_ + h * HD_ + j;
#pragma unroll
      for (int t = 0; t < 32; ++t) r1[t] = bts[t] * b2f(vsrc[(size_t)t * CD_]);
#pragma unroll
      for (int t = 0; t < 32; ++t) r2[t] = bts[32 + t] * b2f(vsrc[(size_t)(32 + t) * CD_]);
    }

    {
      float u[16];
#pragma unroll
      for (int j = 0; j < 16; ++j) {
        float a = r1[j];
#pragma unroll
        for (int i = 0; i < j; ++i) a += (float)AbL[j][i] * u[i];
        u[j] = a;
        Xl[j][tid] = (__bf16)a;
      }
    }
    __syncthreads();

    {
      bf16x8 afr2;
#pragma unroll
      for (int j = 0; j < 8; ++j) {
        const int k = kcol0 + j;
        afr2[j] = (k < 16) ? AbL[16 + l15][k] : (__bf16)0.f;
      }
#pragma unroll
      for (int ct4 = 0; ct4 < 4; ++ct4) {
        const int ct = wave * 4 + ct4;
        bf16x8 bfr2;
#pragma unroll
        for (int j = 0; j < 8; ++j) {
          const int k = kcol0 + j;
          bfr2[j] = (k < 16) ? Xl[k][16 * ct + l15] : (__bf16)0.f;
        }
        f32x4 acc2 = {};
        acc2 = __builtin_amdgcn_mfma_f32_16x16x32_bf16(afr2, bfr2, acc2, 0, 0, 0);
#pragma unroll
        for (int r = 0; r < 4; ++r)
          Cr[rrow + r][16 * ct + l15] = (__bf16)acc2[r];
      }
    }
    __syncthreads();

    {
      float u[16];
#pragma unroll
      for (int j = 0; j < 16; ++j) {
        float a = r1[16 + j] + (float)Cr[j][tid];
#pragma unroll
        for (int i = 0; i < j; ++i) a += (float)AbL[16 + j][16 + i] * u[i];
        u[j] = a;
        Xl[16 + j][tid] = (__bf16)a;
      }
    }
    __syncthreads();

    {
      bf16x8 afr2 = *(const bf16x8*)&AbL[32 + l15][kcol0];
#pragma unroll
      for (int ct4 = 0; ct4 < 4; ++ct4) {
        const int ct = wave * 4 + ct4;
        bf16x8 bfr2;
#pragma unroll
        for (int j = 0; j < 8; ++j) bfr2[j] = Xl[kcol0 + j][16 * ct + l15];
        f32x4 acc2 = {};
        acc2 = __builtin_amdgcn_mfma_f32_16x16x32_bf16(afr2, bfr2, acc2, 0, 0, 0);
#pragma unroll
        for (int r = 0; r < 4; ++r)
          Cr[rrow + r][16 * ct + l15] = (__bf16)acc2[r];
      }
    }
    __syncthreads();

    {
      float u[16];
#pragma unroll
      for (int j = 0; j < 16; ++j) {
        float a = r2[j] + (float)Cr[j][tid];
#pragma unroll
        for (int i = 0; i < j; ++i) a += (float)AbH[j][i] * u[i];
        u[j] = a;
        Xl[32 + j][tid] = (__bf16)a;
      }
    }
    __syncthreads();

    {
      bf16x8 afrA = *(const bf16x8*)&AbL[48 + l15][kcol0];
      bf16x8 afrB;
#pragma unroll
      for (int j = 0; j < 8; ++j) {
        const int k = kcol0 + j;
        afrB[j] = (k < 16) ? AbH[16 + l15][k] : (__bf16)0.f;
      }
#pragma unroll
      for (int ct4 = 0; ct4 < 4; ++ct4) {
        const int ct = wave * 4 + ct4;
        bf16x8 bfrA, bfrB;
#pragma unroll
        for (int j = 0; j < 8; ++j) {
          const int k = kcol0 + j;
          bfrA[j] = Xl[k][16 * ct + l15];
          bfrB[j] = (k < 16) ? Xl[32 + k][16 * ct + l15] : (__bf16)0.f;
        }
        f32x4 acc2 = {};
        acc2 = __builtin_amdgcn_mfma_f32_16x16x32_bf16(afrA, bfrA, acc2, 0, 0, 0);
        acc2 = __builtin_amdgcn_mfma_f32_16x16x32_bf16(afrB, bfrB, acc2, 0, 0, 0);
#pragma unroll
        for (int r = 0; r < 4; ++r)
          Cr[rrow + r][16 * ct + l15] = (__bf16)acc2[r];
      }
    }
    __syncthreads();

    {
      float u[16];
#pragma unroll
      for (int j = 0; j < 16; ++j) {
        float a = r2[16 + j] + (float)Cr[j][tid];
#pragma unroll
        for (int i = 0; i < j; ++i) a += (float)AbH[16 + j][16 + i] * u[i];
        u[j] = a;
        Xl[48 + j][tid] = (__bf16)a;
      }
    }
  }
  __syncthreads();

  // P3: Wk copy (negated, stride 128) + Uloc^T store (stride 64)
#pragma unroll
  for (int kck = 0; kck < 4; ++kck) {
    const int q = tid + kck * 256;
    const int t = q >> 4, d0 = (q & 15) * 8;
    uint4 v = *(const uint4*)&Xl[t][d0];
    v.x ^= 0x80008000u; v.y ^= 0x80008000u; v.z ^= 0x80008000u; v.w ^= 0x80008000u;
    *(uint4*)(void*)(WkG + bhc * (64 * 128) + (size_t)t * 128 + d0) = v;
  }
  {
    const int e = tid >> 1, t8 = (tid & 1) * 32;
#pragma unroll
    for (int i8 = 0; i8 < 4; ++i8) {
      bf16x8 tmp;
#pragma unroll
      for (int jj = 0; jj < 8; ++jj) tmp[jj] = Xl[t8 + i8 * 8 + jj][128 + e];
      *(bf16x8*)(void*)(UlT + bhc * (128 * 64) + (size_t)e * 64 + t8 + i8 * 8) = tmp;
    }
  }
}

// ---------------------------------------------------------------------------
// scan body (R20-verified): u-phase + S-update recomputed from Wk/Ul/KT.
// ---------------------------------------------------------------------------
__device__ __forceinline__ void scan_body(
    const ushort_t* __restrict__ WkG, const ushort_t* __restrict__ UlT,
    const ushort_t* __restrict__ KTG, const float* __restrict__ gtG,
    ushort_t* __restrict__ ScG, int sb, char* smem) {
  const int eh = sb & 1, wg = sb >> 1;
  const int h = wg & 15, b = wg >> 4, hq = h >> 1;
  const int e0 = eh * 64;
  const int tid = threadIdx.x, lane = tid & 63, wave = tid >> 6;
  const int l15 = lane & 15, kcol0 = (lane >> 4) * 8, rrow = (lane >> 4) * 4;
  const int et = wave & 3, dh = wave >> 2;
  const int ue = wave >> 1, ut0 = (wave & 1) * 2;

  char* WkS = smem;
  char* KTS = smem + 32768;
  char* UlS = smem + 65536;
  __bf16 (*S16)[136] = (__bf16(*)[136])(smem + 81920);
  __bf16 (*uS)[72]   = (__bf16(*)[72])(smem + 99328);
  float* escS = (float*)(smem + 108544);

#define SSTAGE(BUF, CN) {                                                     \
    const int cn_ = ((CN) < 32) ? (CN) : 31;                                  \
    const ushort_t* WkR_ = WkG + ((size_t)wg * 32 + cn_) * (64 * 128);        \
    const ushort_t* KTR_ = KTG + (((size_t)b * 8 + hq) * 32 + cn_) * (128 * 64); \
    const ushort_t* UlR_ = UlT + ((size_t)wg * 32 + cn_) * (128 * 64)         \
                               + (size_t)e0 * 64;                             \
    _Pragma("unroll") for (int r_ = 0; r_ < 2; ++r_) {                        \
      const int idx_ = r_ * 512 + tid;                                        \
      const int d_ = idx_ >> 4, sl_ = idx_ & 15;                              \
      const ushort_t* src_ = WkR_ + (size_t)d_ * 128 + ((sl_ ^ (d_ & 7)) << 3); \
      __builtin_amdgcn_global_load_lds(                                       \
          (const __attribute__((address_space(1))) unsigned int*)src_,        \
          (__attribute__((address_space(3))) unsigned int*)                   \
              (WkS + (BUF) * 16384 + r_ * 8192 + wave * 1024), 16, 0, 0);     \
    }                                                                         \
    _Pragma("unroll") for (int r_ = 0; r_ < 2; ++r_) {                        \
      const int idx_ = r_ * 512 + tid;                                        \
      const int d_ = idx_ >> 3, sl_ = idx_ & 7;                               \
      const ushort_t* src_ = KTR_ + (size_t)d_ * 64 + ((sl_ ^ (d_ & 7)) << 3); \
      __builtin_amdgcn_global_load_lds(                                       \
          (const __attribute__((address_space(1))) unsigned int*)src_,        \
          (__attribute__((address_space(3))) unsigned int*)                   \
              (KTS + (BUF) * 16384 + r_ * 8192 + wave * 1024), 16, 0, 0);     \
    }                                                                         \
    {                                                                         \
      const int e_ = tid >> 3, sl_ = tid & 7;                                 \
      const ushort_t* src_ = UlR_ + (size_t)e_ * 64 + ((sl_ ^ (e_ & 7)) << 3); \
      __builtin_amdgcn_global_load_lds(                                       \
          (const __attribute__((address_space(1))) unsigned int*)src_,        \
          (__attribute__((address_space(3))) unsigned int*)                   \
              (UlS + (BUF) * 8192 + wave * 1024), 16, 0, 0);                  \
    }                                                                         \
  }

#define WRD(BUF, ROW, KC)                                                     \
  (*(const bf16x8*)(WkS + (BUF) * 16384 + ((ROW) << 8) +                      \
                    (((KC) << 1) ^ (((ROW) & 7) << 4))))
#define KRD(BUF, ROW, KC)                                                     \
  (*(const bf16x8*)(KTS + (BUF) * 16384 + ((ROW) << 7) +                      \
                    (((KC) << 1) ^ (((ROW) & 7) << 4))))
#define ULS(BUF, E, T)                                                        \
  (*(const ushort_t*)(UlS + (BUF) * 8192 + ((E) << 7) +                       \
                      (((((T) >> 3) << 4)) ^ (((E) & 7) << 4)) + ((T) & 7) * 2))

  f32x4 s_acc[4] = {};
  SSTAGE(0, 0)

  for (int c = 0; c < 32; ++c) {
    const int buf = c & 1;
    ushort_t* ScR = ScG + ((size_t)wg * 32 + c) * CHM_;
    const float* gtR = gtG + ((size_t)wg * 32 + c) * 64;

    __syncthreads();
    SSTAGE(buf ^ 1, c + 1)

    const float g63 = gtR[63];
    if (tid < 64) escS[tid] = __expf(g63 - gtR[tid]);
    const float gCe = __expf(g63);

#pragma unroll
    for (int dl = 0; dl < 4; ++dl)
#pragma unroll
      for (int r = 0; r < 4; ++r)
        S16[16 * et + rrow + r][(4 * dh + dl) * 16 + l15] = (__bf16)s_acc[dl][r];
    asm volatile("s_waitcnt lgkmcnt(0)" ::: "memory");
    __builtin_amdgcn_sched_barrier(0);
    __builtin_amdgcn_s_barrier();
    __builtin_amdgcn_sched_barrier(0);

#pragma unroll
    for (int cc = 0; cc < 2; ++cc) {
      const int idx = tid + cc * 512;
      const int row = idx >> 4, seg = idx & 15;
      *(uint4*)(void*)(ScR + (size_t)(e0 + row) * 128 + seg * 8) =
          *(const uint4*)&S16[row][seg * 8];
    }

#pragma unroll
    for (int t2 = 0; t2 < 2; ++t2) {
      const int tt = ut0 + t2;
      f32x4 a = {};
#pragma unroll
      for (int r = 0; r < 4; ++r)
        a[r] = b2f(ULS(buf, 16 * ue + rrow + r, 16 * tt + l15));
#pragma unroll
      for (int kk = 0; kk < 4; ++kk) {
        bf16x8 af = *(const bf16x8*)&S16[16 * ue + l15][kk * 32 + kcol0];
        bf16x8 bw = WRD(buf, 16 * tt + l15, kk * 32 + kcol0);
        a = __builtin_amdgcn_mfma_f32_16x16x32_bf16(af, bw, a, 0, 0, 0);
      }
      const float es = escS[16 * tt + l15];
#pragma unroll
      for (int r = 0; r < 4; ++r)
        uS[16 * ue + rrow + r][16 * tt + l15] = (__bf16)(a[r] * es);
    }
    asm volatile("s_waitcnt lgkmcnt(0)" ::: "memory");
    __builtin_amdgcn_sched_barrier(0);
    __builtin_amdgcn_s_barrier();
    __builtin_amdgcn_sched_barrier(0);

#pragma unroll
    for (int dl = 0; dl < 4; ++dl)
#pragma unroll
      for (int r = 0; r < 4; ++r) s_acc[dl][r] *= gCe;
#pragma unroll
    for (int ks = 0; ks < 2; ++ks) {
      bf16x8 ua = *(const bf16x8*)&uS[16 * et + l15][ks * 32 + kcol0];
#pragma unroll
      for (int dl = 0; dl < 4; ++dl) {
        bf16x8 kb = KRD(buf, 16 * (4 * dh + dl) + l15, ks * 32 + kcol0);
        s_acc[dl] = __builtin_amdgcn_mfma_f32_16x16x32_bf16(ua, kb, s_acc[dl], 0, 0, 0);
      }
    }
  }
#undef SSTAGE
#undef WRD
#undef KRD
#undef ULS
}

// ---------------------------------------------------------------------------
// FUSED launch: blocks 0..63 = scan, 64..191 = z-gemm tiles (independent).
// ---------------------------------------------------------------------------
__global__ __launch_bounds__(512, 2)
void k_scan_zgemm(const ushort_t* __restrict__ WkG, const ushort_t* __restrict__ UlT,
                  const ushort_t* __restrict__ KTG, const float* __restrict__ gtG,
                  ushort_t* __restrict__ ScG,
                  const ushort_t* __restrict__ xB, const ushort_t* __restrict__ WzB,
                  ushort_t* __restrict__ zbuf) {
  __shared__ alignas(16) char smem[131072];
  if (blockIdx.x < 64)
    scan_body(WkG, UlT, KTG, gtG, ScG, blockIdx.x, smem);
  else
    gemm256_body<ushort_t>(xB, WzB, zbuf, B_ * T_, VD_, HID_,
                           blockIdx.x - 64, (ushort_t*)smem);
}

// ---------------------------------------------------------------------------
// k_out (R19-exact): u = Ul + Wkneg@S_c; Pm recomputed; o = gam*Q@S_c + Pm@u;
// fused gated RMSNorm -> bf16 outg. grid=1024.
// ---------------------------------------------------------------------------
__global__ __launch_bounds__(256, 2)
void k_out(const ushort_t* __restrict__ act,
           const ushort_t* __restrict__ WkG, const ushort_t* __restrict__ UlT,
           const float* __restrict__ gtG,
           const ushort_t* __restrict__ ScG, const ushort_t* __restrict__ zbuf,
           const float* __restrict__ nw, ushort_t* __restrict__ outg) {
  __shared__ __bf16 S16[128][136];
  __shared__ __bf16 uTl[128][72];
  __shared__ __bf16 PmL[64][72];
  __shared__ float Egc[65], Rgc[65], gam[64], nws[128];

  const int bhc = blockIdx.x;
  const int c = bhc & 31, h = (bhc >> 5) & 15, b = bhc >> 9;
  const int hq = h >> 1, t0g = c * 64;
  const int tid = threadIdx.x, lane = tid & 63, wave = tid >> 6;
  const int l15 = lane & 15, kcol0 = (lane >> 4) * 8, rrow = (lane >> 4) * 4;

  const ushort_t* ScR = ScG + (size_t)bhc * CHM_;
  const ushort_t* WkR = WkG + (size_t)bhc * (64 * 128);
  const ushort_t* UlR = UlT + (size_t)bhc * (128 * 64);
  const ushort_t* actQ = act + ((size_t)b * T_ + t0g) * CD_ + hq * HD_;
  const ushort_t* actK = actQ + KD_;

#pragma unroll
  for (int cc = 0; cc < 8; ++cc) {
    const int idx = tid + cc * 256;
    const int row = idx >> 4, seg = idx & 15;
    *(uint4*)&S16[row][seg * 8] =
        *(const uint4*)(const void*)(ScR + (size_t)row * 128 + seg * 8);
  }
  {
    const float gc32 = gtG[(size_t)bhc * 64 + 31];
    if (tid < 65) {
      const float gcv = (tid == 0) ? 0.f : gtG[(size_t)bhc * 64 + tid - 1];
      Egc[tid] = __expf(gcv - gc32);
      Rgc[tid] = __expf(gc32 - gcv);
    }
    if (tid < 64) gam[tid] = __expf(gtG[(size_t)bhc * 64 + tid]);
    if (tid < 128) nws[tid] = nw[tid];
  }
  __syncthreads();

  bf16x8 qf[4];
#pragma unroll
  for (int kk = 0; kk < 4; ++kk)
    qf[kk] = *(const bf16x8*)(const void*)
        (actQ + (size_t)(16 * wave + l15) * CD_ + kk * 32 + kcol0);

  bf16x8 wa[4];
#pragma unroll
  for (int kk = 0; kk < 4; ++kk)
    wa[kk] = *(const bf16x8*)(const void*)(WkR + (size_t)(16 * wave + l15) * 128 + kk * 32 + kcol0);
  f32x4 au[8] = {};
#pragma unroll
  for (int kk = 0; kk < 4; ++kk)
#pragma unroll
    for (int jt = 0; jt < 8; ++jt) {
      bf16x8 sb = *(const bf16x8*)&S16[jt * 16 + l15][kk * 32 + kcol0];
      au[jt] = __builtin_amdgcn_mfma_f32_16x16x32_bf16(wa[kk], sb, au[jt], 0, 0, 0);
    }
#pragma unroll
  for (int jt = 0; jt < 8; ++jt) {
    short4v uv = *(const short4v*)(const void*)(UlR + (size_t)(16 * jt + l15) * 64 + wave * 16 + rrow);
#pragma unroll
    for (int r = 0; r < 4; ++r)
      uTl[16 * jt + l15][16 * wave + rrow + r] = (__bf16)(au[jt][r] + b2f((ushort_t)uv[r]));
  }

#pragma unroll
  for (int st = 0; st < 4; ++st) {
    f32x4 accP = {};
#pragma unroll
    for (int kk = 0; kk < 4; ++kk) {
      bf16x8 kb = *(const bf16x8*)(const void*)
          (actK + (size_t)(st * 16 + l15) * CD_ + kk * 32 + kcol0);
      accP = __builtin_amdgcn_mfma_f32_16x16x32_bf16(qf[kk], kb, accP, 0, 0, 0);
    }
    const int scol = st * 16 + l15;
#pragma unroll
    for (int r = 0; r < 4; ++r) {
      const int t = 16 * wave + rrow + r;
      PmL[t][scol] = (scol <= t) ? (__bf16)(Egc[t + 1] * Rgc[scol + 1] * accP[r])
                                 : (__bf16)0.f;
    }
  }
  __syncthreads();

  f32x4 qs[8] = {}, o2[8] = {};
#pragma unroll
  for (int kk = 0; kk < 4; ++kk)
#pragma unroll
    for (int jt = 0; jt < 8; ++jt) {
      bf16x8 sb = *(const bf16x8*)&S16[jt * 16 + l15][kk * 32 + kcol0];
      qs[jt] = __builtin_amdgcn_mfma_f32_16x16x32_bf16(qf[kk], sb, qs[jt], 0, 0, 0);
    }
#pragma unroll
  for (int ks = 0; ks < 2; ++ks) {
    bf16x8 pa = *(const bf16x8*)&PmL[16 * wave + l15][ks * 32 + kcol0];
#pragma unroll
    for (int jt = 0; jt < 8; ++jt) {
      bf16x8 ub = *(const bf16x8*)&uTl[jt * 16 + l15][ks * 32 + kcol0];
      o2[jt] = __builtin_amdgcn_mfma_f32_16x16x32_bf16(pa, ub, o2[jt], 0, 0, 0);
    }
  }
  float ov[8][4];
  float ss0 = 0.f, ss1 = 0.f, ss2 = 0.f, ss3 = 0.f;
#pragma unroll
  for (int jt = 0; jt < 8; ++jt) {
    ov[jt][0] = gam[16 * wave + rrow + 0] * qs[jt][0] + o2[jt][0];
    ov[jt][1] = gam[16 * wave + rrow + 1] * qs[jt][1] + o2[jt][1];
    ov[jt][2] = gam[16 * wave + rrow + 2] * qs[jt][2] + o2[jt][2];
    ov[jt][3] = gam[16 * wave + rrow + 3] * qs[jt][3] + o2[jt][3];
    ss0 += ov[jt][0] * ov[jt][0];
    ss1 += ov[jt][1] * ov[jt][1];
    ss2 += ov[jt][2] * ov[jt][2];
    ss3 += ov[jt][3] * ov[jt][3];
  }
#pragma unroll
  for (int m = 1; m < 16; m <<= 1) {
    ss0 += __shfl_xor(ss0, m);
    ss1 += __shfl_xor(ss1, m);
    ss2 += __shfl_xor(ss2, m);
    ss3 += __shfl_xor(ss3, m);
  }
  float rr[4];
  rr[0] = 1.f / sqrtf(ss0 * (1.f / HD_) + 1e-6f);
  rr[1] = 1.f / sqrtf(ss1 * (1.f / HD_) + 1e-6f);
  rr[2] = 1.f / sqrtf(ss2 * (1.f / HD_) + 1e-6f);
  rr[3] = 1.f / sqrtf(ss3 * (1.f / HD_) + 1e-6f);
#pragma unroll
  for (int jt = 0; jt < 8; ++jt) {
    const int e = 16 * jt + l15;
    const float wv = nws[e];
#pragma unroll
    for (int r = 0; r < 4; ++r) {
      const int t = 16 * wave + rrow + r;
      const float zf = b2f(zbuf[((size_t)b * T_ + t0g + t) * VD_ + h * HD_ + e]);
      const float g = zf / (1.f + expf(-zf));
      outg[(((size_t)b * T_ + t0g + t) * NV_ + h) * HD_ + e] =
          f2b(ov[jt][r] * rr[r] * wv * g);
    }
  }
}

// ---------------------------------------------------------------------------
extern "C" void kernel_launch(void* const* d_in, const int* in_sizes, int n_in,
                              void* d_out, int out_size, void* d_ws, size_t ws_size,
                              hipStream_t stream) {
  const float* x    = (const float*)d_in[0];
  const float* Wqkv = (const float*)d_in[1];
  const float* Wz   = (const float*)d_in[2];
  const float* Wb   = (const float*)d_in[3];
  const float* Wa   = (const float*)d_in[4];
  const float* cw   = (const float*)d_in[5];
  const float* dtb  = (const float*)d_in[6];
  const float* alog = (const float*)d_in[7];
  const float* nw   = (const float*)d_in[8];
  const float* Wout = (const float*)d_in[9];

  // ---- workspace layout: ~177 MB total ----
  char* p = (char*)d_ws;
  ushort_t* qkv_raw = (ushort_t*)p; p += (size_t)B_ * T_ * CD_ * 2;       // 33.55 MB
  ushort_t* zbuf    = (ushort_t*)p; p += (size_t)B_ * T_ * VD_ * 2;       // 16.78 MB
  ushort_t* act     = (ushort_t*)p; p += (size_t)B_ * T_ * CD_ * 2;       // 33.55 MB
  float*    betaB   = (float*)p;    p += (size_t)B_ * T_ * NV_ * 4;       //  0.26 MB
  float*    gBuf    = (float*)p;    p += (size_t)B_ * T_ * NV_ * 4;       //  0.26 MB
  float*    gtG     = (float*)p;    p += (size_t)1024 * 64 * 4;           //  0.26 MB
  ushort_t* xB      = (ushort_t*)p; p += (size_t)B_ * T_ * HID_ * 2;      // 16.78 MB
  ushort_t* WzB     = (ushort_t*)p; p += (size_t)VD_ * HID_ * 2;          //  8.39 MB
  ushort_t* WoutB   = (ushort_t*)p; p += (size_t)HID_ * VD_ * 2;          //  8.39 MB
  ushort_t* outg    = (ushort_t*)p; p += (size_t)B_ * T_ * VD_ * 2;       // 16.78 MB
  ushort_t* ScG     = (ushort_t*)p; p += (size_t)1024 * CHM_ * 2;         // 33.55 MB
  ushort_t* KTG     = (ushort_t*)p; p += (size_t)512 * 128 * 64 * 2;      //  8.39 MB
  ushort_t* WbB     = (ushort_t*)p; p += (size_t)NV_ * HID_ * 2;          //  0.065 MB
  ushort_t* WaB     = (ushort_t*)p; p += (size_t)NV_ * HID_ * 2;          //  0.065 MB
  // overlays (qkv_raw dead after conv):
  ushort_t* WkG   = qkv_raw;
  ushort_t* UlT   = qkv_raw + (size_t)1024 * 64 * 128;
  ushort_t* WqkvB = act;

  const int M = B_ * T_;  // 4096

  const int n0 = M * HID_ / 4, n1 = CD_ * HID_ / 4;
  const int n2 = VD_ * HID_ / 4, n3 = HID_ * VD_ / 4;
  const int n4 = NV_ * HID_ / 4, n5 = NV_ * HID_ / 4;
  hipLaunchKernelGGL(k_cast6, dim3((n0 + n1 + n2 + n3 + n4 + n5 + 255) / 256), dim3(256), 0, stream,
                     x, xB, n0, Wqkv, WqkvB, n1, Wz, WzB, n2,
                     Wout, WoutB, n3, Wb, WbB, n4, Wa, WaB, n5);

  hipLaunchKernelGGL(k_gemm256<ushort_t>, dim3((M / 256) * (CD_ / 256)), dim3(512), 0, stream,
                     xB, WqkvB, qkv_raw, M, CD_, HID_);
  hipLaunchKernelGGL(k_proj_ba2, dim3(M / 4), dim3(256), 0, stream,
                     xB, WbB, WaB, dtb, alog, betaB, gBuf);
  hipLaunchKernelGGL(k_conv_silu_norm, dim3(M), dim3(256), 0, stream,
                     qkv_raw, cw, act);
  hipLaunchKernelGGL(k_prep, dim3(B_ * NV_ * 32), dim3(256), 0, stream,
                     act, gBuf, betaB, WkG, UlT, KTG, gtG);
  hipLaunchKernelGGL(k_scan_zgemm, dim3(64 + (M / 256) * (VD_ / 256)), dim3(512), 0, stream,
                     WkG, UlT, KTG, gtG, ScG, xB, WzB, zbuf);
  hipLaunchKernelGGL(k_out, dim3(B_ * NV_ * 32), dim3(256), 0, stream,
                     act, WkG, UlT, gtG, ScG, zbuf, nw, outg);
  hipLaunchKernelGGL(k_gemm256x128<float>, dim3((M / 256) * (HID_ / 128)), dim3(512), 0, stream,
                     outg, WoutB, (float*)d_out, M, HID_, VD_);
}

// Round 22
// 371.268 us; speedup vs baseline: 1.4609x; 1.0056x over previous
//
#include <hip/hip_runtime.h>
#include <cstdint>
#include <cstddef>

// GatedDeltaNet forward, MI355X/gfx950.
// R22 = R21 with the GEMM LDS swizzle fixed: (row&3)<<4 -> ((row>>1)&3)<<4
// (old variant left lanes r,r+4,r+8,r+12 on the same bank slot = 4-way
// conflict; new constant is injective over r mod 8 -> 2-way = free).
// Applied on BOTH sides (pre-swizzled global source + ds_read offset) in
// gemm256 and gemm256x128. Everything else R21-exact.

typedef unsigned short ushort_t;
typedef __attribute__((ext_vector_type(8))) __bf16 bf16x8;
typedef __attribute__((ext_vector_type(4))) float f32x4;
typedef __attribute__((ext_vector_type(4))) short short4v;

#define B_   2
#define T_   2048
#define HID_ 2048
#define NK_  8
#define NV_  16
#define HD_  128
#define KD_  1024
#define VD_  2048
#define CD_  4096
#define CHM_ 16384

#define SWZ(ROW) ((((ROW) >> 1) & 3) << 4)

__device__ __forceinline__ float b2f(ushort_t u) {
  union { unsigned int i; float f; } v; v.i = ((unsigned int)u) << 16; return v.f;
}
__device__ __forceinline__ ushort_t f2b(float f) {   // RNE bf16 round
  unsigned int x = __builtin_bit_cast(unsigned int, f);
  unsigned int r = x + 0x7fffu + ((x >> 16) & 1u);
  return (ushort_t)(r >> 16);
}

// ---------------------------------------------------------------------------
// fp32 -> bf16 casts: single kernel, six (src,dst) ranges
// ---------------------------------------------------------------------------
__global__ __launch_bounds__(256)
void k_cast6(const float* __restrict__ s0, ushort_t* __restrict__ d0, int n0,
             const float* __restrict__ s1, ushort_t* __restrict__ d1, int n1,
             const float* __restrict__ s2, ushort_t* __restrict__ d2, int n2,
             const float* __restrict__ s3, ushort_t* __restrict__ d3, int n3,
             const float* __restrict__ s4, ushort_t* __restrict__ d4, int n4,
             const float* __restrict__ s5, ushort_t* __restrict__ d5, int n5) {
  int i = blockIdx.x * 256 + threadIdx.x;
  const float* s; ushort_t* d;
  if (i < n0) { s = s0; d = d0; }
  else if (i < n0 + n1) { i -= n0; s = s1; d = d1; }
  else if (i < n0 + n1 + n2) { i -= n0 + n1; s = s2; d = d2; }
  else if (i < n0 + n1 + n2 + n3) { i -= n0 + n1 + n2; s = s3; d = d3; }
  else if (i < n0 + n1 + n2 + n3 + n4) { i -= n0 + n1 + n2 + n3; s = s4; d = d4; }
  else { i -= n0 + n1 + n2 + n3 + n4; if (i >= n5) return; s = s5; d = d5; }
  float4 v = *(const float4*)(s + (size_t)i * 4);
  short4v o;
  o[0] = (short)f2b(v.x); o[1] = (short)f2b(v.y);
  o[2] = (short)f2b(v.z); o[3] = (short)f2b(v.w);
  *(short4v*)(d + (size_t)i * 4) = o;
}

// ---------------------------------------------------------------------------
// GEMM 256x256 body, BK=64, 8 waves, counted-vmcnt pipeline (R8-verified;
// R22 swizzle).
// ---------------------------------------------------------------------------
#define LPOS(BUF, OP, HALF) ((((BUF) * 2 + (OP)) * 2 + (HALF)) * 8192)

template <typename OutT>
__device__ __forceinline__ void gemm256_body(
    const ushort_t* __restrict__ A, const ushort_t* __restrict__ Bw,
    OutT* __restrict__ C, int M, int N, int K, int tile, ushort_t* lds) {
  const int tid = threadIdx.x;
  const int lane = tid & 63, wave = tid >> 6;
  const int wm = wave >> 2, wc = wave & 3;
  const int l15 = lane & 15;
  const int ks16 = (lane >> 4) * 16;
  const int r4 = (lane >> 4) * 4;
  const int nkt = K >> 6;
  const int nbx = N >> 8;
  const size_t row0 = (size_t)(tile / nbx) * 256;
  const size_t col0 = (size_t)(tile % nbx) * 256;

#define STAGE4(BUF, HALF, KT) {                                               \
    const int kt_ = ((KT) < nkt) ? (KT) : (nkt - 1);                          \
    const int kb_ = kt_ * 64 + (HALF) * 32;                                   \
    _Pragma("unroll") for (int r_ = 0; r_ < 2; ++r_) {                        \
      const int wb_ = r_ * 8192 + wave * 1024;                                \
      const int o_  = wb_ + lane * 16;                                        \
      const int row_ = o_ >> 6;                                               \
      const int src_ = (o_ & 63) ^ SWZ(row_);                                 \
      const ushort_t* ga_ = A  + (row0 + row_) * (size_t)K + kb_ + (src_ >> 1); \
      const ushort_t* gb_ = Bw + (col0 + row_) * (size_t)K + kb_ + (src_ >> 1); \
      __builtin_amdgcn_global_load_lds(                                       \
          (const __attribute__((address_space(1))) unsigned int*)ga_,         \
          (__attribute__((address_space(3))) unsigned int*)                   \
              (lds + LPOS(BUF, 0, HALF) + (wb_ >> 1)), 16, 0, 0);             \
      __builtin_amdgcn_global_load_lds(                                       \
          (const __attribute__((address_space(1))) unsigned int*)gb_,         \
          (__attribute__((address_space(3))) unsigned int*)                   \
              (lds + LPOS(BUF, 1, HALF) + (wb_ >> 1)), 16, 0, 0);             \
    }                                                                         \
  }

#define RD(BUF, OP, HALF, ROW)                                                \
  (*(const bf16x8*)((const char*)(lds + LPOS(BUF, OP, HALF)) +                \
                    ((((ROW) * 64 + ks16)) ^ SWZ(ROW))))

  f32x4 acc[8][4] = {};
  STAGE4(0, 0, 0)
  STAGE4(0, 1, 0)
  STAGE4(1, 0, 1)

  for (int kt = 0; kt < nkt; ++kt) {
    const int cb = kt & 1, nb = cb ^ 1;
    asm volatile("s_waitcnt vmcnt(8)" ::: "memory");
    __builtin_amdgcn_s_barrier();
    {
      bf16x8 af[8], bfr[4];
#pragma unroll
      for (int mf = 0; mf < 8; ++mf) af[mf] = RD(cb, 0, 0, wm * 128 + mf * 16 + l15);
#pragma unroll
      for (int nf = 0; nf < 4; ++nf) bfr[nf] = RD(cb, 1, 0, wc * 64 + nf * 16 + l15);
      STAGE4(nb, 1, kt + 1)
      __builtin_amdgcn_s_setprio(1);
#pragma unroll
      for (int mf = 0; mf < 8; ++mf)
#pragma unroll
        for (int nf = 0; nf < 4; ++nf)
          acc[mf][nf] = __builtin_amdgcn_mfma_f32_16x16x32_bf16(af[mf], bfr[nf], acc[mf][nf], 0, 0, 0);
      __builtin_amdgcn_s_setprio(0);
    }
    asm volatile("s_waitcnt vmcnt(8)" ::: "memory");
    __builtin_amdgcn_s_barrier();
    {
      bf16x8 af[8], bfr[4];
#pragma unroll
      for (int mf = 0; mf < 8; ++mf) af[mf] = RD(cb, 0, 1, wm * 128 + mf * 16 + l15);
#pragma unroll
      for (int nf = 0; nf < 4; ++nf) bfr[nf] = RD(cb, 1, 1, wc * 64 + nf * 16 + l15);
      STAGE4(cb, 0, kt + 2)
      __builtin_amdgcn_s_setprio(1);
#pragma unroll
      for (int mf = 0; mf < 8; ++mf)
#pragma unroll
        for (int nf = 0; nf < 4; ++nf)
          acc[mf][nf] = __builtin_amdgcn_mfma_f32_16x16x32_bf16(af[mf], bfr[nf], acc[mf][nf], 0, 0, 0);
      __builtin_amdgcn_s_setprio(0);
    }
  }
#undef STAGE4
#undef RD

#pragma unroll
  for (int mf = 0; mf < 8; ++mf)
#pragma unroll
    for (int nf = 0; nf < 4; ++nf)
#pragma unroll
      for (int j = 0; j < 4; ++j) {
        const size_t row = row0 + wm * 128 + mf * 16 + r4 + j;
        const size_t col = col0 + wc * 64 + nf * 16 + l15;
        if constexpr (sizeof(OutT) == 4)
          C[row * (size_t)N + col] = acc[mf][nf][j];
        else
          C[row * (size_t)N + col] = (OutT)f2b(acc[mf][nf][j]);
      }
}

template <typename OutT>
__global__ __launch_bounds__(512, 2)
void k_gemm256(const ushort_t* __restrict__ A, const ushort_t* __restrict__ Bw,
               OutT* __restrict__ C, int M, int N, int K) {
  __shared__ alignas(16) ushort_t lds[2 * 2 * 2 * 8192];
  const int nwg = gridDim.x;
  const int q8 = nwg >> 3, r8 = nwg & 7;
  const int xcd = blockIdx.x & 7, idx8 = blockIdx.x >> 3;
  const int s = (xcd < r8) ? (xcd * (q8 + 1) + idx8)
                           : (r8 * (q8 + 1) + (xcd - r8) * q8 + idx8);
  gemm256_body<OutT>(A, Bw, C, M, N, K, s, lds);
}

// ---------------------------------------------------------------------------
// GEMM 256x128 tile (R17-verified; R22 swizzle): vmcnt(6), 3 loads/half.
// ---------------------------------------------------------------------------
#define LPA(BUF, HALF) (((BUF) * 2 + (HALF)) * 8192)
#define LPB(BUF, HALF) (32768 + ((BUF) * 2 + (HALF)) * 4096)

template <typename OutT>
__global__ __launch_bounds__(512, 1)
void k_gemm256x128(const ushort_t* __restrict__ A, const ushort_t* __restrict__ Bw,
                   OutT* __restrict__ C, int M, int N, int K) {
  __shared__ alignas(16) ushort_t lds[49152];   // 96 KB
  const int tid = threadIdx.x;
  const int lane = tid & 63, wave = tid >> 6;
  const int wm = wave >> 1, wc = wave & 1;
  const int l15 = lane & 15;
  const int ks16 = (lane >> 4) * 16;
  const int r4 = (lane >> 4) * 4;
  const int nkt = K >> 6;
  const int nbx = N >> 7;
  const int nwg = gridDim.x;
  const int q8 = nwg >> 3, r8 = nwg & 7;
  const int xcd = blockIdx.x & 7, idx8 = blockIdx.x >> 3;
  const int s = (xcd < r8) ? (xcd * (q8 + 1) + idx8)
                           : (r8 * (q8 + 1) + (xcd - r8) * q8 + idx8);
  const size_t row0 = (size_t)(s / nbx) * 256;
  const size_t col0 = (size_t)(s % nbx) * 128;

#define STG3(BUF, HALF, KT) {                                                 \
    const int kt_ = ((KT) < nkt) ? (KT) : (nkt - 1);                          \
    const int kb_ = kt_ * 64 + (HALF) * 32;                                   \
    _Pragma("unroll") for (int r_ = 0; r_ < 2; ++r_) {                        \
      const int wb_ = r_ * 8192 + wave * 1024;                                \
      const int o_  = wb_ + lane * 16;                                        \
      const int row_ = o_ >> 6;                                               \
      const int src_ = (o_ & 63) ^ SWZ(row_);                                 \
      const ushort_t* ga_ = A + (row0 + row_) * (size_t)K + kb_ + (src_ >> 1); \
      __builtin_amdgcn_global_load_lds(                                       \
          (const __attribute__((address_space(1))) unsigned int*)ga_,         \
          (__attribute__((address_space(3))) unsigned int*)                   \
              (lds + LPA(BUF, HALF) + (wb_ >> 1)), 16, 0, 0);                 \
    }                                                                         \
    {                                                                         \
      const int wb_ = wave * 1024;                                            \
      const int o_  = wb_ + lane * 16;                                        \
      const int row_ = o_ >> 6;                                               \
      const int src_ = (o_ & 63) ^ SWZ(row_);                                 \
      const ushort_t* gb_ = Bw + (col0 + row_) * (size_t)K + kb_ + (src_ >> 1); \
      __builtin_amdgcn_global_load_lds(                                       \
          (const __attribute__((address_space(1))) unsigned int*)gb_,         \
          (__attribute__((address_space(3))) unsigned int*)                   \
              (lds + LPB(BUF, HALF) + (wb_ >> 1)), 16, 0, 0);                 \
    }                                                                         \
  }

#define RDA(BUF, HALF, ROW)                                                   \
  (*(const bf16x8*)((const char*)(lds + LPA(BUF, HALF)) +                     \
                    ((((ROW) * 64 + ks16)) ^ SWZ(ROW))))
#define RDB(BUF, HALF, ROW)                                                   \
  (*(const bf16x8*)((const char*)(lds + LPB(BUF, HALF)) +                     \
                    ((((ROW) * 64 + ks16)) ^ SWZ(ROW))))

  f32x4 acc[4][4] = {};
  STG3(0, 0, 0)
  STG3(0, 1, 0)
  STG3(1, 0, 1)

  for (int kt = 0; kt < nkt; ++kt) {
    const int cb = kt & 1, nb = cb ^ 1;
    asm volatile("s_waitcnt vmcnt(6)" ::: "memory");
    __builtin_amdgcn_s_barrier();
    {
      bf16x8 af[4], bfr[4];
#pragma unroll
      for (int mf = 0; mf < 4; ++mf) af[mf] = RDA(cb, 0, wm * 64 + mf * 16 + l15);
#pragma unroll
      for (int nf = 0; nf < 4; ++nf) bfr[nf] = RDB(cb, 0, wc * 64 + nf * 16 + l15);
      STG3(nb, 1, kt + 1)
      __builtin_amdgcn_s_setprio(1);
#pragma unroll
      for (int mf = 0; mf < 4; ++mf)
#pragma unroll
        for (int nf = 0; nf < 4; ++nf)
          acc[mf][nf] = __builtin_amdgcn_mfma_f32_16x16x32_bf16(af[mf], bfr[nf], acc[mf][nf], 0, 0, 0);
      __builtin_amdgcn_s_setprio(0);
    }
    asm volatile("s_waitcnt vmcnt(6)" ::: "memory");
    __builtin_amdgcn_s_barrier();
    {
      bf16x8 af[4], bfr[4];
#pragma unroll
      for (int mf = 0; mf < 4; ++mf) af[mf] = RDA(cb, 1, wm * 64 + mf * 16 + l15);
#pragma unroll
      for (int nf = 0; nf < 4; ++nf) bfr[nf] = RDB(cb, 1, wc * 64 + nf * 16 + l15);
      STG3(cb, 0, kt + 2)
      __builtin_amdgcn_s_setprio(1);
#pragma unroll
      for (int mf = 0; mf < 4; ++mf)
#pragma unroll
        for (int nf = 0; nf < 4; ++nf)
          acc[mf][nf] = __builtin_amdgcn_mfma_f32_16x16x32_bf16(af[mf], bfr[nf], acc[mf][nf], 0, 0, 0);
      __builtin_amdgcn_s_setprio(0);
    }
  }
#undef STG3
#undef RDA
#undef RDB

#pragma unroll
  for (int mf = 0; mf < 4; ++mf)
#pragma unroll
    for (int nf = 0; nf < 4; ++nf)
#pragma unroll
      for (int j = 0; j < 4; ++j) {
        const size_t row = row0 + wm * 64 + mf * 16 + r4 + j;
        const size_t col = col0 + wc * 64 + nf * 16 + l15;
        if constexpr (sizeof(OutT) == 4)
          C[row * (size_t)N + col] = acc[mf][nf][j];
        else
          C[row * (size_t)N + col] = (OutT)f2b(acc[mf][nf][j]);
      }
}

// ---------------------------------------------------------------------------
// b/a projection (R21-verified): grid 1024 x 4 rows, bf16 x/W, 2 barriers.
// ---------------------------------------------------------------------------
__global__ __launch_bounds__(256)
void k_proj_ba2(const ushort_t* __restrict__ xB, const ushort_t* __restrict__ WbB,
                const ushort_t* __restrict__ WaB, const float* __restrict__ dtb,
                const float* __restrict__ alog,
                float* __restrict__ beta, float* __restrict__ gout) {
  __shared__ alignas(16) ushort_t xs[4][2048];   // 16 KB
  __shared__ float part[32][8][4];               //  4 KB
  const int tid = threadIdx.x;
  const int bt0 = blockIdx.x * 4;
#pragma unroll
  for (int r = 0; r < 4; ++r)
    *(uint4*)&xs[r][tid * 8] =
        *(const uint4*)(const void*)(xB + (size_t)(bt0 + r) * HID_ + tid * 8);
  __syncthreads();
  const int o = tid & 31, seg = tid >> 5;        // 32 outputs x 8 segs(256)
  const ushort_t* W = (o < 16) ? (WbB + (size_t)o * HID_)
                               : (WaB + (size_t)(o - 16) * HID_);
  float acc0 = 0.f, acc1 = 0.f, acc2 = 0.f, acc3 = 0.f;
  for (int j = 0; j < 32; ++j) {
    const int k = seg * 256 + j * 8;
    bf16x8 wv = *(const bf16x8*)(const void*)(W + k);
    bf16x8 x0 = *(const bf16x8*)&xs[0][k];
    bf16x8 x1 = *(const bf16x8*)&xs[1][k];
    bf16x8 x2 = *(const bf16x8*)&xs[2][k];
    bf16x8 x3 = *(const bf16x8*)&xs[3][k];
#pragma unroll
    for (int i = 0; i < 8; ++i) {
      const float w = (float)wv[i];
      acc0 += w * (float)x0[i];
      acc1 += w * (float)x1[i];
      acc2 += w * (float)x2[i];
      acc3 += w * (float)x3[i];
    }
  }
  part[o][seg][0] = acc0; part[o][seg][1] = acc1;
  part[o][seg][2] = acc2; part[o][seg][3] = acc3;
  __syncthreads();
  if (tid < 128) {
    const int r = tid >> 5, oo = tid & 31;
    float t_ = 0.f;
#pragma unroll
    for (int s2 = 0; s2 < 8; ++s2) t_ += part[oo][s2][r];
    const int bt = bt0 + r;
    if (oo < 16) {
      beta[(size_t)bt * NV_ + oo] = 1.f / (1.f + expf(-t_));
    } else {
      const int hh = oo - 16;
      float aa = t_ + dtb[hh];
      float sp = (aa > 20.f) ? aa : log1pf(expf(aa));
      gout[(size_t)bt * NV_ + hh] = -expf(alog[hh]) * sp;
    }
  }
}

// ---------------------------------------------------------------------------
// Fused depthwise causal conv1d (K=4) + silu + l2norm(q,k). (R14-verified)
// ---------------------------------------------------------------------------
__global__ __launch_bounds__(256)
void k_conv_silu_norm(const ushort_t* __restrict__ qkv, const float* __restrict__ cw,
                      ushort_t* __restrict__ act) {
  const int bt = blockIdx.x;
  const int tid = threadIdx.x;
  const int t = bt & (T_ - 1);
  const int c = tid * 16;
  const ushort_t* rowp = qkv + (size_t)bt * CD_ + c;

  float wf[16][4];
#pragma unroll
  for (int i = 0; i < 16; ++i) {
    float4 w = *(const float4*)&cw[(c + i) * 4];
    wf[i][0] = w.x; wf[i][1] = w.y; wf[i][2] = w.z; wf[i][3] = w.w;
  }
  float a[16];
#pragma unroll
  for (int i = 0; i < 16; ++i) a[i] = 0.f;
#pragma unroll
  for (int j = 0; j < 4; ++j) {
    const int tt = t - 3 + j;
    if (tt >= 0) {
      const ushort_t* src = rowp + ((ptrdiff_t)j - 3) * CD_;
      bf16x8 v0 = *(const bf16x8*)(const void*)src;
      bf16x8 v1 = *(const bf16x8*)(const void*)(src + 8);
#pragma unroll
      for (int i = 0; i < 8; ++i) {
        a[i]     += (float)v0[i] * wf[i][j];
        a[8 + i] += (float)v1[i] * wf[8 + i][j];
      }
    }
  }
#pragma unroll
  for (int i = 0; i < 16; ++i) a[i] = a[i] / (1.f + expf(-a[i]));
  float ss = 0.f;
#pragma unroll
  for (int i = 0; i < 16; ++i) ss += a[i] * a[i];
  ss += __shfl_xor(ss, 1); ss += __shfl_xor(ss, 2); ss += __shfl_xor(ss, 4);
  const int seg = tid >> 3;
  float scale = 1.f;
  if (seg < 16) {
    scale = 1.f / fmaxf(sqrtf(ss), 1e-12f);
    if (seg < 8) scale *= 0.08838834764831845f;
  }
  ushort_t ov[16];
#pragma unroll
  for (int i = 0; i < 16; ++i) ov[i] = f2b(a[i] * scale);
  ushort_t* dst = act + (size_t)bt * CD_ + c;
  *(uint4*)(void*)dst       = *(const uint4*)&ov[0];
  *(uint4*)(void*)(dst + 8) = *(const uint4*)&ov[8];
}

// ---------------------------------------------------------------------------
// k_prep: per-chunk parallel precompute. grid = 1024. (R20-exact)
// ---------------------------------------------------------------------------
__global__ __launch_bounds__(256, 1)
void k_prep(const ushort_t* __restrict__ act, const float* __restrict__ gB,
            const float* __restrict__ betaB,
            ushort_t* __restrict__ WkG, ushort_t* __restrict__ UlT,
            ushort_t* __restrict__ KTG, float* __restrict__ gtG) {
  __shared__ __bf16 Kl[64][136];
  __shared__ __bf16 AbL[64][40];
  __shared__ __bf16 AbH[32][33];
  __shared__ __bf16 Xl[64][264];
  __shared__ alignas(16) __bf16 Cr[16][264];
  __shared__ float gc[65], Et[65], Rt[65], bts[64], geT[64];

  const int wg = blockIdx.x;
  const int c = wg & 31, h = (wg >> 5) & 15, b = wg >> 9;
  const int hq = h >> 1, t0 = c * 64;
  const int tid = threadIdx.x, lane = tid & 63, wave = tid >> 6;
  const int l15 = lane & 15, kcol0 = (lane >> 4) * 8, rrow = (lane >> 4) * 4;
  const size_t bhc = (size_t)wg;

  const ushort_t* baseQ = act + (size_t)b * T_ * CD_ + hq * HD_;
  const ushort_t* baseK = baseQ + KD_;

  if (tid < 64) {
    float g = gB[((size_t)b * T_ + t0 + tid) * NV_ + h];
    bts[tid] = betaB[((size_t)b * T_ + t0 + tid) * NV_ + h];
#pragma unroll
    for (int o = 1; o < 64; o <<= 1) {
      float up = __shfl_up(g, (unsigned)o);
      if (tid >= o) g += up;
    }
    gc[tid + 1] = g;
    if (tid == 0) gc[0] = 0.f;
  }
  __syncthreads();
  if (tid < 65) {
    float gm = gc[32];
    Et[tid] = __expf(gc[tid] - gm);
    Rt[tid] = __expf(gm - gc[tid]);
  }
  if (tid < 64) {
    geT[tid] = bts[tid] * __expf(gc[tid + 1]);
    gtG[bhc * 64 + tid] = gc[tid + 1];
  }
  {
    const int t = tid >> 2, d0 = (tid & 3) * 32;
    const ushort_t* src = baseK + (size_t)(t0 + t) * CD_ + d0;
#pragma unroll
    for (int j = 0; j < 4; ++j)
      *(uint4*)&Kl[t][d0 + j * 8] = *(const uint4*)(const void*)(src + j * 8);
  }
  __syncthreads();

  // P1: Ab (strict lower, -beta*scale*KK^T) in LDS
  {
    bf16x8 kf[4];
#pragma unroll
    for (int kk = 0; kk < 4; ++kk)
      kf[kk] = *(const bf16x8*)&Kl[16 * wave + l15][kk * 32 + kcol0];
#pragma unroll
    for (int st = 0; st < 4; ++st) {
      if (st <= wave) {
        f32x4 accA = {};
#pragma unroll
        for (int kk = 0; kk < 4; ++kk) {
          bf16x8 bfr = *(const bf16x8*)&Kl[st * 16 + l15][kk * 32 + kcol0];
          accA = __builtin_amdgcn_mfma_f32_16x16x32_bf16(kf[kk], bfr, accA, 0, 0, 0);
        }
        const int scol = st * 16 + l15;
#pragma unroll
        for (int r = 0; r < 4; ++r) {
          const int t = 16 * wave + rrow + r;
          if (scol < t) {
            const float av = -bts[t] * Et[t + 1] * Rt[scol + 1] * accA[r];
            if (scol < 32) AbL[t][scol] = (__bf16)av;
            else           AbH[t - 32][scol - 32] = (__bf16)av;
          }
        }
      }
    }
  }
  __syncthreads();

  // KT store (raw K^T, shared by the v-head pair; even h only)
  if ((h & 1) == 0) {
    const size_t kto = (((size_t)b * 8 + hq) * 32 + c) * (128 * 64);
    const int d = tid >> 1, t8 = (tid & 1) * 32;
#pragma unroll
    for (int i8 = 0; i8 < 4; ++i8) {
      bf16x8 tmp;
#pragma unroll
      for (int jj = 0; jj < 8; ++jj) tmp[jj] = Kl[t8 + i8 * 8 + jj][d];
      *(bf16x8*)(void*)(KTG + kto + (size_t)d * 64 + t8 + i8 * 8) = tmp;
    }
  }

  // P2: block-16 recursive triangular solve (R19-verified).
  {
    float r1[32], r2[32];
    if (tid < 128) {
      const int d = tid;
#pragma unroll
      for (int t = 0; t < 32; ++t) r1[t] = geT[t] * (float)Kl[t][d];
#pragma unroll
      for (int t = 0; t < 32; ++t) r2[t] = geT[32 + t] * (float)Kl[32 + t][d];
    } else {
      const int j = tid - 128;
      const ushort_t* vsrc = act + ((size_t)b * T_ + t0) * CD_ + 2 * KD_ + h * HD_ + j;
#pragma unroll
      for (int t = 0; t < 32; ++t) r1[t] = bts[t] * b2f(vsrc[(size_t)t * CD_]);
#pragma unroll
      for (int t = 0; t < 32; ++t) r2[t] = bts[32 + t] * b2f(vsrc[(size_t)(32 + t) * CD_]);
    }

    {
      float u[16];
#pragma unroll
      for (int j = 0; j < 16; ++j) {
        float a = r1[j];
#pragma unroll
        for (int i = 0; i < j; ++i) a += (float)AbL[j][i] * u[i];
        u[j] = a;
        Xl[j][tid] = (__bf16)a;
      }
    }
    __syncthreads();

    {
      bf16x8 afr2;
#pragma unroll
      for (int j = 0; j < 8; ++j) {
        const int k = kcol0 + j;
        afr2[j] = (k < 16) ? AbL[16 + l15][k] : (__bf16)0.f;
      }
#pragma unroll
      for (int ct4 = 0; ct4 < 4; ++ct4) {
        const int ct = wave * 4 + ct4;
        bf16x8 bfr2;
#pragma unroll
        for (int j = 0; j < 8; ++j) {
          const int k = kcol0 + j;
          bfr2[j] = (k < 16) ? Xl[k][16 * ct + l15] : (__bf16)0.f;
        }
        f32x4 acc2 = {};
        acc2 = __builtin_amdgcn_mfma_f32_16x16x32_bf16(afr2, bfr2, acc2, 0, 0, 0);
#pragma unroll
        for (int r = 0; r < 4; ++r)
          Cr[rrow + r][16 * ct + l15] = (__bf16)acc2[r];
      }
    }
    __syncthreads();

    {
      float u[16];
#pragma unroll
      for (int j = 0; j < 16; ++j) {
        float a = r1[16 + j] + (float)Cr[j][tid];
#pragma unroll
        for (int i = 0; i < j; ++i) a += (float)AbL[16 + j][16 + i] * u[i];
        u[j] = a;
        Xl[16 + j][tid] = (__bf16)a;
      }
    }
    __syncthreads();

    {
      bf16x8 afr2 = *(const bf16x8*)&AbL[32 + l15][kcol0];
#pragma unroll
      for (int ct4 = 0; ct4 < 4; ++ct4) {
        const int ct = wave * 4 + ct4;
        bf16x8 bfr2;
#pragma unroll
        for (int j = 0; j < 8; ++j) bfr2[j] = Xl[kcol0 + j][16 * ct + l15];
        f32x4 acc2 = {};
        acc2 = __builtin_amdgcn_mfma_f32_16x16x32_bf16(afr2, bfr2, acc2, 0, 0, 0);
#pragma unroll
        for (int r = 0; r < 4; ++r)
          Cr[rrow + r][16 * ct + l15] = (__bf16)acc2[r];
      }
    }
    __syncthreads();

    {
      float u[16];
#pragma unroll
      for (int j = 0; j < 16; ++j) {
        float a = r2[j] + (float)Cr[j][tid];
#pragma unroll
        for (int i = 0; i < j; ++i) a += (float)AbH[j][i] * u[i];
        u[j] = a;
        Xl[32 + j][tid] = (__bf16)a;
      }
    }
    __syncthreads();

    {
      bf16x8 afrA = *(const bf16x8*)&AbL[48 + l15][kcol0];
      bf16x8 afrB;
#pragma unroll
      for (int j = 0; j < 8; ++j) {
        const int k = kcol0 + j;
        afrB[j] = (k < 16) ? AbH[16 + l15][k] : (__bf16)0.f;
      }
#pragma unroll
      for (int ct4 = 0; ct4 < 4; ++ct4) {
        const int ct = wave * 4 + ct4;
        bf16x8 bfrA, bfrB;
#pragma unroll
        for (int j = 0; j < 8; ++j) {
          const int k = kcol0 + j;
          bfrA[j] = Xl[k][16 * ct + l15];
          bfrB[j] = (k < 16) ? Xl[32 + k][16 * ct + l15] : (__bf16)0.f;
        }
        f32x4 acc2 = {};
        acc2 = __builtin_amdgcn_mfma_f32_16x16x32_bf16(afrA, bfrA, acc2, 0, 0, 0);
        acc2 = __builtin_amdgcn_mfma_f32_16x16x32_bf16(afrB, bfrB, acc2, 0, 0, 0);
#pragma unroll
        for (int r = 0; r < 4; ++r)
          Cr[rrow + r][16 * ct + l15] = (__bf16)acc2[r];
      }
    }
    __syncthreads();

    {
      float u[16];
#pragma unroll
      for (int j = 0; j < 16; ++j) {
        float a = r2[16 + j] + (float)Cr[j][tid];
#pragma unroll
        for (int i = 0; i < j; ++i) a += (float)AbH[16 + j][16 + i] * u[i];
        u[j] = a;
        Xl[48 + j][tid] = (__bf16)a;
      }
    }
  }
  __syncthreads();

  // P3: Wk copy (negated, stride 128) + Uloc^T store (stride 64)
#pragma unroll
  for (int kck = 0; kck < 4; ++kck) {
    const int q = tid + kck * 256;
    const int t = q >> 4, d0 = (q & 15) * 8;
    uint4 v = *(const uint4*)&Xl[t][d0];
    v.x ^= 0x80008000u; v.y ^= 0x80008000u; v.z ^= 0x80008000u; v.w ^= 0x80008000u;
    *(uint4*)(void*)(WkG + bhc * (64 * 128) + (size_t)t * 128 + d0) = v;
  }
  {
    const int e = tid >> 1, t8 = (tid & 1) * 32;
#pragma unroll
    for (int i8 = 0; i8 < 4; ++i8) {
      bf16x8 tmp;
#pragma unroll
      for (int jj = 0; jj < 8; ++jj) tmp[jj] = Xl[t8 + i8 * 8 + jj][128 + e];
      *(bf16x8*)(void*)(UlT + bhc * (128 * 64) + (size_t)e * 64 + t8 + i8 * 8) = tmp;
    }
  }
}

// ---------------------------------------------------------------------------
// scan body (R20-verified): u-phase + S-update recomputed from Wk/Ul/KT.
// ---------------------------------------------------------------------------
__device__ __forceinline__ void scan_body(
    const ushort_t* __restrict__ WkG, const ushort_t* __restrict__ UlT,
    const ushort_t* __restrict__ KTG, const float* __restrict__ gtG,
    ushort_t* __restrict__ ScG, int sb, char* smem) {
  const int eh = sb & 1, wg = sb >> 1;
  const int h = wg & 15, b = wg >> 4, hq = h >> 1;
  const int e0 = eh * 64;
  const int tid = threadIdx.x, lane = tid & 63, wave = tid >> 6;
  const int l15 = lane & 15, kcol0 = (lane >> 4) * 8, rrow = (lane >> 4) * 4;
  const int et = wave & 3, dh = wave >> 2;
  const int ue = wave >> 1, ut0 = (wave & 1) * 2;

  char* WkS = smem;
  char* KTS = smem + 32768;
  char* UlS = smem + 65536;
  __bf16 (*S16)[136] = (__bf16(*)[136])(smem + 81920);
  __bf16 (*uS)[72]   = (__bf16(*)[72])(smem + 99328);
  float* escS = (float*)(smem + 108544);

#define SSTAGE(BUF, CN) {                                                     \
    const int cn_ = ((CN) < 32) ? (CN) : 31;                                  \
    const ushort_t* WkR_ = WkG + ((size_t)wg * 32 + cn_) * (64 * 128);        \
    const ushort_t* KTR_ = KTG + (((size_t)b * 8 + hq) * 32 + cn_) * (128 * 64); \
    const ushort_t* UlR_ = UlT + ((size_t)wg * 32 + cn_) * (128 * 64)         \
                               + (size_t)e0 * 64;                             \
    _Pragma("unroll") for (int r_ = 0; r_ < 2; ++r_) {                        \
      const int idx_ = r_ * 512 + tid;                                        \
      const int d_ = idx_ >> 4, sl_ = idx_ & 15;                              \
      const ushort_t* src_ = WkR_ + (size_t)d_ * 128 + ((sl_ ^ (d_ & 7)) << 3); \
      __builtin_amdgcn_global_load_lds(                                       \
          (const __attribute__((address_space(1))) unsigned int*)src_,        \
          (__attribute__((address_space(3))) unsigned int*)                   \
              (WkS + (BUF) * 16384 + r_ * 8192 + wave * 1024), 16, 0, 0);     \
    }                                                                         \
    _Pragma("unroll") for (int r_ = 0; r_ < 2; ++r_) {                        \
      const int idx_ = r_ * 512 + tid;                                        \
      const int d_ = idx_ >> 3, sl_ = idx_ & 7;                               \
      const ushort_t* src_ = KTR_ + (size_t)d_ * 64 + ((sl_ ^ (d_ & 7)) << 3); \
      __builtin_amdgcn_global_load_lds(                                       \
          (const __attribute__((address_space(1))) unsigned int*)src_,        \
          (__attribute__((address_space(3))) unsigned int*)                   \
              (KTS + (BUF) * 16384 + r_ * 8192 + wave * 1024), 16, 0, 0);     \
    }                                                                         \
    {                                                                         \
      const int e_ = tid >> 3, sl_ = tid & 7;                                 \
      const ushort_t* src_ = UlR_ + (size_t)e_ * 64 + ((sl_ ^ (e_ & 7)) << 3); \
      __builtin_amdgcn_global_load_lds(                                       \
          (const __attribute__((address_space(1))) unsigned int*)src_,        \
          (__attribute__((address_space(3))) unsigned int*)                   \
              (UlS + (BUF) * 8192 + wave * 1024), 16, 0, 0);                  \
    }                                                                         \
  }

#define WRD(BUF, ROW, KC)                                                     \
  (*(const bf16x8*)(WkS + (BUF) * 16384 + ((ROW) << 8) +                      \
                    (((KC) << 1) ^ (((ROW) & 7) << 4))))
#define KRD(BUF, ROW, KC)                                                     \
  (*(const bf16x8*)(KTS + (BUF) * 16384 + ((ROW) << 7) +                      \
                    (((KC) << 1) ^ (((ROW) & 7) << 4))))
#define ULS(BUF, E, T)                                                        \
  (*(const ushort_t*)(UlS + (BUF) * 8192 + ((E) << 7) +                       \
                      (((((T) >> 3) << 4)) ^ (((E) & 7) << 4)) + ((T) & 7) * 2))

  f32x4 s_acc[4] = {};
  SSTAGE(0, 0)

  for (int c = 0; c < 32; ++c) {
    const int buf = c & 1;
    ushort_t* ScR = ScG + ((size_t)wg * 32 + c) * CHM_;
    const float* gtR = gtG + ((size_t)wg * 32 + c) * 64;

    __syncthreads();
    SSTAGE(buf ^ 1, c + 1)

    const float g63 = gtR[63];
    if (tid < 64) escS[tid] = __expf(g63 - gtR[tid]);
    const float gCe = __expf(g63);

#pragma unroll
    for (int dl = 0; dl < 4; ++dl)
#pragma unroll
      for (int r = 0; r < 4; ++r)
        S16[16 * et + rrow + r][(4 * dh + dl) * 16 + l15] = (__bf16)s_acc[dl][r];
    asm volatile("s_waitcnt lgkmcnt(0)" ::: "memory");
    __builtin_amdgcn_sched_barrier(0);
    __builtin_amdgcn_s_barrier();
    __builtin_amdgcn_sched_barrier(0);

#pragma unroll
    for (int cc = 0; cc < 2; ++cc) {
      const int idx = tid + cc * 512;
      const int row = idx >> 4, seg = idx & 15;
      *(uint4*)(void*)(ScR + (size_t)(e0 + row) * 128 + seg * 8) =
          *(const uint4*)&S16[row][seg * 8];
    }

#pragma unroll
    for (int t2 = 0; t2 < 2; ++t2) {
      const int tt = ut0 + t2;
      f32x4 a = {};
#pragma unroll
      for (int r = 0; r < 4; ++r)
        a[r] = b2f(ULS(buf, 16 * ue + rrow + r, 16 * tt + l15));
#pragma unroll
      for (int kk = 0; kk < 4; ++kk) {
        bf16x8 af = *(const bf16x8*)&S16[16 * ue + l15][kk * 32 + kcol0];
        bf16x8 bw = WRD(buf, 16 * tt + l15, kk * 32 + kcol0);
        a = __builtin_amdgcn_mfma_f32_16x16x32_bf16(af, bw, a, 0, 0, 0);
      }
      const float es = escS[16 * tt + l15];
#pragma unroll
      for (int r = 0; r < 4; ++r)
        uS[16 * ue + rrow + r][16 * tt + l15] = (__bf16)(a[r] * es);
    }
    asm volatile("s_waitcnt lgkmcnt(0)" ::: "memory");
    __builtin_amdgcn_sched_barrier(0);
    __builtin_amdgcn_s_barrier();
    __builtin_amdgcn_sched_barrier(0);

#pragma unroll
    for (int dl = 0; dl < 4; ++dl)
#pragma unroll
      for (int r = 0; r < 4; ++r) s_acc[dl][r] *= gCe;
#pragma unroll
    for (int ks = 0; ks < 2; ++ks) {
      bf16x8 ua = *(const bf16x8*)&uS[16 * et + l15][ks * 32 + kcol0];
#pragma unroll
      for (int dl = 0; dl < 4; ++dl) {
        bf16x8 kb = KRD(buf, 16 * (4 * dh + dl) + l15, ks * 32 + kcol0);
        s_acc[dl] = __builtin_amdgcn_mfma_f32_16x16x32_bf16(ua, kb, s_acc[dl], 0, 0, 0);
      }
    }
  }
#undef SSTAGE
#undef WRD
#undef KRD
#undef ULS
}

// ---------------------------------------------------------------------------
// FUSED launch: blocks 0..63 = scan, 64..191 = z-gemm tiles (independent).
// ---------------------------------------------------------------------------
__global__ __launch_bounds__(512, 2)
void k_scan_zgemm(const ushort_t* __restrict__ WkG, const ushort_t* __restrict__ UlT,
                  const ushort_t* __restrict__ KTG, const float* __restrict__ gtG,
                  ushort_t* __restrict__ ScG,
                  const ushort_t* __restrict__ xB, const ushort_t* __restrict__ WzB,
                  ushort_t* __restrict__ zbuf) {
  __shared__ alignas(16) char smem[131072];
  if (blockIdx.x < 64)
    scan_body(WkG, UlT, KTG, gtG, ScG, blockIdx.x, smem);
  else
    gemm256_body<ushort_t>(xB, WzB, zbuf, B_ * T_, VD_, HID_,
                           blockIdx.x - 64, (ushort_t*)smem);
}

// ---------------------------------------------------------------------------
// k_out (R19-exact): u = Ul + Wkneg@S_c; Pm recomputed; o = gam*Q@S_c + Pm@u;
// fused gated RMSNorm -> bf16 outg. grid=1024.
// ---------------------------------------------------------------------------
__global__ __launch_bounds__(256, 2)
void k_out(const ushort_t* __restrict__ act,
           const ushort_t* __restrict__ WkG, const ushort_t* __restrict__ UlT,
           const float* __restrict__ gtG,
           const ushort_t* __restrict__ ScG, const ushort_t* __restrict__ zbuf,
           const float* __restrict__ nw, ushort_t* __restrict__ outg) {
  __shared__ __bf16 S16[128][136];
  __shared__ __bf16 uTl[128][72];
  __shared__ __bf16 PmL[64][72];
  __shared__ float Egc[65], Rgc[65], gam[64], nws[128];

  const int bhc = blockIdx.x;
  const int c = bhc & 31, h = (bhc >> 5) & 15, b = bhc >> 9;
  const int hq = h >> 1, t0g = c * 64;
  const int tid = threadIdx.x, lane = tid & 63, wave = tid >> 6;
  const int l15 = lane & 15, kcol0 = (lane >> 4) * 8, rrow = (lane >> 4) * 4;

  const ushort_t* ScR = ScG + (size_t)bhc * CHM_;
  const ushort_t* WkR = WkG + (size_t)bhc * (64 * 128);
  const ushort_t* UlR = UlT + (size_t)bhc * (128 * 64);
  const ushort_t* actQ = act + ((size_t)b * T_ + t0g) * CD_ + hq * HD_;
  const ushort_t* actK = actQ + KD_;

#pragma unroll
  for (int cc = 0; cc < 8; ++cc) {
    const int idx = tid + cc * 256;
    const int row = idx >> 4, seg = idx & 15;
    *(uint4*)&S16[row][seg * 8] =
        *(const uint4*)(const void*)(ScR + (size_t)row * 128 + seg * 8);
  }
  {
    const float gc32 = gtG[(size_t)bhc * 64 + 31];
    if (tid < 65) {
      const float gcv = (tid == 0) ? 0.f : gtG[(size_t)bhc * 64 + tid - 1];
      Egc[tid] = __expf(gcv - gc32);
      Rgc[tid] = __expf(gc32 - gcv);
    }
    if (tid < 64) gam[tid] = __expf(gtG[(size_t)bhc * 64 + tid]);
    if (tid < 128) nws[tid] = nw[tid];
  }
  __syncthreads();

  bf16x8 qf[4];
#pragma unroll
  for (int kk = 0; kk < 4; ++kk)
    qf[kk] = *(const bf16x8*)(const void*)
        (actQ + (size_t)(16 * wave + l15) * CD_ + kk * 32 + kcol0);

  bf16x8 wa[4];
#pragma unroll
  for (int kk = 0; kk < 4; ++kk)
    wa[kk] = *(const bf16x8*)(const void*)(WkR + (size_t)(16 * wave + l15) * 128 + kk * 32 + kcol0);
  f32x4 au[8] = {};
#pragma unroll
  for (int kk = 0; kk < 4; ++kk)
#pragma unroll
    for (int jt = 0; jt < 8; ++jt) {
      bf16x8 sb = *(const bf16x8*)&S16[jt * 16 + l15][kk * 32 + kcol0];
      au[jt] = __builtin_amdgcn_mfma_f32_16x16x32_bf16(wa[kk], sb, au[jt], 0, 0, 0);
    }
#pragma unroll
  for (int jt = 0; jt < 8; ++jt) {
    short4v uv = *(const short4v*)(const void*)(UlR + (size_t)(16 * jt + l15) * 64 + wave * 16 + rrow);
#pragma unroll
    for (int r = 0; r < 4; ++r)
      uTl[16 * jt + l15][16 * wave + rrow + r] = (__bf16)(au[jt][r] + b2f((ushort_t)uv[r]));
  }

#pragma unroll
  for (int st = 0; st < 4; ++st) {
    f32x4 accP = {};
#pragma unroll
    for (int kk = 0; kk < 4; ++kk) {
      bf16x8 kb = *(const bf16x8*)(const void*)
          (actK + (size_t)(st * 16 + l15) * CD_ + kk * 32 + kcol0);
      accP = __builtin_amdgcn_mfma_f32_16x16x32_bf16(qf[kk], kb, accP, 0, 0, 0);
    }
    const int scol = st * 16 + l15;
#pragma unroll
    for (int r = 0; r < 4; ++r) {
      const int t = 16 * wave + rrow + r;
      PmL[t][scol] = (scol <= t) ? (__bf16)(Egc[t + 1] * Rgc[scol + 1] * accP[r])
                                 : (__bf16)0.f;
    }
  }
  __syncthreads();

  f32x4 qs[8] = {}, o2[8] = {};
#pragma unroll
  for (int kk = 0; kk < 4; ++kk)
#pragma unroll
    for (int jt = 0; jt < 8; ++jt) {
      bf16x8 sb = *(const bf16x8*)&S16[jt * 16 + l15][kk * 32 + kcol0];
      qs[jt] = __builtin_amdgcn_mfma_f32_16x16x32_bf16(qf[kk], sb, qs[jt], 0, 0, 0);
    }
#pragma unroll
  for (int ks = 0; ks < 2; ++ks) {
    bf16x8 pa = *(const bf16x8*)&PmL[16 * wave + l15][ks * 32 + kcol0];
#pragma unroll
    for (int jt = 0; jt < 8; ++jt) {
      bf16x8 ub = *(const bf16x8*)&uTl[jt * 16 + l15][ks * 32 + kcol0];
      o2[jt] = __builtin_amdgcn_mfma_f32_16x16x32_bf16(pa, ub, o2[jt], 0, 0, 0);
    }
  }
  float ov[8][4];
  float ss0 = 0.f, ss1 = 0.f, ss2 = 0.f, ss3 = 0.f;
#pragma unroll
  for (int jt = 0; jt < 8; ++jt) {
    ov[jt][0] = gam[16 * wave + rrow + 0] * qs[jt][0] + o2[jt][0];
    ov[jt][1] = gam[16 * wave + rrow + 1] * qs[jt][1] + o2[jt][1];
    ov[jt][2] = gam[16 * wave + rrow + 2] * qs[jt][2] + o2[jt][2];
    ov[jt][3] = gam[16 * wave + rrow + 3] * qs[jt][3] + o2[jt][3];
    ss0 += ov[jt][0] * ov[jt][0];
    ss1 += ov[jt][1] * ov[jt][1];
    ss2 += ov[jt][2] * ov[jt][2];
    ss3 += ov[jt][3] * ov[jt][3];
  }
#pragma unroll
  for (int m = 1; m < 16; m <<= 1) {
    ss0 += __shfl_xor(ss0, m);
    ss1 += __shfl_xor(ss1, m);
    ss2 += __shfl_xor(ss2, m);
    ss3 += __shfl_xor(ss3, m);
  }
  float rr[4];
  rr[0] = 1.f / sqrtf(ss0 * (1.f / HD_) + 1e-6f);
  rr[1] = 1.f / sqrtf(ss1 * (1.f / HD_) + 1e-6f);
  rr[2] = 1.f / sqrtf(ss2 * (1.f / HD_) + 1e-6f);
  rr[3] = 1.f / sqrtf(ss3 * (1.f / HD_) + 1e-6f);
#pragma unroll
  for (int jt = 0; jt < 8; ++jt) {
    const int e = 16 * jt + l15;
    const float wv = nws[e];
#pragma unroll
    for (int r = 0; r < 4; ++r) {
      const int t = 16 * wave + rrow + r;
      const float zf = b2f(zbuf[((size_t)b * T_ + t0g + t) * VD_ + h * HD_ + e]);
      const float g = zf / (1.f + expf(-zf));
      outg[(((size_t)b * T_ + t0g + t) * NV_ + h) * HD_ + e] =
          f2b(ov[jt][r] * rr[r] * wv * g);
    }
  }
}

// ---------------------------------------------------------------------------
extern "C" void kernel_launch(void* const* d_in, const int* in_sizes, int n_in,
                              void* d_out, int out_size, void* d_ws, size_t ws_size,
                              hipStream_t stream) {
  const float* x    = (const float*)d_in[0];
  const float* Wqkv = (const float*)d_in[1];
  const float* Wz   = (const float*)d_in[2];
  const float* Wb   = (const float*)d_in[3];
  const float* Wa   = (const float*)d_in[4];
  const float* cw   = (const float*)d_in[5];
  const float* dtb  = (const float*)d_in[6];
  const float* alog = (const float*)d_in[7];
  const float* nw   = (const float*)d_in[8];
  const float* Wout = (const float*)d_in[9];

  // ---- workspace layout: ~177 MB total ----
  char* p = (char*)d_ws;
  ushort_t* qkv_raw = (ushort_t*)p; p += (size_t)B_ * T_ * CD_ * 2;       // 33.55 MB
  ushort_t* zbuf    = (ushort_t*)p; p += (size_t)B_ * T_ * VD_ * 2;       // 16.78 MB
  ushort_t* act     = (ushort_t*)p; p += (size_t)B_ * T_ * CD_ * 2;       // 33.55 MB
  float*    betaB   = (float*)p;    p += (size_t)B_ * T_ * NV_ * 4;       //  0.26 MB
  float*    gBuf    = (float*)p;    p += (size_t)B_ * T_ * NV_ * 4;       //  0.26 MB
  float*    gtG     = (float*)p;    p += (size_t)1024 * 64 * 4;           //  0.26 MB
  ushort_t* xB      = (ushort_t*)p; p += (size_t)B_ * T_ * HID_ * 2;      // 16.78 MB
  ushort_t* WzB     = (ushort_t*)p; p += (size_t)VD_ * HID_ * 2;          //  8.39 MB
  ushort_t* WoutB   = (ushort_t*)p; p += (size_t)HID_ * VD_ * 2;          //  8.39 MB
  ushort_t* outg    = (ushort_t*)p; p += (size_t)B_ * T_ * VD_ * 2;       // 16.78 MB
  ushort_t* ScG     = (ushort_t*)p; p += (size_t)1024 * CHM_ * 2;         // 33.55 MB
  ushort_t* KTG     = (ushort_t*)p; p += (size_t)512 * 128 * 64 * 2;      //  8.39 MB
  ushort_t* WbB     = (ushort_t*)p; p += (size_t)NV_ * HID_ * 2;          //  0.065 MB
  ushort_t* WaB     = (ushort_t*)p; p += (size_t)NV_ * HID_ * 2;          //  0.065 MB
  // overlays (qkv_raw dead after conv):
  ushort_t* WkG   = qkv_raw;
  ushort_t* UlT   = qkv_raw + (size_t)1024 * 64 * 128;
  ushort_t* WqkvB = act;

  const int M = B_ * T_;  // 4096

  const int n0 = M * HID_ / 4, n1 = CD_ * HID_ / 4;
  const int n2 = VD_ * HID_ / 4, n3 = HID_ * VD_ / 4;
  const int n4 = NV_ * HID_ / 4, n5 = NV_ * HID_ / 4;
  hipLaunchKernelGGL(k_cast6, dim3((n0 + n1 + n2 + n3 + n4 + n5 + 255) / 256), dim3(256), 0, stream,
                     x, xB, n0, Wqkv, WqkvB, n1, Wz, WzB, n2,
                     Wout, WoutB, n3, Wb, WbB, n4, Wa, WaB, n5);

  hipLaunchKernelGGL(k_gemm256<ushort_t>, dim3((M / 256) * (CD_ / 256)), dim3(512), 0, stream,
                     xB, WqkvB, qkv_raw, M, CD_, HID_);
  hipLaunchKernelGGL(k_proj_ba2, dim3(M / 4), dim3(256), 0, stream,
                     xB, WbB, WaB, dtb, alog, betaB, gBuf);
  hipLaunchKernelGGL(k_conv_silu_norm, dim3(M), dim3(256), 0, stream,
                     qkv_raw, cw, act);
  hipLaunchKernelGGL(k_prep, dim3(B_ * NV_ * 32), dim3(256), 0, stream,
                     act, gBuf, betaB, WkG, UlT, KTG, gtG);
  hipLaunchKernelGGL(k_scan_zgemm, dim3(64 + (M / 256) * (VD_ / 256)), dim3(512), 0, stream,
                     WkG, UlT, KTG, gtG, ScG, xB, WzB, zbuf);
  hipLaunchKernelGGL(k_out, dim3(B_ * NV_ * 32), dim3(256), 0, stream,
                     act, WkG, UlT, gtG, ScG, zbuf, nw, outg);
  hipLaunchKernelGGL(k_gemm256x128<float>, dim3((M / 256) * (HID_ / 128)), dim3(512), 0, stream,
                     outg, WoutB, (float*)d_out, M, HID_, VD_);
}

// Round 23
// 356.964 us; speedup vs baseline: 1.5194x; 1.0401x over previous
//
#include <hip/hip_runtime.h>
#include <cstdint>
#include <cstddef>

// GatedDeltaNet forward, MI355X/gfx950.
// R23 = R22 with k_conv_silu_norm rewritten: 4 rows/block (grid 1024), each
// thread loads the 7 needed rows ONCE (4x ILP, 16->7 row-loads) and emits 4
// rows; XCD-chunked block swizzle so boundary rows are L2-local. Per-output
// math order unchanged (bit-identical numerics). Everything else R22-exact.

typedef unsigned short ushort_t;
typedef __attribute__((ext_vector_type(8))) __bf16 bf16x8;
typedef __attribute__((ext_vector_type(4))) float f32x4;
typedef __attribute__((ext_vector_type(4))) short short4v;

#define B_   2
#define T_   2048
#define HID_ 2048
#define NK_  8
#define NV_  16
#define HD_  128
#define KD_  1024
#define VD_  2048
#define CD_  4096
#define CHM_ 16384

#define SWZ(ROW) ((((ROW) >> 1) & 3) << 4)

__device__ __forceinline__ float b2f(ushort_t u) {
  union { unsigned int i; float f; } v; v.i = ((unsigned int)u) << 16; return v.f;
}
__device__ __forceinline__ ushort_t f2b(float f) {   // RNE bf16 round
  unsigned int x = __builtin_bit_cast(unsigned int, f);
  unsigned int r = x + 0x7fffu + ((x >> 16) & 1u);
  return (ushort_t)(r >> 16);
}

// ---------------------------------------------------------------------------
// fp32 -> bf16 casts: single kernel, six (src,dst) ranges
// ---------------------------------------------------------------------------
__global__ __launch_bounds__(256)
void k_cast6(const float* __restrict__ s0, ushort_t* __restrict__ d0, int n0,
             const float* __restrict__ s1, ushort_t* __restrict__ d1, int n1,
             const float* __restrict__ s2, ushort_t* __restrict__ d2, int n2,
             const float* __restrict__ s3, ushort_t* __restrict__ d3, int n3,
             const float* __restrict__ s4, ushort_t* __restrict__ d4, int n4,
             const float* __restrict__ s5, ushort_t* __restrict__ d5, int n5) {
  int i = blockIdx.x * 256 + threadIdx.x;
  const float* s; ushort_t* d;
  if (i < n0) { s = s0; d = d0; }
  else if (i < n0 + n1) { i -= n0; s = s1; d = d1; }
  else if (i < n0 + n1 + n2) { i -= n0 + n1; s = s2; d = d2; }
  else if (i < n0 + n1 + n2 + n3) { i -= n0 + n1 + n2; s = s3; d = d3; }
  else if (i < n0 + n1 + n2 + n3 + n4) { i -= n0 + n1 + n2 + n3; s = s4; d = d4; }
  else { i -= n0 + n1 + n2 + n3 + n4; if (i >= n5) return; s = s5; d = d5; }
  float4 v = *(const float4*)(s + (size_t)i * 4);
  short4v o;
  o[0] = (short)f2b(v.x); o[1] = (short)f2b(v.y);
  o[2] = (short)f2b(v.z); o[3] = (short)f2b(v.w);
  *(short4v*)(d + (size_t)i * 4) = o;
}

// ---------------------------------------------------------------------------
// GEMM 256x256 body, BK=64, 8 waves, counted-vmcnt pipeline (R8-verified;
// R22 swizzle).
// ---------------------------------------------------------------------------
#define LPOS(BUF, OP, HALF) ((((BUF) * 2 + (OP)) * 2 + (HALF)) * 8192)

template <typename OutT>
__device__ __forceinline__ void gemm256_body(
    const ushort_t* __restrict__ A, const ushort_t* __restrict__ Bw,
    OutT* __restrict__ C, int M, int N, int K, int tile, ushort_t* lds) {
  const int tid = threadIdx.x;
  const int lane = tid & 63, wave = tid >> 6;
  const int wm = wave >> 2, wc = wave & 3;
  const int l15 = lane & 15;
  const int ks16 = (lane >> 4) * 16;
  const int r4 = (lane >> 4) * 4;
  const int nkt = K >> 6;
  const int nbx = N >> 8;
  const size_t row0 = (size_t)(tile / nbx) * 256;
  const size_t col0 = (size_t)(tile % nbx) * 256;

#define STAGE4(BUF, HALF, KT) {                                               \
    const int kt_ = ((KT) < nkt) ? (KT) : (nkt - 1);                          \
    const int kb_ = kt_ * 64 + (HALF) * 32;                                   \
    _Pragma("unroll") for (int r_ = 0; r_ < 2; ++r_) {                        \
      const int wb_ = r_ * 8192 + wave * 1024;                                \
      const int o_  = wb_ + lane * 16;                                        \
      const int row_ = o_ >> 6;                                               \
      const int src_ = (o_ & 63) ^ SWZ(row_);                                 \
      const ushort_t* ga_ = A  + (row0 + row_) * (size_t)K + kb_ + (src_ >> 1); \
      const ushort_t* gb_ = Bw + (col0 + row_) * (size_t)K + kb_ + (src_ >> 1); \
      __builtin_amdgcn_global_load_lds(                                       \
          (const __attribute__((address_space(1))) unsigned int*)ga_,         \
          (__attribute__((address_space(3))) unsigned int*)                   \
              (lds + LPOS(BUF, 0, HALF) + (wb_ >> 1)), 16, 0, 0);             \
      __builtin_amdgcn_global_load_lds(                                       \
          (const __attribute__((address_space(1))) unsigned int*)gb_,         \
          (__attribute__((address_space(3))) unsigned int*)                   \
              (lds + LPOS(BUF, 1, HALF) + (wb_ >> 1)), 16, 0, 0);             \
    }                                                                         \
  }

#define RD(BUF, OP, HALF, ROW)                                                \
  (*(const bf16x8*)((const char*)(lds + LPOS(BUF, OP, HALF)) +                \
                    ((((ROW) * 64 + ks16)) ^ SWZ(ROW))))

  f32x4 acc[8][4] = {};
  STAGE4(0, 0, 0)
  STAGE4(0, 1, 0)
  STAGE4(1, 0, 1)

  for (int kt = 0; kt < nkt; ++kt) {
    const int cb = kt & 1, nb = cb ^ 1;
    asm volatile("s_waitcnt vmcnt(8)" ::: "memory");
    __builtin_amdgcn_s_barrier();
    {
      bf16x8 af[8], bfr[4];
#pragma unroll
      for (int mf = 0; mf < 8; ++mf) af[mf] = RD(cb, 0, 0, wm * 128 + mf * 16 + l15);
#pragma unroll
      for (int nf = 0; nf < 4; ++nf) bfr[nf] = RD(cb, 1, 0, wc * 64 + nf * 16 + l15);
      STAGE4(nb, 1, kt + 1)
      __builtin_amdgcn_s_setprio(1);
#pragma unroll
      for (int mf = 0; mf < 8; ++mf)
#pragma unroll
        for (int nf = 0; nf < 4; ++nf)
          acc[mf][nf] = __builtin_amdgcn_mfma_f32_16x16x32_bf16(af[mf], bfr[nf], acc[mf][nf], 0, 0, 0);
      __builtin_amdgcn_s_setprio(0);
    }
    asm volatile("s_waitcnt vmcnt(8)" ::: "memory");
    __builtin_amdgcn_s_barrier();
    {
      bf16x8 af[8], bfr[4];
#pragma unroll
      for (int mf = 0; mf < 8; ++mf) af[mf] = RD(cb, 0, 1, wm * 128 + mf * 16 + l15);
#pragma unroll
      for (int nf = 0; nf < 4; ++nf) bfr[nf] = RD(cb, 1, 1, wc * 64 + nf * 16 + l15);
      STAGE4(cb, 0, kt + 2)
      __builtin_amdgcn_s_setprio(1);
#pragma unroll
      for (int mf = 0; mf < 8; ++mf)
#pragma unroll
        for (int nf = 0; nf < 4; ++nf)
          acc[mf][nf] = __builtin_amdgcn_mfma_f32_16x16x32_bf16(af[mf], bfr[nf], acc[mf][nf], 0, 0, 0);
      __builtin_amdgcn_s_setprio(0);
    }
  }
#undef STAGE4
#undef RD

#pragma unroll
  for (int mf = 0; mf < 8; ++mf)
#pragma unroll
    for (int nf = 0; nf < 4; ++nf)
#pragma unroll
      for (int j = 0; j < 4; ++j) {
        const size_t row = row0 + wm * 128 + mf * 16 + r4 + j;
        const size_t col = col0 + wc * 64 + nf * 16 + l15;
        if constexpr (sizeof(OutT) == 4)
          C[row * (size_t)N + col] = acc[mf][nf][j];
        else
          C[row * (size_t)N + col] = (OutT)f2b(acc[mf][nf][j]);
      }
}

template <typename OutT>
__global__ __launch_bounds__(512, 2)
void k_gemm256(const ushort_t* __restrict__ A, const ushort_t* __restrict__ Bw,
               OutT* __restrict__ C, int M, int N, int K) {
  __shared__ alignas(16) ushort_t lds[2 * 2 * 2 * 8192];
  const int nwg = gridDim.x;
  const int q8 = nwg >> 3, r8 = nwg & 7;
  const int xcd = blockIdx.x & 7, idx8 = blockIdx.x >> 3;
  const int s = (xcd < r8) ? (xcd * (q8 + 1) + idx8)
                           : (r8 * (q8 + 1) + (xcd - r8) * q8 + idx8);
  gemm256_body<OutT>(A, Bw, C, M, N, K, s, lds);
}

// ---------------------------------------------------------------------------
// GEMM 256x128 tile (R17-verified; R22 swizzle): vmcnt(6), 3 loads/half.
// ---------------------------------------------------------------------------
#define LPA(BUF, HALF) (((BUF) * 2 + (HALF)) * 8192)
#define LPB(BUF, HALF) (32768 + ((BUF) * 2 + (HALF)) * 4096)

template <typename OutT>
__global__ __launch_bounds__(512, 1)
void k_gemm256x128(const ushort_t* __restrict__ A, const ushort_t* __restrict__ Bw,
                   OutT* __restrict__ C, int M, int N, int K) {
  __shared__ alignas(16) ushort_t lds[49152];   // 96 KB
  const int tid = threadIdx.x;
  const int lane = tid & 63, wave = tid >> 6;
  const int wm = wave >> 1, wc = wave & 1;
  const int l15 = lane & 15;
  const int ks16 = (lane >> 4) * 16;
  const int r4 = (lane >> 4) * 4;
  const int nkt = K >> 6;
  const int nbx = N >> 7;
  const int nwg = gridDim.x;
  const int q8 = nwg >> 3, r8 = nwg & 7;
  const int xcd = blockIdx.x & 7, idx8 = blockIdx.x >> 3;
  const int s = (xcd < r8) ? (xcd * (q8 + 1) + idx8)
                           : (r8 * (q8 + 1) + (xcd - r8) * q8 + idx8);
  const size_t row0 = (size_t)(s / nbx) * 256;
  const size_t col0 = (size_t)(s % nbx) * 128;

#define STG3(BUF, HALF, KT) {                                                 \
    const int kt_ = ((KT) < nkt) ? (KT) : (nkt - 1);                          \
    const int kb_ = kt_ * 64 + (HALF) * 32;                                   \
    _Pragma("unroll") for (int r_ = 0; r_ < 2; ++r_) {                        \
      const int wb_ = r_ * 8192 + wave * 1024;                                \
      const int o_  = wb_ + lane * 16;                                        \
      const int row_ = o_ >> 6;                                               \
      const int src_ = (o_ & 63) ^ SWZ(row_);                                 \
      const ushort_t* ga_ = A + (row0 + row_) * (size_t)K + kb_ + (src_ >> 1); \
      __builtin_amdgcn_global_load_lds(                                       \
          (const __attribute__((address_space(1))) unsigned int*)ga_,         \
          (__attribute__((address_space(3))) unsigned int*)                   \
              (lds + LPA(BUF, HALF) + (wb_ >> 1)), 16, 0, 0);                 \
    }                                                                         \
    {                                                                         \
      const int wb_ = wave * 1024;                                            \
      const int o_  = wb_ + lane * 16;                                        \
      const int row_ = o_ >> 6;                                               \
      const int src_ = (o_ & 63) ^ SWZ(row_);                                 \
      const ushort_t* gb_ = Bw + (col0 + row_) * (size_t)K + kb_ + (src_ >> 1); \
      __builtin_amdgcn_global_load_lds(                                       \
          (const __attribute__((address_space(1))) unsigned int*)gb_,         \
          (__attribute__((address_space(3))) unsigned int*)                   \
              (lds + LPB(BUF, HALF) + (wb_ >> 1)), 16, 0, 0);                 \
    }                                                                         \
  }

#define RDA(BUF, HALF, ROW)                                                   \
  (*(const bf16x8*)((const char*)(lds + LPA(BUF, HALF)) +                     \
                    ((((ROW) * 64 + ks16)) ^ SWZ(ROW))))
#define RDB(BUF, HALF, ROW)                                                   \
  (*(const bf16x8*)((const char*)(lds + LPB(BUF, HALF)) +                     \
                    ((((ROW) * 64 + ks16)) ^ SWZ(ROW))))

  f32x4 acc[4][4] = {};
  STG3(0, 0, 0)
  STG3(0, 1, 0)
  STG3(1, 0, 1)

  for (int kt = 0; kt < nkt; ++kt) {
    const int cb = kt & 1, nb = cb ^ 1;
    asm volatile("s_waitcnt vmcnt(6)" ::: "memory");
    __builtin_amdgcn_s_barrier();
    {
      bf16x8 af[4], bfr[4];
#pragma unroll
      for (int mf = 0; mf < 4; ++mf) af[mf] = RDA(cb, 0, wm * 64 + mf * 16 + l15);
#pragma unroll
      for (int nf = 0; nf < 4; ++nf) bfr[nf] = RDB(cb, 0, wc * 64 + nf * 16 + l15);
      STG3(nb, 1, kt + 1)
      __builtin_amdgcn_s_setprio(1);
#pragma unroll
      for (int mf = 0; mf < 4; ++mf)
#pragma unroll
        for (int nf = 0; nf < 4; ++nf)
          acc[mf][nf] = __builtin_amdgcn_mfma_f32_16x16x32_bf16(af[mf], bfr[nf], acc[mf][nf], 0, 0, 0);
      __builtin_amdgcn_s_setprio(0);
    }
    asm volatile("s_waitcnt vmcnt(6)" ::: "memory");
    __builtin_amdgcn_s_barrier();
    {
      bf16x8 af[4], bfr[4];
#pragma unroll
      for (int mf = 0; mf < 4; ++mf) af[mf] = RDA(cb, 1, wm * 64 + mf * 16 + l15);
#pragma unroll
      for (int nf = 0; nf < 4; ++nf) bfr[nf] = RDB(cb, 1, wc * 64 + nf * 16 + l15);
      STG3(cb, 0, kt + 2)
      __builtin_amdgcn_s_setprio(1);
#pragma unroll
      for (int mf = 0; mf < 4; ++mf)
#pragma unroll
        for (int nf = 0; nf < 4; ++nf)
          acc[mf][nf] = __builtin_amdgcn_mfma_f32_16x16x32_bf16(af[mf], bfr[nf], acc[mf][nf], 0, 0, 0);
      __builtin_amdgcn_s_setprio(0);
    }
  }
#undef STG3
#undef RDA
#undef RDB

#pragma unroll
  for (int mf = 0; mf < 4; ++mf)
#pragma unroll
    for (int nf = 0; nf < 4; ++nf)
#pragma unroll
      for (int j = 0; j < 4; ++j) {
        const size_t row = row0 + wm * 64 + mf * 16 + r4 + j;
        const size_t col = col0 + wc * 64 + nf * 16 + l15;
        if constexpr (sizeof(OutT) == 4)
          C[row * (size_t)N + col] = acc[mf][nf][j];
        else
          C[row * (size_t)N + col] = (OutT)f2b(acc[mf][nf][j]);
      }
}

// ---------------------------------------------------------------------------
// b/a projection (R21-verified): grid 1024 x 4 rows, bf16 x/W, 2 barriers.
// ---------------------------------------------------------------------------
__global__ __launch_bounds__(256)
void k_proj_ba2(const ushort_t* __restrict__ xB, const ushort_t* __restrict__ WbB,
                const ushort_t* __restrict__ WaB, const float* __restrict__ dtb,
                const float* __restrict__ alog,
                float* __restrict__ beta, float* __restrict__ gout) {
  __shared__ alignas(16) ushort_t xs[4][2048];   // 16 KB
  __shared__ float part[32][8][4];               //  4 KB
  const int tid = threadIdx.x;
  const int bt0 = blockIdx.x * 4;
#pragma unroll
  for (int r = 0; r < 4; ++r)
    *(uint4*)&xs[r][tid * 8] =
        *(const uint4*)(const void*)(xB + (size_t)(bt0 + r) * HID_ + tid * 8);
  __syncthreads();
  const int o = tid & 31, seg = tid >> 5;        // 32 outputs x 8 segs(256)
  const ushort_t* W = (o < 16) ? (WbB + (size_t)o * HID_)
                               : (WaB + (size_t)(o - 16) * HID_);
  float acc0 = 0.f, acc1 = 0.f, acc2 = 0.f, acc3 = 0.f;
  for (int j = 0; j < 32; ++j) {
    const int k = seg * 256 + j * 8;
    bf16x8 wv = *(const bf16x8*)(const void*)(W + k);
    bf16x8 x0 = *(const bf16x8*)&xs[0][k];
    bf16x8 x1 = *(const bf16x8*)&xs[1][k];
    bf16x8 x2 = *(const bf16x8*)&xs[2][k];
    bf16x8 x3 = *(const bf16x8*)&xs[3][k];
#pragma unroll
    for (int i = 0; i < 8; ++i) {
      const float w = (float)wv[i];
      acc0 += w * (float)x0[i];
      acc1 += w * (float)x1[i];
      acc2 += w * (float)x2[i];
      acc3 += w * (float)x3[i];
    }
  }
  part[o][seg][0] = acc0; part[o][seg][1] = acc1;
  part[o][seg][2] = acc2; part[o][seg][3] = acc3;
  __syncthreads();
  if (tid < 128) {
    const int r = tid >> 5, oo = tid & 31;
    float t_ = 0.f;
#pragma unroll
    for (int s2 = 0; s2 < 8; ++s2) t_ += part[oo][s2][r];
    const int bt = bt0 + r;
    if (oo < 16) {
      beta[(size_t)bt * NV_ + oo] = 1.f / (1.f + expf(-t_));
    } else {
      const int hh = oo - 16;
      float aa = t_ + dtb[hh];
      float sp = (aa > 20.f) ? aa : log1pf(expf(aa));
      gout[(size_t)bt * NV_ + hh] = -expf(alog[hh]) * sp;
    }
  }
}

// ---------------------------------------------------------------------------
// Fused depthwise causal conv1d (K=4) + silu + l2norm(q,k).
// R23: 4 rows/block, 7 rows loaded once, XCD-chunked swizzle. grid = 1024.
// Per-output math order identical to R14 (bit-identical numerics).
// ---------------------------------------------------------------------------
__global__ __launch_bounds__(256)
void k_conv_silu_norm(const ushort_t* __restrict__ qkv, const float* __restrict__ cw,
                      ushort_t* __restrict__ act) {
  // chunked XCD swizzle: XCD (bid&7) gets the contiguous sb range; bijective.
  const int bid = blockIdx.x;
  const int sb = (bid & 7) * 128 + (bid >> 3);   // 0..1023
  const int bt0 = sb * 4;
  const int tid = threadIdx.x;
  const int t0 = bt0 & (T_ - 1);                 // all 4 rows in same batch
  const int c = tid * 16;
  const ushort_t* base = qkv + (size_t)bt0 * CD_ + c;

  float wf[16][4];
#pragma unroll
  for (int i = 0; i < 16; ++i) {
    float4 w = *(const float4*)&cw[(c + i) * 4];
    wf[i][0] = w.x; wf[i][1] = w.y; wf[i][2] = w.z; wf[i][3] = w.w;
  }

  // load rows t0-3 .. t0+3 (kv[idx] = row t0+idx-3), zero if before batch start
  bf16x8 v0[7], v1[7];
#pragma unroll
  for (int idx = 0; idx < 7; ++idx) {
    if (t0 + idx - 3 >= 0) {
      const ushort_t* src = base + ((ptrdiff_t)idx - 3) * CD_;
      v0[idx] = *(const bf16x8*)(const void*)src;
      v1[idx] = *(const bf16x8*)(const void*)(src + 8);
    } else {
      bf16x8 z = {};
      v0[idx] = z; v1[idx] = z;
    }
  }

  const int seg = tid >> 3;
#pragma unroll
  for (int ot = 0; ot < 4; ++ot) {
    float a[16];
#pragma unroll
    for (int i = 0; i < 16; ++i) a[i] = 0.f;
#pragma unroll
    for (int j = 0; j < 4; ++j) {
      const int ridx = ot + j;   // row t0+ot-3+j
#pragma unroll
      for (int i = 0; i < 8; ++i) {
        a[i]     += (float)v0[ridx][i] * wf[i][j];
        a[8 + i] += (float)v1[ridx][i] * wf[8 + i][j];
      }
    }
#pragma unroll
    for (int i = 0; i < 16; ++i) a[i] = a[i] / (1.f + expf(-a[i]));
    float ss = 0.f;
#pragma unroll
    for (int i = 0; i < 16; ++i) ss += a[i] * a[i];
    ss += __shfl_xor(ss, 1); ss += __shfl_xor(ss, 2); ss += __shfl_xor(ss, 4);
    float scale = 1.f;
    if (seg < 16) {
      scale = 1.f / fmaxf(sqrtf(ss), 1e-12f);
      if (seg < 8) scale *= 0.08838834764831845f;
    }
    ushort_t ov[16];
#pragma unroll
    for (int i = 0; i < 16; ++i) ov[i] = f2b(a[i] * scale);
    ushort_t* dst = act + (size_t)(bt0 + ot) * CD_ + c;
    *(uint4*)(void*)dst       = *(const uint4*)&ov[0];
    *(uint4*)(void*)(dst + 8) = *(const uint4*)&ov[8];
  }
}

// ---------------------------------------------------------------------------
// k_prep: per-chunk parallel precompute. grid = 1024. (R20-exact)
// ---------------------------------------------------------------------------
__global__ __launch_bounds__(256, 1)
void k_prep(const ushort_t* __restrict__ act, const float* __restrict__ gB,
            const float* __restrict__ betaB,
            ushort_t* __restrict__ WkG, ushort_t* __restrict__ UlT,
            ushort_t* __restrict__ KTG, float* __restrict__ gtG) {
  __shared__ __bf16 Kl[64][136];
  __shared__ __bf16 AbL[64][40];
  __shared__ __bf16 AbH[32][33];
  __shared__ __bf16 Xl[64][264];
  __shared__ alignas(16) __bf16 Cr[16][264];
  __shared__ float gc[65], Et[65], Rt[65], bts[64], geT[64];

  const int wg = blockIdx.x;
  const int c = wg & 31, h = (wg >> 5) & 15, b = wg >> 9;
  const int hq = h >> 1, t0 = c * 64;
  const int tid = threadIdx.x, lane = tid & 63, wave = tid >> 6;
  const int l15 = lane & 15, kcol0 = (lane >> 4) * 8, rrow = (lane >> 4) * 4;
  const size_t bhc = (size_t)wg;

  const ushort_t* baseQ = act + (size_t)b * T_ * CD_ + hq * HD_;
  const ushort_t* baseK = baseQ + KD_;

  if (tid < 64) {
    float g = gB[((size_t)b * T_ + t0 + tid) * NV_ + h];
    bts[tid] = betaB[((size_t)b * T_ + t0 + tid) * NV_ + h];
#pragma unroll
    for (int o = 1; o < 64; o <<= 1) {
      float up = __shfl_up(g, (unsigned)o);
      if (tid >= o) g += up;
    }
    gc[tid + 1] = g;
    if (tid == 0) gc[0] = 0.f;
  }
  __syncthreads();
  if (tid < 65) {
    float gm = gc[32];
    Et[tid] = __expf(gc[tid] - gm);
    Rt[tid] = __expf(gm - gc[tid]);
  }
  if (tid < 64) {
    geT[tid] = bts[tid] * __expf(gc[tid + 1]);
    gtG[bhc * 64 + tid] = gc[tid + 1];
  }
  {
    const int t = tid >> 2, d0 = (tid & 3) * 32;
    const ushort_t* src = baseK + (size_t)(t0 + t) * CD_ + d0;
#pragma unroll
    for (int j = 0; j < 4; ++j)
      *(uint4*)&Kl[t][d0 + j * 8] = *(const uint4*)(const void*)(src + j * 8);
  }
  __syncthreads();

  // P1: Ab (strict lower, -beta*scale*KK^T) in LDS
  {
    bf16x8 kf[4];
#pragma unroll
    for (int kk = 0; kk < 4; ++kk)
      kf[kk] = *(const bf16x8*)&Kl[16 * wave + l15][kk * 32 + kcol0];
#pragma unroll
    for (int st = 0; st < 4; ++st) {
      if (st <= wave) {
        f32x4 accA = {};
#pragma unroll
        for (int kk = 0; kk < 4; ++kk) {
          bf16x8 bfr = *(const bf16x8*)&Kl[st * 16 + l15][kk * 32 + kcol0];
          accA = __builtin_amdgcn_mfma_f32_16x16x32_bf16(kf[kk], bfr, accA, 0, 0, 0);
        }
        const int scol = st * 16 + l15;
#pragma unroll
        for (int r = 0; r < 4; ++r) {
          const int t = 16 * wave + rrow + r;
          if (scol < t) {
            const float av = -bts[t] * Et[t + 1] * Rt[scol + 1] * accA[r];
            if (scol < 32) AbL[t][scol] = (__bf16)av;
            else           AbH[t - 32][scol - 32] = (__bf16)av;
          }
        }
      }
    }
  }
  __syncthreads();

  // KT store (raw K^T, shared by the v-head pair; even h only)
  if ((h & 1) == 0) {
    const size_t kto = (((size_t)b * 8 + hq) * 32 + c) * (128 * 64);
    const int d = tid >> 1, t8 = (tid & 1) * 32;
#pragma unroll
    for (int i8 = 0; i8 < 4; ++i8) {
      bf16x8 tmp;
#pragma unroll
      for (int jj = 0; jj < 8; ++jj) tmp[jj] = Kl[t8 + i8 * 8 + jj][d];
      *(bf16x8*)(void*)(KTG + kto + (size_t)d * 64 + t8 + i8 * 8) = tmp;
    }
  }

  // P2: block-16 recursive triangular solve (R19-verified).
  {
    float r1[32], r2[32];
    if (tid < 128) {
      const int d = tid;
#pragma unroll
      for (int t = 0; t < 32; ++t) r1[t] = geT[t] * (float)Kl[t][d];
#pragma unroll
      for (int t = 0; t < 32; ++t) r2[t] = geT[32 + t] * (float)Kl[32 + t][d];
    } else {
      const int j = tid - 128;
      const ushort_t* vsrc = act + ((size_t)b * T_ + t0) * CD_ + 2 * KD_ + h * HD_ + j;
#pragma unroll
      for (int t = 0; t < 32; ++t) r1[t] = bts[t] * b2f(vsrc[(size_t)t * CD_]);
#pragma unroll
      for (int t = 0; t < 32; ++t) r2[t] = bts[32 + t] * b2f(vsrc[(size_t)(32 + t) * CD_]);
    }

    {
      float u[16];
#pragma unroll
      for (int j = 0; j < 16; ++j) {
        float a = r1[j];
#pragma unroll
        for (int i = 0; i < j; ++i) a += (float)AbL[j][i] * u[i];
        u[j] = a;
        Xl[j][tid] = (__bf16)a;
      }
    }
    __syncthreads();

    {
      bf16x8 afr2;
#pragma unroll
      for (int j = 0; j < 8; ++j) {
        const int k = kcol0 + j;
        afr2[j] = (k < 16) ? AbL[16 + l15][k] : (__bf16)0.f;
      }
#pragma unroll
      for (int ct4 = 0; ct4 < 4; ++ct4) {
        const int ct = wave * 4 + ct4;
        bf16x8 bfr2;
#pragma unroll
        for (int j = 0; j < 8; ++j) {
          const int k = kcol0 + j;
          bfr2[j] = (k < 16) ? Xl[k][16 * ct + l15] : (__bf16)0.f;
        }
        f32x4 acc2 = {};
        acc2 = __builtin_amdgcn_mfma_f32_16x16x32_bf16(afr2, bfr2, acc2, 0, 0, 0);
#pragma unroll
        for (int r = 0; r < 4; ++r)
          Cr[rrow + r][16 * ct + l15] = (__bf16)acc2[r];
      }
    }
    __syncthreads();

    {
      float u[16];
#pragma unroll
      for (int j = 0; j < 16; ++j) {
        float a = r1[16 + j] + (float)Cr[j][tid];
#pragma unroll
        for (int i = 0; i < j; ++i) a += (float)AbL[16 + j][16 + i] * u[i];
        u[j] = a;
        Xl[16 + j][tid] = (__bf16)a;
      }
    }
    __syncthreads();

    {
      bf16x8 afr2 = *(const bf16x8*)&AbL[32 + l15][kcol0];
#pragma unroll
      for (int ct4 = 0; ct4 < 4; ++ct4) {
        const int ct = wave * 4 + ct4;
        bf16x8 bfr2;
#pragma unroll
        for (int j = 0; j < 8; ++j) bfr2[j] = Xl[kcol0 + j][16 * ct + l15];
        f32x4 acc2 = {};
        acc2 = __builtin_amdgcn_mfma_f32_16x16x32_bf16(afr2, bfr2, acc2, 0, 0, 0);
#pragma unroll
        for (int r = 0; r < 4; ++r)
          Cr[rrow + r][16 * ct + l15] = (__bf16)acc2[r];
      }
    }
    __syncthreads();

    {
      float u[16];
#pragma unroll
      for (int j = 0; j < 16; ++j) {
        float a = r2[j] + (float)Cr[j][tid];
#pragma unroll
        for (int i = 0; i < j; ++i) a += (float)AbH[j][i] * u[i];
        u[j] = a;
        Xl[32 + j][tid] = (__bf16)a;
      }
    }
    __syncthreads();

    {
      bf16x8 afrA = *(const bf16x8*)&AbL[48 + l15][kcol0];
      bf16x8 afrB;
#pragma unroll
      for (int j = 0; j < 8; ++j) {
        const int k = kcol0 + j;
        afrB[j] = (k < 16) ? AbH[16 + l15][k] : (__bf16)0.f;
      }
#pragma unroll
      for (int ct4 = 0; ct4 < 4; ++ct4) {
        const int ct = wave * 4 + ct4;
        bf16x8 bfrA, bfrB;
#pragma unroll
        for (int j = 0; j < 8; ++j) {
          const int k = kcol0 + j;
          bfrA[j] = Xl[k][16 * ct + l15];
          bfrB[j] = (k < 16) ? Xl[32 + k][16 * ct + l15] : (__bf16)0.f;
        }
        f32x4 acc2 = {};
        acc2 = __builtin_amdgcn_mfma_f32_16x16x32_bf16(afrA, bfrA, acc2, 0, 0, 0);
        acc2 = __builtin_amdgcn_mfma_f32_16x16x32_bf16(afrB, bfrB, acc2, 0, 0, 0);
#pragma unroll
        for (int r = 0; r < 4; ++r)
          Cr[rrow + r][16 * ct + l15] = (__bf16)acc2[r];
      }
    }
    __syncthreads();

    {
      float u[16];
#pragma unroll
      for (int j = 0; j < 16; ++j) {
        float a = r2[16 + j] + (float)Cr[j][tid];
#pragma unroll
        for (int i = 0; i < j; ++i) a += (float)AbH[16 + j][16 + i] * u[i];
        u[j] = a;
        Xl[48 + j][tid] = (__bf16)a;
      }
    }
  }
  __syncthreads();

  // P3: Wk copy (negated, stride 128) + Uloc^T store (stride 64)
#pragma unroll
  for (int kck = 0; kck < 4; ++kck) {
    const int q = tid + kck * 256;
    const int t = q >> 4, d0 = (q & 15) * 8;
    uint4 v = *(const uint4*)&Xl[t][d0];
    v.x ^= 0x80008000u; v.y ^= 0x80008000u; v.z ^= 0x80008000u; v.w ^= 0x80008000u;
    *(uint4*)(void*)(WkG + bhc * (64 * 128) + (size_t)t * 128 + d0) = v;
  }
  {
    const int e = tid >> 1, t8 = (tid & 1) * 32;
#pragma unroll
    for (int i8 = 0; i8 < 4; ++i8) {
      bf16x8 tmp;
#pragma unroll
      for (int jj = 0; jj < 8; ++jj) tmp[jj] = Xl[t8 + i8 * 8 + jj][128 + e];
      *(bf16x8*)(void*)(UlT + bhc * (128 * 64) + (size_t)e * 64 + t8 + i8 * 8) = tmp;
    }
  }
}

// ---------------------------------------------------------------------------
// scan body (R20-verified): u-phase + S-update recomputed from Wk/Ul/KT.
// ---------------------------------------------------------------------------
__device__ __forceinline__ void scan_body(
    const ushort_t* __restrict__ WkG, const ushort_t* __restrict__ UlT,
    const ushort_t* __restrict__ KTG, const float* __restrict__ gtG,
    ushort_t* __restrict__ ScG, int sb, char* smem) {
  const int eh = sb & 1, wg = sb >> 1;
  const int h = wg & 15, b = wg >> 4, hq = h >> 1;
  const int e0 = eh * 64;
  const int tid = threadIdx.x, lane = tid & 63, wave = tid >> 6;
  const int l15 = lane & 15, kcol0 = (lane >> 4) * 8, rrow = (lane >> 4) * 4;
  const int et = wave & 3, dh = wave >> 2;
  const int ue = wave >> 1, ut0 = (wave & 1) * 2;

  char* WkS = smem;
  char* KTS = smem + 32768;
  char* UlS = smem + 65536;
  __bf16 (*S16)[136] = (__bf16(*)[136])(smem + 81920);
  __bf16 (*uS)[72]   = (__bf16(*)[72])(smem + 99328);
  float* escS = (float*)(smem + 108544);

#define SSTAGE(BUF, CN) {                                                     \
    const int cn_ = ((CN) < 32) ? (CN) : 31;                                  \
    const ushort_t* WkR_ = WkG + ((size_t)wg * 32 + cn_) * (64 * 128);        \
    const ushort_t* KTR_ = KTG + (((size_t)b * 8 + hq) * 32 + cn_) * (128 * 64); \
    const ushort_t* UlR_ = UlT + ((size_t)wg * 32 + cn_) * (128 * 64)         \
                               + (size_t)e0 * 64;                             \
    _Pragma("unroll") for (int r_ = 0; r_ < 2; ++r_) {                        \
      const int idx_ = r_ * 512 + tid;                                        \
      const int d_ = idx_ >> 4, sl_ = idx_ & 15;                              \
      const ushort_t* src_ = WkR_ + (size_t)d_ * 128 + ((sl_ ^ (d_ & 7)) << 3); \
      __builtin_amdgcn_global_load_lds(                                       \
          (const __attribute__((address_space(1))) unsigned int*)src_,        \
          (__attribute__((address_space(3))) unsigned int*)                   \
              (WkS + (BUF) * 16384 + r_ * 8192 + wave * 1024), 16, 0, 0);     \
    }                                                                         \
    _Pragma("unroll") for (int r_ = 0; r_ < 2; ++r_) {                        \
      const int idx_ = r_ * 512 + tid;                                        \
      const int d_ = idx_ >> 3, sl_ = idx_ & 7;                               \
      const ushort_t* src_ = KTR_ + (size_t)d_ * 64 + ((sl_ ^ (d_ & 7)) << 3); \
      __builtin_amdgcn_global_load_lds(                                       \
          (const __attribute__((address_space(1))) unsigned int*)src_,        \
          (__attribute__((address_space(3))) unsigned int*)                   \
              (KTS + (BUF) * 16384 + r_ * 8192 + wave * 1024), 16, 0, 0);     \
    }                                                                         \
    {                                                                         \
      const int e_ = tid >> 3, sl_ = tid & 7;                                 \
      const ushort_t* src_ = UlR_ + (size_t)e_ * 64 + ((sl_ ^ (e_ & 7)) << 3); \
      __builtin_amdgcn_global_load_lds(                                       \
          (const __attribute__((address_space(1))) unsigned int*)src_,        \
          (__attribute__((address_space(3))) unsigned int*)                   \
              (UlS + (BUF) * 8192 + wave * 1024), 16, 0, 0);                  \
    }                                                                         \
  }

#define WRD(BUF, ROW, KC)                                                     \
  (*(const bf16x8*)(WkS + (BUF) * 16384 + ((ROW) << 8) +                      \
                    (((KC) << 1) ^ (((ROW) & 7) << 4))))
#define KRD(BUF, ROW, KC)                                                     \
  (*(const bf16x8*)(KTS + (BUF) * 16384 + ((ROW) << 7) +                      \
                    (((KC) << 1) ^ (((ROW) & 7) << 4))))
#define ULS(BUF, E, T)                                                        \
  (*(const ushort_t*)(UlS + (BUF) * 8192 + ((E) << 7) +                       \
                      (((((T) >> 3) << 4)) ^ (((E) & 7) << 4)) + ((T) & 7) * 2))

  f32x4 s_acc[4] = {};
  SSTAGE(0, 0)

  for (int c = 0; c < 32; ++c) {
    const int buf = c & 1;
    ushort_t* ScR = ScG + ((size_t)wg * 32 + c) * CHM_;
    const float* gtR = gtG + ((size_t)wg * 32 + c) * 64;

    __syncthreads();
    SSTAGE(buf ^ 1, c + 1)

    const float g63 = gtR[63];
    if (tid < 64) escS[tid] = __expf(g63 - gtR[tid]);
    const float gCe = __expf(g63);

#pragma unroll
    for (int dl = 0; dl < 4; ++dl)
#pragma unroll
      for (int r = 0; r < 4; ++r)
        S16[16 * et + rrow + r][(4 * dh + dl) * 16 + l15] = (__bf16)s_acc[dl][r];
    asm volatile("s_waitcnt lgkmcnt(0)" ::: "memory");
    __builtin_amdgcn_sched_barrier(0);
    __builtin_amdgcn_s_barrier();
    __builtin_amdgcn_sched_barrier(0);

#pragma unroll
    for (int cc = 0; cc < 2; ++cc) {
      const int idx = tid + cc * 512;
      const int row = idx >> 4, seg = idx & 15;
      *(uint4*)(void*)(ScR + (size_t)(e0 + row) * 128 + seg * 8) =
          *(const uint4*)&S16[row][seg * 8];
    }

#pragma unroll
    for (int t2 = 0; t2 < 2; ++t2) {
      const int tt = ut0 + t2;
      f32x4 a = {};
#pragma unroll
      for (int r = 0; r < 4; ++r)
        a[r] = b2f(ULS(buf, 16 * ue + rrow + r, 16 * tt + l15));
#pragma unroll
      for (int kk = 0; kk < 4; ++kk) {
        bf16x8 af = *(const bf16x8*)&S16[16 * ue + l15][kk * 32 + kcol0];
        bf16x8 bw = WRD(buf, 16 * tt + l15, kk * 32 + kcol0);
        a = __builtin_amdgcn_mfma_f32_16x16x32_bf16(af, bw, a, 0, 0, 0);
      }
      const float es = escS[16 * tt + l15];
#pragma unroll
      for (int r = 0; r < 4; ++r)
        uS[16 * ue + rrow + r][16 * tt + l15] = (__bf16)(a[r] * es);
    }
    asm volatile("s_waitcnt lgkmcnt(0)" ::: "memory");
    __builtin_amdgcn_sched_barrier(0);
    __builtin_amdgcn_s_barrier();
    __builtin_amdgcn_sched_barrier(0);

#pragma unroll
    for (int dl = 0; dl < 4; ++dl)
#pragma unroll
      for (int r = 0; r < 4; ++r) s_acc[dl][r] *= gCe;
#pragma unroll
    for (int ks = 0; ks < 2; ++ks) {
      bf16x8 ua = *(const bf16x8*)&uS[16 * et + l15][ks * 32 + kcol0];
#pragma unroll
      for (int dl = 0; dl < 4; ++dl) {
        bf16x8 kb = KRD(buf, 16 * (4 * dh + dl) + l15, ks * 32 + kcol0);
        s_acc[dl] = __builtin_amdgcn_mfma_f32_16x16x32_bf16(ua, kb, s_acc[dl], 0, 0, 0);
      }
    }
  }
#undef SSTAGE
#undef WRD
#undef KRD
#undef ULS
}

// ---------------------------------------------------------------------------
// FUSED launch: blocks 0..63 = scan, 64..191 = z-gemm tiles (independent).
// ---------------------------------------------------------------------------
__global__ __launch_bounds__(512, 2)
void k_scan_zgemm(const ushort_t* __restrict__ WkG, const ushort_t* __restrict__ UlT,
                  const ushort_t* __restrict__ KTG, const float* __restrict__ gtG,
                  ushort_t* __restrict__ ScG,
                  const ushort_t* __restrict__ xB, const ushort_t* __restrict__ WzB,
                  ushort_t* __restrict__ zbuf) {
  __shared__ alignas(16) char smem[131072];
  if (blockIdx.x < 64)
    scan_body(WkG, UlT, KTG, gtG, ScG, blockIdx.x, smem);
  else
    gemm256_body<ushort_t>(xB, WzB, zbuf, B_ * T_, VD_, HID_,
                           blockIdx.x - 64, (ushort_t*)smem);
}

// ---------------------------------------------------------------------------
// k_out (R19-exact): u = Ul + Wkneg@S_c; Pm recomputed; o = gam*Q@S_c + Pm@u;
// fused gated RMSNorm -> bf16 outg. grid=1024.
// ---------------------------------------------------------------------------
__global__ __launch_bounds__(256, 2)
void k_out(const ushort_t* __restrict__ act,
           const ushort_t* __restrict__ WkG, const ushort_t* __restrict__ UlT,
           const float* __restrict__ gtG,
           const ushort_t* __restrict__ ScG, const ushort_t* __restrict__ zbuf,
           const float* __restrict__ nw, ushort_t* __restrict__ outg) {
  __shared__ __bf16 S16[128][136];
  __shared__ __bf16 uTl[128][72];
  __shared__ __bf16 PmL[64][72];
  __shared__ float Egc[65], Rgc[65], gam[64], nws[128];

  const int bhc = blockIdx.x;
  const int c = bhc & 31, h = (bhc >> 5) & 15, b = bhc >> 9;
  const int hq = h >> 1, t0g = c * 64;
  const int tid = threadIdx.x, lane = tid & 63, wave = tid >> 6;
  const int l15 = lane & 15, kcol0 = (lane >> 4) * 8, rrow = (lane >> 4) * 4;

  const ushort_t* ScR = ScG + (size_t)bhc * CHM_;
  const ushort_t* WkR = WkG + (size_t)bhc * (64 * 128);
  const ushort_t* UlR = UlT + (size_t)bhc * (128 * 64);
  const ushort_t* actQ = act + ((size_t)b * T_ + t0g) * CD_ + hq * HD_;
  const ushort_t* actK = actQ + KD_;

#pragma unroll
  for (int cc = 0; cc < 8; ++cc) {
    const int idx = tid + cc * 256;
    const int row = idx >> 4, seg = idx & 15;
    *(uint4*)&S16[row][seg * 8] =
        *(const uint4*)(const void*)(ScR + (size_t)row * 128 + seg * 8);
  }
  {
    const float gc32 = gtG[(size_t)bhc * 64 + 31];
    if (tid < 65) {
      const float gcv = (tid == 0) ? 0.f : gtG[(size_t)bhc * 64 + tid - 1];
      Egc[tid] = __expf(gcv - gc32);
      Rgc[tid] = __expf(gc32 - gcv);
    }
    if (tid < 64) gam[tid] = __expf(gtG[(size_t)bhc * 64 + tid]);
    if (tid < 128) nws[tid] = nw[tid];
  }
  __syncthreads();

  bf16x8 qf[4];
#pragma unroll
  for (int kk = 0; kk < 4; ++kk)
    qf[kk] = *(const bf16x8*)(const void*)
        (actQ + (size_t)(16 * wave + l15) * CD_ + kk * 32 + kcol0);

  bf16x8 wa[4];
#pragma unroll
  for (int kk = 0; kk < 4; ++kk)
    wa[kk] = *(const bf16x8*)(const void*)(WkR + (size_t)(16 * wave + l15) * 128 + kk * 32 + kcol0);
  f32x4 au[8] = {};
#pragma unroll
  for (int kk = 0; kk < 4; ++kk)
#pragma unroll
    for (int jt = 0; jt < 8; ++jt) {
      bf16x8 sb = *(const bf16x8*)&S16[jt * 16 + l15][kk * 32 + kcol0];
      au[jt] = __builtin_amdgcn_mfma_f32_16x16x32_bf16(wa[kk], sb, au[jt], 0, 0, 0);
    }
#pragma unroll
  for (int jt = 0; jt < 8; ++jt) {
    short4v uv = *(const short4v*)(const void*)(UlR + (size_t)(16 * jt + l15) * 64 + wave * 16 + rrow);
#pragma unroll
    for (int r = 0; r < 4; ++r)
      uTl[16 * jt + l15][16 * wave + rrow + r] = (__bf16)(au[jt][r] + b2f((ushort_t)uv[r]));
  }

#pragma unroll
  for (int st = 0; st < 4; ++st) {
    f32x4 accP = {};
#pragma unroll
    for (int kk = 0; kk < 4; ++kk) {
      bf16x8 kb = *(const bf16x8*)(const void*)
          (actK + (size_t)(st * 16 + l15) * CD_ + kk * 32 + kcol0);
      accP = __builtin_amdgcn_mfma_f32_16x16x32_bf16(qf[kk], kb, accP, 0, 0, 0);
    }
    const int scol = st * 16 + l15;
#pragma unroll
    for (int r = 0; r < 4; ++r) {
      const int t = 16 * wave + rrow + r;
      PmL[t][scol] = (scol <= t) ? (__bf16)(Egc[t + 1] * Rgc[scol + 1] * accP[r])
                                 : (__bf16)0.f;
    }
  }
  __syncthreads();

  f32x4 qs[8] = {}, o2[8] = {};
#pragma unroll
  for (int kk = 0; kk < 4; ++kk)
#pragma unroll
    for (int jt = 0; jt < 8; ++jt) {
      bf16x8 sb = *(const bf16x8*)&S16[jt * 16 + l15][kk * 32 + kcol0];
      qs[jt] = __builtin_amdgcn_mfma_f32_16x16x32_bf16(qf[kk], sb, qs[jt], 0, 0, 0);
    }
#pragma unroll
  for (int ks = 0; ks < 2; ++ks) {
    bf16x8 pa = *(const bf16x8*)&PmL[16 * wave + l15][ks * 32 + kcol0];
#pragma unroll
    for (int jt = 0; jt < 8; ++jt) {
      bf16x8 ub = *(const bf16x8*)&uTl[jt * 16 + l15][ks * 32 + kcol0];
      o2[jt] = __builtin_amdgcn_mfma_f32_16x16x32_bf16(pa, ub, o2[jt], 0, 0, 0);
    }
  }
  float ov[8][4];
  float ss0 = 0.f, ss1 = 0.f, ss2 = 0.f, ss3 = 0.f;
#pragma unroll
  for (int jt = 0; jt < 8; ++jt) {
    ov[jt][0] = gam[16 * wave + rrow + 0] * qs[jt][0] + o2[jt][0];
    ov[jt][1] = gam[16 * wave + rrow + 1] * qs[jt][1] + o2[jt][1];
    ov[jt][2] = gam[16 * wave + rrow + 2] * qs[jt][2] + o2[jt][2];
    ov[jt][3] = gam[16 * wave + rrow + 3] * qs[jt][3] + o2[jt][3];
    ss0 += ov[jt][0] * ov[jt][0];
    ss1 += ov[jt][1] * ov[jt][1];
    ss2 += ov[jt][2] * ov[jt][2];
    ss3 += ov[jt][3] * ov[jt][3];
  }
#pragma unroll
  for (int m = 1; m < 16; m <<= 1) {
    ss0 += __shfl_xor(ss0, m);
    ss1 += __shfl_xor(ss1, m);
    ss2 += __shfl_xor(ss2, m);
    ss3 += __shfl_xor(ss3, m);
  }
  float rr[4];
  rr[0] = 1.f / sqrtf(ss0 * (1.f / HD_) + 1e-6f);
  rr[1] = 1.f / sqrtf(ss1 * (1.f / HD_) + 1e-6f);
  rr[2] = 1.f / sqrtf(ss2 * (1.f / HD_) + 1e-6f);
  rr[3] = 1.f / sqrtf(ss3 * (1.f / HD_) + 1e-6f);
#pragma unroll
  for (int jt = 0; jt < 8; ++jt) {
    const int e = 16 * jt + l15;
    const float wv = nws[e];
#pragma unroll
    for (int r = 0; r < 4; ++r) {
      const int t = 16 * wave + rrow + r;
      const float zf = b2f(zbuf[((size_t)b * T_ + t0g + t) * VD_ + h * HD_ + e]);
      const float g = zf / (1.f + expf(-zf));
      outg[(((size_t)b * T_ + t0g + t) * NV_ + h) * HD_ + e] =
          f2b(ov[jt][r] * rr[r] * wv * g);
    }
  }
}

// ---------------------------------------------------------------------------
extern "C" void kernel_launch(void* const* d_in, const int* in_sizes, int n_in,
                              void* d_out, int out_size, void* d_ws, size_t ws_size,
                              hipStream_t stream) {
  const float* x    = (const float*)d_in[0];
  const float* Wqkv = (const float*)d_in[1];
  const float* Wz   = (const float*)d_in[2];
  const float* Wb   = (const float*)d_in[3];
  const float* Wa   = (const float*)d_in[4];
  const float* cw   = (const float*)d_in[5];
  const float* dtb  = (const float*)d_in[6];
  const float* alog = (const float*)d_in[7];
  const float* nw   = (const float*)d_in[8];
  const float* Wout = (const float*)d_in[9];

  // ---- workspace layout: ~177 MB total ----
  char* p = (char*)d_ws;
  ushort_t* qkv_raw = (ushort_t*)p; p += (size_t)B_ * T_ * CD_ * 2;       // 33.55 MB
  ushort_t* zbuf    = (ushort_t*)p; p += (size_t)B_ * T_ * VD_ * 2;       // 16.78 MB
  ushort_t* act     = (ushort_t*)p; p += (size_t)B_ * T_ * CD_ * 2;       // 33.55 MB
  float*    betaB   = (float*)p;    p += (size_t)B_ * T_ * NV_ * 4;       //  0.26 MB
  float*    gBuf    = (float*)p;    p += (size_t)B_ * T_ * NV_ * 4;       //  0.26 MB
  float*    gtG     = (float*)p;    p += (size_t)1024 * 64 * 4;           //  0.26 MB
  ushort_t* xB      = (ushort_t*)p; p += (size_t)B_ * T_ * HID_ * 2;      // 16.78 MB
  ushort_t* WzB     = (ushort_t*)p; p += (size_t)VD_ * HID_ * 2;          //  8.39 MB
  ushort_t* WoutB   = (ushort_t*)p; p += (size_t)HID_ * VD_ * 2;          //  8.39 MB
  ushort_t* outg    = (ushort_t*)p; p += (size_t)B_ * T_ * VD_ * 2;       // 16.78 MB
  ushort_t* ScG     = (ushort_t*)p; p += (size_t)1024 * CHM_ * 2;         // 33.55 MB
  ushort_t* KTG     = (ushort_t*)p; p += (size_t)512 * 128 * 64 * 2;      //  8.39 MB
  ushort_t* WbB     = (ushort_t*)p; p += (size_t)NV_ * HID_ * 2;          //  0.065 MB
  ushort_t* WaB     = (ushort_t*)p; p += (size_t)NV_ * HID_ * 2;          //  0.065 MB
  // overlays (qkv_raw dead after conv):
  ushort_t* WkG   = qkv_raw;
  ushort_t* UlT   = qkv_raw + (size_t)1024 * 64 * 128;
  ushort_t* WqkvB = act;

  const int M = B_ * T_;  // 4096

  const int n0 = M * HID_ / 4, n1 = CD_ * HID_ / 4;
  const int n2 = VD_ * HID_ / 4, n3 = HID_ * VD_ / 4;
  const int n4 = NV_ * HID_ / 4, n5 = NV_ * HID_ / 4;
  hipLaunchKernelGGL(k_cast6, dim3((n0 + n1 + n2 + n3 + n4 + n5 + 255) / 256), dim3(256), 0, stream,
                     x, xB, n0, Wqkv, WqkvB, n1, Wz, WzB, n2,
                     Wout, WoutB, n3, Wb, WbB, n4, Wa, WaB, n5);

  hipLaunchKernelGGL(k_gemm256<ushort_t>, dim3((M / 256) * (CD_ / 256)), dim3(512), 0, stream,
                     xB, WqkvB, qkv_raw, M, CD_, HID_);
  hipLaunchKernelGGL(k_proj_ba2, dim3(M / 4), dim3(256), 0, stream,
                     xB, WbB, WaB, dtb, alog, betaB, gBuf);
  hipLaunchKernelGGL(k_conv_silu_norm, dim3(M / 4), dim3(256), 0, stream,
                     qkv_raw, cw, act);
  hipLaunchKernelGGL(k_prep, dim3(B_ * NV_ * 32), dim3(256), 0, stream,
                     act, gBuf, betaB, WkG, UlT, KTG, gtG);
  hipLaunchKernelGGL(k_scan_zgemm, dim3(64 + (M / 256) * (VD_ / 256)), dim3(512), 0, stream,
                     WkG, UlT, KTG, gtG, ScG, xB, WzB, zbuf);
  hipLaunchKernelGGL(k_out, dim3(B_ * NV_ * 32), dim3(256), 0, stream,
                     act, WkG, UlT, gtG, ScG, zbuf, nw, outg);
  hipLaunchKernelGGL(k_gemm256x128<float>, dim3((M / 256) * (HID_ / 128)), dim3(512), 0, stream,
                     outg, WoutB, (float*)d_out, M, HID_, VD_);
}